// Round 1
// baseline (4830.289 us; speedup 1.0000x reference)
//
#include <hip/hip_runtime.h>
#include <hip/hip_bf16.h>

constexpr int Nn = 20000;
constexpr int Ee = 320000;
constexpr int Dd = 256;
constexpr int Bb = 16;
constexpr float EPSc = 1e-5f;

// ------------------------------------------------------------------ graph prep
__global__ void hist_edges_k(const int* __restrict__ src, const int* __restrict__ dst,
                             int* __restrict__ cin, int* __restrict__ cout) {
  int e = blockIdx.x * 256 + threadIdx.x;
  if (e < Ee) { atomicAdd(&cin[dst[e]], 1); atomicAdd(&cout[src[e]], 1); }
}

__global__ void hist_batch_k(const int* __restrict__ batch, float* __restrict__ cntf) {
  int v = blockIdx.x * 256 + threadIdx.x;
  if (v < Nn) atomicAdd(&cntf[batch[v]], 1.0f);
}

__global__ __launch_bounds__(1024) void scan_k(const int* __restrict__ cin,
                                               const int* __restrict__ cout,
                                               int* __restrict__ off_in, int* __restrict__ off_out,
                                               int* __restrict__ cur_in, int* __restrict__ cur_out) {
  __shared__ int part[1024];
  const int tid = threadIdx.x;
  for (int which = 0; which < 2; ++which) {
    const int* cnt = which ? cout : cin;
    int* off = which ? off_out : off_in;
    int* curp = which ? cur_out : cur_in;
    int vals[20];
    int base = tid * 20;
    int local = 0;
#pragma unroll
    for (int i = 0; i < 20; ++i) {
      int idx = base + i;
      int v = (idx < Nn) ? cnt[idx] : 0;
      vals[i] = v; local += v;
    }
    part[tid] = local;
    __syncthreads();
    for (int ofs = 1; ofs < 1024; ofs <<= 1) {
      int t = (tid >= ofs) ? part[tid - ofs] : 0;
      __syncthreads();
      part[tid] += t;
      __syncthreads();
    }
    int run = part[tid] - local;  // exclusive prefix
#pragma unroll
    for (int i = 0; i < 20; ++i) {
      int idx = base + i;
      if (idx < Nn) { off[idx] = run; curp[idx] = run; run += vals[i]; }
    }
    if (tid == 0) off[Nn] = Ee;
    __syncthreads();
  }
}

__global__ void scatter_k(const int* __restrict__ src, const int* __restrict__ dst,
                          int* __restrict__ cur_in, int* __restrict__ cur_out,
                          int* __restrict__ in_src, int* __restrict__ in_eid,
                          int* __restrict__ out_dst, int* __restrict__ out_eid) {
  int e = blockIdx.x * 256 + threadIdx.x;
  if (e < Ee) {
    int d = dst[e], s = src[e];
    int p = atomicAdd(&cur_in[d], 1);  in_src[p] = s;  in_eid[p] = e;
    int q = atomicAdd(&cur_out[s], 1); out_dst[q] = d; out_eid[q] = e;
  }
}

__global__ void prep_bsum_k(const float* __restrict__ bs, const float* __restrict__ bin,
                            const float* __restrict__ bout, float* __restrict__ bsum) {
  int t = threadIdx.x;
  for (int l = 0; l < 3; ++l) bsum[l * 256 + t] = bs[l * 256 + t] + bin[l * 256 + t] + bout[l * 256 + t];
}

__global__ void copy_x_k(const float* __restrict__ x, float* __restrict__ dstp, int dup) {
  const int n4 = Nn * Dd / 4;
  int i = blockIdx.x * 256 + threadIdx.x;
  if (i < n4) {
    float4 v = ((const float4*)x)[i];
    ((float4*)dstp)[i] = v;
    if (dup) ((float4*)dstp)[i + n4] = v;
  }
}

// ------------------------------------------------------------------ aggregation
// G[base+v][:] = sum over CSR bucket of m * h[base+nbr][:]
__global__ __launch_bounds__(256) void agg_k(const float* __restrict__ h, float* __restrict__ G,
                                             const int* __restrict__ offs, const int* __restrict__ nbr,
                                             const int* __restrict__ eid, const float* __restrict__ mask,
                                             int batched) {
  int blk = blockIdx.x;
  int half = 0, v = blk;
  if (batched) { half = (blk >= Nn) ? 1 : 0; v = blk - half * Nn; }
  const size_t base = (size_t)half * Nn;
  const int tid = threadIdx.x;
  const int s = offs[v], e = offs[v + 1];
  float acc = 0.0f;
  for (int i = s; i < e; ++i) {
    int u = nbr[i];
    float m = 1.0f;
    if (mask) { float mv = mask[eid[i]]; m = half ? (1.0f - mv) : mv; }
    acc += m * h[(base + u) * Dd + tid];
  }
  G[(base + v) * Dd + tid] = acc;
}

// ------------------------------------------------------------------ GEMM  C[M x 256] (+)= A[M x 256] @ W[256 x 256]^T
// MODE 0: C = bias + A@W^T ; MODE 1: C += A@W^T ; MODE 2: C += A@W^T then relu+BN
template <int MODE>
__global__ __launch_bounds__(256) void gemm256_k(const float* __restrict__ A, const float* __restrict__ W,
                                                 float* __restrict__ C, int M,
                                                 const float* __restrict__ bias, const float* __restrict__ gma,
                                                 const float* __restrict__ bta, const float* __restrict__ rmn,
                                                 const float* __restrict__ rvr) {
  __shared__ float As[16][68];
  __shared__ float Bs[16][68];
  const int tid = threadIdx.x;
  const int row0 = blockIdx.x * 64;
  const int col0 = blockIdx.y * 64;
  const int tx = tid & 15, ty = tid >> 4;
  const int lr = tid >> 2;
  const int lk = (tid & 3) << 2;
  float acc[4][4] = {};
  for (int kt = 0; kt < 256; kt += 16) {
    int ar = row0 + lr;
    float4 a = make_float4(0.f, 0.f, 0.f, 0.f);
    if (ar < M) a = *(const float4*)(A + (size_t)ar * 256 + kt + lk);
    float4 w = *(const float4*)(W + (size_t)(col0 + lr) * 256 + kt + lk);
    As[lk + 0][lr] = a.x; As[lk + 1][lr] = a.y; As[lk + 2][lr] = a.z; As[lk + 3][lr] = a.w;
    Bs[lk + 0][lr] = w.x; Bs[lk + 1][lr] = w.y; Bs[lk + 2][lr] = w.z; Bs[lk + 3][lr] = w.w;
    __syncthreads();
#pragma unroll
    for (int kk = 0; kk < 16; ++kk) {
      const float4 av = *(const float4*)&As[kk][ty << 2];
      const float4 bv = *(const float4*)&Bs[kk][tx << 2];
      acc[0][0] += av.x * bv.x; acc[0][1] += av.x * bv.y; acc[0][2] += av.x * bv.z; acc[0][3] += av.x * bv.w;
      acc[1][0] += av.y * bv.x; acc[1][1] += av.y * bv.y; acc[1][2] += av.y * bv.z; acc[1][3] += av.y * bv.w;
      acc[2][0] += av.z * bv.x; acc[2][1] += av.z * bv.y; acc[2][2] += av.z * bv.z; acc[2][3] += av.z * bv.w;
      acc[3][0] += av.w * bv.x; acc[3][1] += av.w * bv.y; acc[3][2] += av.w * bv.z; acc[3][3] += av.w * bv.w;
    }
    __syncthreads();
  }
#pragma unroll
  for (int i = 0; i < 4; ++i) {
    int r = row0 + (ty << 2) + i;
    if (r >= M) continue;
    float* Cp = C + (size_t)r * 256 + col0 + (tx << 2);
    float v0 = acc[i][0], v1 = acc[i][1], v2 = acc[i][2], v3 = acc[i][3];
    const int c0 = col0 + (tx << 2);
    if (MODE == 0) {
      v0 += bias[c0 + 0]; v1 += bias[c0 + 1]; v2 += bias[c0 + 2]; v3 += bias[c0 + 3];
    } else {
      float4 co = *(const float4*)Cp;
      v0 += co.x; v1 += co.y; v2 += co.z; v3 += co.w;
      if (MODE == 2) {
        float t[4] = {v0, v1, v2, v3};
#pragma unroll
        for (int j = 0; j < 4; ++j) {
          int cc = c0 + j;
          float vv = fmaxf(t[j], 0.0f);
          t[j] = (vv - rmn[cc]) * rsqrtf(rvr[cc] + EPSc) * gma[cc] + bta[cc];
        }
        v0 = t[0]; v1 = t[1]; v2 = t[2]; v3 = t[3];
      }
    }
    *(float4*)Cp = make_float4(v0, v1, v2, v3);
  }
}

// ------------------------------------------------------------------ fused edge MLP -> mask
__global__ __launch_bounds__(256) void edge_mlp_k(const float* __restrict__ emb,
                                                  const int* __restrict__ src, const int* __restrict__ dst,
                                                  const float* __restrict__ W1, const float* __restrict__ b1,
                                                  const float* __restrict__ W2, const float* __restrict__ b2,
                                                  const float* __restrict__ w3, const float* __restrict__ b3,
                                                  float* __restrict__ maskOut) {
  __shared__ int s_src[64], s_dst[64];
  __shared__ float zc[64][36];    // 32-wide k chunk of z, pad 36
  __shared__ float wc[128][36];   // W1 chunk
  __shared__ float h1s[64][129];  // layer1 out (pad 129: conflict-free scalar reads)
  __shared__ float h2s[64][65];   // layer2 out
  __shared__ float red[4][64];
  const int tid = threadIdx.x;
  const int e0 = blockIdx.x * 64;
  if (tid < 64) { s_src[tid] = src[e0 + tid]; s_dst[tid] = dst[e0 + tid]; }
  __syncthreads();

  // ---- layer 1: h1[64 e][128 o], k = 512 (src 0..255, dst 256..511)
  const int og = tid & 31;  // outputs og + 32*j
  const int eg = tid >> 5;  // edges eg*8 + i
  float acc[8][4] = {};
  const int r = tid >> 3;
  const int c4 = (tid & 7) << 2;
  for (int c = 0; c < 16; ++c) {  // 16 chunks of 32 k
#pragma unroll
    for (int p = 0; p < 2; ++p) {
      int row = p * 32 + r;
      int node = (c < 8) ? s_src[row] : s_dst[row];
      int col = (c & 7) * 32 + c4;
      *(float4*)&zc[row][c4] = *(const float4*)(emb + (size_t)node * 256 + col);
    }
#pragma unroll
    for (int p = 0; p < 4; ++p) {
      int row = p * 32 + r;
      *(float4*)&wc[row][c4] = *(const float4*)(W1 + (size_t)row * 512 + c * 32 + c4);
    }
    __syncthreads();
#pragma unroll
    for (int k4 = 0; k4 < 8; ++k4) {
      float4 w[4];
#pragma unroll
      for (int j = 0; j < 4; ++j) w[j] = *(const float4*)&wc[og + 32 * j][k4 << 2];
#pragma unroll
      for (int i = 0; i < 8; ++i) {
        float4 z = *(const float4*)&zc[eg * 8 + i][k4 << 2];
#pragma unroll
        for (int j = 0; j < 4; ++j)
          acc[i][j] += z.x * w[j].x + z.y * w[j].y + z.z * w[j].z + z.w * w[j].w;
      }
    }
    __syncthreads();
  }
#pragma unroll
  for (int j = 0; j < 4; ++j) {
    float bj = b1[og + 32 * j];
#pragma unroll
    for (int i = 0; i < 8; ++i)
      h1s[eg * 8 + i][og + 32 * j] = fmaxf(acc[i][j] + bj, 0.0f);
  }
  __syncthreads();

  // ---- layer 2: h2[64 e][64 o]
  {
    const int e = tid & 63, oj = tid >> 6;
    float a2[16] = {};
    for (int k4 = 0; k4 < 32; ++k4) {
      float hv0 = h1s[e][k4 * 4 + 0], hv1 = h1s[e][k4 * 4 + 1];
      float hv2 = h1s[e][k4 * 4 + 2], hv3 = h1s[e][k4 * 4 + 3];
#pragma unroll
      for (int j = 0; j < 16; ++j) {
        float4 w = *(const float4*)(W2 + (size_t)(oj * 16 + j) * 128 + (k4 << 2));
        a2[j] += hv0 * w.x + hv1 * w.y + hv2 * w.z + hv3 * w.w;
      }
    }
#pragma unroll
    for (int j = 0; j < 16; ++j) h2s[e][oj * 16 + j] = fmaxf(a2[j] + b2[oj * 16 + j], 0.0f);
  }
  __syncthreads();

  // ---- layer 3 + sigmoid
  {
    const int e = tid & 63, oj = tid >> 6;
    float p = 0.0f;
#pragma unroll
    for (int j = 0; j < 16; ++j) { int k = oj * 16 + j; p += h2s[e][k] * w3[k]; }
    red[oj][e] = p;
    __syncthreads();
    if (tid < 64) {
      float sum = red[0][tid] + red[1][tid] + red[2][tid] + red[3][tid] + b3[0];
      maskOut[e0 + tid] = 1.0f / (1.0f + expf(-sum));
    }
  }
}

// ------------------------------------------------------------------ pooling / tails
__global__ __launch_bounds__(256) void gemb_sum_k(const float* __restrict__ h, const int* __restrict__ batch,
                                                  float* __restrict__ gsum, int batched) {
  const int halfBlocks = Nn / 16;
  int blk = blockIdx.x;
  int half = 0, bi = blk;
  if (batched) { half = (blk >= halfBlocks) ? 1 : 0; bi = blk - half * halfBlocks; }
  const int v0 = bi * 16;
  const int tid = threadIdx.x;
  const size_t base = (size_t)half * Nn;
  float* out = gsum + (size_t)half * (Bb * Dd);
  float acc = 0.0f;
  int curb = batch[v0];
  for (int i = 0; i < 16; ++i) {
    int v = v0 + i;
    int b = batch[v];
    if (b != curb) { atomicAdd(&out[curb * Dd + tid], acc); acc = 0.0f; curb = b; }
    acc += h[(base + v) * Dd + tid];
  }
  atomicAdd(&out[curb * Dd + tid], acc);
}

__global__ void gemb_scale_k(float* __restrict__ g, const float* __restrict__ cntf) {
  int blk = blockIdx.x;  // sets*16 blocks
  int b = blk & 15;
  g[blk * Dd + threadIdx.x] /= fmaxf(cntf[b], 1.0f);
}

__global__ void anchor_k(const float* __restrict__ g, const float* __restrict__ anchors,
                         float* __restrict__ s_out) {
  __shared__ float red4[4];
  const int b = blockIdx.x, tid = threadIdx.x;
  float gv = g[b * Dd + tid];
  float total = 0.0f;
  for (int k = 0; k < 6; ++k) {
    float d = gv - anchors[k * Dd + tid];
    float v = d * d;
    for (int o = 32; o > 0; o >>= 1) v += __shfl_xor(v, o);
    if ((tid & 63) == 0) red4[tid >> 6] = v;
    __syncthreads();
    if (tid == 0) total += sqrtf(red4[0] + red4[1] + red4[2] + red4[3]);
    __syncthreads();
  }
  if (tid == 0) s_out[b] = total;
}

__global__ void logits_k(const float* __restrict__ gsub, const float* __restrict__ gcomp,
                         const float* __restrict__ Wc, const float* __restrict__ bc,
                         float* __restrict__ outL) {
  __shared__ float red4[4];
  const int blk = blockIdx.x;  // 0..31
  const int set = blk >> 4, b = blk & 15;
  const float* g = set ? gcomp : gsub;
  const int tid = threadIdx.x;
  float gv = g[b * Dd + tid];
  for (int c = 0; c < 2; ++c) {
    float v = gv * Wc[c * Dd + tid];
    for (int o = 32; o > 0; o >>= 1) v += __shfl_xor(v, o);
    if ((tid & 63) == 0) red4[tid >> 6] = v;
    __syncthreads();
    if (tid == 0) outL[set * 32 + b * 2 + c] = red4[0] + red4[1] + red4[2] + red4[3] + bc[c];
    __syncthreads();
  }
}

__global__ void final_k(const float* __restrict__ L, const int* __restrict__ labels,
                        const float* __restrict__ s_orig, const float* __restrict__ s_sub,
                        float* __restrict__ out) {
  if (threadIdx.x == 0) {
    float Lp = 0, Lu = 0, La = 0;
    const float u = 0.5f;
    for (int b = 0; b < 16; ++b) {
      float l0 = L[b * 2], l1 = L[b * 2 + 1];
      float m = fmaxf(l0, l1);
      float lse = m + logf(expf(l0 - m) + expf(l1 - m));
      int lab = labels[b];
      Lp += -((lab ? l1 : l0) - lse);
      float c0 = L[32 + b * 2], c1 = L[32 + b * 2 + 1];
      float mm = fmaxf(c0, c1);
      float e0 = expf(c0 - mm), e1 = expf(c1 - mm), Z = e0 + e1;
      Lu += u * (logf(u) - logf(e0 / Z + 1e-8f)) + u * (logf(u) - logf(e1 / Z + 1e-8f));
      float dd = s_sub[b] - s_orig[b];
      La += dd * dd;
    }
    Lp /= 16.0f; Lu /= 16.0f; La /= 16.0f;
    out[0] = 0.5f * Lp + 0.3f * Lu + 0.2f * La;
    out[1] = Lp; out[2] = Lu; out[3] = La;
  }
}

// ------------------------------------------------------------------ host
extern "C" void kernel_launch(void* const* d_in, const int* in_sizes, int n_in,
                              void* d_out, int out_size, void* d_ws, size_t ws_size,
                              hipStream_t stream) {
  (void)in_sizes; (void)n_in; (void)out_size; (void)ws_size;
  const float* x    = (const float*)d_in[0];
  const int* ei     = (const int*)d_in[1];
  const int* batch  = (const int*)d_in[2];
  const int* labels = (const int*)d_in[3];
  const float* mw1 = (const float*)d_in[4];
  const float* mb1 = (const float*)d_in[5];
  const float* mw2 = (const float*)d_in[6];
  const float* mb2 = (const float*)d_in[7];
  const float* mw3 = (const float*)d_in[8];
  const float* mb3 = (const float*)d_in[9];
  const float* Ws   = (const float*)d_in[10];
  const float* bs   = (const float*)d_in[11];
  const float* Win  = (const float*)d_in[12];
  const float* bin_ = (const float*)d_in[13];
  const float* Wout = (const float*)d_in[14];
  const float* bout = (const float*)d_in[15];
  const float* gma  = (const float*)d_in[16];
  const float* bta  = (const float*)d_in[17];
  const float* rmn  = (const float*)d_in[18];
  const float* rvr  = (const float*)d_in[19];
  const float* anchors = (const float*)d_in[20];
  const float* Wc   = (const float*)d_in[21];
  const float* bc   = (const float*)d_in[22];
  const int* srcp = ei;
  const int* dstp = ei + Ee;

  float* fws = (float*)d_ws;
  const size_t HD = (size_t)2 * Nn * Dd;
  float* bufA = fws;
  float* bufB = bufA + HD;
  float* bufG = bufB + HD;
  int* off_in   = (int*)(bufG + HD);
  int* off_out  = off_in + (Nn + 1);
  int* cur_in   = off_out + (Nn + 1);
  int* cur_out  = cur_in + Nn;
  int* in_src   = cur_out + Nn;
  int* in_eid   = in_src + Ee;
  int* out_dst  = in_eid + Ee;
  int* out_eid  = out_dst + Ee;
  int* counts_in  = out_eid + Ee;
  int* counts_out = counts_in + Nn;
  float* cntf      = (float*)(counts_out + Nn);
  float* gemb_orig = cntf + Bb;
  float* gemb_sub  = gemb_orig + Bb * Dd;
  float* gemb_comp = gemb_sub + Bb * Dd;
  float* bsum    = gemb_comp + Bb * Dd;
  float* s_orig  = bsum + 3 * Dd;
  float* s_sub   = s_orig + Bb;
  float* logitsb = s_sub + Bb;

  float* outF = (float*)d_out;
  float* maskp = outF + 4;

  const size_t zero_bytes = (char*)bsum - (char*)counts_in;
  hipMemsetAsync(counts_in, 0, zero_bytes, stream);

  hist_edges_k<<<(Ee + 255) / 256, 256, 0, stream>>>(srcp, dstp, counts_in, counts_out);
  hist_batch_k<<<(Nn + 255) / 256, 256, 0, stream>>>(batch, cntf);
  scan_k<<<1, 1024, 0, stream>>>(counts_in, counts_out, off_in, off_out, cur_in, cur_out);
  scatter_k<<<(Ee + 255) / 256, 256, 0, stream>>>(srcp, dstp, cur_in, cur_out, in_src, in_eid, out_dst, out_eid);
  prep_bsum_k<<<1, 256, 0, stream>>>(bs, bin_, bout, bsum);

  auto enc_layer = [&](float* curb, float* nxtb, int M, int batched, const float* mptr, int l) {
    dim3 gg((M + 63) / 64, 4);
    gemm256_k<0><<<gg, 256, 0, stream>>>(curb, Ws + (size_t)l * 65536, nxtb, M, bsum + l * 256,
                                         nullptr, nullptr, nullptr, nullptr);
    agg_k<<<M, 256, 0, stream>>>(curb, bufG, off_in, in_src, in_eid, mptr, batched);
    gemm256_k<1><<<gg, 256, 0, stream>>>(bufG, Win + (size_t)l * 65536, nxtb, M, nullptr,
                                         nullptr, nullptr, nullptr, nullptr);
    agg_k<<<M, 256, 0, stream>>>(curb, bufG, off_out, out_dst, out_eid, mptr, batched);
    gemm256_k<2><<<gg, 256, 0, stream>>>(bufG, Wout + (size_t)l * 65536, nxtb, M, nullptr,
                                         gma + l * 256, bta + l * 256, rmn + l * 256, rvr + l * 256);
  };

  // ---- encoder #1 (ones mask), M = N
  float* p = bufA;
  float* q = bufB;
  copy_x_k<<<(Nn * Dd / 4 + 255) / 256, 256, 0, stream>>>(x, p, 0);
  for (int l = 0; l < 3; ++l) { enc_layer(p, q, Nn, 0, nullptr, l); float* t = p; p = q; q = t; }
  // p = node_emb

  gemb_sum_k<<<Nn / 16, 256, 0, stream>>>(p, batch, gemb_orig, 0);
  gemb_scale_k<<<Bb, 256, 0, stream>>>(gemb_orig, cntf);
  anchor_k<<<Bb, 256, 0, stream>>>(gemb_orig, anchors, s_orig);

  edge_mlp_k<<<Ee / 64, 256, 0, stream>>>(p, srcp, dstp, mw1, mb1, mw2, mb2, mw3, mb3, maskp);

  // ---- batched encoders #2/#3 (mask & 1-mask), M = 2N; node_emb no longer needed
  copy_x_k<<<(Nn * Dd / 4 + 255) / 256, 256, 0, stream>>>(x, q, 1);
  { float* t = p; p = q; q = t; }  // p = [x; x]
  for (int l = 0; l < 3; ++l) { enc_layer(p, q, 2 * Nn, 1, maskp, l); float* t = p; p = q; q = t; }
  // p = [h_sub; h_comp]

  gemb_sum_k<<<2 * (Nn / 16), 256, 0, stream>>>(p, batch, gemb_sub, 1);
  gemb_scale_k<<<2 * Bb, 256, 0, stream>>>(gemb_sub, cntf);
  anchor_k<<<Bb, 256, 0, stream>>>(gemb_sub, anchors, s_sub);
  logits_k<<<2 * Bb, 256, 0, stream>>>(gemb_sub, gemb_comp, Wc, bc, logitsb);
  final_k<<<1, 64, 0, stream>>>(logitsb, labels, s_orig, s_sub, outF);
}

// Round 3
// 3332.355 us; speedup vs baseline: 1.4495x; 1.4495x over previous
//
#include <hip/hip_runtime.h>
#include <hip/hip_bf16.h>

constexpr int Nn = 20000;
constexpr int Ee = 320000;
constexpr int Dd = 256;
constexpr int Bb = 16;
constexpr float EPSc = 1e-5f;

// ------------------------------------------------------------------ graph prep
__global__ void hist_edges_k(const int* __restrict__ src, const int* __restrict__ dst,
                             int* __restrict__ cin, int* __restrict__ cout) {
  int e = blockIdx.x * 256 + threadIdx.x;
  if (e < Ee) { atomicAdd(&cin[dst[e]], 1); atomicAdd(&cout[src[e]], 1); }
}

__global__ void hist_batch_k(const int* __restrict__ batch, float* __restrict__ cntf) {
  int v = blockIdx.x * 256 + threadIdx.x;
  if (v < Nn) atomicAdd(&cntf[batch[v]], 1.0f);
}

__global__ __launch_bounds__(1024) void scan_k(const int* __restrict__ cin,
                                               const int* __restrict__ cout,
                                               int* __restrict__ off_in, int* __restrict__ off_out,
                                               int* __restrict__ cur_in, int* __restrict__ cur_out) {
  __shared__ int part[1024];
  const int tid = threadIdx.x;
  for (int which = 0; which < 2; ++which) {
    const int* cnt = which ? cout : cin;
    int* off = which ? off_out : off_in;
    int* curp = which ? cur_out : cur_in;
    int vals[20];
    int base = tid * 20;
    int local = 0;
#pragma unroll
    for (int i = 0; i < 20; ++i) {
      int idx = base + i;
      int v = (idx < Nn) ? cnt[idx] : 0;
      vals[i] = v; local += v;
    }
    part[tid] = local;
    __syncthreads();
    for (int ofs = 1; ofs < 1024; ofs <<= 1) {
      int t = (tid >= ofs) ? part[tid - ofs] : 0;
      __syncthreads();
      part[tid] += t;
      __syncthreads();
    }
    int run = part[tid] - local;  // exclusive prefix
#pragma unroll
    for (int i = 0; i < 20; ++i) {
      int idx = base + i;
      if (idx < Nn) { off[idx] = run; curp[idx] = run; run += vals[i]; }
    }
    if (tid == 0) off[Nn] = Ee;
    __syncthreads();
  }
}

__global__ void scatter_k(const int* __restrict__ src, const int* __restrict__ dst,
                          int* __restrict__ cur_in, int* __restrict__ cur_out,
                          int* __restrict__ in_src, int* __restrict__ in_eid,
                          int* __restrict__ out_dst, int* __restrict__ out_eid) {
  int e = blockIdx.x * 256 + threadIdx.x;
  if (e < Ee) {
    int d = dst[e], s = src[e];
    int p = atomicAdd(&cur_in[d], 1);  in_src[p] = s;  in_eid[p] = e;
    int q = atomicAdd(&cur_out[s], 1); out_dst[q] = d; out_eid[q] = e;
  }
}

__global__ void prep_bsum_k(const float* __restrict__ bs, const float* __restrict__ bin,
                            const float* __restrict__ bout, float* __restrict__ bsum) {
  int t = threadIdx.x;
  for (int l = 0; l < 3; ++l) bsum[l * 256 + t] = bs[l * 256 + t] + bin[l * 256 + t] + bout[l * 256 + t];
}

__global__ void copy_x_k(const float* __restrict__ x, float* __restrict__ dstp, int dup) {
  const int n4 = Nn * Dd / 4;
  int i = blockIdx.x * 256 + threadIdx.x;
  if (i < n4) {
    float4 v = ((const float4*)x)[i];
    ((float4*)dstp)[i] = v;
    if (dup) ((float4*)dstp)[i + n4] = v;
  }
}

// ------------------------------------------------------------------ aggregation
__global__ __launch_bounds__(256) void agg_k(const float* __restrict__ h, float* __restrict__ G,
                                             const int* __restrict__ offs, const int* __restrict__ nbr,
                                             const int* __restrict__ eid, const float* __restrict__ mask,
                                             int batched) {
  int blk = blockIdx.x;
  int half = 0, v = blk;
  if (batched) { half = (blk >= Nn) ? 1 : 0; v = blk - half * Nn; }
  const size_t base = (size_t)half * Nn;
  const int tid = threadIdx.x;
  const int s = offs[v], e = offs[v + 1];
  float acc = 0.0f;
  for (int i = s; i < e; ++i) {
    int u = nbr[i];
    float m = 1.0f;
    if (mask) { float mv = mask[eid[i]]; m = half ? (1.0f - mv) : mv; }
    acc += m * h[(base + u) * Dd + tid];
  }
  G[(base + v) * Dd + tid] = acc;
}

// ------------------------------------------------------------------ GEMM  C[M x NCOL] (+)= A[M x 256] @ W[NCOL x 256]^T
// W row stride = WSTRIDE. MODE 0: C = bias + A@W^T ; MODE 1: C += A@W^T ;
// MODE 2: C += A@W^T then relu+BN ; MODE 3: C = A@W^T (no bias)
template <int MODE, int WSTRIDE, int NCOL>
__global__ __launch_bounds__(256) void gemm256_k(const float* __restrict__ A, const float* __restrict__ W,
                                                 float* __restrict__ C, int M,
                                                 const float* __restrict__ bias, const float* __restrict__ gma,
                                                 const float* __restrict__ bta, const float* __restrict__ rmn,
                                                 const float* __restrict__ rvr) {
  __shared__ float As[16][68];
  __shared__ float Bs[16][68];
  const int tid = threadIdx.x;
  const int row0 = blockIdx.x * 64;
  const int col0 = blockIdx.y * 64;
  const int tx = tid & 15, ty = tid >> 4;
  const int lr = tid >> 2;
  const int lk = (tid & 3) << 2;
  float acc[4][4] = {};
  for (int kt = 0; kt < 256; kt += 16) {
    int ar = row0 + lr;
    float4 a = make_float4(0.f, 0.f, 0.f, 0.f);
    if (ar < M) a = *(const float4*)(A + (size_t)ar * 256 + kt + lk);
    float4 w = *(const float4*)(W + (size_t)(col0 + lr) * WSTRIDE + kt + lk);
    As[lk + 0][lr] = a.x; As[lk + 1][lr] = a.y; As[lk + 2][lr] = a.z; As[lk + 3][lr] = a.w;
    Bs[lk + 0][lr] = w.x; Bs[lk + 1][lr] = w.y; Bs[lk + 2][lr] = w.z; Bs[lk + 3][lr] = w.w;
    __syncthreads();
#pragma unroll
    for (int kk = 0; kk < 16; ++kk) {
      const float4 av = *(const float4*)&As[kk][ty << 2];
      const float4 bv = *(const float4*)&Bs[kk][tx << 2];
      acc[0][0] += av.x * bv.x; acc[0][1] += av.x * bv.y; acc[0][2] += av.x * bv.z; acc[0][3] += av.x * bv.w;
      acc[1][0] += av.y * bv.x; acc[1][1] += av.y * bv.y; acc[1][2] += av.y * bv.z; acc[1][3] += av.y * bv.w;
      acc[2][0] += av.z * bv.x; acc[2][1] += av.z * bv.y; acc[2][2] += av.z * bv.z; acc[2][3] += av.z * bv.w;
      acc[3][0] += av.w * bv.x; acc[3][1] += av.w * bv.y; acc[3][2] += av.w * bv.z; acc[3][3] += av.w * bv.w;
    }
    __syncthreads();
  }
#pragma unroll
  for (int i = 0; i < 4; ++i) {
    int r = row0 + (ty << 2) + i;
    if (r >= M) continue;
    float* Cp = C + (size_t)r * NCOL + col0 + (tx << 2);
    float v0 = acc[i][0], v1 = acc[i][1], v2 = acc[i][2], v3 = acc[i][3];
    const int c0 = col0 + (tx << 2);
    if (MODE == 0) {
      v0 += bias[c0 + 0]; v1 += bias[c0 + 1]; v2 += bias[c0 + 2]; v3 += bias[c0 + 3];
    } else if (MODE == 1 || MODE == 2) {
      float4 co = *(const float4*)Cp;
      v0 += co.x; v1 += co.y; v2 += co.z; v3 += co.w;
      if (MODE == 2) {
        float t[4] = {v0, v1, v2, v3};
#pragma unroll
        for (int j = 0; j < 4; ++j) {
          int cc = c0 + j;
          float vv = fmaxf(t[j], 0.0f);
          t[j] = (vv - rmn[cc]) * rsqrtf(rvr[cc] + EPSc) * gma[cc] + bta[cc];
        }
        v0 = t[0]; v1 = t[1]; v2 = t[2]; v3 = t[3];
      }
    }
    *(float4*)Cp = make_float4(v0, v1, v2, v3);
  }
}

// ------------------------------------------------------------------ edge MLP (after per-node projection)
// h1[e][o] = relu(Psrc[src[e]][o] + Pdst[dst[e]][o])   (b1 folded into Psrc)
// h2[e][o] = relu(h1 @ W2^T + b2);  mask = sigmoid(h2 . w3 + b3)
__global__ __launch_bounds__(256) void edge_mlp2_k(const float* __restrict__ Psrc,
                                                   const float* __restrict__ Pdst,
                                                   const int* __restrict__ src, const int* __restrict__ dst,
                                                   const float* __restrict__ W2, const float* __restrict__ b2,
                                                   const float* __restrict__ w3, const float* __restrict__ b3,
                                                   float* __restrict__ maskOut) {
  __shared__ float h1s[64][129];
  __shared__ float red[16][64];
  __shared__ int s_src[64], s_dst[64];
  const int tid = threadIdx.x;
  const int e0 = blockIdx.x * 64;
  if (tid < 64) { s_src[tid] = src[e0 + tid]; s_dst[tid] = dst[e0 + tid]; }
  __syncthreads();

  // ---- layer 1: gather + add + relu
  {
    const int ei = tid >> 2, q = tid & 3;
    const float* ps = Psrc + (size_t)s_src[ei] * 128 + q * 32;
    const float* pd = Pdst + (size_t)s_dst[ei] * 128 + q * 32;
#pragma unroll
    for (int j4 = 0; j4 < 8; ++j4) {
      float4 a = *(const float4*)(ps + j4 * 4);
      float4 b = *(const float4*)(pd + j4 * 4);
      float* hp = &h1s[ei][q * 32 + j4 * 4];
      hp[0] = fmaxf(a.x + b.x, 0.f);
      hp[1] = fmaxf(a.y + b.y, 0.f);
      hp[2] = fmaxf(a.z + b.z, 0.f);
      hp[3] = fmaxf(a.w + b.w, 0.f);
    }
  }
  __syncthreads();

  // ---- layer 2 (register tile: 4 edges x 4 outs) + layer 3 partial
  const int eg = tid & 15;   // edges eg*4 .. eg*4+3
  const int og = tid >> 4;   // outs  og*4 .. og*4+3
  float acc[4][4] = {};
  for (int k4 = 0; k4 < 32; ++k4) {
    float4 w[4];
#pragma unroll
    for (int j = 0; j < 4; ++j)
      w[j] = *(const float4*)(W2 + (size_t)(og * 4 + j) * 128 + (k4 << 2));
#pragma unroll
    for (int i = 0; i < 4; ++i) {
      const float* hp = &h1s[eg * 4 + i][k4 << 2];
      float h0 = hp[0], h1 = hp[1], h2 = hp[2], h3 = hp[3];
#pragma unroll
      for (int j = 0; j < 4; ++j)
        acc[i][j] += h0 * w[j].x + h1 * w[j].y + h2 * w[j].z + h3 * w[j].w;
    }
  }
  float b2v[4], w3v[4];
#pragma unroll
  for (int j = 0; j < 4; ++j) { b2v[j] = b2[og * 4 + j]; w3v[j] = w3[og * 4 + j]; }
#pragma unroll
  for (int i = 0; i < 4; ++i) {
    float p = 0.f;
#pragma unroll
    for (int j = 0; j < 4; ++j) p += fmaxf(acc[i][j] + b2v[j], 0.f) * w3v[j];
    red[og][eg * 4 + i] = p;
  }
  __syncthreads();
  if (tid < 64) {
    float s = b3[0];
#pragma unroll
    for (int g = 0; g < 16; ++g) s += red[g][tid];
    maskOut[e0 + tid] = 1.0f / (1.0f + expf(-s));
  }
}

// ------------------------------------------------------------------ pooling / tails
__global__ __launch_bounds__(256) void gemb_sum_k(const float* __restrict__ h, const int* __restrict__ batch,
                                                  float* __restrict__ gsum, int batched) {
  const int halfBlocks = Nn / 16;
  int blk = blockIdx.x;
  int half = 0, bi = blk;
  if (batched) { half = (blk >= halfBlocks) ? 1 : 0; bi = blk - half * halfBlocks; }
  const int v0 = bi * 16;
  const int tid = threadIdx.x;
  const size_t base = (size_t)half * Nn;
  float* out = gsum + (size_t)half * (Bb * Dd);
  float acc = 0.0f;
  int curb = batch[v0];
  for (int i = 0; i < 16; ++i) {
    int v = v0 + i;
    int b = batch[v];
    if (b != curb) { atomicAdd(&out[curb * Dd + tid], acc); acc = 0.0f; curb = b; }
    acc += h[(base + v) * Dd + tid];
  }
  atomicAdd(&out[curb * Dd + tid], acc);
}

__global__ void gemb_scale_k(float* __restrict__ g, const float* __restrict__ cntf) {
  int blk = blockIdx.x;  // sets*16 blocks
  int b = blk & 15;
  g[blk * Dd + threadIdx.x] /= fmaxf(cntf[b], 1.0f);
}

__global__ void anchor_k(const float* __restrict__ g, const float* __restrict__ anchors,
                         float* __restrict__ s_out) {
  __shared__ float red4[4];
  const int b = blockIdx.x, tid = threadIdx.x;
  float gv = g[b * Dd + tid];
  float total = 0.0f;
  for (int k = 0; k < 6; ++k) {
    float d = gv - anchors[k * Dd + tid];
    float v = d * d;
    for (int o = 32; o > 0; o >>= 1) v += __shfl_xor(v, o);
    if ((tid & 63) == 0) red4[tid >> 6] = v;
    __syncthreads();
    if (tid == 0) total += sqrtf(red4[0] + red4[1] + red4[2] + red4[3]);
    __syncthreads();
  }
  if (tid == 0) s_out[b] = total;
}

__global__ void logits_k(const float* __restrict__ gsub, const float* __restrict__ gcomp,
                         const float* __restrict__ Wc, const float* __restrict__ bc,
                         float* __restrict__ outL) {
  __shared__ float red4[4];
  const int blk = blockIdx.x;  // 0..31
  const int set = blk >> 4, b = blk & 15;
  const float* g = set ? gcomp : gsub;
  const int tid = threadIdx.x;
  float gv = g[b * Dd + tid];
  for (int c = 0; c < 2; ++c) {
    float v = gv * Wc[c * Dd + tid];
    for (int o = 32; o > 0; o >>= 1) v += __shfl_xor(v, o);
    if ((tid & 63) == 0) red4[tid >> 6] = v;
    __syncthreads();
    if (tid == 0) outL[set * 32 + b * 2 + c] = red4[0] + red4[1] + red4[2] + red4[3] + bc[c];
    __syncthreads();
  }
}

__global__ void final_k(const float* __restrict__ L, const int* __restrict__ labels,
                        const float* __restrict__ s_orig, const float* __restrict__ s_sub,
                        float* __restrict__ out) {
  if (threadIdx.x == 0) {
    float Lp = 0, Lu = 0, La = 0;
    const float u = 0.5f;
    for (int b = 0; b < 16; ++b) {
      float l0 = L[b * 2], l1 = L[b * 2 + 1];
      float m = fmaxf(l0, l1);
      float lse = m + logf(expf(l0 - m) + expf(l1 - m));
      int lab = labels[b];
      Lp += -((lab ? l1 : l0) - lse);
      float c0 = L[32 + b * 2], c1 = L[32 + b * 2 + 1];
      float mm = fmaxf(c0, c1);
      float e0 = expf(c0 - mm), e1 = expf(c1 - mm), Z = e0 + e1;
      Lu += u * (logf(u) - logf(e0 / Z + 1e-8f)) + u * (logf(u) - logf(e1 / Z + 1e-8f));
      float dd = s_sub[b] - s_orig[b];
      La += dd * dd;
    }
    Lp /= 16.0f; Lu /= 16.0f; La /= 16.0f;
    out[0] = 0.5f * Lp + 0.3f * Lu + 0.2f * La;
    out[1] = Lp; out[2] = Lu; out[3] = La;
  }
}

// ------------------------------------------------------------------ host
extern "C" void kernel_launch(void* const* d_in, const int* in_sizes, int n_in,
                              void* d_out, int out_size, void* d_ws, size_t ws_size,
                              hipStream_t stream) {
  (void)in_sizes; (void)n_in; (void)out_size; (void)ws_size;
  const float* x    = (const float*)d_in[0];
  const int* ei     = (const int*)d_in[1];
  const int* batch  = (const int*)d_in[2];
  const int* labels = (const int*)d_in[3];
  const float* mw1 = (const float*)d_in[4];
  const float* mb1 = (const float*)d_in[5];
  const float* mw2 = (const float*)d_in[6];
  const float* mb2 = (const float*)d_in[7];
  const float* mw3 = (const float*)d_in[8];
  const float* mb3 = (const float*)d_in[9];
  const float* Ws   = (const float*)d_in[10];
  const float* bs   = (const float*)d_in[11];
  const float* Win  = (const float*)d_in[12];
  const float* bin_ = (const float*)d_in[13];
  const float* Wout = (const float*)d_in[14];
  const float* bout = (const float*)d_in[15];
  const float* gma  = (const float*)d_in[16];
  const float* bta  = (const float*)d_in[17];
  const float* rmn  = (const float*)d_in[18];
  const float* rvr  = (const float*)d_in[19];
  const float* anchors = (const float*)d_in[20];
  const float* Wc   = (const float*)d_in[21];
  const float* bc   = (const float*)d_in[22];
  const int* srcp = ei;
  const int* dstp = ei + Ee;

  float* fws = (float*)d_ws;
  const size_t HD = (size_t)2 * Nn * Dd;
  float* bufA = fws;
  float* bufB = bufA + HD;
  float* bufG = bufB + HD;
  int* off_in   = (int*)(bufG + HD);
  int* off_out  = off_in + (Nn + 1);
  int* cur_in   = off_out + (Nn + 1);
  int* cur_out  = cur_in + Nn;
  int* in_src   = cur_out + Nn;
  int* in_eid   = in_src + Ee;
  int* out_dst  = in_eid + Ee;
  int* out_eid  = out_dst + Ee;
  int* counts_in  = out_eid + Ee;
  int* counts_out = counts_in + Nn;
  float* cntf      = (float*)(counts_out + Nn);
  float* gemb_orig = cntf + Bb;
  float* gemb_sub  = gemb_orig + Bb * Dd;
  float* gemb_comp = gemb_sub + Bb * Dd;
  float* bsum    = gemb_comp + Bb * Dd;
  float* s_orig  = bsum + 3 * Dd;
  float* s_sub   = s_orig + Bb;
  float* logitsb = s_sub + Bb;

  float* outF = (float*)d_out;
  float* maskp = outF + 4;

  const size_t zero_bytes = (char*)bsum - (char*)counts_in;
  hipMemsetAsync(counts_in, 0, zero_bytes, stream);

  hist_edges_k<<<(Ee + 255) / 256, 256, 0, stream>>>(srcp, dstp, counts_in, counts_out);
  hist_batch_k<<<(Nn + 255) / 256, 256, 0, stream>>>(batch, cntf);
  scan_k<<<1, 1024, 0, stream>>>(counts_in, counts_out, off_in, off_out, cur_in, cur_out);
  scatter_k<<<(Ee + 255) / 256, 256, 0, stream>>>(srcp, dstp, cur_in, cur_out, in_src, in_eid, out_dst, out_eid);
  prep_bsum_k<<<1, 256, 0, stream>>>(bs, bin_, bout, bsum);

  auto enc_layer = [&](float* curb, float* nxtb, int M, int batched, const float* mptr, int l) {
    dim3 gg((M + 63) / 64, 4);
    gemm256_k<0, 256, 256><<<gg, 256, 0, stream>>>(curb, Ws + (size_t)l * 65536, nxtb, M, bsum + l * 256,
                                                   nullptr, nullptr, nullptr, nullptr);
    agg_k<<<M, 256, 0, stream>>>(curb, bufG, off_in, in_src, in_eid, mptr, batched);
    gemm256_k<1, 256, 256><<<gg, 256, 0, stream>>>(bufG, Win + (size_t)l * 65536, nxtb, M, nullptr,
                                                   nullptr, nullptr, nullptr, nullptr);
    agg_k<<<M, 256, 0, stream>>>(curb, bufG, off_out, out_dst, out_eid, mptr, batched);
    gemm256_k<2, 256, 256><<<gg, 256, 0, stream>>>(bufG, Wout + (size_t)l * 65536, nxtb, M, nullptr,
                                                   gma + l * 256, bta + l * 256, rmn + l * 256, rvr + l * 256);
  };

  // ---- encoder #1 (ones mask), M = N
  float* p = bufA;
  float* q = bufB;
  copy_x_k<<<(Nn * Dd / 4 + 255) / 256, 256, 0, stream>>>(x, p, 0);
  for (int l = 0; l < 3; ++l) { enc_layer(p, q, Nn, 0, nullptr, l); float* t = p; p = q; q = t; }
  // p = node_emb

  gemb_sum_k<<<Nn / 16, 256, 0, stream>>>(p, batch, gemb_orig, 0);
  gemb_scale_k<<<Bb, 256, 0, stream>>>(gemb_orig, cntf);
  anchor_k<<<Bb, 256, 0, stream>>>(gemb_orig, anchors, s_orig);

  // ---- per-node projections for edge MLP layer 1 (b1 folded into Psrc)
  float* Psrc = bufG;
  float* Pdst = bufG + (size_t)Nn * 128;
  {
    dim3 gp((Nn + 63) / 64, 2);
    gemm256_k<0, 512, 128><<<gp, 256, 0, stream>>>(p, mw1, Psrc, Nn, mb1, nullptr, nullptr, nullptr, nullptr);
    gemm256_k<3, 512, 128><<<gp, 256, 0, stream>>>(p, mw1 + 256, Pdst, Nn, nullptr, nullptr, nullptr, nullptr, nullptr);
  }
  edge_mlp2_k<<<Ee / 64, 256, 0, stream>>>(Psrc, Pdst, srcp, dstp, mw2, mb2, mw3, mb3, maskp);

  // ---- batched encoders #2/#3 (mask & 1-mask), M = 2N
  copy_x_k<<<(Nn * Dd / 4 + 255) / 256, 256, 0, stream>>>(x, q, 1);
  { float* t = p; p = q; q = t; }  // p = [x; x]
  for (int l = 0; l < 3; ++l) { enc_layer(p, q, 2 * Nn, 1, maskp, l); float* t = p; p = q; q = t; }
  // p = [h_sub; h_comp]

  gemb_sum_k<<<2 * (Nn / 16), 256, 0, stream>>>(p, batch, gemb_sub, 1);
  gemb_scale_k<<<2 * Bb, 256, 0, stream>>>(gemb_sub, cntf);
  anchor_k<<<Bb, 256, 0, stream>>>(gemb_sub, anchors, s_sub);
  logits_k<<<2 * Bb, 256, 0, stream>>>(gemb_sub, gemb_comp, Wc, bc, logitsb);
  final_k<<<1, 64, 0, stream>>>(logitsb, labels, s_orig, s_sub, outF);
}

// Round 4
// 2329.611 us; speedup vs baseline: 2.0734x; 1.4304x over previous
//
#include <hip/hip_runtime.h>
#include <hip/hip_bf16.h>

constexpr int Nn = 20000;
constexpr int Ee = 320000;
constexpr int Dd = 256;
constexpr int Bb = 16;
constexpr float EPSc = 1e-5f;

// ------------------------------------------------------------------ graph prep
__global__ void hist_edges_k(const int* __restrict__ src, const int* __restrict__ dst,
                             int* __restrict__ cin, int* __restrict__ cout) {
  int e = blockIdx.x * 256 + threadIdx.x;
  if (e < Ee) { atomicAdd(&cin[dst[e]], 1); atomicAdd(&cout[src[e]], 1); }
}

// batch is sorted: count via binary search, no atomics
__global__ void cnt_batch_k(const int* __restrict__ batch, float* __restrict__ cntf) {
  int b = threadIdx.x;
  if (b < Bb) {
    int lo = 0, hi = Nn;
    while (lo < hi) { int mid = (lo + hi) >> 1; if (batch[mid] < b) lo = mid + 1; else hi = mid; }
    int lb = lo;
    lo = 0; hi = Nn;
    while (lo < hi) { int mid = (lo + hi) >> 1; if (batch[mid] <= b) lo = mid + 1; else hi = mid; }
    cntf[b] = (float)(lo - lb);
  }
}

__global__ __launch_bounds__(1024) void scan_k(const int* __restrict__ cin,
                                               const int* __restrict__ cout,
                                               int* __restrict__ off_in, int* __restrict__ off_out,
                                               int* __restrict__ cur_in, int* __restrict__ cur_out) {
  __shared__ int part[1024];
  const int tid = threadIdx.x;
  for (int which = 0; which < 2; ++which) {
    const int* cnt = which ? cout : cin;
    int* off = which ? off_out : off_in;
    int* curp = which ? cur_out : cur_in;
    int vals[20];
    int base = tid * 20;
    int local = 0;
#pragma unroll
    for (int i = 0; i < 20; ++i) {
      int idx = base + i;
      int v = (idx < Nn) ? cnt[idx] : 0;
      vals[i] = v; local += v;
    }
    part[tid] = local;
    __syncthreads();
    for (int ofs = 1; ofs < 1024; ofs <<= 1) {
      int t = (tid >= ofs) ? part[tid - ofs] : 0;
      __syncthreads();
      part[tid] += t;
      __syncthreads();
    }
    int run = part[tid] - local;  // exclusive prefix
#pragma unroll
    for (int i = 0; i < 20; ++i) {
      int idx = base + i;
      if (idx < Nn) { off[idx] = run; curp[idx] = run; run += vals[i]; }
    }
    if (tid == 0) off[Nn] = Ee;
    __syncthreads();
  }
}

__global__ void scatter_k(const int* __restrict__ src, const int* __restrict__ dst,
                          int* __restrict__ cur_in, int* __restrict__ cur_out,
                          int* __restrict__ in_src, int* __restrict__ in_eid,
                          int* __restrict__ out_dst, int* __restrict__ out_eid) {
  int e = blockIdx.x * 256 + threadIdx.x;
  if (e < Ee) {
    int d = dst[e], s = src[e];
    int p = atomicAdd(&cur_in[d], 1);  in_src[p] = s;  in_eid[p] = e;
    int q = atomicAdd(&cur_out[s], 1); out_dst[q] = d; out_eid[q] = e;
  }
}

__global__ void prep_bsum_k(const float* __restrict__ bs, const float* __restrict__ bin,
                            const float* __restrict__ bout, float* __restrict__ bsum) {
  int t = threadIdx.x;
  for (int l = 0; l < 3; ++l) bsum[l * 256 + t] = bs[l * 256 + t] + bin[l * 256 + t] + bout[l * 256 + t];
}

__global__ void copy_x_k(const float* __restrict__ x, float* __restrict__ dstp, int dup) {
  const int n4 = Nn * Dd / 4;
  int i = blockIdx.x * 256 + threadIdx.x;
  if (i < n4) {
    float4 v = ((const float4*)x)[i];
    ((float4*)dstp)[i] = v;
    if (dup) ((float4*)dstp)[i + n4] = v;
  }
}

// ------------------------------------------------------------------ aggregation (float4, 4 nodes/block)
__global__ __launch_bounds__(256) void agg3_k(const float* __restrict__ h, float* __restrict__ G,
                                              const int* __restrict__ offs, const int* __restrict__ nbr,
                                              const int* __restrict__ eid, const float* __restrict__ mask,
                                              int batched) {
  const int grp = threadIdx.x >> 6;
  const int lane = threadIdx.x & 63;
  const int node = blockIdx.x * 4 + grp;
  const int Mtot = batched ? 2 * Nn : Nn;
  if (node >= Mtot) return;
  const int half = (batched && node >= Nn) ? 1 : 0;
  const int v = node - half * Nn;
  const size_t base = (size_t)half * Nn;
  const int s = offs[v], e = offs[v + 1];
  float4 acc = make_float4(0.f, 0.f, 0.f, 0.f);
  const float* hb = h + base * 256 + lane * 4;
  for (int i = s; i < e; ++i) {
    int u = nbr[i];
    float m = 1.0f;
    if (mask) { float mv = mask[eid[i]]; m = half ? (1.0f - mv) : mv; }
    float4 hv = *(const float4*)(hb + (size_t)u * 256);
    acc.x += m * hv.x; acc.y += m * hv.y; acc.z += m * hv.z; acc.w += m * hv.w;
  }
  *(float4*)(G + (size_t)node * 256 + lane * 4) = acc;
}

// ------------------------------------------------------------------ segmented GEMM (K = NSEG*256, 256x256 weights)
// MODE 0: C = bias + sum_seg A@W^T ; MODE 2: C += A0@W0^T then relu+BN
template <int NSEG, int MODE>
__global__ __launch_bounds__(256) void gemmseg_k(const float* __restrict__ A0, const float* __restrict__ W0,
                                                 const float* __restrict__ A1, const float* __restrict__ W1,
                                                 float* __restrict__ C, int M,
                                                 const float* __restrict__ bias, const float* __restrict__ gma,
                                                 const float* __restrict__ bta, const float* __restrict__ rmn,
                                                 const float* __restrict__ rvr) {
  __shared__ float As[16][68];
  __shared__ float Bs[16][68];
  const int tid = threadIdx.x;
  const int row0 = blockIdx.x * 64;
  const int col0 = blockIdx.y * 64;
  const int tx = tid & 15, ty = tid >> 4;
  const int lr = tid >> 2;
  const int lk = (tid & 3) << 2;
  const int ar = row0 + lr;
  float acc[4][4] = {};
  for (int kt = 0; kt < NSEG * 256; kt += 16) {
    const float* Aseg = (NSEG == 1 || kt < 256) ? A0 : A1;
    const float* Wseg = (NSEG == 1 || kt < 256) ? W0 : W1;
    const int kc = kt & 255;
    float4 a = make_float4(0.f, 0.f, 0.f, 0.f);
    if (ar < M) a = *(const float4*)(Aseg + (size_t)ar * 256 + kc + lk);
    float4 w = *(const float4*)(Wseg + (size_t)(col0 + lr) * 256 + kc + lk);
    As[lk + 0][lr] = a.x; As[lk + 1][lr] = a.y; As[lk + 2][lr] = a.z; As[lk + 3][lr] = a.w;
    Bs[lk + 0][lr] = w.x; Bs[lk + 1][lr] = w.y; Bs[lk + 2][lr] = w.z; Bs[lk + 3][lr] = w.w;
    __syncthreads();
#pragma unroll
    for (int kk = 0; kk < 16; ++kk) {
      const float4 av = *(const float4*)&As[kk][ty << 2];
      const float4 bv = *(const float4*)&Bs[kk][tx << 2];
      acc[0][0] += av.x * bv.x; acc[0][1] += av.x * bv.y; acc[0][2] += av.x * bv.z; acc[0][3] += av.x * bv.w;
      acc[1][0] += av.y * bv.x; acc[1][1] += av.y * bv.y; acc[1][2] += av.y * bv.z; acc[1][3] += av.y * bv.w;
      acc[2][0] += av.z * bv.x; acc[2][1] += av.z * bv.y; acc[2][2] += av.z * bv.z; acc[2][3] += av.z * bv.w;
      acc[3][0] += av.w * bv.x; acc[3][1] += av.w * bv.y; acc[3][2] += av.w * bv.z; acc[3][3] += av.w * bv.w;
    }
    __syncthreads();
  }
#pragma unroll
  for (int i = 0; i < 4; ++i) {
    int r = row0 + (ty << 2) + i;
    if (r >= M) continue;
    float* Cp = C + (size_t)r * 256 + col0 + (tx << 2);
    float v0 = acc[i][0], v1 = acc[i][1], v2 = acc[i][2], v3 = acc[i][3];
    const int c0 = col0 + (tx << 2);
    if (MODE == 0) {
      v0 += bias[c0 + 0]; v1 += bias[c0 + 1]; v2 += bias[c0 + 2]; v3 += bias[c0 + 3];
    } else {
      float4 co = *(const float4*)Cp;
      float t[4] = {v0 + co.x, v1 + co.y, v2 + co.z, v3 + co.w};
#pragma unroll
      for (int j = 0; j < 4; ++j) {
        int cc = c0 + j;
        float vv = fmaxf(t[j], 0.0f);
        t[j] = (vv - rmn[cc]) * rsqrtf(rvr[cc] + EPSc) * gma[cc] + bta[cc];
      }
      v0 = t[0]; v1 = t[1]; v2 = t[2]; v3 = t[3];
    }
    *(float4*)Cp = make_float4(v0, v1, v2, v3);
  }
}

// ------------------------------------------------------------------ proj GEMM  C[M x 128] = A[M x 256] @ W[128 x 256]^T (W stride 512)
// MODE 0: + bias ; MODE 3: none
template <int MODE>
__global__ __launch_bounds__(256) void gemmproj_k(const float* __restrict__ A, const float* __restrict__ W,
                                                  float* __restrict__ C, int M,
                                                  const float* __restrict__ bias) {
  __shared__ float As[16][68];
  __shared__ float Bs[16][68];
  const int tid = threadIdx.x;
  const int row0 = blockIdx.x * 64;
  const int col0 = blockIdx.y * 64;
  const int tx = tid & 15, ty = tid >> 4;
  const int lr = tid >> 2;
  const int lk = (tid & 3) << 2;
  const int ar = row0 + lr;
  float acc[4][4] = {};
  for (int kt = 0; kt < 256; kt += 16) {
    float4 a = make_float4(0.f, 0.f, 0.f, 0.f);
    if (ar < M) a = *(const float4*)(A + (size_t)ar * 256 + kt + lk);
    float4 w = *(const float4*)(W + (size_t)(col0 + lr) * 512 + kt + lk);
    As[lk + 0][lr] = a.x; As[lk + 1][lr] = a.y; As[lk + 2][lr] = a.z; As[lk + 3][lr] = a.w;
    Bs[lk + 0][lr] = w.x; Bs[lk + 1][lr] = w.y; Bs[lk + 2][lr] = w.z; Bs[lk + 3][lr] = w.w;
    __syncthreads();
#pragma unroll
    for (int kk = 0; kk < 16; ++kk) {
      const float4 av = *(const float4*)&As[kk][ty << 2];
      const float4 bv = *(const float4*)&Bs[kk][tx << 2];
      acc[0][0] += av.x * bv.x; acc[0][1] += av.x * bv.y; acc[0][2] += av.x * bv.z; acc[0][3] += av.x * bv.w;
      acc[1][0] += av.y * bv.x; acc[1][1] += av.y * bv.y; acc[1][2] += av.y * bv.z; acc[1][3] += av.y * bv.w;
      acc[2][0] += av.z * bv.x; acc[2][1] += av.z * bv.y; acc[2][2] += av.z * bv.z; acc[2][3] += av.z * bv.w;
      acc[3][0] += av.w * bv.x; acc[3][1] += av.w * bv.y; acc[3][2] += av.w * bv.z; acc[3][3] += av.w * bv.w;
    }
    __syncthreads();
  }
#pragma unroll
  for (int i = 0; i < 4; ++i) {
    int r = row0 + (ty << 2) + i;
    if (r >= M) continue;
    float* Cp = C + (size_t)r * 128 + col0 + (tx << 2);
    float v0 = acc[i][0], v1 = acc[i][1], v2 = acc[i][2], v3 = acc[i][3];
    if (MODE == 0) {
      const int c0 = col0 + (tx << 2);
      v0 += bias[c0 + 0]; v1 += bias[c0 + 1]; v2 += bias[c0 + 2]; v3 += bias[c0 + 3];
    }
    *(float4*)Cp = make_float4(v0, v1, v2, v3);
  }
}

// ------------------------------------------------------------------ edge MLP (after per-node projection)
__global__ __launch_bounds__(256) void edge_mlp2_k(const float* __restrict__ Psrc,
                                                   const float* __restrict__ Pdst,
                                                   const int* __restrict__ src, const int* __restrict__ dst,
                                                   const float* __restrict__ W2, const float* __restrict__ b2,
                                                   const float* __restrict__ w3, const float* __restrict__ b3,
                                                   float* __restrict__ maskOut) {
  __shared__ float h1s[64][129];
  __shared__ float red[16][64];
  __shared__ int s_src[64], s_dst[64];
  const int tid = threadIdx.x;
  const int e0 = blockIdx.x * 64;
  if (tid < 64) { s_src[tid] = src[e0 + tid]; s_dst[tid] = dst[e0 + tid]; }
  __syncthreads();

  {
    const int ei = tid >> 2, q = tid & 3;
    const float* ps = Psrc + (size_t)s_src[ei] * 128 + q * 32;
    const float* pd = Pdst + (size_t)s_dst[ei] * 128 + q * 32;
#pragma unroll
    for (int j4 = 0; j4 < 8; ++j4) {
      float4 a = *(const float4*)(ps + j4 * 4);
      float4 b = *(const float4*)(pd + j4 * 4);
      float* hp = &h1s[ei][q * 32 + j4 * 4];
      hp[0] = fmaxf(a.x + b.x, 0.f);
      hp[1] = fmaxf(a.y + b.y, 0.f);
      hp[2] = fmaxf(a.z + b.z, 0.f);
      hp[3] = fmaxf(a.w + b.w, 0.f);
    }
  }
  __syncthreads();

  const int eg = tid & 15;
  const int og = tid >> 4;
  float acc[4][4] = {};
  for (int k4 = 0; k4 < 32; ++k4) {
    float4 w[4];
#pragma unroll
    for (int j = 0; j < 4; ++j)
      w[j] = *(const float4*)(W2 + (size_t)(og * 4 + j) * 128 + (k4 << 2));
#pragma unroll
    for (int i = 0; i < 4; ++i) {
      const float* hp = &h1s[eg * 4 + i][k4 << 2];
      float h0 = hp[0], h1 = hp[1], h2 = hp[2], h3 = hp[3];
#pragma unroll
      for (int j = 0; j < 4; ++j)
        acc[i][j] += h0 * w[j].x + h1 * w[j].y + h2 * w[j].z + h3 * w[j].w;
    }
  }
  float b2v[4], w3v[4];
#pragma unroll
  for (int j = 0; j < 4; ++j) { b2v[j] = b2[og * 4 + j]; w3v[j] = w3[og * 4 + j]; }
#pragma unroll
  for (int i = 0; i < 4; ++i) {
    float p = 0.f;
#pragma unroll
    for (int j = 0; j < 4; ++j) p += fmaxf(acc[i][j] + b2v[j], 0.f) * w3v[j];
    red[og][eg * 4 + i] = p;
  }
  __syncthreads();
  if (tid < 64) {
    float s = b3[0];
#pragma unroll
    for (int g = 0; g < 16; ++g) s += red[g][tid];
    maskOut[e0 + tid] = 1.0f / (1.0f + expf(-s));
  }
}

// ------------------------------------------------------------------ pooling / tails
__global__ __launch_bounds__(256) void gemb_sum_k(const float* __restrict__ h, const int* __restrict__ batch,
                                                  float* __restrict__ gsum, int batched) {
  const int halfBlocks = Nn / 16;
  int blk = blockIdx.x;
  int half = 0, bi = blk;
  if (batched) { half = (blk >= halfBlocks) ? 1 : 0; bi = blk - half * halfBlocks; }
  const int v0 = bi * 16;
  const int tid = threadIdx.x;
  const size_t base = (size_t)half * Nn;
  float* out = gsum + (size_t)half * (Bb * Dd);
  float acc = 0.0f;
  int curb = batch[v0];
  for (int i = 0; i < 16; ++i) {
    int v = v0 + i;
    int b = batch[v];
    if (b != curb) { atomicAdd(&out[curb * Dd + tid], acc); acc = 0.0f; curb = b; }
    acc += h[(base + v) * Dd + tid];
  }
  atomicAdd(&out[curb * Dd + tid], acc);
}

__global__ void gemb_scale_k(float* __restrict__ g, const float* __restrict__ cntf) {
  int blk = blockIdx.x;
  int b = blk & 15;
  g[blk * Dd + threadIdx.x] /= fmaxf(cntf[b], 1.0f);
}

__global__ void anchor_k(const float* __restrict__ g, const float* __restrict__ anchors,
                         float* __restrict__ s_out) {
  __shared__ float red4[4];
  const int b = blockIdx.x, tid = threadIdx.x;
  float gv = g[b * Dd + tid];
  float total = 0.0f;
  for (int k = 0; k < 6; ++k) {
    float d = gv - anchors[k * Dd + tid];
    float v = d * d;
    for (int o = 32; o > 0; o >>= 1) v += __shfl_xor(v, o);
    if ((tid & 63) == 0) red4[tid >> 6] = v;
    __syncthreads();
    if (tid == 0) total += sqrtf(red4[0] + red4[1] + red4[2] + red4[3]);
    __syncthreads();
  }
  if (tid == 0) s_out[b] = total;
}

__global__ void logits_k(const float* __restrict__ gsub, const float* __restrict__ gcomp,
                         const float* __restrict__ Wc, const float* __restrict__ bc,
                         float* __restrict__ outL) {
  __shared__ float red4[4];
  const int blk = blockIdx.x;
  const int set = blk >> 4, b = blk & 15;
  const float* g = set ? gcomp : gsub;
  const int tid = threadIdx.x;
  float gv = g[b * Dd + tid];
  for (int c = 0; c < 2; ++c) {
    float v = gv * Wc[c * Dd + tid];
    for (int o = 32; o > 0; o >>= 1) v += __shfl_xor(v, o);
    if ((tid & 63) == 0) red4[tid >> 6] = v;
    __syncthreads();
    if (tid == 0) outL[set * 32 + b * 2 + c] = red4[0] + red4[1] + red4[2] + red4[3] + bc[c];
    __syncthreads();
  }
}

__global__ void final_k(const float* __restrict__ L, const int* __restrict__ labels,
                        const float* __restrict__ s_orig, const float* __restrict__ s_sub,
                        float* __restrict__ out) {
  if (threadIdx.x == 0) {
    float Lp = 0, Lu = 0, La = 0;
    const float u = 0.5f;
    for (int b = 0; b < 16; ++b) {
      float l0 = L[b * 2], l1 = L[b * 2 + 1];
      float m = fmaxf(l0, l1);
      float lse = m + logf(expf(l0 - m) + expf(l1 - m));
      int lab = labels[b];
      Lp += -((lab ? l1 : l0) - lse);
      float c0 = L[32 + b * 2], c1 = L[32 + b * 2 + 1];
      float mm = fmaxf(c0, c1);
      float e0 = expf(c0 - mm), e1 = expf(c1 - mm), Z = e0 + e1;
      Lu += u * (logf(u) - logf(e0 / Z + 1e-8f)) + u * (logf(u) - logf(e1 / Z + 1e-8f));
      float dd = s_sub[b] - s_orig[b];
      La += dd * dd;
    }
    Lp /= 16.0f; Lu /= 16.0f; La /= 16.0f;
    out[0] = 0.5f * Lp + 0.3f * Lu + 0.2f * La;
    out[1] = Lp; out[2] = Lu; out[3] = La;
  }
}

// ------------------------------------------------------------------ host
extern "C" void kernel_launch(void* const* d_in, const int* in_sizes, int n_in,
                              void* d_out, int out_size, void* d_ws, size_t ws_size,
                              hipStream_t stream) {
  (void)in_sizes; (void)n_in; (void)out_size; (void)ws_size;
  const float* x    = (const float*)d_in[0];
  const int* ei     = (const int*)d_in[1];
  const int* batch  = (const int*)d_in[2];
  const int* labels = (const int*)d_in[3];
  const float* mw1 = (const float*)d_in[4];
  const float* mb1 = (const float*)d_in[5];
  const float* mw2 = (const float*)d_in[6];
  const float* mb2 = (const float*)d_in[7];
  const float* mw3 = (const float*)d_in[8];
  const float* mb3 = (const float*)d_in[9];
  const float* Ws   = (const float*)d_in[10];
  const float* bs   = (const float*)d_in[11];
  const float* Win  = (const float*)d_in[12];
  const float* bin_ = (const float*)d_in[13];
  const float* Wout = (const float*)d_in[14];
  const float* bout = (const float*)d_in[15];
  const float* gma  = (const float*)d_in[16];
  const float* bta  = (const float*)d_in[17];
  const float* rmn  = (const float*)d_in[18];
  const float* rvr  = (const float*)d_in[19];
  const float* anchors = (const float*)d_in[20];
  const float* Wc   = (const float*)d_in[21];
  const float* bc   = (const float*)d_in[22];
  const int* srcp = ei;
  const int* dstp = ei + Ee;

  float* fws = (float*)d_ws;
  const size_t HD = (size_t)2 * Nn * Dd;
  float* bufA = fws;
  float* bufB = bufA + HD;
  float* bufG = bufB + HD;
  int* off_in   = (int*)(bufG + HD);
  int* off_out  = off_in + (Nn + 1);
  int* cur_in   = off_out + (Nn + 1);
  int* cur_out  = cur_in + Nn;
  int* in_src   = cur_out + Nn;
  int* in_eid   = in_src + Ee;
  int* out_dst  = in_eid + Ee;
  int* out_eid  = out_dst + Ee;
  int* counts_in  = out_eid + Ee;
  int* counts_out = counts_in + Nn;
  float* cntf      = (float*)(counts_out + Nn);
  float* gemb_orig = cntf + Bb;
  float* gemb_sub  = gemb_orig + Bb * Dd;
  float* gemb_comp = gemb_sub + Bb * Dd;
  float* bsum    = gemb_comp + Bb * Dd;
  float* s_orig  = bsum + 3 * Dd;
  float* s_sub   = s_orig + Bb;
  float* logitsb = s_sub + Bb;

  float* outF = (float*)d_out;
  float* maskp = outF + 4;

  const size_t zero_bytes = (char*)bsum - (char*)counts_in;
  hipMemsetAsync(counts_in, 0, zero_bytes, stream);

  hist_edges_k<<<(Ee + 255) / 256, 256, 0, stream>>>(srcp, dstp, counts_in, counts_out);
  cnt_batch_k<<<1, 64, 0, stream>>>(batch, cntf);
  scan_k<<<1, 1024, 0, stream>>>(counts_in, counts_out, off_in, off_out, cur_in, cur_out);
  scatter_k<<<(Ee + 255) / 256, 256, 0, stream>>>(srcp, dstp, cur_in, cur_out, in_src, in_eid, out_dst, out_eid);
  prep_bsum_k<<<1, 256, 0, stream>>>(bs, bin_, bout, bsum);

  auto enc_layer = [&](float* curb, float* nxtb, int M, int batched, const float* mptr, int l) {
    dim3 gg((M + 63) / 64, 4);
    agg3_k<<<(M + 3) / 4, 256, 0, stream>>>(curb, bufG, off_in, in_src, in_eid, mptr, batched);
    gemmseg_k<2, 0><<<gg, 256, 0, stream>>>(curb, Ws + (size_t)l * 65536, bufG, Win + (size_t)l * 65536,
                                            nxtb, M, bsum + l * 256, nullptr, nullptr, nullptr, nullptr);
    agg3_k<<<(M + 3) / 4, 256, 0, stream>>>(curb, bufG, off_out, out_dst, out_eid, mptr, batched);
    gemmseg_k<1, 2><<<gg, 256, 0, stream>>>(bufG, Wout + (size_t)l * 65536, nullptr, nullptr,
                                            nxtb, M, nullptr, gma + l * 256, bta + l * 256,
                                            rmn + l * 256, rvr + l * 256);
  };

  // ---- encoder #1 (ones mask), M = N
  float* p = bufA;
  float* q = bufB;
  copy_x_k<<<(Nn * Dd / 4 + 255) / 256, 256, 0, stream>>>(x, p, 0);
  for (int l = 0; l < 3; ++l) { enc_layer(p, q, Nn, 0, nullptr, l); float* t = p; p = q; q = t; }
  // p = node_emb

  gemb_sum_k<<<Nn / 16, 256, 0, stream>>>(p, batch, gemb_orig, 0);
  gemb_scale_k<<<Bb, 256, 0, stream>>>(gemb_orig, cntf);
  anchor_k<<<Bb, 256, 0, stream>>>(gemb_orig, anchors, s_orig);

  // ---- per-node projections for edge MLP layer 1 (b1 folded into Psrc)
  float* Psrc = bufG;
  float* Pdst = bufG + (size_t)Nn * 128;
  {
    dim3 gp((Nn + 63) / 64, 2);
    gemmproj_k<0><<<gp, 256, 0, stream>>>(p, mw1, Psrc, Nn, mb1);
    gemmproj_k<3><<<gp, 256, 0, stream>>>(p, mw1 + 256, Pdst, Nn, nullptr);
  }
  edge_mlp2_k<<<Ee / 64, 256, 0, stream>>>(Psrc, Pdst, srcp, dstp, mw2, mb2, mw3, mb3, maskp);

  // ---- batched encoders #2/#3 (mask & 1-mask), M = 2N
  copy_x_k<<<(Nn * Dd / 4 + 255) / 256, 256, 0, stream>>>(x, q, 1);
  { float* t = p; p = q; q = t; }  // p = [x; x]
  for (int l = 0; l < 3; ++l) { enc_layer(p, q, 2 * Nn, 1, maskp, l); float* t = p; p = q; q = t; }
  // p = [h_sub; h_comp]

  gemb_sum_k<<<2 * (Nn / 16), 256, 0, stream>>>(p, batch, gemb_sub, 1);
  gemb_scale_k<<<2 * Bb, 256, 0, stream>>>(gemb_sub, cntf);
  anchor_k<<<Bb, 256, 0, stream>>>(gemb_sub, anchors, s_sub);
  logits_k<<<2 * Bb, 256, 0, stream>>>(gemb_sub, gemb_comp, Wc, bc, logitsb);
  final_k<<<1, 64, 0, stream>>>(logitsb, labels, s_orig, s_sub, outF);
}

// Round 5
// 1656.217 us; speedup vs baseline: 2.9165x; 1.4066x over previous
//
#include <hip/hip_runtime.h>
#include <hip/hip_bf16.h>

constexpr int Nn = 20000;
constexpr int Ee = 320000;
constexpr int Dd = 256;
constexpr int Bb = 16;
constexpr float EPSc = 1e-5f;

using v8s = __attribute__((ext_vector_type(8))) short;
using v4f = __attribute__((ext_vector_type(4))) float;

__device__ __forceinline__ float b2f(ushort u) { return __uint_as_float(((unsigned)u) << 16); }
__device__ __forceinline__ ushort f2b(float f) {
  __hip_bfloat16 h = __float2bfloat16(f);
  return *reinterpret_cast<ushort*>(&h);
}

// ------------------------------------------------------------------ graph prep
__global__ void hist_edges_k(const int* __restrict__ src, const int* __restrict__ dst,
                             int* __restrict__ cin, int* __restrict__ cout) {
  int e = blockIdx.x * 256 + threadIdx.x;
  if (e < Ee) { atomicAdd(&cin[dst[e]], 1); atomicAdd(&cout[src[e]], 1); }
}

__global__ void cnt_batch_k(const int* __restrict__ batch, float* __restrict__ cntf) {
  int b = threadIdx.x;
  if (b < Bb) {
    int lo = 0, hi = Nn;
    while (lo < hi) { int mid = (lo + hi) >> 1; if (batch[mid] < b) lo = mid + 1; else hi = mid; }
    int lb = lo;
    lo = 0; hi = Nn;
    while (lo < hi) { int mid = (lo + hi) >> 1; if (batch[mid] <= b) lo = mid + 1; else hi = mid; }
    cntf[b] = (float)(lo - lb);
  }
}

__global__ __launch_bounds__(1024) void scan_k(const int* __restrict__ cin,
                                               const int* __restrict__ cout,
                                               int* __restrict__ off_in, int* __restrict__ off_out,
                                               int* __restrict__ cur_in, int* __restrict__ cur_out) {
  __shared__ int part[1024];
  const int tid = threadIdx.x;
  for (int which = 0; which < 2; ++which) {
    const int* cnt = which ? cout : cin;
    int* off = which ? off_out : off_in;
    int* curp = which ? cur_out : cur_in;
    int vals[20];
    int base = tid * 20;
    int local = 0;
#pragma unroll
    for (int i = 0; i < 20; ++i) {
      int idx = base + i;
      int v = (idx < Nn) ? cnt[idx] : 0;
      vals[i] = v; local += v;
    }
    part[tid] = local;
    __syncthreads();
    for (int ofs = 1; ofs < 1024; ofs <<= 1) {
      int t = (tid >= ofs) ? part[tid - ofs] : 0;
      __syncthreads();
      part[tid] += t;
      __syncthreads();
    }
    int run = part[tid] - local;
#pragma unroll
    for (int i = 0; i < 20; ++i) {
      int idx = base + i;
      if (idx < Nn) { off[idx] = run; curp[idx] = run; run += vals[i]; }
    }
    if (tid == 0) off[Nn] = Ee;
    __syncthreads();
  }
}

__global__ void scatter_k(const int* __restrict__ src, const int* __restrict__ dst,
                          int* __restrict__ cur_in, int* __restrict__ cur_out,
                          int* __restrict__ in_src, int* __restrict__ in_eid,
                          int* __restrict__ out_dst, int* __restrict__ out_eid) {
  int e = blockIdx.x * 256 + threadIdx.x;
  if (e < Ee) {
    int d = dst[e], s = src[e];
    int p = atomicAdd(&cur_in[d], 1);  in_src[p] = s;  in_eid[p] = e;
    int q = atomicAdd(&cur_out[s], 1); out_dst[q] = d; out_eid[q] = e;
  }
}

__global__ void prep_bsum_k(const float* __restrict__ bs, const float* __restrict__ bin,
                            const float* __restrict__ bout, float* __restrict__ bsum) {
  int t = threadIdx.x;
  for (int l = 0; l < 3; ++l) bsum[l * 256 + t] = bs[l * 256 + t] + bin[l * 256 + t] + bout[l * 256 + t];
}

__global__ void copyxb_k(const float* __restrict__ x, ushort* __restrict__ h, int dup) {
  const int n4 = Nn * Dd / 4;
  int i = blockIdx.x * 256 + threadIdx.x;
  if (i < n4) {
    float4 v = ((const float4*)x)[i];
    ushort4 o; o.x = f2b(v.x); o.y = f2b(v.y); o.z = f2b(v.z); o.w = f2b(v.w);
    ((ushort4*)h)[i] = o;
    if (dup) ((ushort4*)h)[i + n4] = o;
  }
}

__global__ void c_f2b_k(const float* __restrict__ s, ushort* __restrict__ d, int n) {
  int i = blockIdx.x * 256 + threadIdx.x;
  if (i < n) d[i] = f2b(s[i]);
}

// ------------------------------------------------------------------ aggregation (bf16, 4 nodes/block)
__global__ __launch_bounds__(256) void aggb_k(const ushort* __restrict__ h, ushort* __restrict__ G,
                                              const int* __restrict__ offs, const int* __restrict__ nbr,
                                              const int* __restrict__ eid, const float* __restrict__ mask,
                                              int batched) {
  const int grp = threadIdx.x >> 6;
  const int lane = threadIdx.x & 63;
  const int node = blockIdx.x * 4 + grp;
  const int Mtot = batched ? 2 * Nn : Nn;
  if (node >= Mtot) return;
  const int half = (batched && node >= Nn) ? 1 : 0;
  const int v = node - half * Nn;
  const size_t base = (size_t)half * Nn;
  const int s = offs[v], e = offs[v + 1];
  float a0 = 0.f, a1 = 0.f, a2 = 0.f, a3 = 0.f;
  const ushort* hb = h + base * 256 + lane * 4;
  for (int i = s; i < e; ++i) {
    int u = nbr[i];
    float m = 1.0f;
    if (mask) { float mv = mask[eid[i]]; m = half ? (1.0f - mv) : mv; }
    ushort4 hv = *(const ushort4*)(hb + (size_t)u * 256);
    a0 += m * b2f(hv.x); a1 += m * b2f(hv.y); a2 += m * b2f(hv.z); a3 += m * b2f(hv.w);
  }
  ushort4 o; o.x = f2b(a0); o.y = f2b(a1); o.z = f2b(a2); o.w = f2b(a3);
  *(ushort4*)(G + (size_t)node * 256 + lane * 4) = o;
}

// ------------------------------------------------------------------ MFMA GEMM
// C[M x NCOL] = sum_seg A_seg[M x 256](bf16) @ W_seg[NCOL x 256]^T(bf16, row stride WST)
// EPI 0: bias + relu + BN -> bf16 out ; EPI 1: + bias -> f32 out ; EPI 2: f32 out
template <int NSEG, int EPI, int NCOL, int WST>
__global__ __launch_bounds__(256) void mfma_gemm_k(
    const ushort* __restrict__ A0, const ushort* __restrict__ A1, const ushort* __restrict__ A2,
    const ushort* __restrict__ W0, const ushort* __restrict__ W1, const ushort* __restrict__ W2,
    void* __restrict__ Cout, int M,
    const float* __restrict__ bias, const float* __restrict__ gma,
    const float* __restrict__ bta, const float* __restrict__ rmn, const float* __restrict__ rvr) {
  const int tid = threadIdx.x;
  const int wid = tid >> 6, lane = tid & 63;
  const int wr = wid >> 1, wc = wid & 1;  // 2x2 waves, 64x64 per wave
  const int m0 = blockIdx.x * 128 + wr * 64;
  const int n0 = blockIdx.y * 128 + wc * 64;
  const int lrow = lane & 15;
  const int klo = (lane >> 4) * 8;
  v4f acc[4][4] = {};
  int rowA[4];
#pragma unroll
  for (int fi = 0; fi < 4; ++fi) {
    int r = m0 + fi * 16 + lrow;
    rowA[fi] = (r < M) ? r : (M - 1);
  }
  const ushort* As_[3] = {A0, A1, A2};
  const ushort* Ws_[3] = {W0, W1, W2};
  for (int seg = 0; seg < NSEG; ++seg) {
    const ushort* Ap = As_[seg];
    const ushort* Wp = Ws_[seg];
#pragma unroll 2
    for (int kc = 0; kc < 256; kc += 32) {
      v8s a[4], b[4];
#pragma unroll
      for (int fi = 0; fi < 4; ++fi)
        a[fi] = *(const v8s*)(Ap + (size_t)rowA[fi] * 256 + kc + klo);
#pragma unroll
      for (int fj = 0; fj < 4; ++fj)
        b[fj] = *(const v8s*)(Wp + (size_t)(n0 + fj * 16 + lrow) * WST + kc + klo);
#pragma unroll
      for (int fi = 0; fi < 4; ++fi)
#pragma unroll
        for (int fj = 0; fj < 4; ++fj)
          acc[fi][fj] = __builtin_amdgcn_mfma_f32_16x16x32_bf16(a[fi], b[fj], acc[fi][fj], 0, 0, 0);
    }
  }
#pragma unroll
  for (int fj = 0; fj < 4; ++fj) {
    const int col = n0 + fj * 16 + lrow;
    float bsv = 0.f, g_ = 0.f, bt_ = 0.f, rm_ = 0.f, rv_ = 0.f;
    if (EPI == 0) {
      bsv = bias[col]; g_ = gma[col]; bt_ = bta[col]; rm_ = rmn[col];
      rv_ = rsqrtf(rvr[col] + EPSc);
    } else if (EPI == 1) {
      bsv = bias[col];
    }
#pragma unroll
    for (int fi = 0; fi < 4; ++fi) {
      const int rbase = m0 + fi * 16 + ((lane >> 4) << 2);
#pragma unroll
      for (int r = 0; r < 4; ++r) {
        int row = rbase + r;
        if (row >= M) continue;
        float v = acc[fi][fj][r];
        if (EPI == 0) {
          v += bsv;
          v = fmaxf(v, 0.f);
          v = (v - rm_) * rv_ * g_ + bt_;
          ((ushort*)Cout)[(size_t)row * NCOL + col] = f2b(v);
        } else {
          if (EPI == 1) v += bsv;
          ((float*)Cout)[(size_t)row * NCOL + col] = v;
        }
      }
    }
  }
}

// ------------------------------------------------------------------ edge MLP (fp32, after per-node projection)
__global__ __launch_bounds__(256) void edge_mlp2_k(const float* __restrict__ Psrc,
                                                   const float* __restrict__ Pdst,
                                                   const int* __restrict__ src, const int* __restrict__ dst,
                                                   const float* __restrict__ W2, const float* __restrict__ b2,
                                                   const float* __restrict__ w3, const float* __restrict__ b3,
                                                   float* __restrict__ maskOut) {
  __shared__ float h1s[64][129];
  __shared__ float red[16][64];
  __shared__ int s_src[64], s_dst[64];
  const int tid = threadIdx.x;
  const int e0 = blockIdx.x * 64;
  if (tid < 64) { s_src[tid] = src[e0 + tid]; s_dst[tid] = dst[e0 + tid]; }
  __syncthreads();
  {
    const int ei = tid >> 2, q = tid & 3;
    const float* ps = Psrc + (size_t)s_src[ei] * 128 + q * 32;
    const float* pd = Pdst + (size_t)s_dst[ei] * 128 + q * 32;
#pragma unroll
    for (int j4 = 0; j4 < 8; ++j4) {
      float4 a = *(const float4*)(ps + j4 * 4);
      float4 b = *(const float4*)(pd + j4 * 4);
      float* hp = &h1s[ei][q * 32 + j4 * 4];
      hp[0] = fmaxf(a.x + b.x, 0.f);
      hp[1] = fmaxf(a.y + b.y, 0.f);
      hp[2] = fmaxf(a.z + b.z, 0.f);
      hp[3] = fmaxf(a.w + b.w, 0.f);
    }
  }
  __syncthreads();
  const int eg = tid & 15;
  const int og = tid >> 4;
  float acc[4][4] = {};
  for (int k4 = 0; k4 < 32; ++k4) {
    float4 w[4];
#pragma unroll
    for (int j = 0; j < 4; ++j)
      w[j] = *(const float4*)(W2 + (size_t)(og * 4 + j) * 128 + (k4 << 2));
#pragma unroll
    for (int i = 0; i < 4; ++i) {
      const float* hp = &h1s[eg * 4 + i][k4 << 2];
      float h0 = hp[0], h1 = hp[1], h2 = hp[2], h3 = hp[3];
#pragma unroll
      for (int j = 0; j < 4; ++j)
        acc[i][j] += h0 * w[j].x + h1 * w[j].y + h2 * w[j].z + h3 * w[j].w;
    }
  }
  float b2v[4], w3v[4];
#pragma unroll
  for (int j = 0; j < 4; ++j) { b2v[j] = b2[og * 4 + j]; w3v[j] = w3[og * 4 + j]; }
#pragma unroll
  for (int i = 0; i < 4; ++i) {
    float p = 0.f;
#pragma unroll
    for (int j = 0; j < 4; ++j) p += fmaxf(acc[i][j] + b2v[j], 0.f) * w3v[j];
    red[og][eg * 4 + i] = p;
  }
  __syncthreads();
  if (tid < 64) {
    float s = b3[0];
#pragma unroll
    for (int g = 0; g < 16; ++g) s += red[g][tid];
    maskOut[e0 + tid] = 1.0f / (1.0f + expf(-s));
  }
}

// ------------------------------------------------------------------ pooling / tails
__global__ __launch_bounds__(256) void gemb_sum_k(const ushort* __restrict__ h, const int* __restrict__ batch,
                                                  float* __restrict__ gsum, int batched) {
  const int halfBlocks = Nn / 16;
  int blk = blockIdx.x;
  int half = 0, bi = blk;
  if (batched) { half = (blk >= halfBlocks) ? 1 : 0; bi = blk - half * halfBlocks; }
  const int v0 = bi * 16;
  const int tid = threadIdx.x;
  const size_t base = (size_t)half * Nn;
  float* out = gsum + (size_t)half * (Bb * Dd);
  float acc = 0.0f;
  int curb = batch[v0];
  for (int i = 0; i < 16; ++i) {
    int v = v0 + i;
    int b = batch[v];
    if (b != curb) { atomicAdd(&out[curb * Dd + tid], acc); acc = 0.0f; curb = b; }
    acc += b2f(h[(base + v) * Dd + tid]);
  }
  atomicAdd(&out[curb * Dd + tid], acc);
}

__global__ void gemb_scale_k(float* __restrict__ g, const float* __restrict__ cntf) {
  int blk = blockIdx.x;
  int b = blk & 15;
  g[blk * Dd + threadIdx.x] /= fmaxf(cntf[b], 1.0f);
}

__global__ void anchor_k(const float* __restrict__ g, const float* __restrict__ anchors,
                         float* __restrict__ s_out) {
  __shared__ float red4[4];
  const int b = blockIdx.x, tid = threadIdx.x;
  float gv = g[b * Dd + tid];
  float total = 0.0f;
  for (int k = 0; k < 6; ++k) {
    float d = gv - anchors[k * Dd + tid];
    float v = d * d;
    for (int o = 32; o > 0; o >>= 1) v += __shfl_xor(v, o);
    if ((tid & 63) == 0) red4[tid >> 6] = v;
    __syncthreads();
    if (tid == 0) total += sqrtf(red4[0] + red4[1] + red4[2] + red4[3]);
    __syncthreads();
  }
  if (tid == 0) s_out[b] = total;
}

__global__ void logits_k(const float* __restrict__ gsub, const float* __restrict__ gcomp,
                         const float* __restrict__ Wc, const float* __restrict__ bc,
                         float* __restrict__ outL) {
  __shared__ float red4[4];
  const int blk = blockIdx.x;
  const int set = blk >> 4, b = blk & 15;
  const float* g = set ? gcomp : gsub;
  const int tid = threadIdx.x;
  float gv = g[b * Dd + tid];
  for (int c = 0; c < 2; ++c) {
    float v = gv * Wc[c * Dd + tid];
    for (int o = 32; o > 0; o >>= 1) v += __shfl_xor(v, o);
    if ((tid & 63) == 0) red4[tid >> 6] = v;
    __syncthreads();
    if (tid == 0) outL[set * 32 + b * 2 + c] = red4[0] + red4[1] + red4[2] + red4[3] + bc[c];
    __syncthreads();
  }
}

__global__ void final_k(const float* __restrict__ L, const int* __restrict__ labels,
                        const float* __restrict__ s_orig, const float* __restrict__ s_sub,
                        float* __restrict__ out) {
  if (threadIdx.x == 0) {
    float Lp = 0, Lu = 0, La = 0;
    const float u = 0.5f;
    for (int b = 0; b < 16; ++b) {
      float l0 = L[b * 2], l1 = L[b * 2 + 1];
      float m = fmaxf(l0, l1);
      float lse = m + logf(expf(l0 - m) + expf(l1 - m));
      int lab = labels[b];
      Lp += -((lab ? l1 : l0) - lse);
      float c0 = L[32 + b * 2], c1 = L[32 + b * 2 + 1];
      float mm = fmaxf(c0, c1);
      float e0 = expf(c0 - mm), e1 = expf(c1 - mm), Z = e0 + e1;
      Lu += u * (logf(u) - logf(e0 / Z + 1e-8f)) + u * (logf(u) - logf(e1 / Z + 1e-8f));
      float dd = s_sub[b] - s_orig[b];
      La += dd * dd;
    }
    Lp /= 16.0f; Lu /= 16.0f; La /= 16.0f;
    out[0] = 0.5f * Lp + 0.3f * Lu + 0.2f * La;
    out[1] = Lp; out[2] = Lu; out[3] = La;
  }
}

// ------------------------------------------------------------------ host
extern "C" void kernel_launch(void* const* d_in, const int* in_sizes, int n_in,
                              void* d_out, int out_size, void* d_ws, size_t ws_size,
                              hipStream_t stream) {
  (void)in_sizes; (void)n_in; (void)out_size; (void)ws_size;
  const float* x    = (const float*)d_in[0];
  const int* ei     = (const int*)d_in[1];
  const int* batch  = (const int*)d_in[2];
  const int* labels = (const int*)d_in[3];
  const float* mw1 = (const float*)d_in[4];
  const float* mb1 = (const float*)d_in[5];
  const float* mw2 = (const float*)d_in[6];
  const float* mb2 = (const float*)d_in[7];
  const float* mw3 = (const float*)d_in[8];
  const float* mb3 = (const float*)d_in[9];
  const float* Ws   = (const float*)d_in[10];
  const float* bs   = (const float*)d_in[11];
  const float* Win  = (const float*)d_in[12];
  const float* bin_ = (const float*)d_in[13];
  const float* Wout = (const float*)d_in[14];
  const float* bout = (const float*)d_in[15];
  const float* gma  = (const float*)d_in[16];
  const float* bta  = (const float*)d_in[17];
  const float* rmn  = (const float*)d_in[18];
  const float* rvr  = (const float*)d_in[19];
  const float* anchors = (const float*)d_in[20];
  const float* Wc   = (const float*)d_in[21];
  const float* bc   = (const float*)d_in[22];
  const int* srcp = ei;
  const int* dstp = ei + Ee;

  const size_t NE = (size_t)2 * Nn * Dd;  // bf16 buffer elems
  ushort* hA   = (ushort*)d_ws;
  ushort* hB   = hA + NE;
  ushort* Gin  = hB + NE;
  ushort* Gout = Gin + NE;
  ushort* Wsb   = Gout + NE;      // 3*65536
  ushort* Winb  = Wsb + 3 * 65536;
  ushort* Woutb = Winb + 3 * 65536;
  ushort* mw1b  = Woutb + 3 * 65536;  // 65536
  float* Psrc = (float*)(mw1b + 65536);
  float* Pdst = Psrc + (size_t)Nn * 128;
  int* off_in   = (int*)(Pdst + (size_t)Nn * 128);
  int* off_out  = off_in + (Nn + 1);
  int* cur_in   = off_out + (Nn + 1);
  int* cur_out  = cur_in + Nn;
  int* in_src   = cur_out + Nn;
  int* in_eid   = in_src + Ee;
  int* out_dst  = in_eid + Ee;
  int* out_eid  = out_dst + Ee;
  int* counts_in  = out_eid + Ee;
  int* counts_out = counts_in + Nn;
  float* cntf      = (float*)(counts_out + Nn);
  float* gemb_orig = cntf + Bb;
  float* gemb_sub  = gemb_orig + Bb * Dd;
  float* gemb_comp = gemb_sub + Bb * Dd;
  float* bsum    = gemb_comp + Bb * Dd;
  float* s_orig  = bsum + 3 * Dd;
  float* s_sub   = s_orig + Bb;
  float* logitsb = s_sub + Bb;

  float* outF = (float*)d_out;
  float* maskp = outF + 4;

  const size_t zero_bytes = (char*)bsum - (char*)counts_in;
  hipMemsetAsync(counts_in, 0, zero_bytes, stream);

  hist_edges_k<<<(Ee + 255) / 256, 256, 0, stream>>>(srcp, dstp, counts_in, counts_out);
  cnt_batch_k<<<1, 64, 0, stream>>>(batch, cntf);
  scan_k<<<1, 1024, 0, stream>>>(counts_in, counts_out, off_in, off_out, cur_in, cur_out);
  scatter_k<<<(Ee + 255) / 256, 256, 0, stream>>>(srcp, dstp, cur_in, cur_out, in_src, in_eid, out_dst, out_eid);
  prep_bsum_k<<<1, 256, 0, stream>>>(bs, bin_, bout, bsum);

  // weight conversion to bf16
  c_f2b_k<<<(3 * 65536 + 255) / 256, 256, 0, stream>>>(Ws, Wsb, 3 * 65536);
  c_f2b_k<<<(3 * 65536 + 255) / 256, 256, 0, stream>>>(Win, Winb, 3 * 65536);
  c_f2b_k<<<(3 * 65536 + 255) / 256, 256, 0, stream>>>(Wout, Woutb, 3 * 65536);
  c_f2b_k<<<(65536 + 255) / 256, 256, 0, stream>>>(mw1, mw1b, 65536);

  auto enc_layer = [&](ushort* curb, ushort* nxtb, int M, int batched, const float* mptr, int l) {
    aggb_k<<<(M + 3) / 4, 256, 0, stream>>>(curb, Gin, off_in, in_src, in_eid, mptr, batched);
    aggb_k<<<(M + 3) / 4, 256, 0, stream>>>(curb, Gout, off_out, out_dst, out_eid, mptr, batched);
    dim3 gg((M + 127) / 128, 2);
    mfma_gemm_k<3, 0, 256, 256><<<gg, 256, 0, stream>>>(
        curb, Gin, Gout, Wsb + (size_t)l * 65536, Winb + (size_t)l * 65536, Woutb + (size_t)l * 65536,
        nxtb, M, bsum + l * 256, gma + l * 256, bta + l * 256, rmn + l * 256, rvr + l * 256);
  };

  // ---- encoder #1 (ones mask), M = N
  ushort* p = hA;
  ushort* q = hB;
  copyxb_k<<<(Nn * Dd / 4 + 255) / 256, 256, 0, stream>>>(x, p, 0);
  for (int l = 0; l < 3; ++l) { enc_layer(p, q, Nn, 0, nullptr, l); ushort* t = p; p = q; q = t; }
  // p = node_emb (bf16)

  gemb_sum_k<<<Nn / 16, 256, 0, stream>>>(p, batch, gemb_orig, 0);
  gemb_scale_k<<<Bb, 256, 0, stream>>>(gemb_orig, cntf);
  anchor_k<<<Bb, 256, 0, stream>>>(gemb_orig, anchors, s_orig);

  // ---- per-node projections for edge MLP layer 1 (b1 folded into Psrc)
  {
    dim3 gp((Nn + 127) / 128, 1);
    mfma_gemm_k<1, 1, 128, 512><<<gp, 256, 0, stream>>>(
        p, nullptr, nullptr, mw1b, nullptr, nullptr, Psrc, Nn, mb1, nullptr, nullptr, nullptr, nullptr);
    mfma_gemm_k<1, 2, 128, 512><<<gp, 256, 0, stream>>>(
        p, nullptr, nullptr, mw1b + 256, nullptr, nullptr, Pdst, Nn, nullptr, nullptr, nullptr, nullptr, nullptr);
  }
  edge_mlp2_k<<<Ee / 64, 256, 0, stream>>>(Psrc, Pdst, srcp, dstp, mw2, mb2, mw3, mb3, maskp);

  // ---- batched encoders #2/#3 (mask & 1-mask), M = 2N
  copyxb_k<<<(Nn * Dd / 4 + 255) / 256, 256, 0, stream>>>(x, q, 1);
  { ushort* t = p; p = q; q = t; }  // p = [x; x]
  for (int l = 0; l < 3; ++l) { enc_layer(p, q, 2 * Nn, 1, maskp, l); ushort* t = p; p = q; q = t; }
  // p = [h_sub; h_comp]

  gemb_sum_k<<<2 * (Nn / 16), 256, 0, stream>>>(p, batch, gemb_sub, 1);
  gemb_scale_k<<<2 * Bb, 256, 0, stream>>>(gemb_sub, cntf);
  anchor_k<<<Bb, 256, 0, stream>>>(gemb_sub, anchors, s_sub);
  logits_k<<<2 * Bb, 256, 0, stream>>>(gemb_sub, gemb_comp, Wc, bc, logitsb);
  final_k<<<1, 64, 0, stream>>>(logitsb, labels, s_orig, s_sub, outF);
}

// Round 6
// 1505.177 us; speedup vs baseline: 3.2091x; 1.1003x over previous
//
#include <hip/hip_runtime.h>
#include <hip/hip_bf16.h>

constexpr int Nn = 20000;
constexpr int Ee = 320000;
constexpr int Dd = 256;
constexpr int Bb = 16;
constexpr float EPSc = 1e-5f;

using v8s = __attribute__((ext_vector_type(8))) short;
using v4f = __attribute__((ext_vector_type(4))) float;

__device__ __forceinline__ float b2f(ushort u) { return __uint_as_float(((unsigned)u) << 16); }
__device__ __forceinline__ ushort f2b(float f) {
  __hip_bfloat16 h = __float2bfloat16(f);
  return *reinterpret_cast<ushort*>(&h);
}

// ------------------------------------------------------------------ graph prep
__global__ void hist_edges_k(const int* __restrict__ src, const int* __restrict__ dst,
                             int* __restrict__ cin, int* __restrict__ cout) {
  int e = blockIdx.x * 256 + threadIdx.x;
  if (e < Ee) { atomicAdd(&cin[dst[e]], 1); atomicAdd(&cout[src[e]], 1); }
}

__global__ void cnt_batch_k(const int* __restrict__ batch, float* __restrict__ cntf) {
  int b = threadIdx.x;
  if (b < Bb) {
    int lo = 0, hi = Nn;
    while (lo < hi) { int mid = (lo + hi) >> 1; if (batch[mid] < b) lo = mid + 1; else hi = mid; }
    int lb = lo;
    lo = 0; hi = Nn;
    while (lo < hi) { int mid = (lo + hi) >> 1; if (batch[mid] <= b) lo = mid + 1; else hi = mid; }
    cntf[b] = (float)(lo - lb);
  }
}

__global__ __launch_bounds__(1024) void scan_k(const int* __restrict__ cin,
                                               const int* __restrict__ cout,
                                               int* __restrict__ off_in, int* __restrict__ off_out,
                                               int* __restrict__ cur_in, int* __restrict__ cur_out) {
  __shared__ int part[1024];
  const int tid = threadIdx.x;
  for (int which = 0; which < 2; ++which) {
    const int* cnt = which ? cout : cin;
    int* off = which ? off_out : off_in;
    int* curp = which ? cur_out : cur_in;
    int vals[20];
    int base = tid * 20;
    int local = 0;
#pragma unroll
    for (int i = 0; i < 20; ++i) {
      int idx = base + i;
      int v = (idx < Nn) ? cnt[idx] : 0;
      vals[i] = v; local += v;
    }
    part[tid] = local;
    __syncthreads();
    for (int ofs = 1; ofs < 1024; ofs <<= 1) {
      int t = (tid >= ofs) ? part[tid - ofs] : 0;
      __syncthreads();
      part[tid] += t;
      __syncthreads();
    }
    int run = part[tid] - local;
#pragma unroll
    for (int i = 0; i < 20; ++i) {
      int idx = base + i;
      if (idx < Nn) { off[idx] = run; curp[idx] = run; run += vals[i]; }
    }
    if (tid == 0) off[Nn] = Ee;
    __syncthreads();
  }
}

__global__ void scatter_k(const int* __restrict__ src, const int* __restrict__ dst,
                          int* __restrict__ cur_in, int* __restrict__ cur_out,
                          int* __restrict__ in_src, int* __restrict__ in_eid,
                          int* __restrict__ out_dst, int* __restrict__ out_eid) {
  int e = blockIdx.x * 256 + threadIdx.x;
  if (e < Ee) {
    int d = dst[e], s = src[e];
    int p = atomicAdd(&cur_in[d], 1);  in_src[p] = s;  in_eid[p] = e;
    int q = atomicAdd(&cur_out[s], 1); out_dst[q] = d; out_eid[q] = e;
  }
}

__global__ void prep_bsum_k(const float* __restrict__ bs, const float* __restrict__ bin,
                            const float* __restrict__ bout, float* __restrict__ bsum) {
  int t = threadIdx.x;
  for (int l = 0; l < 3; ++l) bsum[l * 256 + t] = bs[l * 256 + t] + bin[l * 256 + t] + bout[l * 256 + t];
}

__global__ void copyxb_k(const float* __restrict__ x, ushort* __restrict__ h, int dup) {
  const int n4 = Nn * Dd / 4;
  int i = blockIdx.x * 256 + threadIdx.x;
  if (i < n4) {
    float4 v = ((const float4*)x)[i];
    ushort4 o; o.x = f2b(v.x); o.y = f2b(v.y); o.z = f2b(v.z); o.w = f2b(v.w);
    ((ushort4*)h)[i] = o;
    if (dup) ((ushort4*)h)[i + n4] = o;
  }
}

__global__ void c_f2b_k(const float* __restrict__ s, ushort* __restrict__ d, int n) {
  int i = blockIdx.x * 256 + threadIdx.x;
  if (i < n) d[i] = f2b(s[i]);
}

// Wcombb[256][256]: rows 0-127 = mw1[r][0:256], rows 128-255 = mw1[r-128][256:512]
// W2b[64][128] bf16 ; bcomb[256] = [mb1, 0]
__global__ void prep_mlp_k(const float* __restrict__ mw1, const float* __restrict__ mb1,
                           const float* __restrict__ mw2,
                           ushort* __restrict__ Wcombb, ushort* __restrict__ W2b,
                           float* __restrict__ bcomb) {
  int i = blockIdx.x * 256 + threadIdx.x;
  if (i < 65536) {
    int r = i >> 8, c = i & 255;
    float v = (r < 128) ? mw1[r * 512 + c] : mw1[(r - 128) * 512 + 256 + c];
    Wcombb[i] = f2b(v);
  }
  if (i < 8192) W2b[i] = f2b(mw2[i]);
  if (i < 256) bcomb[i] = (i < 128) ? mb1[i] : 0.f;
}

// ------------------------------------------------------------------ aggregation (bf16, both directions in one launch)
__global__ __launch_bounds__(256) void aggb2_k(const ushort* __restrict__ h,
                                               ushort* __restrict__ Gin, ushort* __restrict__ Gout,
                                               const int* __restrict__ off_in, const int* __restrict__ in_src,
                                               const int* __restrict__ in_eid,
                                               const int* __restrict__ off_out, const int* __restrict__ out_dst,
                                               const int* __restrict__ out_eid,
                                               const float* __restrict__ mask, int batched) {
  const int Mtot = batched ? 2 * Nn : Nn;
  const int nb = (Mtot + 3) >> 2;
  int blk = blockIdx.x;
  const int dir = (blk >= nb) ? 1 : 0;
  blk -= dir * nb;
  const int* offs = dir ? off_out : off_in;
  const int* nbr  = dir ? out_dst : in_src;
  const int* eid  = dir ? out_eid : in_eid;
  ushort* G = dir ? Gout : Gin;
  const int grp = threadIdx.x >> 6;
  const int lane = threadIdx.x & 63;
  const int node = blk * 4 + grp;
  if (node >= Mtot) return;
  const int half = (batched && node >= Nn) ? 1 : 0;
  const int v = node - half * Nn;
  const size_t base = (size_t)half * Nn;
  const int s = offs[v], e = offs[v + 1];
  float a0 = 0.f, a1 = 0.f, a2 = 0.f, a3 = 0.f;
  const ushort* hb = h + base * 256 + lane * 4;
  for (int i = s; i < e; ++i) {
    int u = nbr[i];
    float m = 1.0f;
    if (mask) { float mv = mask[eid[i]]; m = half ? (1.0f - mv) : mv; }
    ushort4 hv = *(const ushort4*)(hb + (size_t)u * 256);
    a0 += m * b2f(hv.x); a1 += m * b2f(hv.y); a2 += m * b2f(hv.z); a3 += m * b2f(hv.w);
  }
  ushort4 o; o.x = f2b(a0); o.y = f2b(a1); o.z = f2b(a2); o.w = f2b(a3);
  *(ushort4*)(G + (size_t)node * 256 + lane * 4) = o;
}

// ------------------------------------------------------------------ MFMA GEMM
// C[M x NCOL] = sum_seg A_seg[M x 256](bf16) @ W_seg[NCOL x 256]^T(bf16, row stride WST)
// EPI 0: bias+relu+BN -> bf16 ; EPI 1: +bias -> f32 ; EPI 2: f32 ; EPI 3: +bias -> bf16
template <int NSEG, int EPI, int NCOL, int WST>
__global__ __launch_bounds__(256) void mfma_gemm_k(
    const ushort* __restrict__ A0, const ushort* __restrict__ A1, const ushort* __restrict__ A2,
    const ushort* __restrict__ W0, const ushort* __restrict__ W1, const ushort* __restrict__ W2,
    void* __restrict__ Cout, int M,
    const float* __restrict__ bias, const float* __restrict__ gma,
    const float* __restrict__ bta, const float* __restrict__ rmn, const float* __restrict__ rvr) {
  const int tid = threadIdx.x;
  const int wid = tid >> 6, lane = tid & 63;
  const int wr = wid >> 1, wc = wid & 1;
  const int m0 = blockIdx.x * 128 + wr * 64;
  const int n0 = blockIdx.y * 128 + wc * 64;
  const int lrow = lane & 15;
  const int klo = (lane >> 4) * 8;
  v4f acc[4][4] = {};
  int rowA[4];
#pragma unroll
  for (int fi = 0; fi < 4; ++fi) {
    int r = m0 + fi * 16 + lrow;
    rowA[fi] = (r < M) ? r : (M - 1);
  }
  const ushort* As_[3] = {A0, A1, A2};
  const ushort* Ws_[3] = {W0, W1, W2};
  for (int seg = 0; seg < NSEG; ++seg) {
    const ushort* Ap = As_[seg];
    const ushort* Wp = Ws_[seg];
#pragma unroll 2
    for (int kc = 0; kc < 256; kc += 32) {
      v8s a[4], b[4];
#pragma unroll
      for (int fi = 0; fi < 4; ++fi)
        a[fi] = *(const v8s*)(Ap + (size_t)rowA[fi] * 256 + kc + klo);
#pragma unroll
      for (int fj = 0; fj < 4; ++fj)
        b[fj] = *(const v8s*)(Wp + (size_t)(n0 + fj * 16 + lrow) * WST + kc + klo);
#pragma unroll
      for (int fi = 0; fi < 4; ++fi)
#pragma unroll
        for (int fj = 0; fj < 4; ++fj)
          acc[fi][fj] = __builtin_amdgcn_mfma_f32_16x16x32_bf16(a[fi], b[fj], acc[fi][fj], 0, 0, 0);
    }
  }
#pragma unroll
  for (int fj = 0; fj < 4; ++fj) {
    const int col = n0 + fj * 16 + lrow;
    float bsv = 0.f, g_ = 0.f, bt_ = 0.f, rm_ = 0.f, rv_ = 0.f;
    if (EPI == 0) {
      bsv = bias[col]; g_ = gma[col]; bt_ = bta[col]; rm_ = rmn[col];
      rv_ = rsqrtf(rvr[col] + EPSc);
    } else if (EPI == 1 || EPI == 3) {
      bsv = bias[col];
    }
#pragma unroll
    for (int fi = 0; fi < 4; ++fi) {
      const int rbase = m0 + fi * 16 + ((lane >> 4) << 2);
#pragma unroll
      for (int r = 0; r < 4; ++r) {
        int row = rbase + r;
        if (row >= M) continue;
        float v = acc[fi][fj][r];
        if (EPI == 0) {
          v += bsv;
          v = fmaxf(v, 0.f);
          v = (v - rm_) * rv_ * g_ + bt_;
          ((ushort*)Cout)[(size_t)row * NCOL + col] = f2b(v);
        } else if (EPI == 3) {
          v += bsv;
          ((ushort*)Cout)[(size_t)row * NCOL + col] = f2b(v);
        } else {
          if (EPI == 1) v += bsv;
          ((float*)Cout)[(size_t)row * NCOL + col] = v;
        }
      }
    }
  }
}

// ------------------------------------------------------------------ edge MLP: MFMA, no LDS
// P[n][0:128] = src-part (+b1), P[n][128:256] = dst-part. Per wave: 16 edges.
__global__ __launch_bounds__(256) void edge_mlp3_k(const ushort* __restrict__ P,
                                                   const int* __restrict__ src, const int* __restrict__ dst,
                                                   const ushort* __restrict__ W2b,
                                                   const float* __restrict__ b2, const float* __restrict__ w3,
                                                   const float* __restrict__ b3,
                                                   float* __restrict__ maskOut) {
  const int tid = threadIdx.x;
  const int w = tid >> 6, lane = tid & 63;
  const int e0 = blockIdx.x * 64 + w * 16;
  const int le = lane & 15;
  const int kq = lane >> 4;
  const int klo = kq * 8;
  const int eA = e0 + le;
  const int s_ = src[eA], d_ = dst[eA];
  const ushort* ps = P + (size_t)s_ * 256;
  const ushort* pd = P + (size_t)d_ * 256 + 128;
  v4f acc[4] = {};
#pragma unroll
  for (int kc = 0; kc < 128; kc += 32) {
    v8s as = *(const v8s*)(ps + kc + klo);
    v8s ad = *(const v8s*)(pd + kc + klo);
    v8s h;
#pragma unroll
    for (int j = 0; j < 8; ++j) {
      float v = fmaxf(b2f((ushort)as[j]) + b2f((ushort)ad[j]), 0.f);
      h[j] = (short)f2b(v);
    }
#pragma unroll
    for (int fj = 0; fj < 4; ++fj) {
      v8s b = *(const v8s*)(W2b + (size_t)(fj * 16 + le) * 128 + kc + klo);
      acc[fj] = __builtin_amdgcn_mfma_f32_16x16x32_bf16(h, b, acc[fj], 0, 0, 0);
    }
  }
  // epilogue: lane holds out-col j = fj*16+le for edges (kq*4 + r)
  float b2v[4], w3v[4];
#pragma unroll
  for (int fj = 0; fj < 4; ++fj) { b2v[fj] = b2[fj * 16 + le]; w3v[fj] = w3[fj * 16 + le]; }
  const float b3v = b3[0];
#pragma unroll
  for (int r = 0; r < 4; ++r) {
    float val = 0.f;
#pragma unroll
    for (int fj = 0; fj < 4; ++fj)
      val += fmaxf(acc[fj][r] + b2v[fj], 0.f) * w3v[fj];
    val += __shfl_xor(val, 1);
    val += __shfl_xor(val, 2);
    val += __shfl_xor(val, 4);
    val += __shfl_xor(val, 8);
    if (le == 0) {
      int er = e0 + kq * 4 + r;
      maskOut[er] = 1.0f / (1.0f + expf(-(val + b3v)));
    }
  }
}

// ------------------------------------------------------------------ pooling / tails
__global__ __launch_bounds__(256) void gemb_sum_k(const ushort* __restrict__ h, const int* __restrict__ batch,
                                                  float* __restrict__ gsum, int batched) {
  const int halfBlocks = Nn / 16;
  int blk = blockIdx.x;
  int half = 0, bi = blk;
  if (batched) { half = (blk >= halfBlocks) ? 1 : 0; bi = blk - half * halfBlocks; }
  const int v0 = bi * 16;
  const int tid = threadIdx.x;
  const size_t base = (size_t)half * Nn;
  float* out = gsum + (size_t)half * (Bb * Dd);
  float acc = 0.0f;
  int curb = batch[v0];
  for (int i = 0; i < 16; ++i) {
    int v = v0 + i;
    int b = batch[v];
    if (b != curb) { atomicAdd(&out[curb * Dd + tid], acc); acc = 0.0f; curb = b; }
    acc += b2f(h[(base + v) * Dd + tid]);
  }
  atomicAdd(&out[curb * Dd + tid], acc);
}

__global__ void gemb_scale_k(float* __restrict__ g, const float* __restrict__ cntf) {
  int blk = blockIdx.x;
  int b = blk & 15;
  g[blk * Dd + threadIdx.x] /= fmaxf(cntf[b], 1.0f);
}

__global__ void anchor_k(const float* __restrict__ g, const float* __restrict__ anchors,
                         float* __restrict__ s_out) {
  __shared__ float red4[4];
  const int b = blockIdx.x, tid = threadIdx.x;
  float gv = g[b * Dd + tid];
  float total = 0.0f;
  for (int k = 0; k < 6; ++k) {
    float d = gv - anchors[k * Dd + tid];
    float v = d * d;
    for (int o = 32; o > 0; o >>= 1) v += __shfl_xor(v, o);
    if ((tid & 63) == 0) red4[tid >> 6] = v;
    __syncthreads();
    if (tid == 0) total += sqrtf(red4[0] + red4[1] + red4[2] + red4[3]);
    __syncthreads();
  }
  if (tid == 0) s_out[b] = total;
}

__global__ void logits_k(const float* __restrict__ gsub, const float* __restrict__ gcomp,
                         const float* __restrict__ Wc, const float* __restrict__ bc,
                         float* __restrict__ outL) {
  __shared__ float red4[4];
  const int blk = blockIdx.x;
  const int set = blk >> 4, b = blk & 15;
  const float* g = set ? gcomp : gsub;
  const int tid = threadIdx.x;
  float gv = g[b * Dd + tid];
  for (int c = 0; c < 2; ++c) {
    float v = gv * Wc[c * Dd + tid];
    for (int o = 32; o > 0; o >>= 1) v += __shfl_xor(v, o);
    if ((tid & 63) == 0) red4[tid >> 6] = v;
    __syncthreads();
    if (tid == 0) outL[set * 32 + b * 2 + c] = red4[0] + red4[1] + red4[2] + red4[3] + bc[c];
    __syncthreads();
  }
}

__global__ void final_k(const float* __restrict__ L, const int* __restrict__ labels,
                        const float* __restrict__ s_orig, const float* __restrict__ s_sub,
                        float* __restrict__ out) {
  if (threadIdx.x == 0) {
    float Lp = 0, Lu = 0, La = 0;
    const float u = 0.5f;
    for (int b = 0; b < 16; ++b) {
      float l0 = L[b * 2], l1 = L[b * 2 + 1];
      float m = fmaxf(l0, l1);
      float lse = m + logf(expf(l0 - m) + expf(l1 - m));
      int lab = labels[b];
      Lp += -((lab ? l1 : l0) - lse);
      float c0 = L[32 + b * 2], c1 = L[32 + b * 2 + 1];
      float mm = fmaxf(c0, c1);
      float e0 = expf(c0 - mm), e1 = expf(c1 - mm), Z = e0 + e1;
      Lu += u * (logf(u) - logf(e0 / Z + 1e-8f)) + u * (logf(u) - logf(e1 / Z + 1e-8f));
      float dd = s_sub[b] - s_orig[b];
      La += dd * dd;
    }
    Lp /= 16.0f; Lu /= 16.0f; La /= 16.0f;
    out[0] = 0.5f * Lp + 0.3f * Lu + 0.2f * La;
    out[1] = Lp; out[2] = Lu; out[3] = La;
  }
}

// ------------------------------------------------------------------ host
extern "C" void kernel_launch(void* const* d_in, const int* in_sizes, int n_in,
                              void* d_out, int out_size, void* d_ws, size_t ws_size,
                              hipStream_t stream) {
  (void)in_sizes; (void)n_in; (void)out_size; (void)ws_size;
  const float* x    = (const float*)d_in[0];
  const int* ei     = (const int*)d_in[1];
  const int* batch  = (const int*)d_in[2];
  const int* labels = (const int*)d_in[3];
  const float* mw1 = (const float*)d_in[4];
  const float* mb1 = (const float*)d_in[5];
  const float* mw2 = (const float*)d_in[6];
  const float* mb2 = (const float*)d_in[7];
  const float* mw3 = (const float*)d_in[8];
  const float* mb3 = (const float*)d_in[9];
  const float* Ws   = (const float*)d_in[10];
  const float* bs   = (const float*)d_in[11];
  const float* Win  = (const float*)d_in[12];
  const float* bin_ = (const float*)d_in[13];
  const float* Wout = (const float*)d_in[14];
  const float* bout = (const float*)d_in[15];
  const float* gma  = (const float*)d_in[16];
  const float* bta  = (const float*)d_in[17];
  const float* rmn  = (const float*)d_in[18];
  const float* rvr  = (const float*)d_in[19];
  const float* anchors = (const float*)d_in[20];
  const float* Wc   = (const float*)d_in[21];
  const float* bc   = (const float*)d_in[22];
  const int* srcp = ei;
  const int* dstp = ei + Ee;

  const size_t NE = (size_t)2 * Nn * Dd;
  ushort* hA   = (ushort*)d_ws;
  ushort* hB   = hA + NE;
  ushort* Gin  = hB + NE;
  ushort* Gout = Gin + NE;
  ushort* Wsb   = Gout + NE;
  ushort* Winb  = Wsb + 3 * 65536;
  ushort* Woutb = Winb + 3 * 65536;
  ushort* Wcombb = Woutb + 3 * 65536;  // 65536
  ushort* W2b    = Wcombb + 65536;     // 8192
  ushort* Pb     = W2b + 8192;         // Nn*256
  float* bcomb = (float*)(Pb + (size_t)Nn * 256);
  int* off_in   = (int*)(bcomb + 256);
  int* off_out  = off_in + (Nn + 1);
  int* cur_in   = off_out + (Nn + 1);
  int* cur_out  = cur_in + Nn;
  int* in_src   = cur_out + Nn;
  int* in_eid   = in_src + Ee;
  int* out_dst  = in_eid + Ee;
  int* out_eid  = out_dst + Ee;
  int* counts_in  = out_eid + Ee;
  int* counts_out = counts_in + Nn;
  float* cntf      = (float*)(counts_out + Nn);
  float* gemb_orig = cntf + Bb;
  float* gemb_sub  = gemb_orig + Bb * Dd;
  float* gemb_comp = gemb_sub + Bb * Dd;
  float* bsum    = gemb_comp + Bb * Dd;
  float* s_orig  = bsum + 3 * Dd;
  float* s_sub   = s_orig + Bb;
  float* logitsb = s_sub + Bb;

  float* outF = (float*)d_out;
  float* maskp = outF + 4;

  const size_t zero_bytes = (char*)bsum - (char*)counts_in;
  hipMemsetAsync(counts_in, 0, zero_bytes, stream);

  hist_edges_k<<<(Ee + 255) / 256, 256, 0, stream>>>(srcp, dstp, counts_in, counts_out);
  cnt_batch_k<<<1, 64, 0, stream>>>(batch, cntf);
  scan_k<<<1, 1024, 0, stream>>>(counts_in, counts_out, off_in, off_out, cur_in, cur_out);
  scatter_k<<<(Ee + 255) / 256, 256, 0, stream>>>(srcp, dstp, cur_in, cur_out, in_src, in_eid, out_dst, out_eid);
  prep_bsum_k<<<1, 256, 0, stream>>>(bs, bin_, bout, bsum);

  // weight conversion to bf16
  c_f2b_k<<<(3 * 65536 + 255) / 256, 256, 0, stream>>>(Ws, Wsb, 3 * 65536);
  c_f2b_k<<<(3 * 65536 + 255) / 256, 256, 0, stream>>>(Win, Winb, 3 * 65536);
  c_f2b_k<<<(3 * 65536 + 255) / 256, 256, 0, stream>>>(Wout, Woutb, 3 * 65536);
  prep_mlp_k<<<256, 256, 0, stream>>>(mw1, mb1, mw2, Wcombb, W2b, bcomb);

  auto enc_layer = [&](ushort* curb, ushort* nxtb, int M, int batched, const float* mptr, int l) {
    const int nb = (M + 3) / 4;
    aggb2_k<<<2 * nb, 256, 0, stream>>>(curb, Gin, Gout, off_in, in_src, in_eid,
                                        off_out, out_dst, out_eid, mptr, batched);
    dim3 gg((M + 127) / 128, 2);
    mfma_gemm_k<3, 0, 256, 256><<<gg, 256, 0, stream>>>(
        curb, Gin, Gout, Wsb + (size_t)l * 65536, Winb + (size_t)l * 65536, Woutb + (size_t)l * 65536,
        nxtb, M, bsum + l * 256, gma + l * 256, bta + l * 256, rmn + l * 256, rvr + l * 256);
  };

  // ---- encoder #1 (ones mask), M = N
  ushort* p = hA;
  ushort* q = hB;
  copyxb_k<<<(Nn * Dd / 4 + 255) / 256, 256, 0, stream>>>(x, p, 0);
  for (int l = 0; l < 3; ++l) { enc_layer(p, q, Nn, 0, nullptr, l); ushort* t = p; p = q; q = t; }
  // p = node_emb (bf16)

  gemb_sum_k<<<Nn / 16, 256, 0, stream>>>(p, batch, gemb_orig, 0);
  gemb_scale_k<<<Bb, 256, 0, stream>>>(gemb_orig, cntf);
  anchor_k<<<Bb, 256, 0, stream>>>(gemb_orig, anchors, s_orig);

  // ---- packed projection P = [emb@W1a^T + b1 | emb@W1b^T] (bf16)
  {
    dim3 gp((Nn + 127) / 128, 2);
    mfma_gemm_k<1, 3, 256, 256><<<gp, 256, 0, stream>>>(
        p, nullptr, nullptr, Wcombb, nullptr, nullptr, Pb, Nn, bcomb, nullptr, nullptr, nullptr, nullptr);
  }
  edge_mlp3_k<<<Ee / 64, 256, 0, stream>>>(Pb, srcp, dstp, W2b, mb2, mw3, mb3, maskp);

  // ---- batched encoders #2/#3 (mask & 1-mask), M = 2N
  copyxb_k<<<(Nn * Dd / 4 + 255) / 256, 256, 0, stream>>>(x, q, 1);
  { ushort* t = p; p = q; q = t; }  // p = [x; x]
  for (int l = 0; l < 3; ++l) { enc_layer(p, q, 2 * Nn, 1, maskp, l); ushort* t = p; p = q; q = t; }
  // p = [h_sub; h_comp]

  gemb_sum_k<<<2 * (Nn / 16), 256, 0, stream>>>(p, batch, gemb_sub, 1);
  gemb_scale_k<<<2 * Bb, 256, 0, stream>>>(gemb_sub, cntf);
  anchor_k<<<Bb, 256, 0, stream>>>(gemb_sub, anchors, s_sub);
  logits_k<<<2 * Bb, 256, 0, stream>>>(gemb_sub, gemb_comp, Wc, bc, logitsb);
  final_k<<<1, 64, 0, stream>>>(logitsb, labels, s_orig, s_sub, outF);
}

// Round 7
// 1052.623 us; speedup vs baseline: 4.5888x; 1.4299x over previous
//
#include <hip/hip_runtime.h>
#include <hip/hip_bf16.h>

constexpr int Nn = 20000;
constexpr int Ee = 320000;
constexpr int Dd = 256;
constexpr int Bb = 16;
constexpr float EPSc = 1e-5f;

using v8s = __attribute__((ext_vector_type(8))) short;
using v4f = __attribute__((ext_vector_type(4))) float;

__device__ __forceinline__ float b2f(ushort u) { return __uint_as_float(((unsigned)u) << 16); }
__device__ __forceinline__ ushort f2b(float f) {
  __hip_bfloat16 h = __float2bfloat16(f);
  return *reinterpret_cast<ushort*>(&h);
}

// ------------------------------------------------------------------ graph prep
__global__ void hist_edges_k(const int* __restrict__ src, const int* __restrict__ dst,
                             int* __restrict__ cin, int* __restrict__ cout) {
  int e = blockIdx.x * 256 + threadIdx.x;
  if (e < Ee) { atomicAdd(&cin[dst[e]], 1); atomicAdd(&cout[src[e]], 1); }
}

__global__ void cnt_batch_k(const int* __restrict__ batch, float* __restrict__ cntf) {
  int b = threadIdx.x;
  if (b < Bb) {
    int lo = 0, hi = Nn;
    while (lo < hi) { int mid = (lo + hi) >> 1; if (batch[mid] < b) lo = mid + 1; else hi = mid; }
    int lb = lo;
    lo = 0; hi = Nn;
    while (lo < hi) { int mid = (lo + hi) >> 1; if (batch[mid] <= b) lo = mid + 1; else hi = mid; }
    cntf[b] = (float)(lo - lb);
  }
}

__global__ __launch_bounds__(1024) void scan_k(const int* __restrict__ cin,
                                               const int* __restrict__ cout,
                                               int* __restrict__ off_in, int* __restrict__ off_out,
                                               int* __restrict__ cur_in, int* __restrict__ cur_out) {
  __shared__ int part[1024];
  const int tid = threadIdx.x;
  for (int which = 0; which < 2; ++which) {
    const int* cnt = which ? cout : cin;
    int* off = which ? off_out : off_in;
    int* curp = which ? cur_out : cur_in;
    int vals[20];
    int base = tid * 20;
    int local = 0;
#pragma unroll
    for (int i = 0; i < 20; ++i) {
      int idx = base + i;
      int v = (idx < Nn) ? cnt[idx] : 0;
      vals[i] = v; local += v;
    }
    part[tid] = local;
    __syncthreads();
    for (int ofs = 1; ofs < 1024; ofs <<= 1) {
      int t = (tid >= ofs) ? part[tid - ofs] : 0;
      __syncthreads();
      part[tid] += t;
      __syncthreads();
    }
    int run = part[tid] - local;
#pragma unroll
    for (int i = 0; i < 20; ++i) {
      int idx = base + i;
      if (idx < Nn) { off[idx] = run; curp[idx] = run; run += vals[i]; }
    }
    if (tid == 0) off[Nn] = Ee;
    __syncthreads();
  }
}

__global__ void scatter_k(const int* __restrict__ src, const int* __restrict__ dst,
                          int* __restrict__ cur_in, int* __restrict__ cur_out,
                          int* __restrict__ in_src, int* __restrict__ in_eid,
                          int* __restrict__ out_dst, int* __restrict__ out_eid) {
  int e = blockIdx.x * 256 + threadIdx.x;
  if (e < Ee) {
    int d = dst[e], s = src[e];
    int p = atomicAdd(&cur_in[d], 1);  in_src[p] = s;  in_eid[p] = e;
    int q = atomicAdd(&cur_out[s], 1); out_dst[q] = d; out_eid[q] = e;
  }
}

__global__ void prep_bsum_k(const float* __restrict__ bs, const float* __restrict__ bin,
                            const float* __restrict__ bout, float* __restrict__ bsum) {
  int t = threadIdx.x;
  for (int l = 0; l < 3; ++l) bsum[l * 256 + t] = bs[l * 256 + t] + bin[l * 256 + t] + bout[l * 256 + t];
}

__global__ void copyxb_k(const float* __restrict__ x, ushort* __restrict__ h, int dup) {
  const int n4 = Nn * Dd / 4;
  int i = blockIdx.x * 256 + threadIdx.x;
  if (i < n4) {
    float4 v = ((const float4*)x)[i];
    ushort4 o; o.x = f2b(v.x); o.y = f2b(v.y); o.z = f2b(v.z); o.w = f2b(v.w);
    ((ushort4*)h)[i] = o;
    if (dup) ((ushort4*)h)[i + n4] = o;
  }
}

__global__ void c_f2b_k(const float* __restrict__ s, ushort* __restrict__ d, int n) {
  int i = blockIdx.x * 256 + threadIdx.x;
  if (i < n) d[i] = f2b(s[i]);
}

// Wcombb[256][256]: rows 0-127 = mw1[r][0:256], rows 128-255 = mw1[r-128][256:512]
__global__ void prep_mlp_k(const float* __restrict__ mw1, const float* __restrict__ mb1,
                           const float* __restrict__ mw2,
                           ushort* __restrict__ Wcombb, ushort* __restrict__ W2b,
                           float* __restrict__ bcomb) {
  int i = blockIdx.x * 256 + threadIdx.x;
  if (i < 65536) {
    int r = i >> 8, c = i & 255;
    float v = (r < 128) ? mw1[r * 512 + c] : mw1[(r - 128) * 512 + 256 + c];
    Wcombb[i] = f2b(v);
  }
  if (i < 8192) W2b[i] = f2b(mw2[i]);
  if (i < 256) bcomb[i] = (i < 128) ? mb1[i] : 0.f;
}

// CSR-permuted masks (once per mask; reused by all 3 batched layers x 2 dirs)
__global__ void permmask_k(const float* __restrict__ mask,
                           const int* __restrict__ in_eid, const int* __restrict__ out_eid,
                           float* __restrict__ minA, float* __restrict__ moutA) {
  int i = blockIdx.x * 256 + threadIdx.x;
  if (i < Ee) { minA[i] = mask[in_eid[i]]; moutA[i] = mask[out_eid[i]]; }
}

// ------------------------------------------------------------------ aggregation v3
// 32 lanes/row (16B/lane), 8 nodes/block, 4-deep unrolled gather, streamed mask.
// half = node>=Nn selects h-table half and (1-m) weighting.
__global__ __launch_bounds__(256) void aggb3_k(const ushort* __restrict__ h,
                                               ushort* __restrict__ Gin, ushort* __restrict__ Gout,
                                               const int* __restrict__ off_in, const int* __restrict__ in_src,
                                               const int* __restrict__ off_out, const int* __restrict__ out_dst,
                                               const float* __restrict__ minA, const float* __restrict__ moutA,
                                               int Mtot) {
  const int nb = (Mtot + 7) >> 3;
  int blk = blockIdx.x;
  const int dir = (blk >= nb) ? 1 : 0;
  blk -= dir * nb;
  const int* offs = dir ? off_out : off_in;
  const int* nbr  = dir ? out_dst : in_src;
  const float* ma = dir ? moutA : minA;
  ushort* G = dir ? Gout : Gin;
  const int g = threadIdx.x >> 5;
  const int lane = threadIdx.x & 31;
  const int node = blk * 8 + g;
  if (node >= Mtot) return;
  const int half = (node >= Nn) ? 1 : 0;
  const int v = node - half * Nn;
  const int s = offs[v], e = offs[v + 1];
  const ushort* hb = h + (size_t)half * Nn * 256 + lane * 8;
  float acc[8] = {};
  int i = s;
  for (; i + 4 <= e; i += 4) {
    int u0 = nbr[i], u1 = nbr[i + 1], u2 = nbr[i + 2], u3 = nbr[i + 3];
    float m0 = 1.f, m1 = 1.f, m2 = 1.f, m3 = 1.f;
    if (ma) {
      m0 = ma[i]; m1 = ma[i + 1]; m2 = ma[i + 2]; m3 = ma[i + 3];
      if (half) { m0 = 1.f - m0; m1 = 1.f - m1; m2 = 1.f - m2; m3 = 1.f - m3; }
    }
    v8s r0 = *(const v8s*)(hb + (size_t)u0 * 256);
    v8s r1 = *(const v8s*)(hb + (size_t)u1 * 256);
    v8s r2 = *(const v8s*)(hb + (size_t)u2 * 256);
    v8s r3 = *(const v8s*)(hb + (size_t)u3 * 256);
#pragma unroll
    for (int j = 0; j < 8; ++j)
      acc[j] += m0 * b2f((ushort)r0[j]) + m1 * b2f((ushort)r1[j]) +
                m2 * b2f((ushort)r2[j]) + m3 * b2f((ushort)r3[j]);
  }
  for (; i < e; ++i) {
    int u = nbr[i];
    float m = 1.f;
    if (ma) { m = ma[i]; if (half) m = 1.f - m; }
    v8s r = *(const v8s*)(hb + (size_t)u * 256);
#pragma unroll
    for (int j = 0; j < 8; ++j) acc[j] += m * b2f((ushort)r[j]);
  }
  v8s o;
#pragma unroll
  for (int j = 0; j < 8; ++j) o[j] = (short)f2b(acc[j]);
  *(v8s*)(G + (size_t)node * 256 + lane * 8) = o;
}

// comp = ones - sub (elementwise, bf16)
__global__ void subb_k(const ushort* __restrict__ ones_, const ushort* __restrict__ sub_,
                       ushort* __restrict__ comp_, int n8) {
  int i = blockIdx.x * 256 + threadIdx.x;
  if (i < n8) {
    v8s a = ((const v8s*)ones_)[i];
    v8s b = ((const v8s*)sub_)[i];
    v8s o;
#pragma unroll
    for (int j = 0; j < 8; ++j) o[j] = (short)f2b(b2f((ushort)a[j]) - b2f((ushort)b[j]));
    ((v8s*)comp_)[i] = o;
  }
}

// ------------------------------------------------------------------ MFMA GEMM
template <int NSEG, int EPI, int NCOL, int WST>
__global__ __launch_bounds__(256) void mfma_gemm_k(
    const ushort* __restrict__ A0, const ushort* __restrict__ A1, const ushort* __restrict__ A2,
    const ushort* __restrict__ W0, const ushort* __restrict__ W1, const ushort* __restrict__ W2,
    void* __restrict__ Cout, int M,
    const float* __restrict__ bias, const float* __restrict__ gma,
    const float* __restrict__ bta, const float* __restrict__ rmn, const float* __restrict__ rvr) {
  const int tid = threadIdx.x;
  const int wid = tid >> 6, lane = tid & 63;
  const int wr = wid >> 1, wc = wid & 1;
  const int m0 = blockIdx.x * 128 + wr * 64;
  const int n0 = blockIdx.y * 128 + wc * 64;
  const int lrow = lane & 15;
  const int klo = (lane >> 4) * 8;
  v4f acc[4][4] = {};
  int rowA[4];
#pragma unroll
  for (int fi = 0; fi < 4; ++fi) {
    int r = m0 + fi * 16 + lrow;
    rowA[fi] = (r < M) ? r : (M - 1);
  }
  const ushort* As_[3] = {A0, A1, A2};
  const ushort* Ws_[3] = {W0, W1, W2};
  for (int seg = 0; seg < NSEG; ++seg) {
    const ushort* Ap = As_[seg];
    const ushort* Wp = Ws_[seg];
#pragma unroll 2
    for (int kc = 0; kc < 256; kc += 32) {
      v8s a[4], b[4];
#pragma unroll
      for (int fi = 0; fi < 4; ++fi)
        a[fi] = *(const v8s*)(Ap + (size_t)rowA[fi] * 256 + kc + klo);
#pragma unroll
      for (int fj = 0; fj < 4; ++fj)
        b[fj] = *(const v8s*)(Wp + (size_t)(n0 + fj * 16 + lrow) * WST + kc + klo);
#pragma unroll
      for (int fi = 0; fi < 4; ++fi)
#pragma unroll
        for (int fj = 0; fj < 4; ++fj)
          acc[fi][fj] = __builtin_amdgcn_mfma_f32_16x16x32_bf16(a[fi], b[fj], acc[fi][fj], 0, 0, 0);
    }
  }
#pragma unroll
  for (int fj = 0; fj < 4; ++fj) {
    const int col = n0 + fj * 16 + lrow;
    float bsv = 0.f, g_ = 0.f, bt_ = 0.f, rm_ = 0.f, rv_ = 0.f;
    if (EPI == 0) {
      bsv = bias[col]; g_ = gma[col]; bt_ = bta[col]; rm_ = rmn[col];
      rv_ = rsqrtf(rvr[col] + EPSc);
    } else if (EPI == 1 || EPI == 3) {
      bsv = bias[col];
    }
#pragma unroll
    for (int fi = 0; fi < 4; ++fi) {
      const int rbase = m0 + fi * 16 + ((lane >> 4) << 2);
#pragma unroll
      for (int r = 0; r < 4; ++r) {
        int row = rbase + r;
        if (row >= M) continue;
        float v = acc[fi][fj][r];
        if (EPI == 0) {
          v += bsv;
          v = fmaxf(v, 0.f);
          v = (v - rm_) * rv_ * g_ + bt_;
          ((ushort*)Cout)[(size_t)row * NCOL + col] = f2b(v);
        } else if (EPI == 3) {
          v += bsv;
          ((ushort*)Cout)[(size_t)row * NCOL + col] = f2b(v);
        } else {
          if (EPI == 1) v += bsv;
          ((float*)Cout)[(size_t)row * NCOL + col] = v;
        }
      }
    }
  }
}

// ------------------------------------------------------------------ edge MLP: MFMA, no LDS
__global__ __launch_bounds__(256) void edge_mlp3_k(const ushort* __restrict__ P,
                                                   const int* __restrict__ src, const int* __restrict__ dst,
                                                   const ushort* __restrict__ W2b,
                                                   const float* __restrict__ b2, const float* __restrict__ w3,
                                                   const float* __restrict__ b3,
                                                   float* __restrict__ maskOut) {
  const int tid = threadIdx.x;
  const int w = tid >> 6, lane = tid & 63;
  const int e0 = blockIdx.x * 64 + w * 16;
  const int le = lane & 15;
  const int kq = lane >> 4;
  const int klo = kq * 8;
  const int eA = e0 + le;
  const int s_ = src[eA], d_ = dst[eA];
  const ushort* ps = P + (size_t)s_ * 256;
  const ushort* pd = P + (size_t)d_ * 256 + 128;
  v4f acc[4] = {};
#pragma unroll
  for (int kc = 0; kc < 128; kc += 32) {
    v8s as = *(const v8s*)(ps + kc + klo);
    v8s ad = *(const v8s*)(pd + kc + klo);
    v8s h;
#pragma unroll
    for (int j = 0; j < 8; ++j) {
      float v = fmaxf(b2f((ushort)as[j]) + b2f((ushort)ad[j]), 0.f);
      h[j] = (short)f2b(v);
    }
#pragma unroll
    for (int fj = 0; fj < 4; ++fj) {
      v8s b = *(const v8s*)(W2b + (size_t)(fj * 16 + le) * 128 + kc + klo);
      acc[fj] = __builtin_amdgcn_mfma_f32_16x16x32_bf16(h, b, acc[fj], 0, 0, 0);
    }
  }
  float b2v[4], w3v[4];
#pragma unroll
  for (int fj = 0; fj < 4; ++fj) { b2v[fj] = b2[fj * 16 + le]; w3v[fj] = w3[fj * 16 + le]; }
  const float b3v = b3[0];
#pragma unroll
  for (int r = 0; r < 4; ++r) {
    float val = 0.f;
#pragma unroll
    for (int fj = 0; fj < 4; ++fj)
      val += fmaxf(acc[fj][r] + b2v[fj], 0.f) * w3v[fj];
    val += __shfl_xor(val, 1);
    val += __shfl_xor(val, 2);
    val += __shfl_xor(val, 4);
    val += __shfl_xor(val, 8);
    if (le == 0) {
      int er = e0 + kq * 4 + r;
      maskOut[er] = 1.0f / (1.0f + expf(-(val + b3v)));
    }
  }
}

// ------------------------------------------------------------------ pooling / tails
__global__ __launch_bounds__(256) void gemb_sum_k(const ushort* __restrict__ h, const int* __restrict__ batch,
                                                  float* __restrict__ gsum, int batched) {
  const int halfBlocks = Nn / 16;
  int blk = blockIdx.x;
  int half = 0, bi = blk;
  if (batched) { half = (blk >= halfBlocks) ? 1 : 0; bi = blk - half * halfBlocks; }
  const int v0 = bi * 16;
  const int tid = threadIdx.x;
  const size_t base = (size_t)half * Nn;
  float* out = gsum + (size_t)half * (Bb * Dd);
  float acc = 0.0f;
  int curb = batch[v0];
  for (int i = 0; i < 16; ++i) {
    int v = v0 + i;
    int b = batch[v];
    if (b != curb) { atomicAdd(&out[curb * Dd + tid], acc); acc = 0.0f; curb = b; }
    acc += b2f(h[(base + v) * Dd + tid]);
  }
  atomicAdd(&out[curb * Dd + tid], acc);
}

__global__ void gemb_scale_k(float* __restrict__ g, const float* __restrict__ cntf) {
  int blk = blockIdx.x;
  int b = blk & 15;
  g[blk * Dd + threadIdx.x] /= fmaxf(cntf[b], 1.0f);
}

__global__ void anchor_k(const float* __restrict__ g, const float* __restrict__ anchors,
                         float* __restrict__ s_out) {
  __shared__ float red4[4];
  const int b = blockIdx.x, tid = threadIdx.x;
  float gv = g[b * Dd + tid];
  float total = 0.0f;
  for (int k = 0; k < 6; ++k) {
    float d = gv - anchors[k * Dd + tid];
    float v = d * d;
    for (int o = 32; o > 0; o >>= 1) v += __shfl_xor(v, o);
    if ((tid & 63) == 0) red4[tid >> 6] = v;
    __syncthreads();
    if (tid == 0) total += sqrtf(red4[0] + red4[1] + red4[2] + red4[3]);
    __syncthreads();
  }
  if (tid == 0) s_out[b] = total;
}

__global__ void logits_k(const float* __restrict__ gsub, const float* __restrict__ gcomp,
                         const float* __restrict__ Wc, const float* __restrict__ bc,
                         float* __restrict__ outL) {
  __shared__ float red4[4];
  const int blk = blockIdx.x;
  const int set = blk >> 4, b = blk & 15;
  const float* g = set ? gcomp : gsub;
  const int tid = threadIdx.x;
  float gv = g[b * Dd + tid];
  for (int c = 0; c < 2; ++c) {
    float v = gv * Wc[c * Dd + tid];
    for (int o = 32; o > 0; o >>= 1) v += __shfl_xor(v, o);
    if ((tid & 63) == 0) red4[tid >> 6] = v;
    __syncthreads();
    if (tid == 0) outL[set * 32 + b * 2 + c] = red4[0] + red4[1] + red4[2] + red4[3] + bc[c];
    __syncthreads();
  }
}

__global__ void final_k(const float* __restrict__ L, const int* __restrict__ labels,
                        const float* __restrict__ s_orig, const float* __restrict__ s_sub,
                        float* __restrict__ out) {
  if (threadIdx.x == 0) {
    float Lp = 0, Lu = 0, La = 0;
    const float u = 0.5f;
    for (int b = 0; b < 16; ++b) {
      float l0 = L[b * 2], l1 = L[b * 2 + 1];
      float m = fmaxf(l0, l1);
      float lse = m + logf(expf(l0 - m) + expf(l1 - m));
      int lab = labels[b];
      Lp += -((lab ? l1 : l0) - lse);
      float c0 = L[32 + b * 2], c1 = L[32 + b * 2 + 1];
      float mm = fmaxf(c0, c1);
      float e0 = expf(c0 - mm), e1 = expf(c1 - mm), Z = e0 + e1;
      Lu += u * (logf(u) - logf(e0 / Z + 1e-8f)) + u * (logf(u) - logf(e1 / Z + 1e-8f));
      float dd = s_sub[b] - s_orig[b];
      La += dd * dd;
    }
    Lp /= 16.0f; Lu /= 16.0f; La /= 16.0f;
    out[0] = 0.5f * Lp + 0.3f * Lu + 0.2f * La;
    out[1] = Lp; out[2] = Lu; out[3] = La;
  }
}

// ------------------------------------------------------------------ host
extern "C" void kernel_launch(void* const* d_in, const int* in_sizes, int n_in,
                              void* d_out, int out_size, void* d_ws, size_t ws_size,
                              hipStream_t stream) {
  (void)in_sizes; (void)n_in; (void)out_size; (void)ws_size;
  const float* x    = (const float*)d_in[0];
  const int* ei     = (const int*)d_in[1];
  const int* batch  = (const int*)d_in[2];
  const int* labels = (const int*)d_in[3];
  const float* mw1 = (const float*)d_in[4];
  const float* mb1 = (const float*)d_in[5];
  const float* mw2 = (const float*)d_in[6];
  const float* mb2 = (const float*)d_in[7];
  const float* mw3 = (const float*)d_in[8];
  const float* mb3 = (const float*)d_in[9];
  const float* Ws   = (const float*)d_in[10];
  const float* bs   = (const float*)d_in[11];
  const float* Win  = (const float*)d_in[12];
  const float* bin_ = (const float*)d_in[13];
  const float* Wout = (const float*)d_in[14];
  const float* bout = (const float*)d_in[15];
  const float* gma  = (const float*)d_in[16];
  const float* bta  = (const float*)d_in[17];
  const float* rmn  = (const float*)d_in[18];
  const float* rvr  = (const float*)d_in[19];
  const float* anchors = (const float*)d_in[20];
  const float* Wc   = (const float*)d_in[21];
  const float* bc   = (const float*)d_in[22];
  const int* srcp = ei;
  const int* dstp = ei + Ee;

  const size_t NE = (size_t)2 * Nn * Dd;
  const size_t NH = (size_t)Nn * Dd;  // one-half table elems
  ushort* hA   = (ushort*)d_ws;
  ushort* hB   = hA + NE;
  ushort* Gin  = hB + NE;
  ushort* Gout = Gin + NE;
  ushort* Ginx = Gout + NE;  // ones-agg of x (in), NH
  ushort* Goutx = Ginx + NH; // ones-agg of x (out), NH
  ushort* Wsb   = Goutx + NH;
  ushort* Winb  = Wsb + 3 * 65536;
  ushort* Woutb = Winb + 3 * 65536;
  ushort* Wcombb = Woutb + 3 * 65536;
  ushort* W2b    = Wcombb + 65536;
  ushort* Pb     = W2b + 8192;  // Nn*256
  float* bcomb = (float*)(Pb + NH);
  float* minA  = bcomb + 256;   // Ee
  float* moutA = minA + Ee;     // Ee
  int* off_in   = (int*)(moutA + Ee);
  int* off_out  = off_in + (Nn + 1);
  int* cur_in   = off_out + (Nn + 1);
  int* cur_out  = cur_in + Nn;
  int* in_src   = cur_out + Nn;
  int* in_eid   = in_src + Ee;
  int* out_dst  = in_eid + Ee;
  int* out_eid  = out_dst + Ee;
  int* counts_in  = out_eid + Ee;
  int* counts_out = counts_in + Nn;
  float* cntf      = (float*)(counts_out + Nn);
  float* gemb_orig = cntf + Bb;
  float* gemb_sub  = gemb_orig + Bb * Dd;
  float* gemb_comp = gemb_sub + Bb * Dd;
  float* bsum    = gemb_comp + Bb * Dd;
  float* s_orig  = bsum + 3 * Dd;
  float* s_sub   = s_orig + Bb;
  float* logitsb = s_sub + Bb;

  float* outF = (float*)d_out;
  float* maskp = outF + 4;

  const size_t zero_bytes = (char*)bsum - (char*)counts_in;
  hipMemsetAsync(counts_in, 0, zero_bytes, stream);

  hist_edges_k<<<(Ee + 255) / 256, 256, 0, stream>>>(srcp, dstp, counts_in, counts_out);
  cnt_batch_k<<<1, 64, 0, stream>>>(batch, cntf);
  scan_k<<<1, 1024, 0, stream>>>(counts_in, counts_out, off_in, off_out, cur_in, cur_out);
  scatter_k<<<(Ee + 255) / 256, 256, 0, stream>>>(srcp, dstp, cur_in, cur_out, in_src, in_eid, out_dst, out_eid);
  prep_bsum_k<<<1, 256, 0, stream>>>(bs, bin_, bout, bsum);

  c_f2b_k<<<(3 * 65536 + 255) / 256, 256, 0, stream>>>(Ws, Wsb, 3 * 65536);
  c_f2b_k<<<(3 * 65536 + 255) / 256, 256, 0, stream>>>(Win, Winb, 3 * 65536);
  c_f2b_k<<<(3 * 65536 + 255) / 256, 256, 0, stream>>>(Wout, Woutb, 3 * 65536);
  prep_mlp_k<<<256, 256, 0, stream>>>(mw1, mb1, mw2, Wcombb, W2b, bcomb);

  auto run_agg = [&](ushort* curb, ushort* GinT, ushort* GoutT, int Mtot,
                     const float* minp, const float* moutp) {
    const int nb = (Mtot + 7) / 8;
    aggb3_k<<<2 * nb, 256, 0, stream>>>(curb, GinT, GoutT, off_in, in_src, off_out, out_dst,
                                        minp, moutp, Mtot);
  };
  auto run_gemm = [&](ushort* curb, ushort* GinT, ushort* GoutT, ushort* nxtb, int M, int l) {
    dim3 gg((M + 127) / 128, 2);
    mfma_gemm_k<3, 0, 256, 256><<<gg, 256, 0, stream>>>(
        curb, GinT, GoutT, Wsb + (size_t)l * 65536, Winb + (size_t)l * 65536, Woutb + (size_t)l * 65536,
        nxtb, M, bsum + l * 256, gma + l * 256, bta + l * 256, rmn + l * 256, rvr + l * 256);
  };

  // ---- encoder #1 (ones mask), M = N; layer 0 aggs preserved in Ginx/Goutx
  ushort* p = hA;
  ushort* q = hB;
  copyxb_k<<<(Nn * Dd / 4 + 255) / 256, 256, 0, stream>>>(x, p, 0);
  run_agg(p, Ginx, Goutx, Nn, nullptr, nullptr);
  run_gemm(p, Ginx, Goutx, q, Nn, 0);
  { ushort* t = p; p = q; q = t; }
  for (int l = 1; l < 3; ++l) {
    run_agg(p, Gin, Gout, Nn, nullptr, nullptr);
    run_gemm(p, Gin, Gout, q, Nn, l);
    ushort* t = p; p = q; q = t;
  }
  // p = node_emb (bf16)

  gemb_sum_k<<<Nn / 16, 256, 0, stream>>>(p, batch, gemb_orig, 0);
  gemb_scale_k<<<Bb, 256, 0, stream>>>(gemb_orig, cntf);
  anchor_k<<<Bb, 256, 0, stream>>>(gemb_orig, anchors, s_orig);

  // ---- packed projection P = [emb@W1a^T + b1 | emb@W1b^T]
  {
    dim3 gp((Nn + 127) / 128, 2);
    mfma_gemm_k<1, 3, 256, 256><<<gp, 256, 0, stream>>>(
        p, nullptr, nullptr, Wcombb, nullptr, nullptr, Pb, Nn, bcomb, nullptr, nullptr, nullptr, nullptr);
  }
  edge_mlp3_k<<<Ee / 64, 256, 0, stream>>>(Pb, srcp, dstp, W2b, mb2, mw3, mb3, maskp);
  permmask_k<<<(Ee + 255) / 256, 256, 0, stream>>>(maskp, in_eid, out_eid, minA, moutA);

  // ---- batched encoders #2/#3 (mask & 1-mask), M = 2N
  copyxb_k<<<(Nn * Dd / 4 + 255) / 256, 256, 0, stream>>>(x, q, 1);
  { ushort* t = p; p = q; q = t; }  // p = [x; x]
  // layer 0: gather sub half only; comp = ones - sub
  {
    run_agg(p, Gin, Gout, Nn, minA, moutA);
    const int n8 = Nn * Dd / 8;
    subb_k<<<(n8 + 255) / 256, 256, 0, stream>>>(Ginx, Gin, Gin + NH, n8);
    subb_k<<<(n8 + 255) / 256, 256, 0, stream>>>(Goutx, Gout, Gout + NH, n8);
    run_gemm(p, Gin, Gout, q, 2 * Nn, 0);
    ushort* t = p; p = q; q = t;
  }
  for (int l = 1; l < 3; ++l) {
    run_agg(p, Gin, Gout, 2 * Nn, minA, moutA);
    run_gemm(p, Gin, Gout, q, 2 * Nn, l);
    ushort* t = p; p = q; q = t;
  }
  // p = [h_sub; h_comp]

  gemb_sum_k<<<2 * (Nn / 16), 256, 0, stream>>>(p, batch, gemb_sub, 1);
  gemb_scale_k<<<2 * Bb, 256, 0, stream>>>(gemb_sub, cntf);
  anchor_k<<<Bb, 256, 0, stream>>>(gemb_sub, anchors, s_sub);
  logits_k<<<2 * Bb, 256, 0, stream>>>(gemb_sub, gemb_comp, Wc, bc, logitsb);
  final_k<<<1, 64, 0, stream>>>(logitsb, labels, s_orig, s_sub, outF);
}

// Round 8
// 987.993 us; speedup vs baseline: 4.8890x; 1.0654x over previous
//
#include <hip/hip_runtime.h>
#include <hip/hip_bf16.h>

constexpr int Nn = 20000;
constexpr int Ee = 320000;
constexpr int Dd = 256;
constexpr int Bb = 16;
constexpr float EPSc = 1e-5f;

using v8s = __attribute__((ext_vector_type(8))) short;
using v4f = __attribute__((ext_vector_type(4))) float;

__device__ __forceinline__ float b2f(ushort u) { return __uint_as_float(((unsigned)u) << 16); }
__device__ __forceinline__ ushort f2b(float f) {
  __hip_bfloat16 h = __float2bfloat16(f);
  return *reinterpret_cast<ushort*>(&h);
}

// ------------------------------------------------------------------ graph prep
__global__ void hist_edges_k(const int* __restrict__ src, const int* __restrict__ dst,
                             int* __restrict__ cin, int* __restrict__ cout) {
  int e = blockIdx.x * 256 + threadIdx.x;
  if (e < Ee) { atomicAdd(&cin[dst[e]], 1); atomicAdd(&cout[src[e]], 1); }
}

__global__ void cnt_batch_k(const int* __restrict__ batch, float* __restrict__ cntf) {
  int b = threadIdx.x;
  if (b < Bb) {
    int lo = 0, hi = Nn;
    while (lo < hi) { int mid = (lo + hi) >> 1; if (batch[mid] < b) lo = mid + 1; else hi = mid; }
    int lb = lo;
    lo = 0; hi = Nn;
    while (lo < hi) { int mid = (lo + hi) >> 1; if (batch[mid] <= b) lo = mid + 1; else hi = mid; }
    cntf[b] = (float)(lo - lb);
  }
}

__global__ __launch_bounds__(1024) void scan_k(const int* __restrict__ cin,
                                               const int* __restrict__ cout,
                                               int* __restrict__ off_in, int* __restrict__ off_out,
                                               int* __restrict__ cur_in, int* __restrict__ cur_out) {
  __shared__ int part[1024];
  const int tid = threadIdx.x;
  for (int which = 0; which < 2; ++which) {
    const int* cnt = which ? cout : cin;
    int* off = which ? off_out : off_in;
    int* curp = which ? cur_out : cur_in;
    int vals[20];
    int base = tid * 20;
    int local = 0;
#pragma unroll
    for (int i = 0; i < 20; ++i) {
      int idx = base + i;
      int v = (idx < Nn) ? cnt[idx] : 0;
      vals[i] = v; local += v;
    }
    part[tid] = local;
    __syncthreads();
    for (int ofs = 1; ofs < 1024; ofs <<= 1) {
      int t = (tid >= ofs) ? part[tid - ofs] : 0;
      __syncthreads();
      part[tid] += t;
      __syncthreads();
    }
    int run = part[tid] - local;
#pragma unroll
    for (int i = 0; i < 20; ++i) {
      int idx = base + i;
      if (idx < Nn) { off[idx] = run; curp[idx] = run; run += vals[i]; }
    }
    if (tid == 0) off[Nn] = Ee;
    __syncthreads();
  }
}

__global__ void scatter_k(const int* __restrict__ src, const int* __restrict__ dst,
                          int* __restrict__ cur_in, int* __restrict__ cur_out,
                          int* __restrict__ in_src, int* __restrict__ in_eid,
                          int* __restrict__ out_dst, int* __restrict__ out_eid) {
  int e = blockIdx.x * 256 + threadIdx.x;
  if (e < Ee) {
    int d = dst[e], s = src[e];
    int p = atomicAdd(&cur_in[d], 1);  in_src[p] = s;  in_eid[p] = e;
    int q = atomicAdd(&cur_out[s], 1); out_dst[q] = d; out_eid[q] = e;
  }
}

__global__ void prep_bsum_k(const float* __restrict__ bs, const float* __restrict__ bin,
                            const float* __restrict__ bout, float* __restrict__ bsum) {
  int t = threadIdx.x;
  for (int l = 0; l < 3; ++l) bsum[l * 256 + t] = bs[l * 256 + t] + bin[l * 256 + t] + bout[l * 256 + t];
}

__global__ void copyxb_k(const float* __restrict__ x, ushort* __restrict__ h, int dup) {
  const int n4 = Nn * Dd / 4;
  int i = blockIdx.x * 256 + threadIdx.x;
  if (i < n4) {
    float4 v = ((const float4*)x)[i];
    ushort4 o; o.x = f2b(v.x); o.y = f2b(v.y); o.z = f2b(v.z); o.w = f2b(v.w);
    ((ushort4*)h)[i] = o;
    if (dup) ((ushort4*)h)[i + n4] = o;
  }
}

__global__ void c_f2b_k(const float* __restrict__ s, ushort* __restrict__ d, int n) {
  int i = blockIdx.x * 256 + threadIdx.x;
  if (i < n) d[i] = f2b(s[i]);
}

// Wcombb[256][256]: rows 0-127 = mw1[r][0:256], rows 128-255 = mw1[r-128][256:512]
__global__ void prep_mlp_k(const float* __restrict__ mw1, const float* __restrict__ mb1,
                           const float* __restrict__ mw2,
                           ushort* __restrict__ Wcombb, ushort* __restrict__ W2b,
                           float* __restrict__ bcomb) {
  int i = blockIdx.x * 256 + threadIdx.x;
  if (i < 65536) {
    int r = i >> 8, c = i & 255;
    float v = (r < 128) ? mw1[r * 512 + c] : mw1[(r - 128) * 512 + 256 + c];
    Wcombb[i] = f2b(v);
  }
  if (i < 8192) W2b[i] = f2b(mw2[i]);
  if (i < 256) bcomb[i] = (i < 128) ? mb1[i] : 0.f;
}

__global__ void permmask_k(const float* __restrict__ mask,
                           const int* __restrict__ in_eid, const int* __restrict__ out_eid,
                           float* __restrict__ minA, float* __restrict__ moutA) {
  int i = blockIdx.x * 256 + threadIdx.x;
  if (i < Ee) { minA[i] = mask[in_eid[i]]; moutA[i] = mask[out_eid[i]]; }
}

// ------------------------------------------------------------------ aggregation v3
__global__ __launch_bounds__(256) void aggb3_k(const ushort* __restrict__ h,
                                               ushort* __restrict__ Gin, ushort* __restrict__ Gout,
                                               const int* __restrict__ off_in, const int* __restrict__ in_src,
                                               const int* __restrict__ off_out, const int* __restrict__ out_dst,
                                               const float* __restrict__ minA, const float* __restrict__ moutA,
                                               int Mtot) {
  const int nb = (Mtot + 7) >> 3;
  int blk = blockIdx.x;
  const int dir = (blk >= nb) ? 1 : 0;
  blk -= dir * nb;
  const int* offs = dir ? off_out : off_in;
  const int* nbr  = dir ? out_dst : in_src;
  const float* ma = dir ? moutA : minA;
  ushort* G = dir ? Gout : Gin;
  const int g = threadIdx.x >> 5;
  const int lane = threadIdx.x & 31;
  const int node = blk * 8 + g;
  if (node >= Mtot) return;
  const int half = (node >= Nn) ? 1 : 0;
  const int v = node - half * Nn;
  const int s = offs[v], e = offs[v + 1];
  const ushort* hb = h + (size_t)half * Nn * 256 + lane * 8;
  float acc[8] = {};
  int i = s;
  for (; i + 4 <= e; i += 4) {
    int u0 = nbr[i], u1 = nbr[i + 1], u2 = nbr[i + 2], u3 = nbr[i + 3];
    float m0 = 1.f, m1 = 1.f, m2 = 1.f, m3 = 1.f;
    if (ma) {
      m0 = ma[i]; m1 = ma[i + 1]; m2 = ma[i + 2]; m3 = ma[i + 3];
      if (half) { m0 = 1.f - m0; m1 = 1.f - m1; m2 = 1.f - m2; m3 = 1.f - m3; }
    }
    v8s r0 = *(const v8s*)(hb + (size_t)u0 * 256);
    v8s r1 = *(const v8s*)(hb + (size_t)u1 * 256);
    v8s r2 = *(const v8s*)(hb + (size_t)u2 * 256);
    v8s r3 = *(const v8s*)(hb + (size_t)u3 * 256);
#pragma unroll
    for (int j = 0; j < 8; ++j)
      acc[j] += m0 * b2f((ushort)r0[j]) + m1 * b2f((ushort)r1[j]) +
                m2 * b2f((ushort)r2[j]) + m3 * b2f((ushort)r3[j]);
  }
  for (; i < e; ++i) {
    int u = nbr[i];
    float m = 1.f;
    if (ma) { m = ma[i]; if (half) m = 1.f - m; }
    v8s r = *(const v8s*)(hb + (size_t)u * 256);
#pragma unroll
    for (int j = 0; j < 8; ++j) acc[j] += m * b2f((ushort)r[j]);
  }
  v8s o;
#pragma unroll
  for (int j = 0; j < 8; ++j) o[j] = (short)f2b(acc[j]);
  *(v8s*)(G + (size_t)node * 256 + lane * 8) = o;
}

// comp = ones - sub (elementwise, bf16)
__global__ void subb_k(const ushort* __restrict__ ones_, const ushort* __restrict__ sub_,
                       ushort* __restrict__ comp_, int n8) {
  int i = blockIdx.x * 256 + threadIdx.x;
  if (i < n8) {
    v8s a = ((const v8s*)ones_)[i];
    v8s b = ((const v8s*)sub_)[i];
    v8s o;
#pragma unroll
    for (int j = 0; j < 8; ++j) o[j] = (short)f2b(b2f((ushort)a[j]) - b2f((ushort)b[j]));
    ((v8s*)comp_)[i] = o;
  }
}

// ------------------------------------------------------------------ MFMA GEMM v2
// 64-row x 128-col block, 4 waves (each 32x64, 2x4 frags). bf16 out via LDS repack.
// EPI 0: bias+relu+BN ; EPI 3: +bias
template <int NSEG, int EPI, int NCOL, int WST>
__global__ __launch_bounds__(256) void mfma_gemm2_k(
    const ushort* __restrict__ A0, const ushort* __restrict__ A1, const ushort* __restrict__ A2,
    const ushort* __restrict__ W0, const ushort* __restrict__ W1, const ushort* __restrict__ W2,
    ushort* __restrict__ Cout, int M,
    const float* __restrict__ bias, const float* __restrict__ gma,
    const float* __restrict__ bta, const float* __restrict__ rmn, const float* __restrict__ rvr) {
  __shared__ ushort eplds[4][32][72];
  const int tid = threadIdx.x;
  const int wid = tid >> 6, lane = tid & 63;
  const int wr = wid & 1, wc = wid >> 1;
  const int m0 = blockIdx.x * 64 + wr * 32;
  const int n0 = blockIdx.y * 128 + wc * 64;
  const int lrow = lane & 15;
  const int klo = (lane >> 4) * 8;
  v4f acc[2][4] = {};
  int rowA[2];
#pragma unroll
  for (int fi = 0; fi < 2; ++fi) {
    int r = m0 + fi * 16 + lrow;
    rowA[fi] = (r < M) ? r : (M - 1);
  }
  const ushort* As_[3] = {A0, A1, A2};
  const ushort* Ws_[3] = {W0, W1, W2};
  for (int seg = 0; seg < NSEG; ++seg) {
    const ushort* Ap = As_[seg];
    const ushort* Wp = Ws_[seg];
#pragma unroll 2
    for (int kc = 0; kc < 256; kc += 32) {
      v8s a[2], b[4];
#pragma unroll
      for (int fi = 0; fi < 2; ++fi)
        a[fi] = *(const v8s*)(Ap + (size_t)rowA[fi] * 256 + kc + klo);
#pragma unroll
      for (int fj = 0; fj < 4; ++fj)
        b[fj] = *(const v8s*)(Wp + (size_t)(n0 + fj * 16 + lrow) * WST + kc + klo);
#pragma unroll
      for (int fi = 0; fi < 2; ++fi)
#pragma unroll
        for (int fj = 0; fj < 4; ++fj)
          acc[fi][fj] = __builtin_amdgcn_mfma_f32_16x16x32_bf16(a[fi], b[fj], acc[fi][fj], 0, 0, 0);
    }
  }
  // epilogue -> LDS (wave-private region, no barrier needed)
#pragma unroll
  for (int fj = 0; fj < 4; ++fj) {
    const int col = n0 + fj * 16 + lrow;
    float bsv = 0.f, g_ = 0.f, bt_ = 0.f, rm_ = 0.f, rv_ = 0.f;
    if (EPI == 0) {
      bsv = bias[col]; g_ = gma[col]; bt_ = bta[col]; rm_ = rmn[col];
      rv_ = rsqrtf(rvr[col] + EPSc);
    } else {
      bsv = bias[col];
    }
#pragma unroll
    for (int fi = 0; fi < 2; ++fi) {
      const int rl0 = fi * 16 + ((lane >> 4) << 2);
#pragma unroll
      for (int r = 0; r < 4; ++r) {
        float v = acc[fi][fj][r];
        v += bsv;
        if (EPI == 0) {
          v = fmaxf(v, 0.f);
          v = (v - rm_) * rv_ * g_ + bt_;
        }
        eplds[wid][rl0 + r][fj * 16 + lrow] = f2b(v);
      }
    }
  }
  // coalesced 16B stores
#pragma unroll
  for (int i = 0; i < 4; ++i) {
    const int rl = (lane >> 2) + (i & 1) * 16;
    const int oct = (lane & 3) + (i >> 1) * 4;
    v8s val = *(const v8s*)&eplds[wid][rl][oct * 8];
    const int grow = m0 + rl;
    if (grow < M)
      *(v8s*)(Cout + (size_t)grow * NCOL + n0 + oct * 8) = val;
  }
}

// ------------------------------------------------------------------ edge MLP: MFMA, no LDS
__global__ __launch_bounds__(256) void edge_mlp3_k(const ushort* __restrict__ P,
                                                   const int* __restrict__ src, const int* __restrict__ dst,
                                                   const ushort* __restrict__ W2b,
                                                   const float* __restrict__ b2, const float* __restrict__ w3,
                                                   const float* __restrict__ b3,
                                                   float* __restrict__ maskOut) {
  const int tid = threadIdx.x;
  const int w = tid >> 6, lane = tid & 63;
  const int e0 = blockIdx.x * 64 + w * 16;
  const int le = lane & 15;
  const int kq = lane >> 4;
  const int klo = kq * 8;
  const int eA = e0 + le;
  const int s_ = src[eA], d_ = dst[eA];
  const ushort* ps = P + (size_t)s_ * 256;
  const ushort* pd = P + (size_t)d_ * 256 + 128;
  v4f acc[4] = {};
#pragma unroll
  for (int kc = 0; kc < 128; kc += 32) {
    v8s as = *(const v8s*)(ps + kc + klo);
    v8s ad = *(const v8s*)(pd + kc + klo);
    v8s h;
#pragma unroll
    for (int j = 0; j < 8; ++j) {
      float v = fmaxf(b2f((ushort)as[j]) + b2f((ushort)ad[j]), 0.f);
      h[j] = (short)f2b(v);
    }
#pragma unroll
    for (int fj = 0; fj < 4; ++fj) {
      v8s b = *(const v8s*)(W2b + (size_t)(fj * 16 + le) * 128 + kc + klo);
      acc[fj] = __builtin_amdgcn_mfma_f32_16x16x32_bf16(h, b, acc[fj], 0, 0, 0);
    }
  }
  float b2v[4], w3v[4];
#pragma unroll
  for (int fj = 0; fj < 4; ++fj) { b2v[fj] = b2[fj * 16 + le]; w3v[fj] = w3[fj * 16 + le]; }
  const float b3v = b3[0];
#pragma unroll
  for (int r = 0; r < 4; ++r) {
    float val = 0.f;
#pragma unroll
    for (int fj = 0; fj < 4; ++fj)
      val += fmaxf(acc[fj][r] + b2v[fj], 0.f) * w3v[fj];
    val += __shfl_xor(val, 1);
    val += __shfl_xor(val, 2);
    val += __shfl_xor(val, 4);
    val += __shfl_xor(val, 8);
    if (le == 0) {
      int er = e0 + kq * 4 + r;
      maskOut[er] = 1.0f / (1.0f + expf(-(val + b3v)));
    }
  }
}

// ------------------------------------------------------------------ pooling / tails
__global__ __launch_bounds__(256) void gemb_sum_k(const ushort* __restrict__ h, const int* __restrict__ batch,
                                                  float* __restrict__ gsum, int batched) {
  const int halfBlocks = Nn / 16;
  int blk = blockIdx.x;
  int half = 0, bi = blk;
  if (batched) { half = (blk >= halfBlocks) ? 1 : 0; bi = blk - half * halfBlocks; }
  const int v0 = bi * 16;
  const int tid = threadIdx.x;
  const size_t base = (size_t)half * Nn;
  float* out = gsum + (size_t)half * (Bb * Dd);
  float acc = 0.0f;
  int curb = batch[v0];
  for (int i = 0; i < 16; ++i) {
    int v = v0 + i;
    int b = batch[v];
    if (b != curb) { atomicAdd(&out[curb * Dd + tid], acc); acc = 0.0f; curb = b; }
    acc += b2f(h[(base + v) * Dd + tid]);
  }
  atomicAdd(&out[curb * Dd + tid], acc);
}

__global__ void gemb_scale_k(float* __restrict__ g, const float* __restrict__ cntf) {
  int blk = blockIdx.x;
  int b = blk & 15;
  g[blk * Dd + threadIdx.x] /= fmaxf(cntf[b], 1.0f);
}

__global__ void anchor_k(const float* __restrict__ g, const float* __restrict__ anchors,
                         float* __restrict__ s_out) {
  __shared__ float red4[4];
  const int b = blockIdx.x, tid = threadIdx.x;
  float gv = g[b * Dd + tid];
  float total = 0.0f;
  for (int k = 0; k < 6; ++k) {
    float d = gv - anchors[k * Dd + tid];
    float v = d * d;
    for (int o = 32; o > 0; o >>= 1) v += __shfl_xor(v, o);
    if ((tid & 63) == 0) red4[tid >> 6] = v;
    __syncthreads();
    if (tid == 0) total += sqrtf(red4[0] + red4[1] + red4[2] + red4[3]);
    __syncthreads();
  }
  if (tid == 0) s_out[b] = total;
}

__global__ void logits_k(const float* __restrict__ gsub, const float* __restrict__ gcomp,
                         const float* __restrict__ Wc, const float* __restrict__ bc,
                         float* __restrict__ outL) {
  __shared__ float red4[4];
  const int blk = blockIdx.x;
  const int set = blk >> 4, b = blk & 15;
  const float* g = set ? gcomp : gsub;
  const int tid = threadIdx.x;
  float gv = g[b * Dd + tid];
  for (int c = 0; c < 2; ++c) {
    float v = gv * Wc[c * Dd + tid];
    for (int o = 32; o > 0; o >>= 1) v += __shfl_xor(v, o);
    if ((tid & 63) == 0) red4[tid >> 6] = v;
    __syncthreads();
    if (tid == 0) outL[set * 32 + b * 2 + c] = red4[0] + red4[1] + red4[2] + red4[3] + bc[c];
    __syncthreads();
  }
}

__global__ void final_k(const float* __restrict__ L, const int* __restrict__ labels,
                        const float* __restrict__ s_orig, const float* __restrict__ s_sub,
                        float* __restrict__ out) {
  if (threadIdx.x == 0) {
    float Lp = 0, Lu = 0, La = 0;
    const float u = 0.5f;
    for (int b = 0; b < 16; ++b) {
      float l0 = L[b * 2], l1 = L[b * 2 + 1];
      float m = fmaxf(l0, l1);
      float lse = m + logf(expf(l0 - m) + expf(l1 - m));
      int lab = labels[b];
      Lp += -((lab ? l1 : l0) - lse);
      float c0 = L[32 + b * 2], c1 = L[32 + b * 2 + 1];
      float mm = fmaxf(c0, c1);
      float e0 = expf(c0 - mm), e1 = expf(c1 - mm), Z = e0 + e1;
      Lu += u * (logf(u) - logf(e0 / Z + 1e-8f)) + u * (logf(u) - logf(e1 / Z + 1e-8f));
      float dd = s_sub[b] - s_orig[b];
      La += dd * dd;
    }
    Lp /= 16.0f; Lu /= 16.0f; La /= 16.0f;
    out[0] = 0.5f * Lp + 0.3f * Lu + 0.2f * La;
    out[1] = Lp; out[2] = Lu; out[3] = La;
  }
}

// ------------------------------------------------------------------ host
extern "C" void kernel_launch(void* const* d_in, const int* in_sizes, int n_in,
                              void* d_out, int out_size, void* d_ws, size_t ws_size,
                              hipStream_t stream) {
  (void)in_sizes; (void)n_in; (void)out_size; (void)ws_size;
  const float* x    = (const float*)d_in[0];
  const int* ei     = (const int*)d_in[1];
  const int* batch  = (const int*)d_in[2];
  const int* labels = (const int*)d_in[3];
  const float* mw1 = (const float*)d_in[4];
  const float* mb1 = (const float*)d_in[5];
  const float* mw2 = (const float*)d_in[6];
  const float* mb2 = (const float*)d_in[7];
  const float* mw3 = (const float*)d_in[8];
  const float* mb3 = (const float*)d_in[9];
  const float* Ws   = (const float*)d_in[10];
  const float* bs   = (const float*)d_in[11];
  const float* Win  = (const float*)d_in[12];
  const float* bin_ = (const float*)d_in[13];
  const float* Wout = (const float*)d_in[14];
  const float* bout = (const float*)d_in[15];
  const float* gma  = (const float*)d_in[16];
  const float* bta  = (const float*)d_in[17];
  const float* rmn  = (const float*)d_in[18];
  const float* rvr  = (const float*)d_in[19];
  const float* anchors = (const float*)d_in[20];
  const float* Wc   = (const float*)d_in[21];
  const float* bc   = (const float*)d_in[22];
  const int* srcp = ei;
  const int* dstp = ei + Ee;

  const size_t NE = (size_t)2 * Nn * Dd;
  const size_t NH = (size_t)Nn * Dd;
  ushort* hA   = (ushort*)d_ws;
  ushort* hB   = hA + NE;
  ushort* Gin  = hB + NE;
  ushort* Gout = Gin + NE;
  ushort* Ginx = Gout + NE;
  ushort* Goutx = Ginx + NH;
  ushort* Wsb   = Goutx + NH;
  ushort* Winb  = Wsb + 3 * 65536;
  ushort* Woutb = Winb + 3 * 65536;
  ushort* Wcombb = Woutb + 3 * 65536;
  ushort* W2b    = Wcombb + 65536;
  ushort* Pb     = W2b + 8192;
  float* bcomb = (float*)(Pb + NH);
  float* minA  = bcomb + 256;
  float* moutA = minA + Ee;
  int* off_in   = (int*)(moutA + Ee);
  int* off_out  = off_in + (Nn + 1);
  int* cur_in   = off_out + (Nn + 1);
  int* cur_out  = cur_in + Nn;
  int* in_src   = cur_out + Nn;
  int* in_eid   = in_src + Ee;
  int* out_dst  = in_eid + Ee;
  int* out_eid  = out_dst + Ee;
  int* counts_in  = out_eid + Ee;
  int* counts_out = counts_in + Nn;
  float* cntf      = (float*)(counts_out + Nn);
  float* gemb_orig = cntf + Bb;
  float* gemb_sub  = gemb_orig + Bb * Dd;
  float* gemb_comp = gemb_sub + Bb * Dd;
  float* bsum    = gemb_comp + Bb * Dd;
  float* s_orig  = bsum + 3 * Dd;
  float* s_sub   = s_orig + Bb;
  float* logitsb = s_sub + Bb;

  float* outF = (float*)d_out;
  float* maskp = outF + 4;

  const size_t zero_bytes = (char*)bsum - (char*)counts_in;
  hipMemsetAsync(counts_in, 0, zero_bytes, stream);

  hist_edges_k<<<(Ee + 255) / 256, 256, 0, stream>>>(srcp, dstp, counts_in, counts_out);
  cnt_batch_k<<<1, 64, 0, stream>>>(batch, cntf);
  scan_k<<<1, 1024, 0, stream>>>(counts_in, counts_out, off_in, off_out, cur_in, cur_out);
  scatter_k<<<(Ee + 255) / 256, 256, 0, stream>>>(srcp, dstp, cur_in, cur_out, in_src, in_eid, out_dst, out_eid);
  prep_bsum_k<<<1, 256, 0, stream>>>(bs, bin_, bout, bsum);

  c_f2b_k<<<(3 * 65536 + 255) / 256, 256, 0, stream>>>(Ws, Wsb, 3 * 65536);
  c_f2b_k<<<(3 * 65536 + 255) / 256, 256, 0, stream>>>(Win, Winb, 3 * 65536);
  c_f2b_k<<<(3 * 65536 + 255) / 256, 256, 0, stream>>>(Wout, Woutb, 3 * 65536);
  prep_mlp_k<<<256, 256, 0, stream>>>(mw1, mb1, mw2, Wcombb, W2b, bcomb);

  auto run_agg = [&](ushort* curb, ushort* GinT, ushort* GoutT, int Mtot,
                     const float* minp, const float* moutp) {
    const int nb = (Mtot + 7) / 8;
    aggb3_k<<<2 * nb, 256, 0, stream>>>(curb, GinT, GoutT, off_in, in_src, off_out, out_dst,
                                        minp, moutp, Mtot);
  };
  auto run_gemm = [&](ushort* curb, ushort* GinT, ushort* GoutT, ushort* nxtb, int M, int l) {
    dim3 gg((M + 63) / 64, 2);
    mfma_gemm2_k<3, 0, 256, 256><<<gg, 256, 0, stream>>>(
        curb, GinT, GoutT, Wsb + (size_t)l * 65536, Winb + (size_t)l * 65536, Woutb + (size_t)l * 65536,
        nxtb, M, bsum + l * 256, gma + l * 256, bta + l * 256, rmn + l * 256, rvr + l * 256);
  };

  // ---- encoder #1 (ones mask), M = N; layer 0 aggs preserved in Ginx/Goutx
  ushort* p = hA;
  ushort* q = hB;
  copyxb_k<<<(Nn * Dd / 4 + 255) / 256, 256, 0, stream>>>(x, p, 0);
  run_agg(p, Ginx, Goutx, Nn, nullptr, nullptr);
  run_gemm(p, Ginx, Goutx, q, Nn, 0);
  { ushort* t = p; p = q; q = t; }
  for (int l = 1; l < 3; ++l) {
    run_agg(p, Gin, Gout, Nn, nullptr, nullptr);
    run_gemm(p, Gin, Gout, q, Nn, l);
    ushort* t = p; p = q; q = t;
  }
  // p = node_emb (bf16)

  gemb_sum_k<<<Nn / 16, 256, 0, stream>>>(p, batch, gemb_orig, 0);
  gemb_scale_k<<<Bb, 256, 0, stream>>>(gemb_orig, cntf);
  anchor_k<<<Bb, 256, 0, stream>>>(gemb_orig, anchors, s_orig);

  // ---- packed projection P = [emb@W1a^T + b1 | emb@W1b^T]
  {
    dim3 gp((Nn + 63) / 64, 2);
    mfma_gemm2_k<1, 3, 256, 256><<<gp, 256, 0, stream>>>(
        p, nullptr, nullptr, Wcombb, nullptr, nullptr, Pb, Nn, bcomb, nullptr, nullptr, nullptr, nullptr);
  }
  edge_mlp3_k<<<Ee / 64, 256, 0, stream>>>(Pb, srcp, dstp, W2b, mb2, mw3, mb3, maskp);
  permmask_k<<<(Ee + 255) / 256, 256, 0, stream>>>(maskp, in_eid, out_eid, minA, moutA);

  // ---- batched encoders #2/#3 (mask & 1-mask), M = 2N
  copyxb_k<<<(Nn * Dd / 4 + 255) / 256, 256, 0, stream>>>(x, q, 1);
  { ushort* t = p; p = q; q = t; }  // p = [x; x]
  {
    run_agg(p, Gin, Gout, Nn, minA, moutA);
    const int n8 = Nn * Dd / 8;
    subb_k<<<(n8 + 255) / 256, 256, 0, stream>>>(Ginx, Gin, Gin + NH, n8);
    subb_k<<<(n8 + 255) / 256, 256, 0, stream>>>(Goutx, Gout, Gout + NH, n8);
    run_gemm(p, Gin, Gout, q, 2 * Nn, 0);
    ushort* t = p; p = q; q = t;
  }
  for (int l = 1; l < 3; ++l) {
    run_agg(p, Gin, Gout, 2 * Nn, minA, moutA);
    run_gemm(p, Gin, Gout, q, 2 * Nn, l);
    ushort* t = p; p = q; q = t;
  }
  // p = [h_sub; h_comp]

  gemb_sum_k<<<2 * (Nn / 16), 256, 0, stream>>>(p, batch, gemb_sub, 1);
  gemb_scale_k<<<2 * Bb, 256, 0, stream>>>(gemb_sub, cntf);
  anchor_k<<<Bb, 256, 0, stream>>>(gemb_sub, anchors, s_sub);
  logits_k<<<2 * Bb, 256, 0, stream>>>(gemb_sub, gemb_comp, Wc, bc, logitsb);
  final_k<<<1, 64, 0, stream>>>(logitsb, labels, s_orig, s_sub, outF);
}

// Round 9
// 978.251 us; speedup vs baseline: 4.9377x; 1.0100x over previous
//
#include <hip/hip_runtime.h>
#include <hip/hip_bf16.h>

constexpr int Nn = 20000;
constexpr int Ee = 320000;
constexpr int Dd = 256;
constexpr int Bb = 16;
constexpr float EPSc = 1e-5f;

using v8s = __attribute__((ext_vector_type(8))) short;
using v4f = __attribute__((ext_vector_type(4))) float;

__device__ __forceinline__ float b2f(ushort u) { return __uint_as_float(((unsigned)u) << 16); }
__device__ __forceinline__ ushort f2b(float f) {
  __hip_bfloat16 h = __float2bfloat16(f);
  return *reinterpret_cast<ushort*>(&h);
}

// ------------------------------------------------------------------ graph prep
__global__ void hist_edges_k(const int* __restrict__ src, const int* __restrict__ dst,
                             int* __restrict__ cin, int* __restrict__ cout) {
  int e = blockIdx.x * 256 + threadIdx.x;
  if (e < Ee) { atomicAdd(&cin[dst[e]], 1); atomicAdd(&cout[src[e]], 1); }
}

__global__ void cnt_batch_k(const int* __restrict__ batch, float* __restrict__ cntf) {
  int b = threadIdx.x;
  if (b < Bb) {
    int lo = 0, hi = Nn;
    while (lo < hi) { int mid = (lo + hi) >> 1; if (batch[mid] < b) lo = mid + 1; else hi = mid; }
    int lb = lo;
    lo = 0; hi = Nn;
    while (lo < hi) { int mid = (lo + hi) >> 1; if (batch[mid] <= b) lo = mid + 1; else hi = mid; }
    cntf[b] = (float)(lo - lb);
  }
}

__global__ __launch_bounds__(1024) void scan_k(const int* __restrict__ cin,
                                               const int* __restrict__ cout,
                                               int* __restrict__ off_in, int* __restrict__ off_out,
                                               int* __restrict__ cur_in, int* __restrict__ cur_out) {
  __shared__ int part[1024];
  const int tid = threadIdx.x;
  for (int which = 0; which < 2; ++which) {
    const int* cnt = which ? cout : cin;
    int* off = which ? off_out : off_in;
    int* curp = which ? cur_out : cur_in;
    int vals[20];
    int base = tid * 20;
    int local = 0;
#pragma unroll
    for (int i = 0; i < 20; ++i) {
      int idx = base + i;
      int v = (idx < Nn) ? cnt[idx] : 0;
      vals[i] = v; local += v;
    }
    part[tid] = local;
    __syncthreads();
    for (int ofs = 1; ofs < 1024; ofs <<= 1) {
      int t = (tid >= ofs) ? part[tid - ofs] : 0;
      __syncthreads();
      part[tid] += t;
      __syncthreads();
    }
    int run = part[tid] - local;
#pragma unroll
    for (int i = 0; i < 20; ++i) {
      int idx = base + i;
      if (idx < Nn) { off[idx] = run; curp[idx] = run; run += vals[i]; }
    }
    if (tid == 0) off[Nn] = Ee;
    __syncthreads();
  }
}

__global__ void scatter_k(const int* __restrict__ src, const int* __restrict__ dst,
                          int* __restrict__ cur_in, int* __restrict__ cur_out,
                          int* __restrict__ in_src, int* __restrict__ in_eid,
                          int* __restrict__ out_dst, int* __restrict__ out_eid) {
  int e = blockIdx.x * 256 + threadIdx.x;
  if (e < Ee) {
    int d = dst[e], s = src[e];
    int p = atomicAdd(&cur_in[d], 1);  in_src[p] = s;  in_eid[p] = e;
    int q = atomicAdd(&cur_out[s], 1); out_dst[q] = d; out_eid[q] = e;
  }
}

__global__ void prep_bsum_k(const float* __restrict__ bs, const float* __restrict__ bin,
                            const float* __restrict__ bout, float* __restrict__ bsum) {
  int t = threadIdx.x;
  for (int l = 0; l < 3; ++l) bsum[l * 256 + t] = bs[l * 256 + t] + bin[l * 256 + t] + bout[l * 256 + t];
}

__global__ void copyxb_k(const float* __restrict__ x, ushort* __restrict__ h) {
  const int n4 = Nn * Dd / 4;
  int i = blockIdx.x * 256 + threadIdx.x;
  if (i < n4) {
    float4 v = ((const float4*)x)[i];
    ushort4 o; o.x = f2b(v.x); o.y = f2b(v.y); o.z = f2b(v.z); o.w = f2b(v.w);
    ((ushort4*)h)[i] = o;
  }
}

__global__ void c_f2b_k(const float* __restrict__ s, ushort* __restrict__ d, int n) {
  int i = blockIdx.x * 256 + threadIdx.x;
  if (i < n) d[i] = f2b(s[i]);
}

// Wcombb[256][256]: rows 0-127 = mw1[r][0:256], rows 128-255 = mw1[r-128][256:512]
__global__ void prep_mlp_k(const float* __restrict__ mw1, const float* __restrict__ mb1,
                           const float* __restrict__ mw2,
                           ushort* __restrict__ Wcombb, ushort* __restrict__ W2b,
                           float* __restrict__ bcomb) {
  int i = blockIdx.x * 256 + threadIdx.x;
  if (i < 65536) {
    int r = i >> 8, c = i & 255;
    float v = (r < 128) ? mw1[r * 512 + c] : mw1[(r - 128) * 512 + 256 + c];
    Wcombb[i] = f2b(v);
  }
  if (i < 8192) W2b[i] = f2b(mw2[i]);
  if (i < 256) bcomb[i] = (i < 128) ? mb1[i] : 0.f;
}

__global__ void permmask_k(const float* __restrict__ mask,
                           const int* __restrict__ in_eid, const int* __restrict__ out_eid,
                           float* __restrict__ minA, float* __restrict__ moutA) {
  int i = blockIdx.x * 256 + threadIdx.x;
  if (i < Ee) { minA[i] = mask[in_eid[i]]; moutA[i] = mask[out_eid[i]]; }
}

// ------------------------------------------------------------------ GEMM768: Y[M x 768] = A[M x 256] @ [Ws|Win|Wout]^T, raw bf16 out
__global__ __launch_bounds__(256) void gemm768_k(
    const ushort* __restrict__ A, const ushort* __restrict__ W0,
    const ushort* __restrict__ W1, const ushort* __restrict__ W2,
    ushort* __restrict__ Y, int M) {
  __shared__ ushort eplds[4][32][72];
  const int tid = threadIdx.x;
  const int wid = tid >> 6, lane = tid & 63;
  const int wr = wid & 1, wc = wid >> 1;
  const int m0 = blockIdx.x * 64 + wr * 32;
  const int seg = blockIdx.y >> 1;
  const ushort* Wp = (seg == 0) ? W0 : ((seg == 1) ? W1 : W2);
  const int nw0 = (blockIdx.y & 1) * 128 + wc * 64;  // col within weight (0..255)
  const int lrow = lane & 15;
  const int klo = (lane >> 4) * 8;
  v4f acc[2][4] = {};
  int rowA[2];
#pragma unroll
  for (int fi = 0; fi < 2; ++fi) {
    int r = m0 + fi * 16 + lrow;
    rowA[fi] = (r < M) ? r : (M - 1);
  }
#pragma unroll 2
  for (int kc = 0; kc < 256; kc += 32) {
    v8s a[2], b[4];
#pragma unroll
    for (int fi = 0; fi < 2; ++fi)
      a[fi] = *(const v8s*)(A + (size_t)rowA[fi] * 256 + kc + klo);
#pragma unroll
    for (int fj = 0; fj < 4; ++fj)
      b[fj] = *(const v8s*)(Wp + (size_t)(nw0 + fj * 16 + lrow) * 256 + kc + klo);
#pragma unroll
    for (int fi = 0; fi < 2; ++fi)
#pragma unroll
      for (int fj = 0; fj < 4; ++fj)
        acc[fi][fj] = __builtin_amdgcn_mfma_f32_16x16x32_bf16(a[fi], b[fj], acc[fi][fj], 0, 0, 0);
  }
#pragma unroll
  for (int fj = 0; fj < 4; ++fj)
#pragma unroll
    for (int fi = 0; fi < 2; ++fi) {
      const int rl0 = fi * 16 + ((lane >> 4) << 2);
#pragma unroll
      for (int r = 0; r < 4; ++r)
        eplds[wid][rl0 + r][fj * 16 + lrow] = f2b(acc[fi][fj][r]);
    }
  const int colbase = blockIdx.y * 128 + wc * 64;
#pragma unroll
  for (int i = 0; i < 4; ++i) {
    const int rl = (lane >> 2) + (i & 1) * 16;
    const int oct = (lane & 3) + (i >> 1) * 4;
    v8s val = *(const v8s*)&eplds[wid][rl][oct * 8];
    const int grow = m0 + rl;
    if (grow < M)
      *(v8s*)(Y + (size_t)grow * 768 + colbase + oct * 8) = val;
  }
}

// ------------------------------------------------------------------ agg + epilogue
// out[node] = BN(relu(Y_s[node] + sum_in m*Y_in[u] + sum_out m*Y_out[u] + bsum))
// MM 0: no mask (enc1) ; 1: batched (half from node>=Nn, m / 1-m) ; 2: sub-only (m)
// WR 1: also write raw agg sum (bf16) for comp reconstruction
template <int MM, int WR>
__global__ __launch_bounds__(256) void aggepi_k(
    const ushort* __restrict__ Y, ushort* __restrict__ hout, ushort* __restrict__ raw,
    const int* __restrict__ off_in, const int* __restrict__ in_src,
    const int* __restrict__ off_out, const int* __restrict__ out_dst,
    const float* __restrict__ minA, const float* __restrict__ moutA,
    const float* __restrict__ bsum, const float* __restrict__ gma,
    const float* __restrict__ bta, const float* __restrict__ rmn, const float* __restrict__ rvr,
    int Mtot) {
  const int g = threadIdx.x >> 5;
  const int lane = threadIdx.x & 31;
  const int node = blockIdx.x * 8 + g;
  if (node >= Mtot) return;
  const int half = (MM == 1 && node >= Nn) ? 1 : 0;
  const int v = node - half * Nn;
  const int co = lane * 8;
  float acc[8] = {};
#pragma unroll
  for (int dir = 0; dir < 2; ++dir) {
    const int* offs = dir ? off_out : off_in;
    const int* nbr  = dir ? out_dst : in_src;
    const float* ma = dir ? moutA : minA;
    const ushort* Yg = Y + (size_t)half * Nn * 768 + (dir ? 512 : 256) + co;
    const int s = offs[v], e = offs[v + 1];
    int i = s;
    for (; i + 4 <= e; i += 4) {
      int u0 = nbr[i], u1 = nbr[i + 1], u2 = nbr[i + 2], u3 = nbr[i + 3];
      float m0 = 1.f, m1 = 1.f, m2 = 1.f, m3 = 1.f;
      if (MM != 0) {
        m0 = ma[i]; m1 = ma[i + 1]; m2 = ma[i + 2]; m3 = ma[i + 3];
        if (MM == 1 && half) { m0 = 1.f - m0; m1 = 1.f - m1; m2 = 1.f - m2; m3 = 1.f - m3; }
      }
      v8s r0 = *(const v8s*)(Yg + (size_t)u0 * 768);
      v8s r1 = *(const v8s*)(Yg + (size_t)u1 * 768);
      v8s r2 = *(const v8s*)(Yg + (size_t)u2 * 768);
      v8s r3 = *(const v8s*)(Yg + (size_t)u3 * 768);
#pragma unroll
      for (int j = 0; j < 8; ++j)
        acc[j] += m0 * b2f((ushort)r0[j]) + m1 * b2f((ushort)r1[j]) +
                  m2 * b2f((ushort)r2[j]) + m3 * b2f((ushort)r3[j]);
    }
    for (; i < e; ++i) {
      int u = nbr[i];
      float m = 1.f;
      if (MM != 0) { m = ma[i]; if (MM == 1 && half) m = 1.f - m; }
      v8s r = *(const v8s*)(Yg + (size_t)u * 768);
#pragma unroll
      for (int j = 0; j < 8; ++j) acc[j] += m * b2f((ushort)r[j]);
    }
  }
  if (WR) {
    v8s rw;
#pragma unroll
    for (int j = 0; j < 8; ++j) rw[j] = (short)f2b(acc[j]);
    *(v8s*)(raw + (size_t)v * 256 + co) = rw;
  }
  v8s ys = *(const v8s*)(Y + (size_t)node * 768 + co);
  v8s o;
#pragma unroll
  for (int j = 0; j < 8; ++j) {
    const int col = co + j;
    float val = acc[j] + b2f((ushort)ys[j]) + bsum[col];
    val = fmaxf(val, 0.f);
    val = (val - rmn[col]) * rsqrtf(rvr[col] + EPSc) * gma[col] + bta[col];
    o[j] = (short)f2b(val);
  }
  *(v8s*)(hout + (size_t)node * 256 + co) = o;
}

// batched L0 comp half: out[N+v] = BN(relu(Yx_s[v] + (Aones - Asub) + bsum0))
__global__ void compl0_k(const ushort* __restrict__ Yx, const ushort* __restrict__ Aones,
                         const ushort* __restrict__ Asub, ushort* __restrict__ hout,
                         const float* __restrict__ bsum, const float* __restrict__ gma,
                         const float* __restrict__ bta, const float* __restrict__ rmn,
                         const float* __restrict__ rvr) {
  int i = blockIdx.x * 256 + threadIdx.x;
  if (i >= Nn * 32) return;
  const int v = i >> 5;
  const int co = (i & 31) * 8;
  v8s ys = *(const v8s*)(Yx + (size_t)v * 768 + co);
  v8s ao = *(const v8s*)(Aones + (size_t)v * 256 + co);
  v8s as = *(const v8s*)(Asub + (size_t)v * 256 + co);
  v8s o;
#pragma unroll
  for (int j = 0; j < 8; ++j) {
    const int col = co + j;
    float val = b2f((ushort)ys[j]) + b2f((ushort)ao[j]) - b2f((ushort)as[j]) + bsum[col];
    val = fmaxf(val, 0.f);
    val = (val - rmn[col]) * rsqrtf(rvr[col] + EPSc) * gma[col] + bta[col];
    o[j] = (short)f2b(val);
  }
  *(v8s*)(hout + (size_t)(Nn + v) * 256 + co) = o;
}

// ------------------------------------------------------------------ proj GEMM (mask MLP layer 1), 64x128 tile
template <int EPI>
__global__ __launch_bounds__(256) void mfma_gemm2_k(
    const ushort* __restrict__ A, const ushort* __restrict__ W,
    ushort* __restrict__ Cout, int M, const float* __restrict__ bias) {
  __shared__ ushort eplds[4][32][72];
  const int tid = threadIdx.x;
  const int wid = tid >> 6, lane = tid & 63;
  const int wr = wid & 1, wc = wid >> 1;
  const int m0 = blockIdx.x * 64 + wr * 32;
  const int n0 = blockIdx.y * 128 + wc * 64;
  const int lrow = lane & 15;
  const int klo = (lane >> 4) * 8;
  v4f acc[2][4] = {};
  int rowA[2];
#pragma unroll
  for (int fi = 0; fi < 2; ++fi) {
    int r = m0 + fi * 16 + lrow;
    rowA[fi] = (r < M) ? r : (M - 1);
  }
#pragma unroll 2
  for (int kc = 0; kc < 256; kc += 32) {
    v8s a[2], b[4];
#pragma unroll
    for (int fi = 0; fi < 2; ++fi)
      a[fi] = *(const v8s*)(A + (size_t)rowA[fi] * 256 + kc + klo);
#pragma unroll
    for (int fj = 0; fj < 4; ++fj)
      b[fj] = *(const v8s*)(W + (size_t)(n0 + fj * 16 + lrow) * 256 + kc + klo);
#pragma unroll
    for (int fi = 0; fi < 2; ++fi)
#pragma unroll
      for (int fj = 0; fj < 4; ++fj)
        acc[fi][fj] = __builtin_amdgcn_mfma_f32_16x16x32_bf16(a[fi], b[fj], acc[fi][fj], 0, 0, 0);
  }
#pragma unroll
  for (int fj = 0; fj < 4; ++fj) {
    const int col = n0 + fj * 16 + lrow;
    const float bsv = bias ? bias[col] : 0.f;
#pragma unroll
    for (int fi = 0; fi < 2; ++fi) {
      const int rl0 = fi * 16 + ((lane >> 4) << 2);
#pragma unroll
      for (int r = 0; r < 4; ++r)
        eplds[wid][rl0 + r][fj * 16 + lrow] = f2b(acc[fi][fj][r] + bsv);
    }
  }
#pragma unroll
  for (int i = 0; i < 4; ++i) {
    const int rl = (lane >> 2) + (i & 1) * 16;
    const int oct = (lane & 3) + (i >> 1) * 4;
    v8s val = *(const v8s*)&eplds[wid][rl][oct * 8];
    const int grow = m0 + rl;
    if (grow < M)
      *(v8s*)(Cout + (size_t)grow * 256 + n0 + oct * 8) = val;
  }
}

// ------------------------------------------------------------------ edge MLP: MFMA, no LDS
__global__ __launch_bounds__(256) void edge_mlp3_k(const ushort* __restrict__ P,
                                                   const int* __restrict__ src, const int* __restrict__ dst,
                                                   const ushort* __restrict__ W2b,
                                                   const float* __restrict__ b2, const float* __restrict__ w3,
                                                   const float* __restrict__ b3,
                                                   float* __restrict__ maskOut) {
  const int tid = threadIdx.x;
  const int w = tid >> 6, lane = tid & 63;
  const int e0 = blockIdx.x * 64 + w * 16;
  const int le = lane & 15;
  const int kq = lane >> 4;
  const int klo = kq * 8;
  const int eA = e0 + le;
  const int s_ = src[eA], d_ = dst[eA];
  const ushort* ps = P + (size_t)s_ * 256;
  const ushort* pd = P + (size_t)d_ * 256 + 128;
  v4f acc[4] = {};
#pragma unroll
  for (int kc = 0; kc < 128; kc += 32) {
    v8s as = *(const v8s*)(ps + kc + klo);
    v8s ad = *(const v8s*)(pd + kc + klo);
    v8s h;
#pragma unroll
    for (int j = 0; j < 8; ++j) {
      float v = fmaxf(b2f((ushort)as[j]) + b2f((ushort)ad[j]), 0.f);
      h[j] = (short)f2b(v);
    }
#pragma unroll
    for (int fj = 0; fj < 4; ++fj) {
      v8s b = *(const v8s*)(W2b + (size_t)(fj * 16 + le) * 128 + kc + klo);
      acc[fj] = __builtin_amdgcn_mfma_f32_16x16x32_bf16(h, b, acc[fj], 0, 0, 0);
    }
  }
  float b2v[4], w3v[4];
#pragma unroll
  for (int fj = 0; fj < 4; ++fj) { b2v[fj] = b2[fj * 16 + le]; w3v[fj] = w3[fj * 16 + le]; }
  const float b3v = b3[0];
#pragma unroll
  for (int r = 0; r < 4; ++r) {
    float val = 0.f;
#pragma unroll
    for (int fj = 0; fj < 4; ++fj)
      val += fmaxf(acc[fj][r] + b2v[fj], 0.f) * w3v[fj];
    val += __shfl_xor(val, 1);
    val += __shfl_xor(val, 2);
    val += __shfl_xor(val, 4);
    val += __shfl_xor(val, 8);
    if (le == 0) {
      int er = e0 + kq * 4 + r;
      maskOut[er] = 1.0f / (1.0f + expf(-(val + b3v)));
    }
  }
}

// ------------------------------------------------------------------ pooling / tails
__global__ __launch_bounds__(256) void gemb_sum_k(const ushort* __restrict__ h, const int* __restrict__ batch,
                                                  float* __restrict__ gsum, int batched) {
  const int halfBlocks = Nn / 16;
  int blk = blockIdx.x;
  int half = 0, bi = blk;
  if (batched) { half = (blk >= halfBlocks) ? 1 : 0; bi = blk - half * halfBlocks; }
  const int v0 = bi * 16;
  const int tid = threadIdx.x;
  const size_t base = (size_t)half * Nn;
  float* out = gsum + (size_t)half * (Bb * Dd);
  float acc = 0.0f;
  int curb = batch[v0];
  for (int i = 0; i < 16; ++i) {
    int v = v0 + i;
    int b = batch[v];
    if (b != curb) { atomicAdd(&out[curb * Dd + tid], acc); acc = 0.0f; curb = b; }
    acc += b2f(h[(base + v) * Dd + tid]);
  }
  atomicAdd(&out[curb * Dd + tid], acc);
}

__global__ void gemb_scale_k(float* __restrict__ g, const float* __restrict__ cntf) {
  int blk = blockIdx.x;
  int b = blk & 15;
  g[blk * Dd + threadIdx.x] /= fmaxf(cntf[b], 1.0f);
}

__global__ void anchor_k(const float* __restrict__ g, const float* __restrict__ anchors,
                         float* __restrict__ s_out) {
  __shared__ float red4[4];
  const int b = blockIdx.x, tid = threadIdx.x;
  float gv = g[b * Dd + tid];
  float total = 0.0f;
  for (int k = 0; k < 6; ++k) {
    float d = gv - anchors[k * Dd + tid];
    float v = d * d;
    for (int o = 32; o > 0; o >>= 1) v += __shfl_xor(v, o);
    if ((tid & 63) == 0) red4[tid >> 6] = v;
    __syncthreads();
    if (tid == 0) total += sqrtf(red4[0] + red4[1] + red4[2] + red4[3]);
    __syncthreads();
  }
  if (tid == 0) s_out[b] = total;
}

__global__ void logits_k(const float* __restrict__ gsub, const float* __restrict__ gcomp,
                         const float* __restrict__ Wc, const float* __restrict__ bc,
                         float* __restrict__ outL) {
  __shared__ float red4[4];
  const int blk = blockIdx.x;
  const int set = blk >> 4, b = blk & 15;
  const float* g = set ? gcomp : gsub;
  const int tid = threadIdx.x;
  float gv = g[b * Dd + tid];
  for (int c = 0; c < 2; ++c) {
    float v = gv * Wc[c * Dd + tid];
    for (int o = 32; o > 0; o >>= 1) v += __shfl_xor(v, o);
    if ((tid & 63) == 0) red4[tid >> 6] = v;
    __syncthreads();
    if (tid == 0) outL[set * 32 + b * 2 + c] = red4[0] + red4[1] + red4[2] + red4[3] + bc[c];
    __syncthreads();
  }
}

__global__ void final_k(const float* __restrict__ L, const int* __restrict__ labels,
                        const float* __restrict__ s_orig, const float* __restrict__ s_sub,
                        float* __restrict__ out) {
  if (threadIdx.x == 0) {
    float Lp = 0, Lu = 0, La = 0;
    const float u = 0.5f;
    for (int b = 0; b < 16; ++b) {
      float l0 = L[b * 2], l1 = L[b * 2 + 1];
      float m = fmaxf(l0, l1);
      float lse = m + logf(expf(l0 - m) + expf(l1 - m));
      int lab = labels[b];
      Lp += -((lab ? l1 : l0) - lse);
      float c0 = L[32 + b * 2], c1 = L[32 + b * 2 + 1];
      float mm = fmaxf(c0, c1);
      float e0 = expf(c0 - mm), e1 = expf(c1 - mm), Z = e0 + e1;
      Lu += u * (logf(u) - logf(e0 / Z + 1e-8f)) + u * (logf(u) - logf(e1 / Z + 1e-8f));
      float dd = s_sub[b] - s_orig[b];
      La += dd * dd;
    }
    Lp /= 16.0f; Lu /= 16.0f; La /= 16.0f;
    out[0] = 0.5f * Lp + 0.3f * Lu + 0.2f * La;
    out[1] = Lp; out[2] = Lu; out[3] = La;
  }
}

// ------------------------------------------------------------------ host
extern "C" void kernel_launch(void* const* d_in, const int* in_sizes, int n_in,
                              void* d_out, int out_size, void* d_ws, size_t ws_size,
                              hipStream_t stream) {
  (void)in_sizes; (void)n_in; (void)out_size; (void)ws_size;
  const float* x    = (const float*)d_in[0];
  const int* ei     = (const int*)d_in[1];
  const int* batch  = (const int*)d_in[2];
  const int* labels = (const int*)d_in[3];
  const float* mw1 = (const float*)d_in[4];
  const float* mb1 = (const float*)d_in[5];
  const float* mw2 = (const float*)d_in[6];
  const float* mb2 = (const float*)d_in[7];
  const float* mw3 = (const float*)d_in[8];
  const float* mb3 = (const float*)d_in[9];
  const float* Ws   = (const float*)d_in[10];
  const float* bs   = (const float*)d_in[11];
  const float* Win  = (const float*)d_in[12];
  const float* bin_ = (const float*)d_in[13];
  const float* Wout = (const float*)d_in[14];
  const float* bout = (const float*)d_in[15];
  const float* gma  = (const float*)d_in[16];
  const float* bta  = (const float*)d_in[17];
  const float* rmn  = (const float*)d_in[18];
  const float* rvr  = (const float*)d_in[19];
  const float* anchors = (const float*)d_in[20];
  const float* Wc   = (const float*)d_in[21];
  const float* bc   = (const float*)d_in[22];
  const int* srcp = ei;
  const int* dstp = ei + Ee;

  const size_t NH = (size_t)Nn * Dd;      // 5.12M
  const size_t NE = 2 * NH;               // 10.24M
  ushort* xb   = (ushort*)d_ws;           // NH
  ushort* hA   = xb + NH;                 // NE
  ushort* hB   = hA + NE;                 // NE
  ushort* Ybuf = hB + NE;                 // 2N*768 = 30.72M  (Pb aliases start)
  ushort* Pb   = Ybuf;
  ushort* Aones = Ybuf + (size_t)2 * Nn * 768;  // NH
  ushort* Asub  = Aones + NH;                   // NH
  ushort* Wsb   = Asub + NH;
  ushort* Winb  = Wsb + 3 * 65536;
  ushort* Woutb = Winb + 3 * 65536;
  ushort* Wcombb = Woutb + 3 * 65536;
  ushort* W2b    = Wcombb + 65536;
  float* bcomb = (float*)(W2b + 8192);
  float* minA  = bcomb + 256;
  float* moutA = minA + Ee;
  int* off_in   = (int*)(moutA + Ee);
  int* off_out  = off_in + (Nn + 1);
  int* cur_in   = off_out + (Nn + 1);
  int* cur_out  = cur_in + Nn;
  int* in_src   = cur_out + Nn;
  int* in_eid   = in_src + Ee;
  int* out_dst  = in_eid + Ee;
  int* out_eid  = out_dst + Ee;
  int* counts_in  = out_eid + Ee;
  int* counts_out = counts_in + Nn;
  float* cntf      = (float*)(counts_out + Nn);
  float* gemb_orig = cntf + Bb;
  float* gemb_sub  = gemb_orig + Bb * Dd;
  float* gemb_comp = gemb_sub + Bb * Dd;
  float* bsum    = gemb_comp + Bb * Dd;
  float* s_orig  = bsum + 3 * Dd;
  float* s_sub   = s_orig + Bb;
  float* logitsb = s_sub + Bb;

  float* outF = (float*)d_out;
  float* maskp = outF + 4;

  const size_t zero_bytes = (char*)bsum - (char*)counts_in;
  hipMemsetAsync(counts_in, 0, zero_bytes, stream);

  hist_edges_k<<<(Ee + 255) / 256, 256, 0, stream>>>(srcp, dstp, counts_in, counts_out);
  cnt_batch_k<<<1, 64, 0, stream>>>(batch, cntf);
  scan_k<<<1, 1024, 0, stream>>>(counts_in, counts_out, off_in, off_out, cur_in, cur_out);
  scatter_k<<<(Ee + 255) / 256, 256, 0, stream>>>(srcp, dstp, cur_in, cur_out, in_src, in_eid, out_dst, out_eid);
  prep_bsum_k<<<1, 256, 0, stream>>>(bs, bin_, bout, bsum);

  c_f2b_k<<<(3 * 65536 + 255) / 256, 256, 0, stream>>>(Ws, Wsb, 3 * 65536);
  c_f2b_k<<<(3 * 65536 + 255) / 256, 256, 0, stream>>>(Win, Winb, 3 * 65536);
  c_f2b_k<<<(3 * 65536 + 255) / 256, 256, 0, stream>>>(Wout, Woutb, 3 * 65536);
  prep_mlp_k<<<256, 256, 0, stream>>>(mw1, mb1, mw2, Wcombb, W2b, bcomb);

  auto run_gemm768 = [&](ushort* h, int M, int l) {
    dim3 gg((M + 63) / 64, 6);
    gemm768_k<<<gg, 256, 0, stream>>>(h, Wsb + (size_t)l * 65536, Winb + (size_t)l * 65536,
                                      Woutb + (size_t)l * 65536, Ybuf, M);
  };
  auto bn = [&](int l) { return bsum + l * 256; };

  // ---- encoder #1 (ones mask), M = N
  copyxb_k<<<(Nn * Dd / 4 + 255) / 256, 256, 0, stream>>>(x, xb);
  // L0 (saves raw ones-agg for batched L0 comp reconstruction)
  run_gemm768(xb, Nn, 0);
  aggepi_k<0, 1><<<(Nn + 7) / 8, 256, 0, stream>>>(
      Ybuf, hB, Aones, off_in, in_src, off_out, out_dst, nullptr, nullptr,
      bn(0), gma, bta, rmn, rvr, Nn);
  // L1
  run_gemm768(hB, Nn, 1);
  aggepi_k<0, 0><<<(Nn + 7) / 8, 256, 0, stream>>>(
      Ybuf, hA, nullptr, off_in, in_src, off_out, out_dst, nullptr, nullptr,
      bn(1), gma + 256, bta + 256, rmn + 256, rvr + 256, Nn);
  // L2
  run_gemm768(hA, Nn, 2);
  aggepi_k<0, 0><<<(Nn + 7) / 8, 256, 0, stream>>>(
      Ybuf, hB, nullptr, off_in, in_src, off_out, out_dst, nullptr, nullptr,
      bn(2), gma + 512, bta + 512, rmn + 512, rvr + 512, Nn);
  // node_emb = hB[0..N)

  gemb_sum_k<<<Nn / 16, 256, 0, stream>>>(hB, batch, gemb_orig, 0);
  gemb_scale_k<<<Bb, 256, 0, stream>>>(gemb_orig, cntf);
  anchor_k<<<Bb, 256, 0, stream>>>(gemb_orig, anchors, s_orig);

  // ---- packed projection P = [emb@W1a^T + b1 | emb@W1b^T] (Pb aliases Ybuf start)
  {
    dim3 gp((Nn + 63) / 64, 2);
    mfma_gemm2_k<3><<<gp, 256, 0, stream>>>(hB, Wcombb, Pb, Nn, bcomb);
  }
  edge_mlp3_k<<<Ee / 64, 256, 0, stream>>>(Pb, srcp, dstp, W2b, mb2, mw3, mb3, maskp);
  permmask_k<<<(Ee + 255) / 256, 256, 0, stream>>>(maskp, in_eid, out_eid, minA, moutA);

  // ---- batched encoders #2/#3 (mask & 1-mask), M = 2N
  // L0: Y_x identical for both halves -> compute once (M=N), masked sub agg, comp = ones - sub
  run_gemm768(xb, Nn, 0);
  aggepi_k<2, 1><<<(Nn + 7) / 8, 256, 0, stream>>>(
      Ybuf, hA, Asub, off_in, in_src, off_out, out_dst, minA, moutA,
      bn(0), gma, bta, rmn, rvr, Nn);
  compl0_k<<<(Nn * 32 + 255) / 256, 256, 0, stream>>>(Ybuf, Aones, Asub, hA,
                                                      bn(0), gma, bta, rmn, rvr);
  // L1
  run_gemm768(hA, 2 * Nn, 1);
  aggepi_k<1, 0><<<(2 * Nn + 7) / 8, 256, 0, stream>>>(
      Ybuf, hB, nullptr, off_in, in_src, off_out, out_dst, minA, moutA,
      bn(1), gma + 256, bta + 256, rmn + 256, rvr + 256, 2 * Nn);
  // L2
  run_gemm768(hB, 2 * Nn, 2);
  aggepi_k<1, 0><<<(2 * Nn + 7) / 8, 256, 0, stream>>>(
      Ybuf, hA, nullptr, off_in, in_src, off_out, out_dst, minA, moutA,
      bn(2), gma + 512, bta + 512, rmn + 512, rvr + 512, 2 * Nn);
  // hA = [h_sub; h_comp]

  gemb_sum_k<<<2 * (Nn / 16), 256, 0, stream>>>(hA, batch, gemb_sub, 1);
  gemb_scale_k<<<2 * Bb, 256, 0, stream>>>(gemb_sub, cntf);
  anchor_k<<<Bb, 256, 0, stream>>>(gemb_sub, anchors, s_sub);
  logits_k<<<2 * Bb, 256, 0, stream>>>(gemb_sub, gemb_comp, Wc, bc, logitsb);
  final_k<<<1, 64, 0, stream>>>(logitsb, labels, s_orig, s_sub, outF);
}

// Round 10
// 961.757 us; speedup vs baseline: 5.0224x; 1.0172x over previous
//
#include <hip/hip_runtime.h>
#include <hip/hip_bf16.h>

constexpr int Nn = 20000;
constexpr int Ee = 320000;
constexpr int Dd = 256;
constexpr int Bb = 16;
constexpr float EPSc = 1e-5f;

using v8s = __attribute__((ext_vector_type(8))) short;
using v4f = __attribute__((ext_vector_type(4))) float;

__device__ __forceinline__ float b2f(ushort u) { return __uint_as_float(((unsigned)u) << 16); }
__device__ __forceinline__ ushort f2b(float f) {
  __hip_bfloat16 h = __float2bfloat16(f);
  return *reinterpret_cast<ushort*>(&h);
}

// ------------------------------------------------------------------ graph prep
__global__ void hist_edges_k(const int* __restrict__ src, const int* __restrict__ dst,
                             int* __restrict__ cin, int* __restrict__ cout) {
  int e = blockIdx.x * 256 + threadIdx.x;
  if (e < Ee) { atomicAdd(&cin[dst[e]], 1); atomicAdd(&cout[src[e]], 1); }
}

__global__ void cnt_batch_k(const int* __restrict__ batch, float* __restrict__ cntf) {
  int b = threadIdx.x;
  if (b < Bb) {
    int lo = 0, hi = Nn;
    while (lo < hi) { int mid = (lo + hi) >> 1; if (batch[mid] < b) lo = mid + 1; else hi = mid; }
    int lb = lo;
    lo = 0; hi = Nn;
    while (lo < hi) { int mid = (lo + hi) >> 1; if (batch[mid] <= b) lo = mid + 1; else hi = mid; }
    cntf[b] = (float)(lo - lb);
  }
}

__global__ __launch_bounds__(1024) void scan_k(const int* __restrict__ cin,
                                               const int* __restrict__ cout,
                                               int* __restrict__ off_in, int* __restrict__ off_out,
                                               int* __restrict__ cur_in, int* __restrict__ cur_out) {
  __shared__ int part[1024];
  const int tid = threadIdx.x;
  for (int which = 0; which < 2; ++which) {
    const int* cnt = which ? cout : cin;
    int* off = which ? off_out : off_in;
    int* curp = which ? cur_out : cur_in;
    int vals[20];
    int base = tid * 20;
    int local = 0;
#pragma unroll
    for (int i = 0; i < 20; ++i) {
      int idx = base + i;
      int v = (idx < Nn) ? cnt[idx] : 0;
      vals[i] = v; local += v;
    }
    part[tid] = local;
    __syncthreads();
    for (int ofs = 1; ofs < 1024; ofs <<= 1) {
      int t = (tid >= ofs) ? part[tid - ofs] : 0;
      __syncthreads();
      part[tid] += t;
      __syncthreads();
    }
    int run = part[tid] - local;
#pragma unroll
    for (int i = 0; i < 20; ++i) {
      int idx = base + i;
      if (idx < Nn) { off[idx] = run; curp[idx] = run; run += vals[i]; }
    }
    if (tid == 0) off[Nn] = Ee;
    __syncthreads();
  }
}

__global__ void scatter_k(const int* __restrict__ src, const int* __restrict__ dst,
                          int* __restrict__ cur_in, int* __restrict__ cur_out,
                          int* __restrict__ in_src, int* __restrict__ in_eid,
                          int* __restrict__ out_dst, int* __restrict__ out_eid) {
  int e = blockIdx.x * 256 + threadIdx.x;
  if (e < Ee) {
    int d = dst[e], s = src[e];
    int p = atomicAdd(&cur_in[d], 1);  in_src[p] = s;  in_eid[p] = e;
    int q = atomicAdd(&cur_out[s], 1); out_dst[q] = d; out_eid[q] = e;
  }
}

__global__ void prep_bsum_k(const float* __restrict__ bs, const float* __restrict__ bin,
                            const float* __restrict__ bout, float* __restrict__ bsum) {
  int t = threadIdx.x;
  for (int l = 0; l < 3; ++l) bsum[l * 256 + t] = bs[l * 256 + t] + bin[l * 256 + t] + bout[l * 256 + t];
}

__global__ void copyxb_k(const float* __restrict__ x, ushort* __restrict__ h) {
  const int n4 = Nn * Dd / 4;
  int i = blockIdx.x * 256 + threadIdx.x;
  if (i < n4) {
    float4 v = ((const float4*)x)[i];
    ushort4 o; o.x = f2b(v.x); o.y = f2b(v.y); o.z = f2b(v.z); o.w = f2b(v.w);
    ((ushort4*)h)[i] = o;
  }
}

__global__ void c_f2b_k(const float* __restrict__ s, ushort* __restrict__ d, int n) {
  int i = blockIdx.x * 256 + threadIdx.x;
  if (i < n) d[i] = f2b(s[i]);
}

// Wcombb[256][256]: rows 0-127 = mw1[r][0:256], rows 128-255 = mw1[r-128][256:512]
__global__ void prep_mlp_k(const float* __restrict__ mw1, const float* __restrict__ mb1,
                           const float* __restrict__ mw2,
                           ushort* __restrict__ Wcombb, ushort* __restrict__ W2b,
                           float* __restrict__ bcomb) {
  int i = blockIdx.x * 256 + threadIdx.x;
  if (i < 65536) {
    int r = i >> 8, c = i & 255;
    float v = (r < 128) ? mw1[r * 512 + c] : mw1[(r - 128) * 512 + 256 + c];
    Wcombb[i] = f2b(v);
  }
  if (i < 8192) W2b[i] = f2b(mw2[i]);
  if (i < 256) bcomb[i] = (i < 128) ? mb1[i] : 0.f;
}

__global__ void permmask_k(const float* __restrict__ mask,
                           const int* __restrict__ in_eid, const int* __restrict__ out_eid,
                           float* __restrict__ minA, float* __restrict__ moutA) {
  int i = blockIdx.x * 256 + threadIdx.x;
  if (i < Ee) { minA[i] = mask[in_eid[i]]; moutA[i] = mask[out_eid[i]]; }
}

// ------------------------------------------------------------------ GEMM768 (A-strip register preload)
// Y[M x 768] = A[M x 256] @ [Ws|Win|Wout]^T, raw bf16 out
__global__ __launch_bounds__(256) void gemm768_k(
    const ushort* __restrict__ A, const ushort* __restrict__ W0,
    const ushort* __restrict__ W1, const ushort* __restrict__ W2,
    ushort* __restrict__ Y, int M) {
  __shared__ ushort eplds[4][32][72];
  const int tid = threadIdx.x;
  const int wid = tid >> 6, lane = tid & 63;
  const int wr = wid & 1, wc = wid >> 1;
  const int m0 = blockIdx.x * 64 + wr * 32;
  const int seg = blockIdx.y >> 1;
  const ushort* Wp = (seg == 0) ? W0 : ((seg == 1) ? W1 : W2);
  const int nw0 = (blockIdx.y & 1) * 128 + wc * 64;
  const int lrow = lane & 15;
  const int klo = (lane >> 4) * 8;
  int rowA[2];
#pragma unroll
  for (int fi = 0; fi < 2; ++fi) {
    int r = m0 + fi * 16 + lrow;
    rowA[fi] = (r < M) ? r : (M - 1);
  }
  // preload entire K strip of A (16 independent loads in flight)
  v8s a[8][2];
#pragma unroll
  for (int c = 0; c < 8; ++c)
#pragma unroll
    for (int fi = 0; fi < 2; ++fi)
      a[c][fi] = *(const v8s*)(A + (size_t)rowA[fi] * 256 + c * 32 + klo);
  v4f acc[2][4] = {};
#pragma unroll
  for (int c = 0; c < 8; ++c) {
    v8s b[4];
#pragma unroll
    for (int fj = 0; fj < 4; ++fj)
      b[fj] = *(const v8s*)(Wp + (size_t)(nw0 + fj * 16 + lrow) * 256 + c * 32 + klo);
#pragma unroll
    for (int fi = 0; fi < 2; ++fi)
#pragma unroll
      for (int fj = 0; fj < 4; ++fj)
        acc[fi][fj] = __builtin_amdgcn_mfma_f32_16x16x32_bf16(a[c][fi], b[fj], acc[fi][fj], 0, 0, 0);
  }
#pragma unroll
  for (int fj = 0; fj < 4; ++fj)
#pragma unroll
    for (int fi = 0; fi < 2; ++fi) {
      const int rl0 = fi * 16 + ((lane >> 4) << 2);
#pragma unroll
      for (int r = 0; r < 4; ++r)
        eplds[wid][rl0 + r][fj * 16 + lrow] = f2b(acc[fi][fj][r]);
    }
  const int colbase = blockIdx.y * 128 + wc * 64;
#pragma unroll
  for (int i = 0; i < 4; ++i) {
    const int rl = (lane >> 2) + (i & 1) * 16;
    const int oct = (lane & 3) + (i >> 1) * 4;
    v8s val = *(const v8s*)&eplds[wid][rl][oct * 8];
    const int grow = m0 + rl;
    if (grow < M)
      *(v8s*)(Y + (size_t)grow * 768 + colbase + oct * 8) = val;
  }
}

// ------------------------------------------------------------------ agg + epilogue (single half table)
// out[v] = BN(relu(Y[v][0:256] + sum_in m*Y_in[u] + sum_out m*Y_out[u] + bsum))
// MODE 0: m=1 ; MODE 1: m=mask ; MODE 2: m=1-mask.  WR 1: save raw agg sum.
template <int MODE, int WR>
__global__ __launch_bounds__(256) void aggepi_k(
    const ushort* __restrict__ Y, ushort* __restrict__ hout, ushort* __restrict__ raw,
    const int* __restrict__ off_in, const int* __restrict__ in_src,
    const int* __restrict__ off_out, const int* __restrict__ out_dst,
    const float* __restrict__ minA, const float* __restrict__ moutA,
    const float* __restrict__ bsum, const float* __restrict__ gma,
    const float* __restrict__ bta, const float* __restrict__ rmn, const float* __restrict__ rvr) {
  const int g = threadIdx.x >> 5;
  const int lane = threadIdx.x & 31;
  const int v = blockIdx.x * 8 + g;
  if (v >= Nn) return;
  const int co = lane * 8;
  float acc[8] = {};
#pragma unroll
  for (int dir = 0; dir < 2; ++dir) {
    const int* offs = dir ? off_out : off_in;
    const int* nbr  = dir ? out_dst : in_src;
    const float* ma = dir ? moutA : minA;
    const ushort* Yg = Y + (dir ? 512 : 256) + co;
    const int s = offs[v], e = offs[v + 1];
    int i = s;
    for (; i + 4 <= e; i += 4) {
      int u0 = nbr[i], u1 = nbr[i + 1], u2 = nbr[i + 2], u3 = nbr[i + 3];
      float m0 = 1.f, m1 = 1.f, m2 = 1.f, m3 = 1.f;
      if (MODE == 1) { m0 = ma[i]; m1 = ma[i + 1]; m2 = ma[i + 2]; m3 = ma[i + 3]; }
      if (MODE == 2) {
        m0 = 1.f - ma[i]; m1 = 1.f - ma[i + 1]; m2 = 1.f - ma[i + 2]; m3 = 1.f - ma[i + 3];
      }
      v8s r0 = *(const v8s*)(Yg + (size_t)u0 * 768);
      v8s r1 = *(const v8s*)(Yg + (size_t)u1 * 768);
      v8s r2 = *(const v8s*)(Yg + (size_t)u2 * 768);
      v8s r3 = *(const v8s*)(Yg + (size_t)u3 * 768);
#pragma unroll
      for (int j = 0; j < 8; ++j)
        acc[j] += m0 * b2f((ushort)r0[j]) + m1 * b2f((ushort)r1[j]) +
                  m2 * b2f((ushort)r2[j]) + m3 * b2f((ushort)r3[j]);
    }
    for (; i < e; ++i) {
      int u = nbr[i];
      float m = 1.f;
      if (MODE == 1) m = ma[i];
      if (MODE == 2) m = 1.f - ma[i];
      v8s r = *(const v8s*)(Yg + (size_t)u * 768);
#pragma unroll
      for (int j = 0; j < 8; ++j) acc[j] += m * b2f((ushort)r[j]);
    }
  }
  if (WR) {
    v8s rw;
#pragma unroll
    for (int j = 0; j < 8; ++j) rw[j] = (short)f2b(acc[j]);
    *(v8s*)(raw + (size_t)v * 256 + co) = rw;
  }
  v8s ys = *(const v8s*)(Y + (size_t)v * 768 + co);
  v8s o;
#pragma unroll
  for (int j = 0; j < 8; ++j) {
    const int col = co + j;
    float val = acc[j] + b2f((ushort)ys[j]) + bsum[col];
    val = fmaxf(val, 0.f);
    val = (val - rmn[col]) * rsqrtf(rvr[col] + EPSc) * gma[col] + bta[col];
    o[j] = (short)f2b(val);
  }
  *(v8s*)(hout + (size_t)v * 256 + co) = o;
}

// batched L0 comp half: out[N+v] = BN(relu(Yx_s[v] + (Aones - Asub) + bsum0))
__global__ void compl0_k(const ushort* __restrict__ Yx, const ushort* __restrict__ Aones,
                         const ushort* __restrict__ Asub, ushort* __restrict__ hout,
                         const float* __restrict__ bsum, const float* __restrict__ gma,
                         const float* __restrict__ bta, const float* __restrict__ rmn,
                         const float* __restrict__ rvr) {
  int i = blockIdx.x * 256 + threadIdx.x;
  if (i >= Nn * 32) return;
  const int v = i >> 5;
  const int co = (i & 31) * 8;
  v8s ys = *(const v8s*)(Yx + (size_t)v * 768 + co);
  v8s ao = *(const v8s*)(Aones + (size_t)v * 256 + co);
  v8s as = *(const v8s*)(Asub + (size_t)v * 256 + co);
  v8s o;
#pragma unroll
  for (int j = 0; j < 8; ++j) {
    const int col = co + j;
    float val = b2f((ushort)ys[j]) + b2f((ushort)ao[j]) - b2f((ushort)as[j]) + bsum[col];
    val = fmaxf(val, 0.f);
    val = (val - rmn[col]) * rsqrtf(rvr[col] + EPSc) * gma[col] + bta[col];
    o[j] = (short)f2b(val);
  }
  *(v8s*)(hout + (size_t)(Nn + v) * 256 + co) = o;
}

// ------------------------------------------------------------------ proj GEMM (mask MLP layer 1)
template <int EPI>
__global__ __launch_bounds__(256) void mfma_gemm2_k(
    const ushort* __restrict__ A, const ushort* __restrict__ W,
    ushort* __restrict__ Cout, int M, const float* __restrict__ bias) {
  __shared__ ushort eplds[4][32][72];
  const int tid = threadIdx.x;
  const int wid = tid >> 6, lane = tid & 63;
  const int wr = wid & 1, wc = wid >> 1;
  const int m0 = blockIdx.x * 64 + wr * 32;
  const int n0 = blockIdx.y * 128 + wc * 64;
  const int lrow = lane & 15;
  const int klo = (lane >> 4) * 8;
  int rowA[2];
#pragma unroll
  for (int fi = 0; fi < 2; ++fi) {
    int r = m0 + fi * 16 + lrow;
    rowA[fi] = (r < M) ? r : (M - 1);
  }
  v8s a[8][2];
#pragma unroll
  for (int c = 0; c < 8; ++c)
#pragma unroll
    for (int fi = 0; fi < 2; ++fi)
      a[c][fi] = *(const v8s*)(A + (size_t)rowA[fi] * 256 + c * 32 + klo);
  v4f acc[2][4] = {};
#pragma unroll
  for (int c = 0; c < 8; ++c) {
    v8s b[4];
#pragma unroll
    for (int fj = 0; fj < 4; ++fj)
      b[fj] = *(const v8s*)(W + (size_t)(n0 + fj * 16 + lrow) * 256 + c * 32 + klo);
#pragma unroll
    for (int fi = 0; fi < 2; ++fi)
#pragma unroll
      for (int fj = 0; fj < 4; ++fj)
        acc[fi][fj] = __builtin_amdgcn_mfma_f32_16x16x32_bf16(a[c][fi], b[fj], acc[fi][fj], 0, 0, 0);
  }
#pragma unroll
  for (int fj = 0; fj < 4; ++fj) {
    const int col = n0 + fj * 16 + lrow;
    const float bsv = bias ? bias[col] : 0.f;
#pragma unroll
    for (int fi = 0; fi < 2; ++fi) {
      const int rl0 = fi * 16 + ((lane >> 4) << 2);
#pragma unroll
      for (int r = 0; r < 4; ++r)
        eplds[wid][rl0 + r][fj * 16 + lrow] = f2b(acc[fi][fj][r] + bsv);
    }
  }
#pragma unroll
  for (int i = 0; i < 4; ++i) {
    const int rl = (lane >> 2) + (i & 1) * 16;
    const int oct = (lane & 3) + (i >> 1) * 4;
    v8s val = *(const v8s*)&eplds[wid][rl][oct * 8];
    const int grow = m0 + rl;
    if (grow < M)
      *(v8s*)(Cout + (size_t)grow * 256 + n0 + oct * 8) = val;
  }
}

// ------------------------------------------------------------------ edge MLP: MFMA, no LDS
__global__ __launch_bounds__(256) void edge_mlp3_k(const ushort* __restrict__ P,
                                                   const int* __restrict__ src, const int* __restrict__ dst,
                                                   const ushort* __restrict__ W2b,
                                                   const float* __restrict__ b2, const float* __restrict__ w3,
                                                   const float* __restrict__ b3,
                                                   float* __restrict__ maskOut) {
  const int tid = threadIdx.x;
  const int w = tid >> 6, lane = tid & 63;
  const int e0 = blockIdx.x * 64 + w * 16;
  const int le = lane & 15;
  const int kq = lane >> 4;
  const int klo = kq * 8;
  const int eA = e0 + le;
  const int s_ = src[eA], d_ = dst[eA];
  const ushort* ps = P + (size_t)s_ * 256;
  const ushort* pd = P + (size_t)d_ * 256 + 128;
  v4f acc[4] = {};
#pragma unroll
  for (int kc = 0; kc < 128; kc += 32) {
    v8s as = *(const v8s*)(ps + kc + klo);
    v8s ad = *(const v8s*)(pd + kc + klo);
    v8s h;
#pragma unroll
    for (int j = 0; j < 8; ++j) {
      float v = fmaxf(b2f((ushort)as[j]) + b2f((ushort)ad[j]), 0.f);
      h[j] = (short)f2b(v);
    }
#pragma unroll
    for (int fj = 0; fj < 4; ++fj) {
      v8s b = *(const v8s*)(W2b + (size_t)(fj * 16 + le) * 128 + kc + klo);
      acc[fj] = __builtin_amdgcn_mfma_f32_16x16x32_bf16(h, b, acc[fj], 0, 0, 0);
    }
  }
  float b2v[4], w3v[4];
#pragma unroll
  for (int fj = 0; fj < 4; ++fj) { b2v[fj] = b2[fj * 16 + le]; w3v[fj] = w3[fj * 16 + le]; }
  const float b3v = b3[0];
#pragma unroll
  for (int r = 0; r < 4; ++r) {
    float val = 0.f;
#pragma unroll
    for (int fj = 0; fj < 4; ++fj)
      val += fmaxf(acc[fj][r] + b2v[fj], 0.f) * w3v[fj];
    val += __shfl_xor(val, 1);
    val += __shfl_xor(val, 2);
    val += __shfl_xor(val, 4);
    val += __shfl_xor(val, 8);
    if (le == 0) {
      int er = e0 + kq * 4 + r;
      maskOut[er] = 1.0f / (1.0f + expf(-(val + b3v)));
    }
  }
}

// ------------------------------------------------------------------ pooling / tails
__global__ __launch_bounds__(256) void gemb_sum_k(const ushort* __restrict__ h, const int* __restrict__ batch,
                                                  float* __restrict__ gsum, int batched) {
  const int halfBlocks = Nn / 16;
  int blk = blockIdx.x;
  int half = 0, bi = blk;
  if (batched) { half = (blk >= halfBlocks) ? 1 : 0; bi = blk - half * halfBlocks; }
  const int v0 = bi * 16;
  const int tid = threadIdx.x;
  const size_t base = (size_t)half * Nn;
  float* out = gsum + (size_t)half * (Bb * Dd);
  float acc = 0.0f;
  int curb = batch[v0];
  for (int i = 0; i < 16; ++i) {
    int v = v0 + i;
    int b = batch[v];
    if (b != curb) { atomicAdd(&out[curb * Dd + tid], acc); acc = 0.0f; curb = b; }
    acc += b2f(h[(base + v) * Dd + tid]);
  }
  atomicAdd(&out[curb * Dd + tid], acc);
}

__global__ void gemb_scale_k(float* __restrict__ g, const float* __restrict__ cntf) {
  int blk = blockIdx.x;
  int b = blk & 15;
  g[blk * Dd + threadIdx.x] /= fmaxf(cntf[b], 1.0f);
}

__global__ void anchor_k(const float* __restrict__ g, const float* __restrict__ anchors,
                         float* __restrict__ s_out) {
  __shared__ float red4[4];
  const int b = blockIdx.x, tid = threadIdx.x;
  float gv = g[b * Dd + tid];
  float total = 0.0f;
  for (int k = 0; k < 6; ++k) {
    float d = gv - anchors[k * Dd + tid];
    float v = d * d;
    for (int o = 32; o > 0; o >>= 1) v += __shfl_xor(v, o);
    if ((tid & 63) == 0) red4[tid >> 6] = v;
    __syncthreads();
    if (tid == 0) total += sqrtf(red4[0] + red4[1] + red4[2] + red4[3]);
    __syncthreads();
  }
  if (tid == 0) s_out[b] = total;
}

__global__ void logits_k(const float* __restrict__ gsub, const float* __restrict__ gcomp,
                         const float* __restrict__ Wc, const float* __restrict__ bc,
                         float* __restrict__ outL) {
  __shared__ float red4[4];
  const int blk = blockIdx.x;
  const int set = blk >> 4, b = blk & 15;
  const float* g = set ? gcomp : gsub;
  const int tid = threadIdx.x;
  float gv = g[b * Dd + tid];
  for (int c = 0; c < 2; ++c) {
    float v = gv * Wc[c * Dd + tid];
    for (int o = 32; o > 0; o >>= 1) v += __shfl_xor(v, o);
    if ((tid & 63) == 0) red4[tid >> 6] = v;
    __syncthreads();
    if (tid == 0) outL[set * 32 + b * 2 + c] = red4[0] + red4[1] + red4[2] + red4[3] + bc[c];
    __syncthreads();
  }
}

__global__ void final_k(const float* __restrict__ L, const int* __restrict__ labels,
                        const float* __restrict__ s_orig, const float* __restrict__ s_sub,
                        float* __restrict__ out) {
  if (threadIdx.x == 0) {
    float Lp = 0, Lu = 0, La = 0;
    const float u = 0.5f;
    for (int b = 0; b < 16; ++b) {
      float l0 = L[b * 2], l1 = L[b * 2 + 1];
      float m = fmaxf(l0, l1);
      float lse = m + logf(expf(l0 - m) + expf(l1 - m));
      int lab = labels[b];
      Lp += -((lab ? l1 : l0) - lse);
      float c0 = L[32 + b * 2], c1 = L[32 + b * 2 + 1];
      float mm = fmaxf(c0, c1);
      float e0 = expf(c0 - mm), e1 = expf(c1 - mm), Z = e0 + e1;
      Lu += u * (logf(u) - logf(e0 / Z + 1e-8f)) + u * (logf(u) - logf(e1 / Z + 1e-8f));
      float dd = s_sub[b] - s_orig[b];
      La += dd * dd;
    }
    Lp /= 16.0f; Lu /= 16.0f; La /= 16.0f;
    out[0] = 0.5f * Lp + 0.3f * Lu + 0.2f * La;
    out[1] = Lp; out[2] = Lu; out[3] = La;
  }
}

// ------------------------------------------------------------------ host
extern "C" void kernel_launch(void* const* d_in, const int* in_sizes, int n_in,
                              void* d_out, int out_size, void* d_ws, size_t ws_size,
                              hipStream_t stream) {
  (void)in_sizes; (void)n_in; (void)out_size; (void)ws_size;
  const float* x    = (const float*)d_in[0];
  const int* ei     = (const int*)d_in[1];
  const int* batch  = (const int*)d_in[2];
  const int* labels = (const int*)d_in[3];
  const float* mw1 = (const float*)d_in[4];
  const float* mb1 = (const float*)d_in[5];
  const float* mw2 = (const float*)d_in[6];
  const float* mb2 = (const float*)d_in[7];
  const float* mw3 = (const float*)d_in[8];
  const float* mb3 = (const float*)d_in[9];
  const float* Ws   = (const float*)d_in[10];
  const float* bs   = (const float*)d_in[11];
  const float* Win  = (const float*)d_in[12];
  const float* bin_ = (const float*)d_in[13];
  const float* Wout = (const float*)d_in[14];
  const float* bout = (const float*)d_in[15];
  const float* gma  = (const float*)d_in[16];
  const float* bta  = (const float*)d_in[17];
  const float* rmn  = (const float*)d_in[18];
  const float* rvr  = (const float*)d_in[19];
  const float* anchors = (const float*)d_in[20];
  const float* Wc   = (const float*)d_in[21];
  const float* bc   = (const float*)d_in[22];
  const int* srcp = ei;
  const int* dstp = ei + Ee;

  const size_t NH = (size_t)Nn * Dd;   // 5.12M elems
  const size_t NE = 2 * NH;
  const size_t NY = (size_t)Nn * 768;  // 15.36M elems
  ushort* xb   = (ushort*)d_ws;        // NH
  ushort* hA   = xb + NH;              // NE
  ushort* hB   = hA + NE;              // NE
  ushort* Yx   = hB + NE;              // NY (persistent L0 projection of x)
  ushort* Ybuf = Yx + NY;              // NY (per-layer/half scratch; Pb aliases)
  ushort* Pb   = Ybuf;
  ushort* Aones = Ybuf + NY;           // NH
  ushort* Asub  = Aones + NH;          // NH
  ushort* Wsb   = Asub + NH;
  ushort* Winb  = Wsb + 3 * 65536;
  ushort* Woutb = Winb + 3 * 65536;
  ushort* Wcombb = Woutb + 3 * 65536;
  ushort* W2b    = Wcombb + 65536;
  float* bcomb = (float*)(W2b + 8192);
  float* minA  = bcomb + 256;
  float* moutA = minA + Ee;
  int* off_in   = (int*)(moutA + Ee);
  int* off_out  = off_in + (Nn + 1);
  int* cur_in   = off_out + (Nn + 1);
  int* cur_out  = cur_in + Nn;
  int* in_src   = cur_out + Nn;
  int* in_eid   = in_src + Ee;
  int* out_dst  = in_eid + Ee;
  int* out_eid  = out_dst + Ee;
  int* counts_in  = out_eid + Ee;
  int* counts_out = counts_in + Nn;
  float* cntf      = (float*)(counts_out + Nn);
  float* gemb_orig = cntf + Bb;
  float* gemb_sub  = gemb_orig + Bb * Dd;
  float* gemb_comp = gemb_sub + Bb * Dd;
  float* bsum    = gemb_comp + Bb * Dd;
  float* s_orig  = bsum + 3 * Dd;
  float* s_sub   = s_orig + Bb;
  float* logitsb = s_sub + Bb;

  float* outF = (float*)d_out;
  float* maskp = outF + 4;

  const size_t zero_bytes = (char*)bsum - (char*)counts_in;
  hipMemsetAsync(counts_in, 0, zero_bytes, stream);

  hist_edges_k<<<(Ee + 255) / 256, 256, 0, stream>>>(srcp, dstp, counts_in, counts_out);
  cnt_batch_k<<<1, 64, 0, stream>>>(batch, cntf);
  scan_k<<<1, 1024, 0, stream>>>(counts_in, counts_out, off_in, off_out, cur_in, cur_out);
  scatter_k<<<(Ee + 255) / 256, 256, 0, stream>>>(srcp, dstp, cur_in, cur_out, in_src, in_eid, out_dst, out_eid);
  prep_bsum_k<<<1, 256, 0, stream>>>(bs, bin_, bout, bsum);

  c_f2b_k<<<(3 * 65536 + 255) / 256, 256, 0, stream>>>(Ws, Wsb, 3 * 65536);
  c_f2b_k<<<(3 * 65536 + 255) / 256, 256, 0, stream>>>(Win, Winb, 3 * 65536);
  c_f2b_k<<<(3 * 65536 + 255) / 256, 256, 0, stream>>>(Wout, Woutb, 3 * 65536);
  prep_mlp_k<<<256, 256, 0, stream>>>(mw1, mb1, mw2, Wcombb, W2b, bcomb);

  auto run_gemm768 = [&](const ushort* h, ushort* Yout, int l) {
    dim3 gg((Nn + 63) / 64, 6);
    gemm768_k<<<gg, 256, 0, stream>>>(h, Wsb + (size_t)l * 65536, Winb + (size_t)l * 65536,
                                      Woutb + (size_t)l * 65536, Yout, Nn);
  };
  auto bn = [&](int l) { return bsum + l * 256; };
  const int aggBlocks = (Nn + 7) / 8;

  // ---- encoder #1 (ones mask)
  copyxb_k<<<(Nn * Dd / 4 + 255) / 256, 256, 0, stream>>>(x, xb);
  run_gemm768(xb, Yx, 0);  // persistent: reused by batched L0
  aggepi_k<0, 1><<<aggBlocks, 256, 0, stream>>>(
      Yx, hB, Aones, off_in, in_src, off_out, out_dst, nullptr, nullptr,
      bn(0), gma, bta, rmn, rvr);
  run_gemm768(hB, Ybuf, 1);
  aggepi_k<0, 0><<<aggBlocks, 256, 0, stream>>>(
      Ybuf, hA, nullptr, off_in, in_src, off_out, out_dst, nullptr, nullptr,
      bn(1), gma + 256, bta + 256, rmn + 256, rvr + 256);
  run_gemm768(hA, Ybuf, 2);
  aggepi_k<0, 0><<<aggBlocks, 256, 0, stream>>>(
      Ybuf, hB, nullptr, off_in, in_src, off_out, out_dst, nullptr, nullptr,
      bn(2), gma + 512, bta + 512, rmn + 512, rvr + 512);
  // node_emb = hB

  gemb_sum_k<<<Nn / 16, 256, 0, stream>>>(hB, batch, gemb_orig, 0);
  gemb_scale_k<<<Bb, 256, 0, stream>>>(gemb_orig, cntf);
  anchor_k<<<Bb, 256, 0, stream>>>(gemb_orig, anchors, s_orig);

  // ---- packed projection P = [emb@W1a^T + b1 | emb@W1b^T] (Pb aliases Ybuf)
  {
    dim3 gp((Nn + 63) / 64, 2);
    mfma_gemm2_k<3><<<gp, 256, 0, stream>>>(hB, Wcombb, Pb, Nn, bcomb);
  }
  edge_mlp3_k<<<Ee / 64, 256, 0, stream>>>(Pb, srcp, dstp, W2b, mb2, mw3, mb3, maskp);
  permmask_k<<<(Ee + 255) / 256, 256, 0, stream>>>(maskp, in_eid, out_eid, minA, moutA);

  // ---- batched encoders #2/#3 (mask & 1-mask), processed per half
  // L0: Yx reused (no GEMM); sub = masked agg of Yx; comp = ones - sub
  aggepi_k<1, 1><<<aggBlocks, 256, 0, stream>>>(
      Yx, hA, Asub, off_in, in_src, off_out, out_dst, minA, moutA,
      bn(0), gma, bta, rmn, rvr);
  compl0_k<<<(Nn * 32 + 255) / 256, 256, 0, stream>>>(Yx, Aones, Asub, hA,
                                                      bn(0), gma, bta, rmn, rvr);
  // L1
  run_gemm768(hA, Ybuf, 1);
  aggepi_k<1, 0><<<aggBlocks, 256, 0, stream>>>(
      Ybuf, hB, nullptr, off_in, in_src, off_out, out_dst, minA, moutA,
      bn(1), gma + 256, bta + 256, rmn + 256, rvr + 256);
  run_gemm768(hA + NH, Ybuf, 1);
  aggepi_k<2, 0><<<aggBlocks, 256, 0, stream>>>(
      Ybuf, hB + NH, nullptr, off_in, in_src, off_out, out_dst, minA, moutA,
      bn(1), gma + 256, bta + 256, rmn + 256, rvr + 256);
  // L2
  run_gemm768(hB, Ybuf, 2);
  aggepi_k<1, 0><<<aggBlocks, 256, 0, stream>>>(
      Ybuf, hA, nullptr, off_in, in_src, off_out, out_dst, minA, moutA,
      bn(2), gma + 512, bta + 512, rmn + 512, rvr + 512);
  run_gemm768(hB + NH, Ybuf, 2);
  aggepi_k<2, 0><<<aggBlocks, 256, 0, stream>>>(
      Ybuf, hA + NH, nullptr, off_in, in_src, off_out, out_dst, minA, moutA,
      bn(2), gma + 512, bta + 512, rmn + 512, rvr + 512);
  // hA = [h_sub; h_comp]

  gemb_sum_k<<<2 * (Nn / 16), 256, 0, stream>>>(hA, batch, gemb_sub, 1);
  gemb_scale_k<<<2 * Bb, 256, 0, stream>>>(gemb_sub, cntf);
  anchor_k<<<Bb, 256, 0, stream>>>(gemb_sub, anchors, s_sub);
  logits_k<<<2 * Bb, 256, 0, stream>>>(gemb_sub, gemb_comp, Wc, bc, logitsb);
  final_k<<<1, 64, 0, stream>>>(logitsb, labels, s_orig, s_sub, outF);
}

// Round 11
// 958.996 us; speedup vs baseline: 5.0368x; 1.0029x over previous
//
#include <hip/hip_runtime.h>
#include <hip/hip_bf16.h>

constexpr int Nn = 20000;
constexpr int Ee = 320000;
constexpr int Dd = 256;
constexpr int Bb = 16;
constexpr float EPSc = 1e-5f;

using v8s = __attribute__((ext_vector_type(8))) short;
using v4f = __attribute__((ext_vector_type(4))) float;

__device__ __forceinline__ float b2f(ushort u) { return __uint_as_float(((unsigned)u) << 16); }
__device__ __forceinline__ ushort f2b(float f) {
  __hip_bfloat16 h = __float2bfloat16(f);
  return *reinterpret_cast<ushort*>(&h);
}

// ------------------------------------------------------------------ graph prep
__global__ void hist_edges_k(const int* __restrict__ src, const int* __restrict__ dst,
                             int* __restrict__ cin, int* __restrict__ cout) {
  int e = blockIdx.x * 256 + threadIdx.x;
  if (e < Ee) { atomicAdd(&cin[dst[e]], 1); atomicAdd(&cout[src[e]], 1); }
}

__global__ void cnt_batch_k(const int* __restrict__ batch, float* __restrict__ cntf) {
  int b = threadIdx.x;
  if (b < Bb) {
    int lo = 0, hi = Nn;
    while (lo < hi) { int mid = (lo + hi) >> 1; if (batch[mid] < b) lo = mid + 1; else hi = mid; }
    int lb = lo;
    lo = 0; hi = Nn;
    while (lo < hi) { int mid = (lo + hi) >> 1; if (batch[mid] <= b) lo = mid + 1; else hi = mid; }
    cntf[b] = (float)(lo - lb);
  }
}

__global__ __launch_bounds__(1024) void scan_k(const int* __restrict__ cin,
                                               const int* __restrict__ cout,
                                               int* __restrict__ off_in, int* __restrict__ off_out,
                                               int* __restrict__ cur_in, int* __restrict__ cur_out) {
  __shared__ int part[1024];
  const int tid = threadIdx.x;
  for (int which = 0; which < 2; ++which) {
    const int* cnt = which ? cout : cin;
    int* off = which ? off_out : off_in;
    int* curp = which ? cur_out : cur_in;
    int vals[20];
    int base = tid * 20;
    int local = 0;
#pragma unroll
    for (int i = 0; i < 20; ++i) {
      int idx = base + i;
      int v = (idx < Nn) ? cnt[idx] : 0;
      vals[i] = v; local += v;
    }
    part[tid] = local;
    __syncthreads();
    for (int ofs = 1; ofs < 1024; ofs <<= 1) {
      int t = (tid >= ofs) ? part[tid - ofs] : 0;
      __syncthreads();
      part[tid] += t;
      __syncthreads();
    }
    int run = part[tid] - local;
#pragma unroll
    for (int i = 0; i < 20; ++i) {
      int idx = base + i;
      if (idx < Nn) { off[idx] = run; curp[idx] = run; run += vals[i]; }
    }
    if (tid == 0) off[Nn] = Ee;
    __syncthreads();
  }
}

__global__ void scatter_k(const int* __restrict__ src, const int* __restrict__ dst,
                          int* __restrict__ cur_in, int* __restrict__ cur_out,
                          int* __restrict__ in_src, int* __restrict__ in_eid,
                          int* __restrict__ out_dst, int* __restrict__ out_eid) {
  int e = blockIdx.x * 256 + threadIdx.x;
  if (e < Ee) {
    int d = dst[e], s = src[e];
    int p = atomicAdd(&cur_in[d], 1);  in_src[p] = s;  in_eid[p] = e;
    int q = atomicAdd(&cur_out[s], 1); out_dst[q] = d; out_eid[q] = e;
  }
}

__global__ void prep_bsum_k(const float* __restrict__ bs, const float* __restrict__ bin,
                            const float* __restrict__ bout, float* __restrict__ bsum) {
  int t = threadIdx.x;
  for (int l = 0; l < 3; ++l) bsum[l * 256 + t] = bs[l * 256 + t] + bin[l * 256 + t] + bout[l * 256 + t];
}

__global__ void copyxb_k(const float* __restrict__ x, ushort* __restrict__ h) {
  const int n4 = Nn * Dd / 4;
  int i = blockIdx.x * 256 + threadIdx.x;
  if (i < n4) {
    float4 v = ((const float4*)x)[i];
    ushort4 o; o.x = f2b(v.x); o.y = f2b(v.y); o.z = f2b(v.z); o.w = f2b(v.w);
    ((ushort4*)h)[i] = o;
  }
}

__global__ void c_f2b_k(const float* __restrict__ s, ushort* __restrict__ d, int n) {
  int i = blockIdx.x * 256 + threadIdx.x;
  if (i < n) d[i] = f2b(s[i]);
}

// Wcombb[256][256]: rows 0-127 = mw1[r][0:256], rows 128-255 = mw1[r-128][256:512]
__global__ void prep_mlp_k(const float* __restrict__ mw1, const float* __restrict__ mb1,
                           const float* __restrict__ mw2,
                           ushort* __restrict__ Wcombb, ushort* __restrict__ W2b,
                           float* __restrict__ bcomb) {
  int i = blockIdx.x * 256 + threadIdx.x;
  if (i < 65536) {
    int r = i >> 8, c = i & 255;
    float v = (r < 128) ? mw1[r * 512 + c] : mw1[(r - 128) * 512 + 256 + c];
    Wcombb[i] = f2b(v);
  }
  if (i < 8192) W2b[i] = f2b(mw2[i]);
  if (i < 256) bcomb[i] = (i < 128) ? mb1[i] : 0.f;
}

__global__ void permmask_k(const float* __restrict__ mask,
                           const int* __restrict__ in_eid, const int* __restrict__ out_eid,
                           float* __restrict__ minA, float* __restrict__ moutA) {
  int i = blockIdx.x * 256 + threadIdx.x;
  if (i < Ee) { minA[i] = mask[in_eid[i]]; moutA[i] = mask[out_eid[i]]; }
}

// ------------------------------------------------------------------ GEMM768 (A-strip register preload)
__global__ __launch_bounds__(256) void gemm768_k(
    const ushort* __restrict__ A, const ushort* __restrict__ W0,
    const ushort* __restrict__ W1, const ushort* __restrict__ W2,
    ushort* __restrict__ Y, int M) {
  __shared__ ushort eplds[4][32][72];
  const int tid = threadIdx.x;
  const int wid = tid >> 6, lane = tid & 63;
  const int wr = wid & 1, wc = wid >> 1;
  const int m0 = blockIdx.x * 64 + wr * 32;
  const int seg = blockIdx.y >> 1;
  const ushort* Wp = (seg == 0) ? W0 : ((seg == 1) ? W1 : W2);
  const int nw0 = (blockIdx.y & 1) * 128 + wc * 64;
  const int lrow = lane & 15;
  const int klo = (lane >> 4) * 8;
  int rowA[2];
#pragma unroll
  for (int fi = 0; fi < 2; ++fi) {
    int r = m0 + fi * 16 + lrow;
    rowA[fi] = (r < M) ? r : (M - 1);
  }
  v8s a[8][2];
#pragma unroll
  for (int c = 0; c < 8; ++c)
#pragma unroll
    for (int fi = 0; fi < 2; ++fi)
      a[c][fi] = *(const v8s*)(A + (size_t)rowA[fi] * 256 + c * 32 + klo);
  v4f acc[2][4] = {};
#pragma unroll
  for (int c = 0; c < 8; ++c) {
    v8s b[4];
#pragma unroll
    for (int fj = 0; fj < 4; ++fj)
      b[fj] = *(const v8s*)(Wp + (size_t)(nw0 + fj * 16 + lrow) * 256 + c * 32 + klo);
#pragma unroll
    for (int fi = 0; fi < 2; ++fi)
#pragma unroll
      for (int fj = 0; fj < 4; ++fj)
        acc[fi][fj] = __builtin_amdgcn_mfma_f32_16x16x32_bf16(a[c][fi], b[fj], acc[fi][fj], 0, 0, 0);
  }
#pragma unroll
  for (int fj = 0; fj < 4; ++fj)
#pragma unroll
    for (int fi = 0; fi < 2; ++fi) {
      const int rl0 = fi * 16 + ((lane >> 4) << 2);
#pragma unroll
      for (int r = 0; r < 4; ++r)
        eplds[wid][rl0 + r][fj * 16 + lrow] = f2b(acc[fi][fj][r]);
    }
  const int colbase = blockIdx.y * 128 + wc * 64;
#pragma unroll
  for (int i = 0; i < 4; ++i) {
    const int rl = (lane >> 2) + (i & 1) * 16;
    const int oct = (lane & 3) + (i >> 1) * 4;
    v8s val = *(const v8s*)&eplds[wid][rl][oct * 8];
    const int grow = m0 + rl;
    if (grow < M)
      *(v8s*)(Y + (size_t)grow * 768 + colbase + oct * 8) = val;
  }
}

// ------------------------------------------------------------------ agg + epilogue (8-deep gather unroll)
// out[v] = BN(relu(Y[v][0:256] + sum_in m*Y_in[u] + sum_out m*Y_out[u] + bsum))
// MODE 0: m=1 ; MODE 1: m=mask ; MODE 2: m=1-mask.  WR 1: save raw agg sum.
template <int MODE, int WR>
__global__ __launch_bounds__(256) void aggepi_k(
    const ushort* __restrict__ Y, ushort* __restrict__ hout, ushort* __restrict__ raw,
    const int* __restrict__ off_in, const int* __restrict__ in_src,
    const int* __restrict__ off_out, const int* __restrict__ out_dst,
    const float* __restrict__ minA, const float* __restrict__ moutA,
    const float* __restrict__ bsum, const float* __restrict__ gma,
    const float* __restrict__ bta, const float* __restrict__ rmn, const float* __restrict__ rvr) {
  const int g = threadIdx.x >> 5;
  const int lane = threadIdx.x & 31;
  const int v = blockIdx.x * 8 + g;
  if (v >= Nn) return;
  const int co = lane * 8;
  float acc[8] = {};
#pragma unroll
  for (int dir = 0; dir < 2; ++dir) {
    const int* offs = dir ? off_out : off_in;
    const int* nbr  = dir ? out_dst : in_src;
    const float* ma = dir ? moutA : minA;
    const ushort* Yg = Y + (dir ? 512 : 256) + co;
    const int s = offs[v], e = offs[v + 1];
    int i = s;
    for (; i + 8 <= e; i += 8) {
      int u[8]; float m[8];
#pragma unroll
      for (int t = 0; t < 8; ++t) {
        u[t] = nbr[i + t];
        m[t] = (MODE == 0) ? 1.f : (MODE == 1 ? ma[i + t] : 1.f - ma[i + t]);
      }
      v8s r[8];
#pragma unroll
      for (int t = 0; t < 8; ++t) r[t] = *(const v8s*)(Yg + (size_t)u[t] * 768);
#pragma unroll
      for (int t = 0; t < 8; ++t)
#pragma unroll
        for (int j = 0; j < 8; ++j) acc[j] += m[t] * b2f((ushort)r[t][j]);
    }
    for (; i + 4 <= e; i += 4) {
      int u[4]; float m[4];
#pragma unroll
      for (int t = 0; t < 4; ++t) {
        u[t] = nbr[i + t];
        m[t] = (MODE == 0) ? 1.f : (MODE == 1 ? ma[i + t] : 1.f - ma[i + t]);
      }
      v8s r[4];
#pragma unroll
      for (int t = 0; t < 4; ++t) r[t] = *(const v8s*)(Yg + (size_t)u[t] * 768);
#pragma unroll
      for (int t = 0; t < 4; ++t)
#pragma unroll
        for (int j = 0; j < 8; ++j) acc[j] += m[t] * b2f((ushort)r[t][j]);
    }
    for (; i < e; ++i) {
      int u = nbr[i];
      float m = (MODE == 0) ? 1.f : (MODE == 1 ? ma[i] : 1.f - ma[i]);
      v8s r = *(const v8s*)(Yg + (size_t)u * 768);
#pragma unroll
      for (int j = 0; j < 8; ++j) acc[j] += m * b2f((ushort)r[j]);
    }
  }
  if (WR) {
    v8s rw;
#pragma unroll
    for (int j = 0; j < 8; ++j) rw[j] = (short)f2b(acc[j]);
    *(v8s*)(raw + (size_t)v * 256 + co) = rw;
  }
  v8s ys = *(const v8s*)(Y + (size_t)v * 768 + co);
  v8s o;
#pragma unroll
  for (int j = 0; j < 8; ++j) {
    const int col = co + j;
    float val = acc[j] + b2f((ushort)ys[j]) + bsum[col];
    val = fmaxf(val, 0.f);
    val = (val - rmn[col]) * rsqrtf(rvr[col] + EPSc) * gma[col] + bta[col];
    o[j] = (short)f2b(val);
  }
  *(v8s*)(hout + (size_t)v * 256 + co) = o;
}

// batched L0 comp half: out[N+v] = BN(relu(Yx_s[v] + (Aones - Asub) + bsum0))
__global__ void compl0_k(const ushort* __restrict__ Yx, const ushort* __restrict__ Aones,
                         const ushort* __restrict__ Asub, ushort* __restrict__ hout,
                         const float* __restrict__ bsum, const float* __restrict__ gma,
                         const float* __restrict__ bta, const float* __restrict__ rmn,
                         const float* __restrict__ rvr) {
  int i = blockIdx.x * 256 + threadIdx.x;
  if (i >= Nn * 32) return;
  const int v = i >> 5;
  const int co = (i & 31) * 8;
  v8s ys = *(const v8s*)(Yx + (size_t)v * 768 + co);
  v8s ao = *(const v8s*)(Aones + (size_t)v * 256 + co);
  v8s as = *(const v8s*)(Asub + (size_t)v * 256 + co);
  v8s o;
#pragma unroll
  for (int j = 0; j < 8; ++j) {
    const int col = co + j;
    float val = b2f((ushort)ys[j]) + b2f((ushort)ao[j]) - b2f((ushort)as[j]) + bsum[col];
    val = fmaxf(val, 0.f);
    val = (val - rmn[col]) * rsqrtf(rvr[col] + EPSc) * gma[col] + bta[col];
    o[j] = (short)f2b(val);
  }
  *(v8s*)(hout + (size_t)(Nn + v) * 256 + co) = o;
}

// ------------------------------------------------------------------ proj GEMM (mask MLP layer 1)
template <int EPI>
__global__ __launch_bounds__(256) void mfma_gemm2_k(
    const ushort* __restrict__ A, const ushort* __restrict__ W,
    ushort* __restrict__ Cout, int M, const float* __restrict__ bias) {
  __shared__ ushort eplds[4][32][72];
  const int tid = threadIdx.x;
  const int wid = tid >> 6, lane = tid & 63;
  const int wr = wid & 1, wc = wid >> 1;
  const int m0 = blockIdx.x * 64 + wr * 32;
  const int n0 = blockIdx.y * 128 + wc * 64;
  const int lrow = lane & 15;
  const int klo = (lane >> 4) * 8;
  int rowA[2];
#pragma unroll
  for (int fi = 0; fi < 2; ++fi) {
    int r = m0 + fi * 16 + lrow;
    rowA[fi] = (r < M) ? r : (M - 1);
  }
  v8s a[8][2];
#pragma unroll
  for (int c = 0; c < 8; ++c)
#pragma unroll
    for (int fi = 0; fi < 2; ++fi)
      a[c][fi] = *(const v8s*)(A + (size_t)rowA[fi] * 256 + c * 32 + klo);
  v4f acc[2][4] = {};
#pragma unroll
  for (int c = 0; c < 8; ++c) {
    v8s b[4];
#pragma unroll
    for (int fj = 0; fj < 4; ++fj)
      b[fj] = *(const v8s*)(W + (size_t)(n0 + fj * 16 + lrow) * 256 + c * 32 + klo);
#pragma unroll
    for (int fi = 0; fi < 2; ++fi)
#pragma unroll
      for (int fj = 0; fj < 4; ++fj)
        acc[fi][fj] = __builtin_amdgcn_mfma_f32_16x16x32_bf16(a[c][fi], b[fj], acc[fi][fj], 0, 0, 0);
  }
#pragma unroll
  for (int fj = 0; fj < 4; ++fj) {
    const int col = n0 + fj * 16 + lrow;
    const float bsv = bias ? bias[col] : 0.f;
#pragma unroll
    for (int fi = 0; fi < 2; ++fi) {
      const int rl0 = fi * 16 + ((lane >> 4) << 2);
#pragma unroll
      for (int r = 0; r < 4; ++r)
        eplds[wid][rl0 + r][fj * 16 + lrow] = f2b(acc[fi][fj][r] + bsv);
    }
  }
#pragma unroll
  for (int i = 0; i < 4; ++i) {
    const int rl = (lane >> 2) + (i & 1) * 16;
    const int oct = (lane & 3) + (i >> 1) * 4;
    v8s val = *(const v8s*)&eplds[wid][rl][oct * 8];
    const int grow = m0 + rl;
    if (grow < M)
      *(v8s*)(Cout + (size_t)grow * 256 + n0 + oct * 8) = val;
  }
}

// ------------------------------------------------------------------ edge MLP: MFMA, no LDS, preloaded P fragments
__global__ __launch_bounds__(256) void edge_mlp3_k(const ushort* __restrict__ P,
                                                   const int* __restrict__ src, const int* __restrict__ dst,
                                                   const ushort* __restrict__ W2b,
                                                   const float* __restrict__ b2, const float* __restrict__ w3,
                                                   const float* __restrict__ b3,
                                                   float* __restrict__ maskOut) {
  const int tid = threadIdx.x;
  const int w = tid >> 6, lane = tid & 63;
  const int e0 = blockIdx.x * 64 + w * 16;
  const int le = lane & 15;
  const int kq = lane >> 4;
  const int klo = kq * 8;
  const int eA = e0 + le;
  const int s_ = src[eA], d_ = dst[eA];
  const ushort* ps = P + (size_t)s_ * 256;
  const ushort* pd = P + (size_t)d_ * 256 + 128;
  // preload all 8 fragments (deep gather queue)
  v8s as[4], ad[4];
#pragma unroll
  for (int c = 0; c < 4; ++c) {
    as[c] = *(const v8s*)(ps + c * 32 + klo);
    ad[c] = *(const v8s*)(pd + c * 32 + klo);
  }
  v4f acc[4] = {};
#pragma unroll
  for (int c = 0; c < 4; ++c) {
    v8s h;
#pragma unroll
    for (int j = 0; j < 8; ++j) {
      float v = fmaxf(b2f((ushort)as[c][j]) + b2f((ushort)ad[c][j]), 0.f);
      h[j] = (short)f2b(v);
    }
#pragma unroll
    for (int fj = 0; fj < 4; ++fj) {
      v8s b = *(const v8s*)(W2b + (size_t)(fj * 16 + le) * 128 + c * 32 + klo);
      acc[fj] = __builtin_amdgcn_mfma_f32_16x16x32_bf16(h, b, acc[fj], 0, 0, 0);
    }
  }
  float b2v[4], w3v[4];
#pragma unroll
  for (int fj = 0; fj < 4; ++fj) { b2v[fj] = b2[fj * 16 + le]; w3v[fj] = w3[fj * 16 + le]; }
  const float b3v = b3[0];
#pragma unroll
  for (int r = 0; r < 4; ++r) {
    float val = 0.f;
#pragma unroll
    for (int fj = 0; fj < 4; ++fj)
      val += fmaxf(acc[fj][r] + b2v[fj], 0.f) * w3v[fj];
    val += __shfl_xor(val, 1);
    val += __shfl_xor(val, 2);
    val += __shfl_xor(val, 4);
    val += __shfl_xor(val, 8);
    if (le == 0) {
      int er = e0 + kq * 4 + r;
      maskOut[er] = 1.0f / (1.0f + expf(-(val + b3v)));
    }
  }
}

// ------------------------------------------------------------------ pooling / tails
__global__ __launch_bounds__(256) void gemb_sum_k(const ushort* __restrict__ h, const int* __restrict__ batch,
                                                  float* __restrict__ gsum, int batched) {
  const int halfBlocks = Nn / 16;
  int blk = blockIdx.x;
  int half = 0, bi = blk;
  if (batched) { half = (blk >= halfBlocks) ? 1 : 0; bi = blk - half * halfBlocks; }
  const int v0 = bi * 16;
  const int tid = threadIdx.x;
  const size_t base = (size_t)half * Nn;
  float* out = gsum + (size_t)half * (Bb * Dd);
  float acc = 0.0f;
  int curb = batch[v0];
  for (int i = 0; i < 16; ++i) {
    int v = v0 + i;
    int b = batch[v];
    if (b != curb) { atomicAdd(&out[curb * Dd + tid], acc); acc = 0.0f; curb = b; }
    acc += b2f(h[(base + v) * Dd + tid]);
  }
  atomicAdd(&out[curb * Dd + tid], acc);
}

__global__ void gemb_scale_k(float* __restrict__ g, const float* __restrict__ cntf) {
  int blk = blockIdx.x;
  int b = blk & 15;
  g[blk * Dd + threadIdx.x] /= fmaxf(cntf[b], 1.0f);
}

__global__ void anchor_k(const float* __restrict__ g, const float* __restrict__ anchors,
                         float* __restrict__ s_out) {
  __shared__ float red4[4];
  const int b = blockIdx.x, tid = threadIdx.x;
  float gv = g[b * Dd + tid];
  float total = 0.0f;
  for (int k = 0; k < 6; ++k) {
    float d = gv - anchors[k * Dd + tid];
    float v = d * d;
    for (int o = 32; o > 0; o >>= 1) v += __shfl_xor(v, o);
    if ((tid & 63) == 0) red4[tid >> 6] = v;
    __syncthreads();
    if (tid == 0) total += sqrtf(red4[0] + red4[1] + red4[2] + red4[3]);
    __syncthreads();
  }
  if (tid == 0) s_out[b] = total;
}

__global__ void logits_k(const float* __restrict__ gsub, const float* __restrict__ gcomp,
                         const float* __restrict__ Wc, const float* __restrict__ bc,
                         float* __restrict__ outL) {
  __shared__ float red4[4];
  const int blk = blockIdx.x;
  const int set = blk >> 4, b = blk & 15;
  const float* g = set ? gcomp : gsub;
  const int tid = threadIdx.x;
  float gv = g[b * Dd + tid];
  for (int c = 0; c < 2; ++c) {
    float v = gv * Wc[c * Dd + tid];
    for (int o = 32; o > 0; o >>= 1) v += __shfl_xor(v, o);
    if ((tid & 63) == 0) red4[tid >> 6] = v;
    __syncthreads();
    if (tid == 0) outL[set * 32 + b * 2 + c] = red4[0] + red4[1] + red4[2] + red4[3] + bc[c];
    __syncthreads();
  }
}

__global__ void final_k(const float* __restrict__ L, const int* __restrict__ labels,
                        const float* __restrict__ s_orig, const float* __restrict__ s_sub,
                        float* __restrict__ out) {
  if (threadIdx.x == 0) {
    float Lp = 0, Lu = 0, La = 0;
    const float u = 0.5f;
    for (int b = 0; b < 16; ++b) {
      float l0 = L[b * 2], l1 = L[b * 2 + 1];
      float m = fmaxf(l0, l1);
      float lse = m + logf(expf(l0 - m) + expf(l1 - m));
      int lab = labels[b];
      Lp += -((lab ? l1 : l0) - lse);
      float c0 = L[32 + b * 2], c1 = L[32 + b * 2 + 1];
      float mm = fmaxf(c0, c1);
      float e0 = expf(c0 - mm), e1 = expf(c1 - mm), Z = e0 + e1;
      Lu += u * (logf(u) - logf(e0 / Z + 1e-8f)) + u * (logf(u) - logf(e1 / Z + 1e-8f));
      float dd = s_sub[b] - s_orig[b];
      La += dd * dd;
    }
    Lp /= 16.0f; Lu /= 16.0f; La /= 16.0f;
    out[0] = 0.5f * Lp + 0.3f * Lu + 0.2f * La;
    out[1] = Lp; out[2] = Lu; out[3] = La;
  }
}

// ------------------------------------------------------------------ host
extern "C" void kernel_launch(void* const* d_in, const int* in_sizes, int n_in,
                              void* d_out, int out_size, void* d_ws, size_t ws_size,
                              hipStream_t stream) {
  (void)in_sizes; (void)n_in; (void)out_size; (void)ws_size;
  const float* x    = (const float*)d_in[0];
  const int* ei     = (const int*)d_in[1];
  const int* batch  = (const int*)d_in[2];
  const int* labels = (const int*)d_in[3];
  const float* mw1 = (const float*)d_in[4];
  const float* mb1 = (const float*)d_in[5];
  const float* mw2 = (const float*)d_in[6];
  const float* mb2 = (const float*)d_in[7];
  const float* mw3 = (const float*)d_in[8];
  const float* mb3 = (const float*)d_in[9];
  const float* Ws   = (const float*)d_in[10];
  const float* bs   = (const float*)d_in[11];
  const float* Win  = (const float*)d_in[12];
  const float* bin_ = (const float*)d_in[13];
  const float* Wout = (const float*)d_in[14];
  const float* bout = (const float*)d_in[15];
  const float* gma  = (const float*)d_in[16];
  const float* bta  = (const float*)d_in[17];
  const float* rmn  = (const float*)d_in[18];
  const float* rvr  = (const float*)d_in[19];
  const float* anchors = (const float*)d_in[20];
  const float* Wc   = (const float*)d_in[21];
  const float* bc   = (const float*)d_in[22];
  const int* srcp = ei;
  const int* dstp = ei + Ee;

  const size_t NH = (size_t)Nn * Dd;
  const size_t NE = 2 * NH;
  const size_t NY = (size_t)Nn * 768;
  ushort* xb   = (ushort*)d_ws;
  ushort* hA   = xb + NH;
  ushort* hB   = hA + NE;
  ushort* Yx   = hB + NE;
  ushort* Ybuf = Yx + NY;
  ushort* Pb   = Ybuf;
  ushort* Aones = Ybuf + NY;
  ushort* Asub  = Aones + NH;
  ushort* Wsb   = Asub + NH;
  ushort* Winb  = Wsb + 3 * 65536;
  ushort* Woutb = Winb + 3 * 65536;
  ushort* Wcombb = Woutb + 3 * 65536;
  ushort* W2b    = Wcombb + 65536;
  float* bcomb = (float*)(W2b + 8192);
  float* minA  = bcomb + 256;
  float* moutA = minA + Ee;
  int* off_in   = (int*)(moutA + Ee);
  int* off_out  = off_in + (Nn + 1);
  int* cur_in   = off_out + (Nn + 1);
  int* cur_out  = cur_in + Nn;
  int* in_src   = cur_out + Nn;
  int* in_eid   = in_src + Ee;
  int* out_dst  = in_eid + Ee;
  int* out_eid  = out_dst + Ee;
  int* counts_in  = out_eid + Ee;
  int* counts_out = counts_in + Nn;
  float* cntf      = (float*)(counts_out + Nn);
  float* gemb_orig = cntf + Bb;
  float* gemb_sub  = gemb_orig + Bb * Dd;
  float* gemb_comp = gemb_sub + Bb * Dd;
  float* bsum    = gemb_comp + Bb * Dd;
  float* s_orig  = bsum + 3 * Dd;
  float* s_sub   = s_orig + Bb;
  float* logitsb = s_sub + Bb;

  float* outF = (float*)d_out;
  float* maskp = outF + 4;

  const size_t zero_bytes = (char*)bsum - (char*)counts_in;
  hipMemsetAsync(counts_in, 0, zero_bytes, stream);

  hist_edges_k<<<(Ee + 255) / 256, 256, 0, stream>>>(srcp, dstp, counts_in, counts_out);
  cnt_batch_k<<<1, 64, 0, stream>>>(batch, cntf);
  scan_k<<<1, 1024, 0, stream>>>(counts_in, counts_out, off_in, off_out, cur_in, cur_out);
  scatter_k<<<(Ee + 255) / 256, 256, 0, stream>>>(srcp, dstp, cur_in, cur_out, in_src, in_eid, out_dst, out_eid);
  prep_bsum_k<<<1, 256, 0, stream>>>(bs, bin_, bout, bsum);

  c_f2b_k<<<(3 * 65536 + 255) / 256, 256, 0, stream>>>(Ws, Wsb, 3 * 65536);
  c_f2b_k<<<(3 * 65536 + 255) / 256, 256, 0, stream>>>(Win, Winb, 3 * 65536);
  c_f2b_k<<<(3 * 65536 + 255) / 256, 256, 0, stream>>>(Wout, Woutb, 3 * 65536);
  prep_mlp_k<<<256, 256, 0, stream>>>(mw1, mb1, mw2, Wcombb, W2b, bcomb);

  auto run_gemm768 = [&](const ushort* h, ushort* Yout, int l) {
    dim3 gg((Nn + 63) / 64, 6);
    gemm768_k<<<gg, 256, 0, stream>>>(h, Wsb + (size_t)l * 65536, Winb + (size_t)l * 65536,
                                      Woutb + (size_t)l * 65536, Yout, Nn);
  };
  auto bn = [&](int l) { return bsum + l * 256; };
  const int aggBlocks = (Nn + 7) / 8;

  // ---- encoder #1 (ones mask)
  copyxb_k<<<(Nn * Dd / 4 + 255) / 256, 256, 0, stream>>>(x, xb);
  run_gemm768(xb, Yx, 0);  // persistent: reused by batched L0
  aggepi_k<0, 1><<<aggBlocks, 256, 0, stream>>>(
      Yx, hB, Aones, off_in, in_src, off_out, out_dst, nullptr, nullptr,
      bn(0), gma, bta, rmn, rvr);
  run_gemm768(hB, Ybuf, 1);
  aggepi_k<0, 0><<<aggBlocks, 256, 0, stream>>>(
      Ybuf, hA, nullptr, off_in, in_src, off_out, out_dst, nullptr, nullptr,
      bn(1), gma + 256, bta + 256, rmn + 256, rvr + 256);
  run_gemm768(hA, Ybuf, 2);
  aggepi_k<0, 0><<<aggBlocks, 256, 0, stream>>>(
      Ybuf, hB, nullptr, off_in, in_src, off_out, out_dst, nullptr, nullptr,
      bn(2), gma + 512, bta + 512, rmn + 512, rvr + 512);
  // node_emb = hB

  gemb_sum_k<<<Nn / 16, 256, 0, stream>>>(hB, batch, gemb_orig, 0);
  gemb_scale_k<<<Bb, 256, 0, stream>>>(gemb_orig, cntf);
  anchor_k<<<Bb, 256, 0, stream>>>(gemb_orig, anchors, s_orig);

  // ---- packed projection P = [emb@W1a^T + b1 | emb@W1b^T] (Pb aliases Ybuf)
  {
    dim3 gp((Nn + 63) / 64, 2);
    mfma_gemm2_k<3><<<gp, 256, 0, stream>>>(hB, Wcombb, Pb, Nn, bcomb);
  }
  edge_mlp3_k<<<Ee / 64, 256, 0, stream>>>(Pb, srcp, dstp, W2b, mb2, mw3, mb3, maskp);
  permmask_k<<<(Ee + 255) / 256, 256, 0, stream>>>(maskp, in_eid, out_eid, minA, moutA);

  // ---- batched encoders #2/#3 (mask & 1-mask), processed per half
  aggepi_k<1, 1><<<aggBlocks, 256, 0, stream>>>(
      Yx, hA, Asub, off_in, in_src, off_out, out_dst, minA, moutA,
      bn(0), gma, bta, rmn, rvr);
  compl0_k<<<(Nn * 32 + 255) / 256, 256, 0, stream>>>(Yx, Aones, Asub, hA,
                                                      bn(0), gma, bta, rmn, rvr);
  // L1
  run_gemm768(hA, Ybuf, 1);
  aggepi_k<1, 0><<<aggBlocks, 256, 0, stream>>>(
      Ybuf, hB, nullptr, off_in, in_src, off_out, out_dst, minA, moutA,
      bn(1), gma + 256, bta + 256, rmn + 256, rvr + 256);
  run_gemm768(hA + NH, Ybuf, 1);
  aggepi_k<2, 0><<<aggBlocks, 256, 0, stream>>>(
      Ybuf, hB + NH, nullptr, off_in, in_src, off_out, out_dst, minA, moutA,
      bn(1), gma + 256, bta + 256, rmn + 256, rvr + 256);
  // L2
  run_gemm768(hB, Ybuf, 2);
  aggepi_k<1, 0><<<aggBlocks, 256, 0, stream>>>(
      Ybuf, hA, nullptr, off_in, in_src, off_out, out_dst, minA, moutA,
      bn(2), gma + 512, bta + 512, rmn + 512, rvr + 512);
  run_gemm768(hB + NH, Ybuf, 2);
  aggepi_k<2, 0><<<aggBlocks, 256, 0, stream>>>(
      Ybuf, hA + NH, nullptr, off_in, in_src, off_out, out_dst, minA, moutA,
      bn(2), gma + 512, bta + 512, rmn + 512, rvr + 512);
  // hA = [h_sub; h_comp]

  gemb_sum_k<<<2 * (Nn / 16), 256, 0, stream>>>(hA, batch, gemb_sub, 1);
  gemb_scale_k<<<2 * Bb, 256, 0, stream>>>(gemb_sub, cntf);
  anchor_k<<<Bb, 256, 0, stream>>>(gemb_sub, anchors, s_sub);
  logits_k<<<2 * Bb, 256, 0, stream>>>(gemb_sub, gemb_comp, Wc, bc, logitsb);
  final_k<<<1, 64, 0, stream>>>(logitsb, labels, s_orig, s_sub, outF);
}

// Round 12
// 928.957 us; speedup vs baseline: 5.1997x; 1.0323x over previous
//
#include <hip/hip_runtime.h>
#include <hip/hip_bf16.h>

constexpr int Nn = 20000;
constexpr int Ee = 320000;
constexpr int Dd = 256;
constexpr int Bb = 16;
constexpr float EPSc = 1e-5f;

using v8s = __attribute__((ext_vector_type(8))) short;
using v4f = __attribute__((ext_vector_type(4))) float;

__device__ __forceinline__ float b2f(ushort u) { return __uint_as_float(((unsigned)u) << 16); }
__device__ __forceinline__ ushort f2b(float f) {
  __hip_bfloat16 h = __float2bfloat16(f);
  return *reinterpret_cast<ushort*>(&h);
}

// ------------------------------------------------------------------ graph prep
__global__ void hist_edges_k(const int* __restrict__ src, const int* __restrict__ dst,
                             int* __restrict__ cin, int* __restrict__ cout) {
  int e = blockIdx.x * 256 + threadIdx.x;
  if (e < Ee) { atomicAdd(&cin[dst[e]], 1); atomicAdd(&cout[src[e]], 1); }
}

__global__ void cnt_batch_k(const int* __restrict__ batch, float* __restrict__ cntf) {
  int b = threadIdx.x;
  if (b < Bb) {
    int lo = 0, hi = Nn;
    while (lo < hi) { int mid = (lo + hi) >> 1; if (batch[mid] < b) lo = mid + 1; else hi = mid; }
    int lb = lo;
    lo = 0; hi = Nn;
    while (lo < hi) { int mid = (lo + hi) >> 1; if (batch[mid] <= b) lo = mid + 1; else hi = mid; }
    cntf[b] = (float)(lo - lb);
  }
}

__global__ __launch_bounds__(1024) void scan_k(const int* __restrict__ cin,
                                               const int* __restrict__ cout,
                                               int* __restrict__ off_in, int* __restrict__ off_out,
                                               int* __restrict__ cur_in, int* __restrict__ cur_out) {
  __shared__ int part[1024];
  const int tid = threadIdx.x;
  for (int which = 0; which < 2; ++which) {
    const int* cnt = which ? cout : cin;
    int* off = which ? off_out : off_in;
    int* curp = which ? cur_out : cur_in;
    int vals[20];
    int base = tid * 20;
    int local = 0;
#pragma unroll
    for (int i = 0; i < 20; ++i) {
      int idx = base + i;
      int v = (idx < Nn) ? cnt[idx] : 0;
      vals[i] = v; local += v;
    }
    part[tid] = local;
    __syncthreads();
    for (int ofs = 1; ofs < 1024; ofs <<= 1) {
      int t = (tid >= ofs) ? part[tid - ofs] : 0;
      __syncthreads();
      part[tid] += t;
      __syncthreads();
    }
    int run = part[tid] - local;
#pragma unroll
    for (int i = 0; i < 20; ++i) {
      int idx = base + i;
      if (idx < Nn) { off[idx] = run; curp[idx] = run; run += vals[i]; }
    }
    if (tid == 0) off[Nn] = Ee;
    __syncthreads();
  }
}

__global__ void scatter_k(const int* __restrict__ src, const int* __restrict__ dst,
                          int* __restrict__ cur_in, int* __restrict__ cur_out,
                          int* __restrict__ in_src, int* __restrict__ in_eid,
                          int* __restrict__ out_dst, int* __restrict__ out_eid,
                          int* __restrict__ out_srcn) {
  int e = blockIdx.x * 256 + threadIdx.x;
  if (e < Ee) {
    int d = dst[e], s = src[e];
    int p = atomicAdd(&cur_in[d], 1);  in_src[p] = s;  in_eid[p] = e;
    int q = atomicAdd(&cur_out[s], 1); out_dst[q] = d; out_eid[q] = e; out_srcn[q] = s;
  }
}

__global__ void prep_bsum_k(const float* __restrict__ bs, const float* __restrict__ bin,
                            const float* __restrict__ bout, float* __restrict__ bsum) {
  int t = threadIdx.x;
  for (int l = 0; l < 3; ++l) bsum[l * 256 + t] = bs[l * 256 + t] + bin[l * 256 + t] + bout[l * 256 + t];
}

__global__ void copyxb_k(const float* __restrict__ x, ushort* __restrict__ h) {
  const int n4 = Nn * Dd / 4;
  int i = blockIdx.x * 256 + threadIdx.x;
  if (i < n4) {
    float4 v = ((const float4*)x)[i];
    ushort4 o; o.x = f2b(v.x); o.y = f2b(v.y); o.z = f2b(v.z); o.w = f2b(v.w);
    ((ushort4*)h)[i] = o;
  }
}

__global__ void c_f2b_k(const float* __restrict__ s, ushort* __restrict__ d, int n) {
  int i = blockIdx.x * 256 + threadIdx.x;
  if (i < n) d[i] = f2b(s[i]);
}

// Wcombb[256][256]: rows 0-127 = mw1[r][0:256], rows 128-255 = mw1[r-128][256:512]
__global__ void prep_mlp_k(const float* __restrict__ mw1, const float* __restrict__ mb1,
                           const float* __restrict__ mw2,
                           ushort* __restrict__ Wcombb, ushort* __restrict__ W2b,
                           float* __restrict__ bcomb) {
  int i = blockIdx.x * 256 + threadIdx.x;
  if (i < 65536) {
    int r = i >> 8, c = i & 255;
    float v = (r < 128) ? mw1[r * 512 + c] : mw1[(r - 128) * 512 + 256 + c];
    Wcombb[i] = f2b(v);
  }
  if (i < 8192) W2b[i] = f2b(mw2[i]);
  if (i < 256) bcomb[i] = (i < 128) ? mb1[i] : 0.f;
}

// build in-CSR mask (out-CSR mask written directly by edge MLP)
__global__ void permmask_k(const float* __restrict__ mask,
                           const int* __restrict__ in_eid, float* __restrict__ minA) {
  int i = blockIdx.x * 256 + threadIdx.x;
  if (i < Ee) minA[i] = mask[in_eid[i]];
}

// ------------------------------------------------------------------ GEMM768, XCD-swizzled 1D grid
// grid = gxh*48 blocks; decode so all 6 y-blocks of one x share idx%8 (same XCD L2)
__global__ __launch_bounds__(256) void gemm768_k(
    const ushort* __restrict__ A, const ushort* __restrict__ W0,
    const ushort* __restrict__ W1, const ushort* __restrict__ W2,
    ushort* __restrict__ Y, int M, int gx) {
  __shared__ ushort eplds[4][32][72];
  const int gidx = blockIdx.x;
  const int xhi = gidx / 48;
  const int rem = gidx % 48;
  const int by = rem >> 3;
  const int bx = xhi * 8 + (rem & 7);
  if (bx >= gx) return;
  const int tid = threadIdx.x;
  const int wid = tid >> 6, lane = tid & 63;
  const int wr = wid & 1, wc = wid >> 1;
  const int m0 = bx * 64 + wr * 32;
  const int seg = by >> 1;
  const ushort* Wp = (seg == 0) ? W0 : ((seg == 1) ? W1 : W2);
  const int nw0 = (by & 1) * 128 + wc * 64;
  const int lrow = lane & 15;
  const int klo = (lane >> 4) * 8;
  int rowA[2];
#pragma unroll
  for (int fi = 0; fi < 2; ++fi) {
    int r = m0 + fi * 16 + lrow;
    rowA[fi] = (r < M) ? r : (M - 1);
  }
  v8s a[8][2];
#pragma unroll
  for (int c = 0; c < 8; ++c)
#pragma unroll
    for (int fi = 0; fi < 2; ++fi)
      a[c][fi] = *(const v8s*)(A + (size_t)rowA[fi] * 256 + c * 32 + klo);
  v4f acc[2][4] = {};
#pragma unroll
  for (int c = 0; c < 8; ++c) {
    v8s b[4];
#pragma unroll
    for (int fj = 0; fj < 4; ++fj)
      b[fj] = *(const v8s*)(Wp + (size_t)(nw0 + fj * 16 + lrow) * 256 + c * 32 + klo);
#pragma unroll
    for (int fi = 0; fi < 2; ++fi)
#pragma unroll
      for (int fj = 0; fj < 4; ++fj)
        acc[fi][fj] = __builtin_amdgcn_mfma_f32_16x16x32_bf16(a[c][fi], b[fj], acc[fi][fj], 0, 0, 0);
  }
#pragma unroll
  for (int fj = 0; fj < 4; ++fj)
#pragma unroll
    for (int fi = 0; fi < 2; ++fi) {
      const int rl0 = fi * 16 + ((lane >> 4) << 2);
#pragma unroll
      for (int r = 0; r < 4; ++r)
        eplds[wid][rl0 + r][fj * 16 + lrow] = f2b(acc[fi][fj][r]);
    }
  const int colbase = by * 128 + wc * 64;
#pragma unroll
  for (int i = 0; i < 4; ++i) {
    const int rl = (lane >> 2) + (i & 1) * 16;
    const int oct = (lane & 3) + (i >> 1) * 4;
    v8s val = *(const v8s*)&eplds[wid][rl][oct * 8];
    const int grow = m0 + rl;
    if (grow < M)
      *(v8s*)(Y + (size_t)grow * 768 + colbase + oct * 8) = val;
  }
}

// ------------------------------------------------------------------ agg + epilogue
// MODE 0: m=1, single table ; MODE 1: m=mask, single table (batched L0 sub)
// MODE 2: dual-half batched (node<Nn: m=mask table0 ; node>=Nn: m=1-mask table1)
// WR 1: save raw agg sum
template <int MODE, int WR>
__global__ __launch_bounds__(256) void aggepi_k(
    const ushort* __restrict__ Y, ushort* __restrict__ hout, ushort* __restrict__ raw,
    const int* __restrict__ off_in, const int* __restrict__ in_src,
    const int* __restrict__ off_out, const int* __restrict__ out_dst,
    const float* __restrict__ minA, const float* __restrict__ moutA,
    const float* __restrict__ bsum, const float* __restrict__ gma,
    const float* __restrict__ bta, const float* __restrict__ rmn, const float* __restrict__ rvr,
    int Mtot) {
  const int g = threadIdx.x >> 5;
  const int lane = threadIdx.x & 31;
  const int node = blockIdx.x * 8 + g;
  if (node >= Mtot) return;
  const int half = (MODE == 2 && node >= Nn) ? 1 : 0;
  const int v = node - half * Nn;
  const int co = lane * 8;
  float acc[8] = {};
#pragma unroll
  for (int dir = 0; dir < 2; ++dir) {
    const int* offs = dir ? off_out : off_in;
    const int* nbr  = dir ? out_dst : in_src;
    const float* ma = dir ? moutA : minA;
    const ushort* Yg = Y + (size_t)half * Nn * 768 + (dir ? 512 : 256) + co;
    const int s = offs[v], e = offs[v + 1];
    int i = s;
    for (; i + 4 <= e; i += 4) {
      int u[4]; float m[4];
#pragma unroll
      for (int t = 0; t < 4; ++t) {
        u[t] = nbr[i + t];
        m[t] = (MODE == 0) ? 1.f : ((MODE == 2 && half) ? 1.f - ma[i + t] : ma[i + t]);
      }
      v8s r[4];
#pragma unroll
      for (int t = 0; t < 4; ++t) r[t] = *(const v8s*)(Yg + (size_t)u[t] * 768);
#pragma unroll
      for (int t = 0; t < 4; ++t)
#pragma unroll
        for (int j = 0; j < 8; ++j) acc[j] += m[t] * b2f((ushort)r[t][j]);
    }
    for (; i < e; ++i) {
      int u = nbr[i];
      float m = (MODE == 0) ? 1.f : ((MODE == 2 && half) ? 1.f - ma[i] : ma[i]);
      v8s r = *(const v8s*)(Yg + (size_t)u * 768);
#pragma unroll
      for (int j = 0; j < 8; ++j) acc[j] += m * b2f((ushort)r[j]);
    }
  }
  if (WR) {
    v8s rw;
#pragma unroll
    for (int j = 0; j < 8; ++j) rw[j] = (short)f2b(acc[j]);
    *(v8s*)(raw + (size_t)v * 256 + co) = rw;
  }
  const ushort* Yself = Y + (size_t)half * Nn * 768;
  v8s ys = *(const v8s*)(Yself + (size_t)v * 768 + co);
  v8s o;
#pragma unroll
  for (int j = 0; j < 8; ++j) {
    const int col = co + j;
    float val = acc[j] + b2f((ushort)ys[j]) + bsum[col];
    val = fmaxf(val, 0.f);
    val = (val - rmn[col]) * rsqrtf(rvr[col] + EPSc) * gma[col] + bta[col];
    o[j] = (short)f2b(val);
  }
  *(v8s*)(hout + (size_t)node * 256 + co) = o;
}

// batched L0 comp half: out[N+v] = BN(relu(Yx_s[v] + (Aones - Asub) + bsum0))
__global__ void compl0_k(const ushort* __restrict__ Yx, const ushort* __restrict__ Aones,
                         const ushort* __restrict__ Asub, ushort* __restrict__ hout,
                         const float* __restrict__ bsum, const float* __restrict__ gma,
                         const float* __restrict__ bta, const float* __restrict__ rmn,
                         const float* __restrict__ rvr) {
  int i = blockIdx.x * 256 + threadIdx.x;
  if (i >= Nn * 32) return;
  const int v = i >> 5;
  const int co = (i & 31) * 8;
  v8s ys = *(const v8s*)(Yx + (size_t)v * 768 + co);
  v8s ao = *(const v8s*)(Aones + (size_t)v * 256 + co);
  v8s as = *(const v8s*)(Asub + (size_t)v * 256 + co);
  v8s o;
#pragma unroll
  for (int j = 0; j < 8; ++j) {
    const int col = co + j;
    float val = b2f((ushort)ys[j]) + b2f((ushort)ao[j]) - b2f((ushort)as[j]) + bsum[col];
    val = fmaxf(val, 0.f);
    val = (val - rmn[col]) * rsqrtf(rvr[col] + EPSc) * gma[col] + bta[col];
    o[j] = (short)f2b(val);
  }
  *(v8s*)(hout + (size_t)(Nn + v) * 256 + co) = o;
}

// ------------------------------------------------------------------ proj GEMM (mask MLP layer 1)
template <int EPI>
__global__ __launch_bounds__(256) void mfma_gemm2_k(
    const ushort* __restrict__ A, const ushort* __restrict__ W,
    ushort* __restrict__ Cout, int M, const float* __restrict__ bias) {
  __shared__ ushort eplds[4][32][72];
  const int tid = threadIdx.x;
  const int wid = tid >> 6, lane = tid & 63;
  const int wr = wid & 1, wc = wid >> 1;
  const int m0 = blockIdx.x * 64 + wr * 32;
  const int n0 = blockIdx.y * 128 + wc * 64;
  const int lrow = lane & 15;
  const int klo = (lane >> 4) * 8;
  int rowA[2];
#pragma unroll
  for (int fi = 0; fi < 2; ++fi) {
    int r = m0 + fi * 16 + lrow;
    rowA[fi] = (r < M) ? r : (M - 1);
  }
  v8s a[8][2];
#pragma unroll
  for (int c = 0; c < 8; ++c)
#pragma unroll
    for (int fi = 0; fi < 2; ++fi)
      a[c][fi] = *(const v8s*)(A + (size_t)rowA[fi] * 256 + c * 32 + klo);
  v4f acc[2][4] = {};
#pragma unroll
  for (int c = 0; c < 8; ++c) {
    v8s b[4];
#pragma unroll
    for (int fj = 0; fj < 4; ++fj)
      b[fj] = *(const v8s*)(W + (size_t)(n0 + fj * 16 + lrow) * 256 + c * 32 + klo);
#pragma unroll
    for (int fi = 0; fi < 2; ++fi)
#pragma unroll
      for (int fj = 0; fj < 4; ++fj)
        acc[fi][fj] = __builtin_amdgcn_mfma_f32_16x16x32_bf16(a[c][fi], b[fj], acc[fi][fj], 0, 0, 0);
  }
#pragma unroll
  for (int fj = 0; fj < 4; ++fj) {
    const int col = n0 + fj * 16 + lrow;
    const float bsv = bias ? bias[col] : 0.f;
#pragma unroll
    for (int fi = 0; fi < 2; ++fi) {
      const int rl0 = fi * 16 + ((lane >> 4) << 2);
#pragma unroll
      for (int r = 0; r < 4; ++r)
        eplds[wid][rl0 + r][fj * 16 + lrow] = f2b(acc[fi][fj][r] + bsv);
    }
  }
#pragma unroll
  for (int i = 0; i < 4; ++i) {
    const int rl = (lane >> 2) + (i & 1) * 16;
    const int oct = (lane & 3) + (i >> 1) * 4;
    v8s val = *(const v8s*)&eplds[wid][rl][oct * 8];
    const int grow = m0 + rl;
    if (grow < M)
      *(v8s*)(Cout + (size_t)grow * 256 + n0 + oct * 8) = val;
  }
}

// ------------------------------------------------------------------ edge MLP over out-CSR order
// position i: src = out_srcn[i] (sorted, reused), dst = out_dst[i] (random)
// writes moutA[i] directly + scatters maskOut[out_eid[i]]
__global__ __launch_bounds__(256) void edge_mlp4_k(const ushort* __restrict__ P,
                                                   const int* __restrict__ out_srcn,
                                                   const int* __restrict__ out_dst,
                                                   const int* __restrict__ out_eid,
                                                   const ushort* __restrict__ W2b,
                                                   const float* __restrict__ b2, const float* __restrict__ w3,
                                                   const float* __restrict__ b3,
                                                   float* __restrict__ maskOut, float* __restrict__ moutA) {
  const int tid = threadIdx.x;
  const int w = tid >> 6, lane = tid & 63;
  const int e0 = blockIdx.x * 64 + w * 16;
  const int le = lane & 15;
  const int kq = lane >> 4;
  const int klo = kq * 8;
  const int pA = e0 + le;
  const int s_ = out_srcn[pA], d_ = out_dst[pA];
  const ushort* ps = P + (size_t)s_ * 256;
  const ushort* pd = P + (size_t)d_ * 256 + 128;
  v8s as[4], ad[4];
#pragma unroll
  for (int c = 0; c < 4; ++c) {
    as[c] = *(const v8s*)(ps + c * 32 + klo);
    ad[c] = *(const v8s*)(pd + c * 32 + klo);
  }
  v4f acc[4] = {};
#pragma unroll
  for (int c = 0; c < 4; ++c) {
    v8s h;
#pragma unroll
    for (int j = 0; j < 8; ++j) {
      float v = fmaxf(b2f((ushort)as[c][j]) + b2f((ushort)ad[c][j]), 0.f);
      h[j] = (short)f2b(v);
    }
#pragma unroll
    for (int fj = 0; fj < 4; ++fj) {
      v8s b = *(const v8s*)(W2b + (size_t)(fj * 16 + le) * 128 + c * 32 + klo);
      acc[fj] = __builtin_amdgcn_mfma_f32_16x16x32_bf16(h, b, acc[fj], 0, 0, 0);
    }
  }
  float b2v[4], w3v[4];
#pragma unroll
  for (int fj = 0; fj < 4; ++fj) { b2v[fj] = b2[fj * 16 + le]; w3v[fj] = w3[fj * 16 + le]; }
  const float b3v = b3[0];
#pragma unroll
  for (int r = 0; r < 4; ++r) {
    float val = 0.f;
#pragma unroll
    for (int fj = 0; fj < 4; ++fj)
      val += fmaxf(acc[fj][r] + b2v[fj], 0.f) * w3v[fj];
    val += __shfl_xor(val, 1);
    val += __shfl_xor(val, 2);
    val += __shfl_xor(val, 4);
    val += __shfl_xor(val, 8);
    if (le == 0) {
      int pos = e0 + kq * 4 + r;
      float sig = 1.0f / (1.0f + expf(-(val + b3v)));
      moutA[pos] = sig;
      maskOut[out_eid[pos]] = sig;
    }
  }
}

// ------------------------------------------------------------------ pooling / tails
__global__ __launch_bounds__(256) void gemb_sum_k(const ushort* __restrict__ h, const int* __restrict__ batch,
                                                  float* __restrict__ gsum, int batched) {
  const int halfBlocks = Nn / 16;
  int blk = blockIdx.x;
  int half = 0, bi = blk;
  if (batched) { half = (blk >= halfBlocks) ? 1 : 0; bi = blk - half * halfBlocks; }
  const int v0 = bi * 16;
  const int tid = threadIdx.x;
  const size_t base = (size_t)half * Nn;
  float* out = gsum + (size_t)half * (Bb * Dd);
  float acc = 0.0f;
  int curb = batch[v0];
  for (int i = 0; i < 16; ++i) {
    int v = v0 + i;
    int b = batch[v];
    if (b != curb) { atomicAdd(&out[curb * Dd + tid], acc); acc = 0.0f; curb = b; }
    acc += b2f(h[(base + v) * Dd + tid]);
  }
  atomicAdd(&out[curb * Dd + tid], acc);
}

__global__ void gemb_scale_k(float* __restrict__ g, const float* __restrict__ cntf) {
  int blk = blockIdx.x;
  int b = blk & 15;
  g[blk * Dd + threadIdx.x] /= fmaxf(cntf[b], 1.0f);
}

__global__ void anchor_k(const float* __restrict__ g, const float* __restrict__ anchors,
                         float* __restrict__ s_out) {
  __shared__ float red4[4];
  const int b = blockIdx.x, tid = threadIdx.x;
  float gv = g[b * Dd + tid];
  float total = 0.0f;
  for (int k = 0; k < 6; ++k) {
    float d = gv - anchors[k * Dd + tid];
    float v = d * d;
    for (int o = 32; o > 0; o >>= 1) v += __shfl_xor(v, o);
    if ((tid & 63) == 0) red4[tid >> 6] = v;
    __syncthreads();
    if (tid == 0) total += sqrtf(red4[0] + red4[1] + red4[2] + red4[3]);
    __syncthreads();
  }
  if (tid == 0) s_out[b] = total;
}

__global__ void logits_k(const float* __restrict__ gsub, const float* __restrict__ gcomp,
                         const float* __restrict__ Wc, const float* __restrict__ bc,
                         float* __restrict__ outL) {
  __shared__ float red4[4];
  const int blk = blockIdx.x;
  const int set = blk >> 4, b = blk & 15;
  const float* g = set ? gcomp : gsub;
  const int tid = threadIdx.x;
  float gv = g[b * Dd + tid];
  for (int c = 0; c < 2; ++c) {
    float v = gv * Wc[c * Dd + tid];
    for (int o = 32; o > 0; o >>= 1) v += __shfl_xor(v, o);
    if ((tid & 63) == 0) red4[tid >> 6] = v;
    __syncthreads();
    if (tid == 0) outL[set * 32 + b * 2 + c] = red4[0] + red4[1] + red4[2] + red4[3] + bc[c];
    __syncthreads();
  }
}

__global__ void final_k(const float* __restrict__ L, const int* __restrict__ labels,
                        const float* __restrict__ s_orig, const float* __restrict__ s_sub,
                        float* __restrict__ out) {
  if (threadIdx.x == 0) {
    float Lp = 0, Lu = 0, La = 0;
    const float u = 0.5f;
    for (int b = 0; b < 16; ++b) {
      float l0 = L[b * 2], l1 = L[b * 2 + 1];
      float m = fmaxf(l0, l1);
      float lse = m + logf(expf(l0 - m) + expf(l1 - m));
      int lab = labels[b];
      Lp += -((lab ? l1 : l0) - lse);
      float c0 = L[32 + b * 2], c1 = L[32 + b * 2 + 1];
      float mm = fmaxf(c0, c1);
      float e0 = expf(c0 - mm), e1 = expf(c1 - mm), Z = e0 + e1;
      Lu += u * (logf(u) - logf(e0 / Z + 1e-8f)) + u * (logf(u) - logf(e1 / Z + 1e-8f));
      float dd = s_sub[b] - s_orig[b];
      La += dd * dd;
    }
    Lp /= 16.0f; Lu /= 16.0f; La /= 16.0f;
    out[0] = 0.5f * Lp + 0.3f * Lu + 0.2f * La;
    out[1] = Lp; out[2] = Lu; out[3] = La;
  }
}

// ------------------------------------------------------------------ host
extern "C" void kernel_launch(void* const* d_in, const int* in_sizes, int n_in,
                              void* d_out, int out_size, void* d_ws, size_t ws_size,
                              hipStream_t stream) {
  (void)in_sizes; (void)n_in; (void)out_size; (void)ws_size;
  const float* x    = (const float*)d_in[0];
  const int* ei     = (const int*)d_in[1];
  const int* batch  = (const int*)d_in[2];
  const int* labels = (const int*)d_in[3];
  const float* mw1 = (const float*)d_in[4];
  const float* mb1 = (const float*)d_in[5];
  const float* mw2 = (const float*)d_in[6];
  const float* mb2 = (const float*)d_in[7];
  const float* mw3 = (const float*)d_in[8];
  const float* mb3 = (const float*)d_in[9];
  const float* Ws   = (const float*)d_in[10];
  const float* bs   = (const float*)d_in[11];
  const float* Win  = (const float*)d_in[12];
  const float* bin_ = (const float*)d_in[13];
  const float* Wout = (const float*)d_in[14];
  const float* bout = (const float*)d_in[15];
  const float* gma  = (const float*)d_in[16];
  const float* bta  = (const float*)d_in[17];
  const float* rmn  = (const float*)d_in[18];
  const float* rvr  = (const float*)d_in[19];
  const float* anchors = (const float*)d_in[20];
  const float* Wc   = (const float*)d_in[21];
  const float* bc   = (const float*)d_in[22];
  const int* srcp = ei;
  const int* dstp = ei + Ee;

  const size_t NH = (size_t)Nn * Dd;
  const size_t NY = (size_t)Nn * 768;
  ushort* xb   = (ushort*)d_ws;
  ushort* hA   = xb + NH;              // 2NH
  ushort* hB   = hA + 2 * NH;          // 2NH
  ushort* Yx   = hB + 2 * NH;          // NY (persistent L0 projection of x)
  ushort* Ybuf = Yx + NY;              // 2NY (batched dual-half; Pb aliases)
  ushort* Pb   = Ybuf;
  ushort* Aones = Ybuf + 2 * NY;       // NH
  ushort* Asub  = Aones + NH;          // NH
  ushort* Wsb   = Asub + NH;
  ushort* Winb  = Wsb + 3 * 65536;
  ushort* Woutb = Winb + 3 * 65536;
  ushort* Wcombb = Woutb + 3 * 65536;
  ushort* W2b    = Wcombb + 65536;
  float* bcomb = (float*)(W2b + 8192);
  float* minA  = bcomb + 256;
  float* moutA = minA + Ee;
  int* off_in   = (int*)(moutA + Ee);
  int* off_out  = off_in + (Nn + 1);
  int* cur_in   = off_out + (Nn + 1);
  int* cur_out  = cur_in + Nn;
  int* in_src   = cur_out + Nn;
  int* in_eid   = in_src + Ee;
  int* out_dst  = in_eid + Ee;
  int* out_eid  = out_dst + Ee;
  int* out_srcn = out_eid + Ee;
  int* counts_in  = out_srcn + Ee;
  int* counts_out = counts_in + Nn;
  float* cntf      = (float*)(counts_out + Nn);
  float* gemb_orig = cntf + Bb;
  float* gemb_sub  = gemb_orig + Bb * Dd;
  float* gemb_comp = gemb_sub + Bb * Dd;
  float* bsum    = gemb_comp + Bb * Dd;
  float* s_orig  = bsum + 3 * Dd;
  float* s_sub   = s_orig + Bb;
  float* logitsb = s_sub + Bb;

  float* outF = (float*)d_out;
  float* maskp = outF + 4;

  const size_t zero_bytes = (char*)bsum - (char*)counts_in;
  hipMemsetAsync(counts_in, 0, zero_bytes, stream);

  hist_edges_k<<<(Ee + 255) / 256, 256, 0, stream>>>(srcp, dstp, counts_in, counts_out);
  cnt_batch_k<<<1, 64, 0, stream>>>(batch, cntf);
  scan_k<<<1, 1024, 0, stream>>>(counts_in, counts_out, off_in, off_out, cur_in, cur_out);
  scatter_k<<<(Ee + 255) / 256, 256, 0, stream>>>(srcp, dstp, cur_in, cur_out, in_src, in_eid,
                                                  out_dst, out_eid, out_srcn);
  prep_bsum_k<<<1, 256, 0, stream>>>(bs, bin_, bout, bsum);

  c_f2b_k<<<(3 * 65536 + 255) / 256, 256, 0, stream>>>(Ws, Wsb, 3 * 65536);
  c_f2b_k<<<(3 * 65536 + 255) / 256, 256, 0, stream>>>(Win, Winb, 3 * 65536);
  c_f2b_k<<<(3 * 65536 + 255) / 256, 256, 0, stream>>>(Wout, Woutb, 3 * 65536);
  prep_mlp_k<<<256, 256, 0, stream>>>(mw1, mb1, mw2, Wcombb, W2b, bcomb);

  auto run_gemm768 = [&](const ushort* h, ushort* Yout, int M, int l) {
    const int gx = (M + 63) / 64;
    const int gxh = (gx + 7) / 8;
    gemm768_k<<<gxh * 48, 256, 0, stream>>>(h, Wsb + (size_t)l * 65536, Winb + (size_t)l * 65536,
                                            Woutb + (size_t)l * 65536, Yout, M, gx);
  };
  auto bn = [&](int l) { return bsum + l * 256; };
  const int aggN = (Nn + 7) / 8;
  const int agg2N = (2 * Nn + 7) / 8;

  // ---- encoder #1 (ones mask)
  copyxb_k<<<(Nn * Dd / 4 + 255) / 256, 256, 0, stream>>>(x, xb);
  run_gemm768(xb, Yx, Nn, 0);  // persistent: reused by batched L0
  aggepi_k<0, 1><<<aggN, 256, 0, stream>>>(
      Yx, hB, Aones, off_in, in_src, off_out, out_dst, nullptr, nullptr,
      bn(0), gma, bta, rmn, rvr, Nn);
  run_gemm768(hB, Ybuf, Nn, 1);
  aggepi_k<0, 0><<<aggN, 256, 0, stream>>>(
      Ybuf, hA, nullptr, off_in, in_src, off_out, out_dst, nullptr, nullptr,
      bn(1), gma + 256, bta + 256, rmn + 256, rvr + 256, Nn);
  run_gemm768(hA, Ybuf, Nn, 2);
  aggepi_k<0, 0><<<aggN, 256, 0, stream>>>(
      Ybuf, hB, nullptr, off_in, in_src, off_out, out_dst, nullptr, nullptr,
      bn(2), gma + 512, bta + 512, rmn + 512, rvr + 512, Nn);
  // node_emb = hB

  gemb_sum_k<<<Nn / 16, 256, 0, stream>>>(hB, batch, gemb_orig, 0);
  gemb_scale_k<<<Bb, 256, 0, stream>>>(gemb_orig, cntf);
  anchor_k<<<Bb, 256, 0, stream>>>(gemb_orig, anchors, s_orig);

  // ---- packed projection P = [emb@W1a^T + b1 | emb@W1b^T] (Pb aliases Ybuf)
  {
    dim3 gp((Nn + 63) / 64, 2);
    mfma_gemm2_k<3><<<gp, 256, 0, stream>>>(hB, Wcombb, Pb, Nn, bcomb);
  }
  edge_mlp4_k<<<Ee / 64, 256, 0, stream>>>(Pb, out_srcn, out_dst, out_eid,
                                           W2b, mb2, mw3, mb3, maskp, moutA);
  permmask_k<<<(Ee + 255) / 256, 256, 0, stream>>>(maskp, in_eid, minA);

  // ---- batched encoders #2/#3 (mask & 1-mask)
  // L0: Yx reused; sub = masked agg of Yx; comp = ones - sub
  aggepi_k<1, 1><<<aggN, 256, 0, stream>>>(
      Yx, hA, Asub, off_in, in_src, off_out, out_dst, minA, moutA,
      bn(0), gma, bta, rmn, rvr, Nn);
  compl0_k<<<(Nn * 32 + 255) / 256, 256, 0, stream>>>(Yx, Aones, Asub, hA,
                                                      bn(0), gma, bta, rmn, rvr);
  // L1 (fused halves: M = 2N GEMM, dual-mode agg)
  run_gemm768(hA, Ybuf, 2 * Nn, 1);
  aggepi_k<2, 0><<<agg2N, 256, 0, stream>>>(
      Ybuf, hB, nullptr, off_in, in_src, off_out, out_dst, minA, moutA,
      bn(1), gma + 256, bta + 256, rmn + 256, rvr + 256, 2 * Nn);
  // L2
  run_gemm768(hB, Ybuf, 2 * Nn, 2);
  aggepi_k<2, 0><<<agg2N, 256, 0, stream>>>(
      Ybuf, hA, nullptr, off_in, in_src, off_out, out_dst, minA, moutA,
      bn(2), gma + 512, bta + 512, rmn + 512, rvr + 512, 2 * Nn);
  // hA = [h_sub; h_comp]

  gemb_sum_k<<<2 * (Nn / 16), 256, 0, stream>>>(hA, batch, gemb_sub, 1);
  gemb_scale_k<<<2 * Bb, 256, 0, stream>>>(gemb_sub, cntf);
  anchor_k<<<Bb, 256, 0, stream>>>(gemb_sub, anchors, s_sub);
  logits_k<<<2 * Bb, 256, 0, stream>>>(gemb_sub, gemb_comp, Wc, bc, logitsb);
  final_k<<<1, 64, 0, stream>>>(logitsb, labels, s_orig, s_sub, outF);
}

// Round 13
// 928.458 us; speedup vs baseline: 5.2025x; 1.0005x over previous
//
#include <hip/hip_runtime.h>
#include <hip/hip_bf16.h>

constexpr int Nn = 20000;
constexpr int Ee = 320000;
constexpr int Dd = 256;
constexpr int Bb = 16;
constexpr float EPSc = 1e-5f;

using v8s = __attribute__((ext_vector_type(8))) short;
using v4f = __attribute__((ext_vector_type(4))) float;

__device__ __forceinline__ float b2f(ushort u) { return __uint_as_float(((unsigned)u) << 16); }
__device__ __forceinline__ ushort f2b(float f) {
  __hip_bfloat16 h = __float2bfloat16(f);
  return *reinterpret_cast<ushort*>(&h);
}

// ------------------------------------------------------------------ graph prep
__global__ void hist_edges_k(const int* __restrict__ src, const int* __restrict__ dst,
                             int* __restrict__ cin, int* __restrict__ cout) {
  int e = blockIdx.x * 256 + threadIdx.x;
  if (e < Ee) { atomicAdd(&cin[dst[e]], 1); atomicAdd(&cout[src[e]], 1); }
}

__global__ void cnt_batch_k(const int* __restrict__ batch, float* __restrict__ cntf) {
  int b = threadIdx.x;
  if (b < Bb) {
    int lo = 0, hi = Nn;
    while (lo < hi) { int mid = (lo + hi) >> 1; if (batch[mid] < b) lo = mid + 1; else hi = mid; }
    int lb = lo;
    lo = 0; hi = Nn;
    while (lo < hi) { int mid = (lo + hi) >> 1; if (batch[mid] <= b) lo = mid + 1; else hi = mid; }
    cntf[b] = (float)(lo - lb);
  }
}

__global__ __launch_bounds__(1024) void scan_k(const int* __restrict__ cin,
                                               const int* __restrict__ cout,
                                               int* __restrict__ off_in, int* __restrict__ off_out,
                                               int* __restrict__ cur_in, int* __restrict__ cur_out) {
  __shared__ int part[1024];
  const int tid = threadIdx.x;
  for (int which = 0; which < 2; ++which) {
    const int* cnt = which ? cout : cin;
    int* off = which ? off_out : off_in;
    int* curp = which ? cur_out : cur_in;
    int vals[20];
    int base = tid * 20;
    int local = 0;
#pragma unroll
    for (int i = 0; i < 20; ++i) {
      int idx = base + i;
      int v = (idx < Nn) ? cnt[idx] : 0;
      vals[i] = v; local += v;
    }
    part[tid] = local;
    __syncthreads();
    for (int ofs = 1; ofs < 1024; ofs <<= 1) {
      int t = (tid >= ofs) ? part[tid - ofs] : 0;
      __syncthreads();
      part[tid] += t;
      __syncthreads();
    }
    int run = part[tid] - local;
#pragma unroll
    for (int i = 0; i < 20; ++i) {
      int idx = base + i;
      if (idx < Nn) { off[idx] = run; curp[idx] = run; run += vals[i]; }
    }
    if (tid == 0) off[Nn] = Ee;
    __syncthreads();
  }
}

__global__ void scatter_k(const int* __restrict__ src, const int* __restrict__ dst,
                          int* __restrict__ cur_in, int* __restrict__ cur_out,
                          int* __restrict__ in_src, int* __restrict__ in_eid,
                          int* __restrict__ out_dst, int* __restrict__ out_eid,
                          int* __restrict__ out_srcn) {
  int e = blockIdx.x * 256 + threadIdx.x;
  if (e < Ee) {
    int d = dst[e], s = src[e];
    int p = atomicAdd(&cur_in[d], 1);  in_src[p] = s;  in_eid[p] = e;
    int q = atomicAdd(&cur_out[s], 1); out_dst[q] = d; out_eid[q] = e; out_srcn[q] = s;
  }
}

__global__ void prep_bsum_k(const float* __restrict__ bs, const float* __restrict__ bin,
                            const float* __restrict__ bout, float* __restrict__ bsum) {
  int t = threadIdx.x;
  for (int l = 0; l < 3; ++l) bsum[l * 256 + t] = bs[l * 256 + t] + bin[l * 256 + t] + bout[l * 256 + t];
}

__global__ void copyxb_k(const float* __restrict__ x, ushort* __restrict__ h) {
  const int n4 = Nn * Dd / 4;
  int i = blockIdx.x * 256 + threadIdx.x;
  if (i < n4) {
    float4 v = ((const float4*)x)[i];
    ushort4 o; o.x = f2b(v.x); o.y = f2b(v.y); o.z = f2b(v.z); o.w = f2b(v.w);
    ((ushort4*)h)[i] = o;
  }
}

__global__ void c_f2b_k(const float* __restrict__ s, ushort* __restrict__ d, int n) {
  int i = blockIdx.x * 256 + threadIdx.x;
  if (i < n) d[i] = f2b(s[i]);
}

// Wcombb[256][256]: rows 0-127 = mw1[r][0:256], rows 128-255 = mw1[r-128][256:512]
__global__ void prep_mlp_k(const float* __restrict__ mw1, const float* __restrict__ mb1,
                           const float* __restrict__ mw2,
                           ushort* __restrict__ Wcombb, ushort* __restrict__ W2b,
                           float* __restrict__ bcomb) {
  int i = blockIdx.x * 256 + threadIdx.x;
  if (i < 65536) {
    int r = i >> 8, c = i & 255;
    float v = (r < 128) ? mw1[r * 512 + c] : mw1[(r - 128) * 512 + 256 + c];
    Wcombb[i] = f2b(v);
  }
  if (i < 8192) W2b[i] = f2b(mw2[i]);
  if (i < 256) bcomb[i] = (i < 128) ? mb1[i] : 0.f;
}

// build in-CSR mask (out-CSR mask written directly by edge MLP)
__global__ void permmask_k(const float* __restrict__ mask,
                           const int* __restrict__ in_eid, float* __restrict__ minA) {
  int i = blockIdx.x * 256 + threadIdx.x;
  if (i < Ee) minA[i] = mask[in_eid[i]];
}

// ------------------------------------------------------------------ GEMM768, XCD-swizzled 1D grid
// launch_bounds(256,6): 6 blocks/CU resident; B 2-deep pipeline; NT stores for Y.
__global__ __launch_bounds__(256, 6) void gemm768_k(
    const ushort* __restrict__ A, const ushort* __restrict__ W0,
    const ushort* __restrict__ W1, const ushort* __restrict__ W2,
    ushort* __restrict__ Y, int M, int gx) {
  __shared__ ushort eplds[4][32][72];
  const int gidx = blockIdx.x;
  const int xhi = gidx / 48;
  const int rem = gidx % 48;
  const int by = rem >> 3;
  const int bx = xhi * 8 + (rem & 7);
  if (bx >= gx) return;
  const int tid = threadIdx.x;
  const int wid = tid >> 6, lane = tid & 63;
  const int wr = wid & 1, wc = wid >> 1;
  const int m0 = bx * 64 + wr * 32;
  const int seg = by >> 1;
  const ushort* Wp = (seg == 0) ? W0 : ((seg == 1) ? W1 : W2);
  const int nw0 = (by & 1) * 128 + wc * 64;
  const int lrow = lane & 15;
  const int klo = (lane >> 4) * 8;
  int rowA[2];
#pragma unroll
  for (int fi = 0; fi < 2; ++fi) {
    int r = m0 + fi * 16 + lrow;
    rowA[fi] = (r < M) ? r : (M - 1);
  }
  // preload entire K strip of A
  v8s a[8][2];
#pragma unroll
  for (int c = 0; c < 8; ++c)
#pragma unroll
    for (int fi = 0; fi < 2; ++fi)
      a[c][fi] = *(const v8s*)(A + (size_t)rowA[fi] * 256 + c * 32 + klo);
  // B 2-deep software pipeline
  const ushort* Wbase = Wp + (size_t)(nw0 + lrow) * 256 + klo;
  v8s b0[4], b1[4];
#pragma unroll
  for (int fj = 0; fj < 4; ++fj)
    b0[fj] = *(const v8s*)(Wbase + (size_t)(fj * 16) * 256);
  v4f acc[2][4] = {};
#pragma unroll
  for (int c = 0; c < 8; ++c) {
    v8s* bc = (c & 1) ? b1 : b0;
    v8s* bn = (c & 1) ? b0 : b1;
    if (c < 7) {
#pragma unroll
      for (int fj = 0; fj < 4; ++fj)
        bn[fj] = *(const v8s*)(Wbase + (size_t)(fj * 16) * 256 + (c + 1) * 32);
    }
#pragma unroll
    for (int fi = 0; fi < 2; ++fi)
#pragma unroll
      for (int fj = 0; fj < 4; ++fj)
        acc[fi][fj] = __builtin_amdgcn_mfma_f32_16x16x32_bf16(a[c][fi], bc[fj], acc[fi][fj], 0, 0, 0);
  }
#pragma unroll
  for (int fj = 0; fj < 4; ++fj)
#pragma unroll
    for (int fi = 0; fi < 2; ++fi) {
      const int rl0 = fi * 16 + ((lane >> 4) << 2);
#pragma unroll
      for (int r = 0; r < 4; ++r)
        eplds[wid][rl0 + r][fj * 16 + lrow] = f2b(acc[fi][fj][r]);
    }
  const int colbase = by * 128 + wc * 64;
#pragma unroll
  for (int i = 0; i < 4; ++i) {
    const int rl = (lane >> 2) + (i & 1) * 16;
    const int oct = (lane & 3) + (i >> 1) * 4;
    v8s val = *(const v8s*)&eplds[wid][rl][oct * 8];
    const int grow = m0 + rl;
    if (grow < M)
      __builtin_nontemporal_store(val, (v8s*)(Y + (size_t)grow * 768 + colbase + oct * 8));
  }
}

// ------------------------------------------------------------------ agg + epilogue
// MODE 0: m=1 ; MODE 1: m=mask (batched L0 sub) ; MODE 2: dual-half batched
// WR 1: save raw agg sum
template <int MODE, int WR>
__global__ __launch_bounds__(256) void aggepi_k(
    const ushort* __restrict__ Y, ushort* __restrict__ hout, ushort* __restrict__ raw,
    const int* __restrict__ off_in, const int* __restrict__ in_src,
    const int* __restrict__ off_out, const int* __restrict__ out_dst,
    const float* __restrict__ minA, const float* __restrict__ moutA,
    const float* __restrict__ bsum, const float* __restrict__ gma,
    const float* __restrict__ bta, const float* __restrict__ rmn, const float* __restrict__ rvr,
    int Mtot) {
  const int g = threadIdx.x >> 5;
  const int lane = threadIdx.x & 31;
  const int node = blockIdx.x * 8 + g;
  if (node >= Mtot) return;
  const int half = (MODE == 2 && node >= Nn) ? 1 : 0;
  const int v = node - half * Nn;
  const int co = lane * 8;
  float acc[8] = {};
#pragma unroll
  for (int dir = 0; dir < 2; ++dir) {
    const int* offs = dir ? off_out : off_in;
    const int* nbr  = dir ? out_dst : in_src;
    const float* ma = dir ? moutA : minA;
    const ushort* Yg = Y + (size_t)half * Nn * 768 + (dir ? 512 : 256) + co;
    const int s = offs[v], e = offs[v + 1];
    int i = s;
    for (; i + 4 <= e; i += 4) {
      int u[4]; float m[4];
#pragma unroll
      for (int t = 0; t < 4; ++t) {
        u[t] = nbr[i + t];
        m[t] = (MODE == 0) ? 1.f : ((MODE == 2 && half) ? 1.f - ma[i + t] : ma[i + t]);
      }
      v8s r[4];
#pragma unroll
      for (int t = 0; t < 4; ++t) r[t] = *(const v8s*)(Yg + (size_t)u[t] * 768);
#pragma unroll
      for (int t = 0; t < 4; ++t)
#pragma unroll
        for (int j = 0; j < 8; ++j) acc[j] += m[t] * b2f((ushort)r[t][j]);
    }
    for (; i < e; ++i) {
      int u = nbr[i];
      float m = (MODE == 0) ? 1.f : ((MODE == 2 && half) ? 1.f - ma[i] : ma[i]);
      v8s r = *(const v8s*)(Yg + (size_t)u * 768);
#pragma unroll
      for (int j = 0; j < 8; ++j) acc[j] += m * b2f((ushort)r[j]);
    }
  }
  if (WR) {
    v8s rw;
#pragma unroll
    for (int j = 0; j < 8; ++j) rw[j] = (short)f2b(acc[j]);
    *(v8s*)(raw + (size_t)v * 256 + co) = rw;
  }
  const ushort* Yself = Y + (size_t)half * Nn * 768;
  v8s ys = *(const v8s*)(Yself + (size_t)v * 768 + co);
  v8s o;
#pragma unroll
  for (int j = 0; j < 8; ++j) {
    const int col = co + j;
    float val = acc[j] + b2f((ushort)ys[j]) + bsum[col];
    val = fmaxf(val, 0.f);
    val = (val - rmn[col]) * rsqrtf(rvr[col] + EPSc) * gma[col] + bta[col];
    o[j] = (short)f2b(val);
  }
  *(v8s*)(hout + (size_t)node * 256 + co) = o;
}

// batched L0 comp half: out[N+v] = BN(relu(Yx_s[v] + (Aones - Asub) + bsum0))
__global__ void compl0_k(const ushort* __restrict__ Yx, const ushort* __restrict__ Aones,
                         const ushort* __restrict__ Asub, ushort* __restrict__ hout,
                         const float* __restrict__ bsum, const float* __restrict__ gma,
                         const float* __restrict__ bta, const float* __restrict__ rmn,
                         const float* __restrict__ rvr) {
  int i = blockIdx.x * 256 + threadIdx.x;
  if (i >= Nn * 32) return;
  const int v = i >> 5;
  const int co = (i & 31) * 8;
  v8s ys = *(const v8s*)(Yx + (size_t)v * 768 + co);
  v8s ao = *(const v8s*)(Aones + (size_t)v * 256 + co);
  v8s as = *(const v8s*)(Asub + (size_t)v * 256 + co);
  v8s o;
#pragma unroll
  for (int j = 0; j < 8; ++j) {
    const int col = co + j;
    float val = b2f((ushort)ys[j]) + b2f((ushort)ao[j]) - b2f((ushort)as[j]) + bsum[col];
    val = fmaxf(val, 0.f);
    val = (val - rmn[col]) * rsqrtf(rvr[col] + EPSc) * gma[col] + bta[col];
    o[j] = (short)f2b(val);
  }
  *(v8s*)(hout + (size_t)(Nn + v) * 256 + co) = o;
}

// ------------------------------------------------------------------ proj GEMM (mask MLP layer 1)
template <int EPI>
__global__ __launch_bounds__(256) void mfma_gemm2_k(
    const ushort* __restrict__ A, const ushort* __restrict__ W,
    ushort* __restrict__ Cout, int M, const float* __restrict__ bias) {
  __shared__ ushort eplds[4][32][72];
  const int tid = threadIdx.x;
  const int wid = tid >> 6, lane = tid & 63;
  const int wr = wid & 1, wc = wid >> 1;
  const int m0 = blockIdx.x * 64 + wr * 32;
  const int n0 = blockIdx.y * 128 + wc * 64;
  const int lrow = lane & 15;
  const int klo = (lane >> 4) * 8;
  int rowA[2];
#pragma unroll
  for (int fi = 0; fi < 2; ++fi) {
    int r = m0 + fi * 16 + lrow;
    rowA[fi] = (r < M) ? r : (M - 1);
  }
  v8s a[8][2];
#pragma unroll
  for (int c = 0; c < 8; ++c)
#pragma unroll
    for (int fi = 0; fi < 2; ++fi)
      a[c][fi] = *(const v8s*)(A + (size_t)rowA[fi] * 256 + c * 32 + klo);
  v4f acc[2][4] = {};
#pragma unroll
  for (int c = 0; c < 8; ++c) {
    v8s b[4];
#pragma unroll
    for (int fj = 0; fj < 4; ++fj)
      b[fj] = *(const v8s*)(W + (size_t)(n0 + fj * 16 + lrow) * 256 + c * 32 + klo);
#pragma unroll
    for (int fi = 0; fi < 2; ++fi)
#pragma unroll
      for (int fj = 0; fj < 4; ++fj)
        acc[fi][fj] = __builtin_amdgcn_mfma_f32_16x16x32_bf16(a[c][fi], b[fj], acc[fi][fj], 0, 0, 0);
  }
#pragma unroll
  for (int fj = 0; fj < 4; ++fj) {
    const int col = n0 + fj * 16 + lrow;
    const float bsv = bias ? bias[col] : 0.f;
#pragma unroll
    for (int fi = 0; fi < 2; ++fi) {
      const int rl0 = fi * 16 + ((lane >> 4) << 2);
#pragma unroll
      for (int r = 0; r < 4; ++r)
        eplds[wid][rl0 + r][fj * 16 + lrow] = f2b(acc[fi][fj][r] + bsv);
    }
  }
#pragma unroll
  for (int i = 0; i < 4; ++i) {
    const int rl = (lane >> 2) + (i & 1) * 16;
    const int oct = (lane & 3) + (i >> 1) * 4;
    v8s val = *(const v8s*)&eplds[wid][rl][oct * 8];
    const int grow = m0 + rl;
    if (grow < M)
      *(v8s*)(Cout + (size_t)grow * 256 + n0 + oct * 8) = val;
  }
}

// ------------------------------------------------------------------ edge MLP over out-CSR order
__global__ __launch_bounds__(256) void edge_mlp4_k(const ushort* __restrict__ P,
                                                   const int* __restrict__ out_srcn,
                                                   const int* __restrict__ out_dst,
                                                   const int* __restrict__ out_eid,
                                                   const ushort* __restrict__ W2b,
                                                   const float* __restrict__ b2, const float* __restrict__ w3,
                                                   const float* __restrict__ b3,
                                                   float* __restrict__ maskOut, float* __restrict__ moutA) {
  const int tid = threadIdx.x;
  const int w = tid >> 6, lane = tid & 63;
  const int e0 = blockIdx.x * 64 + w * 16;
  const int le = lane & 15;
  const int kq = lane >> 4;
  const int klo = kq * 8;
  const int pA = e0 + le;
  const int s_ = out_srcn[pA], d_ = out_dst[pA];
  const ushort* ps = P + (size_t)s_ * 256;
  const ushort* pd = P + (size_t)d_ * 256 + 128;
  v8s as[4], ad[4];
#pragma unroll
  for (int c = 0; c < 4; ++c) {
    as[c] = *(const v8s*)(ps + c * 32 + klo);
    ad[c] = *(const v8s*)(pd + c * 32 + klo);
  }
  v4f acc[4] = {};
#pragma unroll
  for (int c = 0; c < 4; ++c) {
    v8s h;
#pragma unroll
    for (int j = 0; j < 8; ++j) {
      float v = fmaxf(b2f((ushort)as[c][j]) + b2f((ushort)ad[c][j]), 0.f);
      h[j] = (short)f2b(v);
    }
#pragma unroll
    for (int fj = 0; fj < 4; ++fj) {
      v8s b = *(const v8s*)(W2b + (size_t)(fj * 16 + le) * 128 + c * 32 + klo);
      acc[fj] = __builtin_amdgcn_mfma_f32_16x16x32_bf16(h, b, acc[fj], 0, 0, 0);
    }
  }
  float b2v[4], w3v[4];
#pragma unroll
  for (int fj = 0; fj < 4; ++fj) { b2v[fj] = b2[fj * 16 + le]; w3v[fj] = w3[fj * 16 + le]; }
  const float b3v = b3[0];
#pragma unroll
  for (int r = 0; r < 4; ++r) {
    float val = 0.f;
#pragma unroll
    for (int fj = 0; fj < 4; ++fj)
      val += fmaxf(acc[fj][r] + b2v[fj], 0.f) * w3v[fj];
    val += __shfl_xor(val, 1);
    val += __shfl_xor(val, 2);
    val += __shfl_xor(val, 4);
    val += __shfl_xor(val, 8);
    if (le == 0) {
      int pos = e0 + kq * 4 + r;
      float sig = 1.0f / (1.0f + expf(-(val + b3v)));
      moutA[pos] = sig;
      maskOut[out_eid[pos]] = sig;
    }
  }
}

// ------------------------------------------------------------------ pooling / tails
__global__ __launch_bounds__(256) void gemb_sum_k(const ushort* __restrict__ h, const int* __restrict__ batch,
                                                  float* __restrict__ gsum, int batched) {
  const int halfBlocks = Nn / 16;
  int blk = blockIdx.x;
  int half = 0, bi = blk;
  if (batched) { half = (blk >= halfBlocks) ? 1 : 0; bi = blk - half * halfBlocks; }
  const int v0 = bi * 16;
  const int tid = threadIdx.x;
  const size_t base = (size_t)half * Nn;
  float* out = gsum + (size_t)half * (Bb * Dd);
  float acc = 0.0f;
  int curb = batch[v0];
  for (int i = 0; i < 16; ++i) {
    int v = v0 + i;
    int b = batch[v];
    if (b != curb) { atomicAdd(&out[curb * Dd + tid], acc); acc = 0.0f; curb = b; }
    acc += b2f(h[(base + v) * Dd + tid]);
  }
  atomicAdd(&out[curb * Dd + tid], acc);
}

__global__ void gemb_scale_k(float* __restrict__ g, const float* __restrict__ cntf) {
  int blk = blockIdx.x;
  int b = blk & 15;
  g[blk * Dd + threadIdx.x] /= fmaxf(cntf[b], 1.0f);
}

__global__ void anchor_k(const float* __restrict__ g, const float* __restrict__ anchors,
                         float* __restrict__ s_out) {
  __shared__ float red4[4];
  const int b = blockIdx.x, tid = threadIdx.x;
  float gv = g[b * Dd + tid];
  float total = 0.0f;
  for (int k = 0; k < 6; ++k) {
    float d = gv - anchors[k * Dd + tid];
    float v = d * d;
    for (int o = 32; o > 0; o >>= 1) v += __shfl_xor(v, o);
    if ((tid & 63) == 0) red4[tid >> 6] = v;
    __syncthreads();
    if (tid == 0) total += sqrtf(red4[0] + red4[1] + red4[2] + red4[3]);
    __syncthreads();
  }
  if (tid == 0) s_out[b] = total;
}

__global__ void logits_k(const float* __restrict__ gsub, const float* __restrict__ gcomp,
                         const float* __restrict__ Wc, const float* __restrict__ bc,
                         float* __restrict__ outL) {
  __shared__ float red4[4];
  const int blk = blockIdx.x;
  const int set = blk >> 4, b = blk & 15;
  const float* g = set ? gcomp : gsub;
  const int tid = threadIdx.x;
  float gv = g[b * Dd + tid];
  for (int c = 0; c < 2; ++c) {
    float v = gv * Wc[c * Dd + tid];
    for (int o = 32; o > 0; o >>= 1) v += __shfl_xor(v, o);
    if ((tid & 63) == 0) red4[tid >> 6] = v;
    __syncthreads();
    if (tid == 0) outL[set * 32 + b * 2 + c] = red4[0] + red4[1] + red4[2] + red4[3] + bc[c];
    __syncthreads();
  }
}

__global__ void final_k(const float* __restrict__ L, const int* __restrict__ labels,
                        const float* __restrict__ s_orig, const float* __restrict__ s_sub,
                        float* __restrict__ out) {
  if (threadIdx.x == 0) {
    float Lp = 0, Lu = 0, La = 0;
    const float u = 0.5f;
    for (int b = 0; b < 16; ++b) {
      float l0 = L[b * 2], l1 = L[b * 2 + 1];
      float m = fmaxf(l0, l1);
      float lse = m + logf(expf(l0 - m) + expf(l1 - m));
      int lab = labels[b];
      Lp += -((lab ? l1 : l0) - lse);
      float c0 = L[32 + b * 2], c1 = L[32 + b * 2 + 1];
      float mm = fmaxf(c0, c1);
      float e0 = expf(c0 - mm), e1 = expf(c1 - mm), Z = e0 + e1;
      Lu += u * (logf(u) - logf(e0 / Z + 1e-8f)) + u * (logf(u) - logf(e1 / Z + 1e-8f));
      float dd = s_sub[b] - s_orig[b];
      La += dd * dd;
    }
    Lp /= 16.0f; Lu /= 16.0f; La /= 16.0f;
    out[0] = 0.5f * Lp + 0.3f * Lu + 0.2f * La;
    out[1] = Lp; out[2] = Lu; out[3] = La;
  }
}

// ------------------------------------------------------------------ host
extern "C" void kernel_launch(void* const* d_in, const int* in_sizes, int n_in,
                              void* d_out, int out_size, void* d_ws, size_t ws_size,
                              hipStream_t stream) {
  (void)in_sizes; (void)n_in; (void)out_size; (void)ws_size;
  const float* x    = (const float*)d_in[0];
  const int* ei     = (const int*)d_in[1];
  const int* batch  = (const int*)d_in[2];
  const int* labels = (const int*)d_in[3];
  const float* mw1 = (const float*)d_in[4];
  const float* mb1 = (const float*)d_in[5];
  const float* mw2 = (const float*)d_in[6];
  const float* mb2 = (const float*)d_in[7];
  const float* mw3 = (const float*)d_in[8];
  const float* mb3 = (const float*)d_in[9];
  const float* Ws   = (const float*)d_in[10];
  const float* bs   = (const float*)d_in[11];
  const float* Win  = (const float*)d_in[12];
  const float* bin_ = (const float*)d_in[13];
  const float* Wout = (const float*)d_in[14];
  const float* bout = (const float*)d_in[15];
  const float* gma  = (const float*)d_in[16];
  const float* bta  = (const float*)d_in[17];
  const float* rmn  = (const float*)d_in[18];
  const float* rvr  = (const float*)d_in[19];
  const float* anchors = (const float*)d_in[20];
  const float* Wc   = (const float*)d_in[21];
  const float* bc   = (const float*)d_in[22];
  const int* srcp = ei;
  const int* dstp = ei + Ee;

  const size_t NH = (size_t)Nn * Dd;
  const size_t NY = (size_t)Nn * 768;
  ushort* xb   = (ushort*)d_ws;
  ushort* hA   = xb + NH;              // 2NH
  ushort* hB   = hA + 2 * NH;          // 2NH
  ushort* Yx   = hB + 2 * NH;          // NY (persistent L0 projection of x)
  ushort* Ybuf = Yx + NY;              // 2NY (batched dual-half; Pb aliases)
  ushort* Pb   = Ybuf;
  ushort* Aones = Ybuf + 2 * NY;       // NH
  ushort* Asub  = Aones + NH;          // NH
  ushort* Wsb   = Asub + NH;
  ushort* Winb  = Wsb + 3 * 65536;
  ushort* Woutb = Winb + 3 * 65536;
  ushort* Wcombb = Woutb + 3 * 65536;
  ushort* W2b    = Wcombb + 65536;
  float* bcomb = (float*)(W2b + 8192);
  float* minA  = bcomb + 256;
  float* moutA = minA + Ee;
  int* off_in   = (int*)(moutA + Ee);
  int* off_out  = off_in + (Nn + 1);
  int* cur_in   = off_out + (Nn + 1);
  int* cur_out  = cur_in + Nn;
  int* in_src   = cur_out + Nn;
  int* in_eid   = in_src + Ee;
  int* out_dst  = in_eid + Ee;
  int* out_eid  = out_dst + Ee;
  int* out_srcn = out_eid + Ee;
  int* counts_in  = out_srcn + Ee;
  int* counts_out = counts_in + Nn;
  float* cntf      = (float*)(counts_out + Nn);
  float* gemb_orig = cntf + Bb;
  float* gemb_sub  = gemb_orig + Bb * Dd;
  float* gemb_comp = gemb_sub + Bb * Dd;
  float* bsum    = gemb_comp + Bb * Dd;
  float* s_orig  = bsum + 3 * Dd;
  float* s_sub   = s_orig + Bb;
  float* logitsb = s_sub + Bb;

  float* outF = (float*)d_out;
  float* maskp = outF + 4;

  const size_t zero_bytes = (char*)bsum - (char*)counts_in;
  hipMemsetAsync(counts_in, 0, zero_bytes, stream);

  hist_edges_k<<<(Ee + 255) / 256, 256, 0, stream>>>(srcp, dstp, counts_in, counts_out);
  cnt_batch_k<<<1, 64, 0, stream>>>(batch, cntf);
  scan_k<<<1, 1024, 0, stream>>>(counts_in, counts_out, off_in, off_out, cur_in, cur_out);
  scatter_k<<<(Ee + 255) / 256, 256, 0, stream>>>(srcp, dstp, cur_in, cur_out, in_src, in_eid,
                                                  out_dst, out_eid, out_srcn);
  prep_bsum_k<<<1, 256, 0, stream>>>(bs, bin_, bout, bsum);

  c_f2b_k<<<(3 * 65536 + 255) / 256, 256, 0, stream>>>(Ws, Wsb, 3 * 65536);
  c_f2b_k<<<(3 * 65536 + 255) / 256, 256, 0, stream>>>(Win, Winb, 3 * 65536);
  c_f2b_k<<<(3 * 65536 + 255) / 256, 256, 0, stream>>>(Wout, Woutb, 3 * 65536);
  prep_mlp_k<<<256, 256, 0, stream>>>(mw1, mb1, mw2, Wcombb, W2b, bcomb);

  auto run_gemm768 = [&](const ushort* h, ushort* Yout, int M, int l) {
    const int gx = (M + 63) / 64;
    const int gxh = (gx + 7) / 8;
    gemm768_k<<<gxh * 48, 256, 0, stream>>>(h, Wsb + (size_t)l * 65536, Winb + (size_t)l * 65536,
                                            Woutb + (size_t)l * 65536, Yout, M, gx);
  };
  auto bn = [&](int l) { return bsum + l * 256; };
  const int aggN = (Nn + 7) / 8;
  const int agg2N = (2 * Nn + 7) / 8;

  // ---- encoder #1 (ones mask)
  copyxb_k<<<(Nn * Dd / 4 + 255) / 256, 256, 0, stream>>>(x, xb);
  run_gemm768(xb, Yx, Nn, 0);  // persistent: reused by batched L0
  aggepi_k<0, 1><<<aggN, 256, 0, stream>>>(
      Yx, hB, Aones, off_in, in_src, off_out, out_dst, nullptr, nullptr,
      bn(0), gma, bta, rmn, rvr, Nn);
  run_gemm768(hB, Ybuf, Nn, 1);
  aggepi_k<0, 0><<<aggN, 256, 0, stream>>>(
      Ybuf, hA, nullptr, off_in, in_src, off_out, out_dst, nullptr, nullptr,
      bn(1), gma + 256, bta + 256, rmn + 256, rvr + 256, Nn);
  run_gemm768(hA, Ybuf, Nn, 2);
  aggepi_k<0, 0><<<aggN, 256, 0, stream>>>(
      Ybuf, hB, nullptr, off_in, in_src, off_out, out_dst, nullptr, nullptr,
      bn(2), gma + 512, bta + 512, rmn + 512, rvr + 512, Nn);
  // node_emb = hB

  gemb_sum_k<<<Nn / 16, 256, 0, stream>>>(hB, batch, gemb_orig, 0);
  gemb_scale_k<<<Bb, 256, 0, stream>>>(gemb_orig, cntf);
  anchor_k<<<Bb, 256, 0, stream>>>(gemb_orig, anchors, s_orig);

  // ---- packed projection P = [emb@W1a^T + b1 | emb@W1b^T] (Pb aliases Ybuf)
  {
    dim3 gp((Nn + 63) / 64, 2);
    mfma_gemm2_k<3><<<gp, 256, 0, stream>>>(hB, Wcombb, Pb, Nn, bcomb);
  }
  edge_mlp4_k<<<Ee / 64, 256, 0, stream>>>(Pb, out_srcn, out_dst, out_eid,
                                           W2b, mb2, mw3, mb3, maskp, moutA);
  permmask_k<<<(Ee + 255) / 256, 256, 0, stream>>>(maskp, in_eid, minA);

  // ---- batched encoders #2/#3 (mask & 1-mask)
  aggepi_k<1, 1><<<aggN, 256, 0, stream>>>(
      Yx, hA, Asub, off_in, in_src, off_out, out_dst, minA, moutA,
      bn(0), gma, bta, rmn, rvr, Nn);
  compl0_k<<<(Nn * 32 + 255) / 256, 256, 0, stream>>>(Yx, Aones, Asub, hA,
                                                      bn(0), gma, bta, rmn, rvr);
  // L1 (fused halves: M = 2N GEMM, dual-mode agg)
  run_gemm768(hA, Ybuf, 2 * Nn, 1);
  aggepi_k<2, 0><<<agg2N, 256, 0, stream>>>(
      Ybuf, hB, nullptr, off_in, in_src, off_out, out_dst, minA, moutA,
      bn(1), gma + 256, bta + 256, rmn + 256, rvr + 256, 2 * Nn);
  // L2
  run_gemm768(hB, Ybuf, 2 * Nn, 2);
  aggepi_k<2, 0><<<agg2N, 256, 0, stream>>>(
      Ybuf, hA, nullptr, off_in, in_src, off_out, out_dst, minA, moutA,
      bn(2), gma + 512, bta + 512, rmn + 512, rvr + 512, 2 * Nn);
  // hA = [h_sub; h_comp]

  gemb_sum_k<<<2 * (Nn / 16), 256, 0, stream>>>(hA, batch, gemb_sub, 1);
  gemb_scale_k<<<2 * Bb, 256, 0, stream>>>(gemb_sub, cntf);
  anchor_k<<<Bb, 256, 0, stream>>>(gemb_sub, anchors, s_sub);
  logits_k<<<2 * Bb, 256, 0, stream>>>(gemb_sub, gemb_comp, Wc, bc, logitsb);
  final_k<<<1, 64, 0, stream>>>(logitsb, labels, s_orig, s_sub, outF);
}

// Round 14
// 753.287 us; speedup vs baseline: 6.4123x; 1.2325x over previous
//
#include <hip/hip_runtime.h>
#include <hip/hip_bf16.h>

constexpr int Nn = 20000;
constexpr int Ee = 320000;
constexpr int Dd = 256;
constexpr int Bb = 16;
constexpr float EPSc = 1e-5f;

using v8s = __attribute__((ext_vector_type(8))) short;
using v4f = __attribute__((ext_vector_type(4))) float;

__device__ __forceinline__ float b2f(ushort u) { return __uint_as_float(((unsigned)u) << 16); }
__device__ __forceinline__ ushort f2b(float f) {
  __hip_bfloat16 h = __float2bfloat16(f);
  return *reinterpret_cast<ushort*>(&h);
}

// ------------------------------------------------------------------ graph prep
__global__ void hist_edges_k(const int* __restrict__ src, const int* __restrict__ dst,
                             int* __restrict__ cin, int* __restrict__ cout) {
  int e = blockIdx.x * 256 + threadIdx.x;
  if (e < Ee) { atomicAdd(&cin[dst[e]], 1); atomicAdd(&cout[src[e]], 1); }
}

__global__ void cnt_batch_k(const int* __restrict__ batch, float* __restrict__ cntf) {
  int b = threadIdx.x;
  if (b < Bb) {
    int lo = 0, hi = Nn;
    while (lo < hi) { int mid = (lo + hi) >> 1; if (batch[mid] < b) lo = mid + 1; else hi = mid; }
    int lb = lo;
    lo = 0; hi = Nn;
    while (lo < hi) { int mid = (lo + hi) >> 1; if (batch[mid] <= b) lo = mid + 1; else hi = mid; }
    cntf[b] = (float)(lo - lb);
  }
}

__global__ __launch_bounds__(1024) void scan_k(const int* __restrict__ cin,
                                               const int* __restrict__ cout,
                                               int* __restrict__ off_in, int* __restrict__ off_out,
                                               int* __restrict__ cur_in, int* __restrict__ cur_out) {
  __shared__ int part[1024];
  const int tid = threadIdx.x;
  for (int which = 0; which < 2; ++which) {
    const int* cnt = which ? cout : cin;
    int* off = which ? off_out : off_in;
    int* curp = which ? cur_out : cur_in;
    int vals[20];
    int base = tid * 20;
    int local = 0;
#pragma unroll
    for (int i = 0; i < 20; ++i) {
      int idx = base + i;
      int v = (idx < Nn) ? cnt[idx] : 0;
      vals[i] = v; local += v;
    }
    part[tid] = local;
    __syncthreads();
    for (int ofs = 1; ofs < 1024; ofs <<= 1) {
      int t = (tid >= ofs) ? part[tid - ofs] : 0;
      __syncthreads();
      part[tid] += t;
      __syncthreads();
    }
    int run = part[tid] - local;
#pragma unroll
    for (int i = 0; i < 20; ++i) {
      int idx = base + i;
      if (idx < Nn) { off[idx] = run; curp[idx] = run; run += vals[i]; }
    }
    if (tid == 0) off[Nn] = Ee;
    __syncthreads();
  }
}

__global__ void scatter_k(const int* __restrict__ src, const int* __restrict__ dst,
                          int* __restrict__ cur_in, int* __restrict__ cur_out,
                          int* __restrict__ in_src, int* __restrict__ in_eid,
                          int* __restrict__ out_dst, int* __restrict__ out_eid,
                          int* __restrict__ out_srcn) {
  int e = blockIdx.x * 256 + threadIdx.x;
  if (e < Ee) {
    int d = dst[e], s = src[e];
    int p = atomicAdd(&cur_in[d], 1);  in_src[p] = s;  in_eid[p] = e;
    int q = atomicAdd(&cur_out[s], 1); out_dst[q] = d; out_eid[q] = e; out_srcn[q] = s;
  }
}

__global__ void prep_bsum_k(const float* __restrict__ bs, const float* __restrict__ bin,
                            const float* __restrict__ bout, float* __restrict__ bsum) {
  int t = threadIdx.x;
  for (int l = 0; l < 3; ++l) bsum[l * 256 + t] = bs[l * 256 + t] + bin[l * 256 + t] + bout[l * 256 + t];
}

__global__ void copyxb_k(const float* __restrict__ x, ushort* __restrict__ h) {
  const int n4 = Nn * Dd / 4;
  int i = blockIdx.x * 256 + threadIdx.x;
  if (i < n4) {
    float4 v = ((const float4*)x)[i];
    ushort4 o; o.x = f2b(v.x); o.y = f2b(v.y); o.z = f2b(v.z); o.w = f2b(v.w);
    ((ushort4*)h)[i] = o;
  }
}

__global__ void c_f2b_k(const float* __restrict__ s, ushort* __restrict__ d, int n) {
  int i = blockIdx.x * 256 + threadIdx.x;
  if (i < n) d[i] = f2b(s[i]);
}

// Wcombb[256][256]: rows 0-127 = mw1[r][0:256], rows 128-255 = mw1[r-128][256:512]
__global__ void prep_mlp_k(const float* __restrict__ mw1, const float* __restrict__ mb1,
                           const float* __restrict__ mw2,
                           ushort* __restrict__ Wcombb, ushort* __restrict__ W2b,
                           float* __restrict__ bcomb) {
  int i = blockIdx.x * 256 + threadIdx.x;
  if (i < 65536) {
    int r = i >> 8, c = i & 255;
    float v = (r < 128) ? mw1[r * 512 + c] : mw1[(r - 128) * 512 + 256 + c];
    Wcombb[i] = f2b(v);
  }
  if (i < 8192) W2b[i] = f2b(mw2[i]);
  if (i < 256) bcomb[i] = (i < 128) ? mb1[i] : 0.f;
}

// build in-CSR mask (out-CSR mask written directly by edge MLP)
__global__ void permmask_k(const float* __restrict__ mask,
                           const int* __restrict__ in_eid, float* __restrict__ minA) {
  int i = blockIdx.x * 256 + threadIdx.x;
  if (i < Ee) minA[i] = mask[in_eid[i]];
}

// ------------------------------------------------------------------ GEMM768 tiled: LDS-staged 128x128 tile
// Y[M x 768] = A[M x 256] @ [Ws|Win|Wout]^T.  4 waves, each 64x64 quadrant (4x4 frags).
// LDS: As[128][40] + Bs[128][40] (pad 40: 2-way-free banks, 16B aligned rows).
__global__ __launch_bounds__(256) void gemm768t_k(
    const ushort* __restrict__ A, const ushort* __restrict__ W0,
    const ushort* __restrict__ W1, const ushort* __restrict__ W2,
    ushort* __restrict__ Y, int M) {
  __shared__ ushort lds[10240];
  ushort* As = lds;
  ushort* Bs = lds + 5120;
  const int tid = threadIdx.x;
  const int wid = tid >> 6, lane = tid & 63;
  const int wr = wid & 1, wc = wid >> 1;
  const int m0 = blockIdx.x * 128;
  const int by = blockIdx.y;
  const int seg = by >> 1;
  const ushort* Wp = (seg == 0) ? W0 : ((seg == 1) ? W1 : W2);
  const int nb0 = (by & 1) * 128;
  const int lrow = lane & 15;
  const int klo = (lane >> 4) * 8;
  // staging coords for this thread (2 chunks of 16B per matrix per iter)
  const int r0 = tid >> 2, c80 = (tid & 3) * 8;            // chunk j = tid
  const int r1 = (tid + 256) >> 2, c81 = ((tid + 256) & 3) * 8;
  int ar0 = m0 + r0; if (ar0 >= M) ar0 = M - 1;
  int ar1 = m0 + r1; if (ar1 >= M) ar1 = M - 1;
  v4f acc[4][4] = {};
  for (int kc = 0; kc < 256; kc += 32) {
    __syncthreads();  // WAR: prior reads done before overwrite
    *(v8s*)&As[r0 * 40 + c80] = *(const v8s*)(A + (size_t)ar0 * 256 + kc + c80);
    *(v8s*)&As[r1 * 40 + c81] = *(const v8s*)(A + (size_t)ar1 * 256 + kc + c81);
    *(v8s*)&Bs[r0 * 40 + c80] = *(const v8s*)(Wp + (size_t)(nb0 + r0) * 256 + kc + c80);
    *(v8s*)&Bs[r1 * 40 + c81] = *(const v8s*)(Wp + (size_t)(nb0 + r1) * 256 + kc + c81);
    __syncthreads();
    v8s a[4], b[4];
#pragma unroll
    for (int f = 0; f < 4; ++f) {
      a[f] = *(const v8s*)&As[(wr * 64 + f * 16 + lrow) * 40 + klo];
      b[f] = *(const v8s*)&Bs[(wc * 64 + f * 16 + lrow) * 40 + klo];
    }
#pragma unroll
    for (int fi = 0; fi < 4; ++fi)
#pragma unroll
      for (int fj = 0; fj < 4; ++fj)
        acc[fi][fj] = __builtin_amdgcn_mfma_f32_16x16x32_bf16(a[fi], b[fj], acc[fi][fj], 0, 0, 0);
  }
  __syncthreads();  // all compute reads done; overlay LDS for epilogue
  ushort* ep = lds + wid * 2304;  // [32][72] per wave (wave-private)
  const int colq = by * 128 + wc * 64;
#pragma unroll
  for (int hf = 0; hf < 2; ++hf) {
#pragma unroll
    for (int fi = 0; fi < 2; ++fi) {
      const int fI = hf * 2 + fi;
      const int rl0 = fi * 16 + ((lane >> 4) << 2);
#pragma unroll
      for (int fj = 0; fj < 4; ++fj)
#pragma unroll
        for (int r = 0; r < 4; ++r)
          ep[(rl0 + r) * 72 + fj * 16 + lrow] = f2b(acc[fI][fj][r]);
    }
#pragma unroll
    for (int i = 0; i < 4; ++i) {
      const int rl = (lane >> 2) + (i & 1) * 16;
      const int oct = (lane & 3) + (i >> 1) * 4;
      v8s val = *(const v8s*)&ep[rl * 72 + oct * 8];
      const int grow = m0 + wr * 64 + hf * 32 + rl;
      if (grow < M)
        *(v8s*)(Y + (size_t)grow * 768 + colq + oct * 8) = val;
    }
  }
}

// ------------------------------------------------------------------ agg + epilogue
// MODE 0: m=1 ; MODE 1: m=mask (batched L0 sub) ; MODE 2: dual-half batched
// WR 1: save raw agg sum
template <int MODE, int WR>
__global__ __launch_bounds__(256) void aggepi_k(
    const ushort* __restrict__ Y, ushort* __restrict__ hout, ushort* __restrict__ raw,
    const int* __restrict__ off_in, const int* __restrict__ in_src,
    const int* __restrict__ off_out, const int* __restrict__ out_dst,
    const float* __restrict__ minA, const float* __restrict__ moutA,
    const float* __restrict__ bsum, const float* __restrict__ gma,
    const float* __restrict__ bta, const float* __restrict__ rmn, const float* __restrict__ rvr,
    int Mtot) {
  const int g = threadIdx.x >> 5;
  const int lane = threadIdx.x & 31;
  const int node = blockIdx.x * 8 + g;
  if (node >= Mtot) return;
  const int half = (MODE == 2 && node >= Nn) ? 1 : 0;
  const int v = node - half * Nn;
  const int co = lane * 8;
  float acc[8] = {};
#pragma unroll
  for (int dir = 0; dir < 2; ++dir) {
    const int* offs = dir ? off_out : off_in;
    const int* nbr  = dir ? out_dst : in_src;
    const float* ma = dir ? moutA : minA;
    const ushort* Yg = Y + (size_t)half * Nn * 768 + (dir ? 512 : 256) + co;
    const int s = offs[v], e = offs[v + 1];
    int i = s;
    for (; i + 4 <= e; i += 4) {
      int u[4]; float m[4];
#pragma unroll
      for (int t = 0; t < 4; ++t) {
        u[t] = nbr[i + t];
        m[t] = (MODE == 0) ? 1.f : ((MODE == 2 && half) ? 1.f - ma[i + t] : ma[i + t]);
      }
      v8s r[4];
#pragma unroll
      for (int t = 0; t < 4; ++t) r[t] = *(const v8s*)(Yg + (size_t)u[t] * 768);
#pragma unroll
      for (int t = 0; t < 4; ++t)
#pragma unroll
        for (int j = 0; j < 8; ++j) acc[j] += m[t] * b2f((ushort)r[t][j]);
    }
    for (; i < e; ++i) {
      int u = nbr[i];
      float m = (MODE == 0) ? 1.f : ((MODE == 2 && half) ? 1.f - ma[i] : ma[i]);
      v8s r = *(const v8s*)(Yg + (size_t)u * 768);
#pragma unroll
      for (int j = 0; j < 8; ++j) acc[j] += m * b2f((ushort)r[j]);
    }
  }
  if (WR) {
    v8s rw;
#pragma unroll
    for (int j = 0; j < 8; ++j) rw[j] = (short)f2b(acc[j]);
    *(v8s*)(raw + (size_t)v * 256 + co) = rw;
  }
  const ushort* Yself = Y + (size_t)half * Nn * 768;
  v8s ys = *(const v8s*)(Yself + (size_t)v * 768 + co);
  v8s o;
#pragma unroll
  for (int j = 0; j < 8; ++j) {
    const int col = co + j;
    float val = acc[j] + b2f((ushort)ys[j]) + bsum[col];
    val = fmaxf(val, 0.f);
    val = (val - rmn[col]) * rsqrtf(rvr[col] + EPSc) * gma[col] + bta[col];
    o[j] = (short)f2b(val);
  }
  *(v8s*)(hout + (size_t)node * 256 + co) = o;
}

// batched L0 comp half: out[N+v] = BN(relu(Yx_s[v] + (Aones - Asub) + bsum0))
__global__ void compl0_k(const ushort* __restrict__ Yx, const ushort* __restrict__ Aones,
                         const ushort* __restrict__ Asub, ushort* __restrict__ hout,
                         const float* __restrict__ bsum, const float* __restrict__ gma,
                         const float* __restrict__ bta, const float* __restrict__ rmn,
                         const float* __restrict__ rvr) {
  int i = blockIdx.x * 256 + threadIdx.x;
  if (i >= Nn * 32) return;
  const int v = i >> 5;
  const int co = (i & 31) * 8;
  v8s ys = *(const v8s*)(Yx + (size_t)v * 768 + co);
  v8s ao = *(const v8s*)(Aones + (size_t)v * 256 + co);
  v8s as = *(const v8s*)(Asub + (size_t)v * 256 + co);
  v8s o;
#pragma unroll
  for (int j = 0; j < 8; ++j) {
    const int col = co + j;
    float val = b2f((ushort)ys[j]) + b2f((ushort)ao[j]) - b2f((ushort)as[j]) + bsum[col];
    val = fmaxf(val, 0.f);
    val = (val - rmn[col]) * rsqrtf(rvr[col] + EPSc) * gma[col] + bta[col];
    o[j] = (short)f2b(val);
  }
  *(v8s*)(hout + (size_t)(Nn + v) * 256 + co) = o;
}

// ------------------------------------------------------------------ proj GEMM (mask MLP layer 1)
template <int EPI>
__global__ __launch_bounds__(256) void mfma_gemm2_k(
    const ushort* __restrict__ A, const ushort* __restrict__ W,
    ushort* __restrict__ Cout, int M, const float* __restrict__ bias) {
  __shared__ ushort eplds[4][32][72];
  const int tid = threadIdx.x;
  const int wid = tid >> 6, lane = tid & 63;
  const int wr = wid & 1, wc = wid >> 1;
  const int m0 = blockIdx.x * 64 + wr * 32;
  const int n0 = blockIdx.y * 128 + wc * 64;
  const int lrow = lane & 15;
  const int klo = (lane >> 4) * 8;
  int rowA[2];
#pragma unroll
  for (int fi = 0; fi < 2; ++fi) {
    int r = m0 + fi * 16 + lrow;
    rowA[fi] = (r < M) ? r : (M - 1);
  }
  v4f acc[2][4] = {};
#pragma unroll
  for (int c = 0; c < 8; ++c) {
    v8s a[2], b[4];
#pragma unroll
    for (int fi = 0; fi < 2; ++fi)
      a[fi] = *(const v8s*)(A + (size_t)rowA[fi] * 256 + c * 32 + klo);
#pragma unroll
    for (int fj = 0; fj < 4; ++fj)
      b[fj] = *(const v8s*)(W + (size_t)(n0 + fj * 16 + lrow) * 256 + c * 32 + klo);
#pragma unroll
    for (int fi = 0; fi < 2; ++fi)
#pragma unroll
      for (int fj = 0; fj < 4; ++fj)
        acc[fi][fj] = __builtin_amdgcn_mfma_f32_16x16x32_bf16(a[fi], b[fj], acc[fi][fj], 0, 0, 0);
  }
#pragma unroll
  for (int fj = 0; fj < 4; ++fj) {
    const int col = n0 + fj * 16 + lrow;
    const float bsv = bias ? bias[col] : 0.f;
#pragma unroll
    for (int fi = 0; fi < 2; ++fi) {
      const int rl0 = fi * 16 + ((lane >> 4) << 2);
#pragma unroll
      for (int r = 0; r < 4; ++r)
        eplds[wid][rl0 + r][fj * 16 + lrow] = f2b(acc[fi][fj][r] + bsv);
    }
  }
#pragma unroll
  for (int i = 0; i < 4; ++i) {
    const int rl = (lane >> 2) + (i & 1) * 16;
    const int oct = (lane & 3) + (i >> 1) * 4;
    v8s val = *(const v8s*)&eplds[wid][rl][oct * 8];
    const int grow = m0 + rl;
    if (grow < M)
      *(v8s*)(Cout + (size_t)grow * 256 + n0 + oct * 8) = val;
  }
}

// ------------------------------------------------------------------ edge MLP over out-CSR order
__global__ __launch_bounds__(256) void edge_mlp4_k(const ushort* __restrict__ P,
                                                   const int* __restrict__ out_srcn,
                                                   const int* __restrict__ out_dst,
                                                   const int* __restrict__ out_eid,
                                                   const ushort* __restrict__ W2b,
                                                   const float* __restrict__ b2, const float* __restrict__ w3,
                                                   const float* __restrict__ b3,
                                                   float* __restrict__ maskOut, float* __restrict__ moutA) {
  const int tid = threadIdx.x;
  const int w = tid >> 6, lane = tid & 63;
  const int e0 = blockIdx.x * 64 + w * 16;
  const int le = lane & 15;
  const int kq = lane >> 4;
  const int klo = kq * 8;
  const int pA = e0 + le;
  const int s_ = out_srcn[pA], d_ = out_dst[pA];
  const ushort* ps = P + (size_t)s_ * 256;
  const ushort* pd = P + (size_t)d_ * 256 + 128;
  v8s as[4], ad[4];
#pragma unroll
  for (int c = 0; c < 4; ++c) {
    as[c] = *(const v8s*)(ps + c * 32 + klo);
    ad[c] = *(const v8s*)(pd + c * 32 + klo);
  }
  v4f acc[4] = {};
#pragma unroll
  for (int c = 0; c < 4; ++c) {
    v8s h;
#pragma unroll
    for (int j = 0; j < 8; ++j) {
      float v = fmaxf(b2f((ushort)as[c][j]) + b2f((ushort)ad[c][j]), 0.f);
      h[j] = (short)f2b(v);
    }
#pragma unroll
    for (int fj = 0; fj < 4; ++fj) {
      v8s b = *(const v8s*)(W2b + (size_t)(fj * 16 + le) * 128 + c * 32 + klo);
      acc[fj] = __builtin_amdgcn_mfma_f32_16x16x32_bf16(h, b, acc[fj], 0, 0, 0);
    }
  }
  float b2v[4], w3v[4];
#pragma unroll
  for (int fj = 0; fj < 4; ++fj) { b2v[fj] = b2[fj * 16 + le]; w3v[fj] = w3[fj * 16 + le]; }
  const float b3v = b3[0];
#pragma unroll
  for (int r = 0; r < 4; ++r) {
    float val = 0.f;
#pragma unroll
    for (int fj = 0; fj < 4; ++fj)
      val += fmaxf(acc[fj][r] + b2v[fj], 0.f) * w3v[fj];
    val += __shfl_xor(val, 1);
    val += __shfl_xor(val, 2);
    val += __shfl_xor(val, 4);
    val += __shfl_xor(val, 8);
    if (le == 0) {
      int pos = e0 + kq * 4 + r;
      float sig = 1.0f / (1.0f + expf(-(val + b3v)));
      moutA[pos] = sig;
      maskOut[out_eid[pos]] = sig;
    }
  }
}

// ------------------------------------------------------------------ pooling / tails
__global__ __launch_bounds__(256) void gemb_sum_k(const ushort* __restrict__ h, const int* __restrict__ batch,
                                                  float* __restrict__ gsum, int batched) {
  const int halfBlocks = Nn / 16;
  int blk = blockIdx.x;
  int half = 0, bi = blk;
  if (batched) { half = (blk >= halfBlocks) ? 1 : 0; bi = blk - half * halfBlocks; }
  const int v0 = bi * 16;
  const int tid = threadIdx.x;
  const size_t base = (size_t)half * Nn;
  float* out = gsum + (size_t)half * (Bb * Dd);
  float acc = 0.0f;
  int curb = batch[v0];
  for (int i = 0; i < 16; ++i) {
    int v = v0 + i;
    int b = batch[v];
    if (b != curb) { atomicAdd(&out[curb * Dd + tid], acc); acc = 0.0f; curb = b; }
    acc += b2f(h[(base + v) * Dd + tid]);
  }
  atomicAdd(&out[curb * Dd + tid], acc);
}

__global__ void gemb_scale_k(float* __restrict__ g, const float* __restrict__ cntf) {
  int blk = blockIdx.x;
  int b = blk & 15;
  g[blk * Dd + threadIdx.x] /= fmaxf(cntf[b], 1.0f);
}

__global__ void anchor_k(const float* __restrict__ g, const float* __restrict__ anchors,
                         float* __restrict__ s_out) {
  __shared__ float red4[4];
  const int b = blockIdx.x, tid = threadIdx.x;
  float gv = g[b * Dd + tid];
  float total = 0.0f;
  for (int k = 0; k < 6; ++k) {
    float d = gv - anchors[k * Dd + tid];
    float v = d * d;
    for (int o = 32; o > 0; o >>= 1) v += __shfl_xor(v, o);
    if ((tid & 63) == 0) red4[tid >> 6] = v;
    __syncthreads();
    if (tid == 0) total += sqrtf(red4[0] + red4[1] + red4[2] + red4[3]);
    __syncthreads();
  }
  if (tid == 0) s_out[b] = total;
}

__global__ void logits_k(const float* __restrict__ gsub, const float* __restrict__ gcomp,
                         const float* __restrict__ Wc, const float* __restrict__ bc,
                         float* __restrict__ outL) {
  __shared__ float red4[4];
  const int blk = blockIdx.x;
  const int set = blk >> 4, b = blk & 15;
  const float* g = set ? gcomp : gsub;
  const int tid = threadIdx.x;
  float gv = g[b * Dd + tid];
  for (int c = 0; c < 2; ++c) {
    float v = gv * Wc[c * Dd + tid];
    for (int o = 32; o > 0; o >>= 1) v += __shfl_xor(v, o);
    if ((tid & 63) == 0) red4[tid >> 6] = v;
    __syncthreads();
    if (tid == 0) outL[set * 32 + b * 2 + c] = red4[0] + red4[1] + red4[2] + red4[3] + bc[c];
    __syncthreads();
  }
}

__global__ void final_k(const float* __restrict__ L, const int* __restrict__ labels,
                        const float* __restrict__ s_orig, const float* __restrict__ s_sub,
                        float* __restrict__ out) {
  if (threadIdx.x == 0) {
    float Lp = 0, Lu = 0, La = 0;
    const float u = 0.5f;
    for (int b = 0; b < 16; ++b) {
      float l0 = L[b * 2], l1 = L[b * 2 + 1];
      float m = fmaxf(l0, l1);
      float lse = m + logf(expf(l0 - m) + expf(l1 - m));
      int lab = labels[b];
      Lp += -((lab ? l1 : l0) - lse);
      float c0 = L[32 + b * 2], c1 = L[32 + b * 2 + 1];
      float mm = fmaxf(c0, c1);
      float e0 = expf(c0 - mm), e1 = expf(c1 - mm), Z = e0 + e1;
      Lu += u * (logf(u) - logf(e0 / Z + 1e-8f)) + u * (logf(u) - logf(e1 / Z + 1e-8f));
      float dd = s_sub[b] - s_orig[b];
      La += dd * dd;
    }
    Lp /= 16.0f; Lu /= 16.0f; La /= 16.0f;
    out[0] = 0.5f * Lp + 0.3f * Lu + 0.2f * La;
    out[1] = Lp; out[2] = Lu; out[3] = La;
  }
}

// ------------------------------------------------------------------ host
extern "C" void kernel_launch(void* const* d_in, const int* in_sizes, int n_in,
                              void* d_out, int out_size, void* d_ws, size_t ws_size,
                              hipStream_t stream) {
  (void)in_sizes; (void)n_in; (void)out_size; (void)ws_size;
  const float* x    = (const float*)d_in[0];
  const int* ei     = (const int*)d_in[1];
  const int* batch  = (const int*)d_in[2];
  const int* labels = (const int*)d_in[3];
  const float* mw1 = (const float*)d_in[4];
  const float* mb1 = (const float*)d_in[5];
  const float* mw2 = (const float*)d_in[6];
  const float* mb2 = (const float*)d_in[7];
  const float* mw3 = (const float*)d_in[8];
  const float* mb3 = (const float*)d_in[9];
  const float* Ws   = (const float*)d_in[10];
  const float* bs   = (const float*)d_in[11];
  const float* Win  = (const float*)d_in[12];
  const float* bin_ = (const float*)d_in[13];
  const float* Wout = (const float*)d_in[14];
  const float* bout = (const float*)d_in[15];
  const float* gma  = (const float*)d_in[16];
  const float* bta  = (const float*)d_in[17];
  const float* rmn  = (const float*)d_in[18];
  const float* rvr  = (const float*)d_in[19];
  const float* anchors = (const float*)d_in[20];
  const float* Wc   = (const float*)d_in[21];
  const float* bc   = (const float*)d_in[22];
  const int* srcp = ei;
  const int* dstp = ei + Ee;

  const size_t NH = (size_t)Nn * Dd;
  const size_t NY = (size_t)Nn * 768;
  ushort* xb   = (ushort*)d_ws;
  ushort* hA   = xb + NH;              // 2NH
  ushort* hB   = hA + 2 * NH;          // 2NH
  ushort* Yx   = hB + 2 * NH;          // NY (persistent L0 projection of x)
  ushort* Ybuf = Yx + NY;              // 2NY (batched dual-half; Pb aliases)
  ushort* Pb   = Ybuf;
  ushort* Aones = Ybuf + 2 * NY;       // NH
  ushort* Asub  = Aones + NH;          // NH
  ushort* Wsb   = Asub + NH;
  ushort* Winb  = Wsb + 3 * 65536;
  ushort* Woutb = Winb + 3 * 65536;
  ushort* Wcombb = Woutb + 3 * 65536;
  ushort* W2b    = Wcombb + 65536;
  float* bcomb = (float*)(W2b + 8192);
  float* minA  = bcomb + 256;
  float* moutA = minA + Ee;
  int* off_in   = (int*)(moutA + Ee);
  int* off_out  = off_in + (Nn + 1);
  int* cur_in   = off_out + (Nn + 1);
  int* cur_out  = cur_in + Nn;
  int* in_src   = cur_out + Nn;
  int* in_eid   = in_src + Ee;
  int* out_dst  = in_eid + Ee;
  int* out_eid  = out_dst + Ee;
  int* out_srcn = out_eid + Ee;
  int* counts_in  = out_srcn + Ee;
  int* counts_out = counts_in + Nn;
  float* cntf      = (float*)(counts_out + Nn);
  float* gemb_orig = cntf + Bb;
  float* gemb_sub  = gemb_orig + Bb * Dd;
  float* gemb_comp = gemb_sub + Bb * Dd;
  float* bsum    = gemb_comp + Bb * Dd;
  float* s_orig  = bsum + 3 * Dd;
  float* s_sub   = s_orig + Bb;
  float* logitsb = s_sub + Bb;

  float* outF = (float*)d_out;
  float* maskp = outF + 4;

  const size_t zero_bytes = (char*)bsum - (char*)counts_in;
  hipMemsetAsync(counts_in, 0, zero_bytes, stream);

  hist_edges_k<<<(Ee + 255) / 256, 256, 0, stream>>>(srcp, dstp, counts_in, counts_out);
  cnt_batch_k<<<1, 64, 0, stream>>>(batch, cntf);
  scan_k<<<1, 1024, 0, stream>>>(counts_in, counts_out, off_in, off_out, cur_in, cur_out);
  scatter_k<<<(Ee + 255) / 256, 256, 0, stream>>>(srcp, dstp, cur_in, cur_out, in_src, in_eid,
                                                  out_dst, out_eid, out_srcn);
  prep_bsum_k<<<1, 256, 0, stream>>>(bs, bin_, bout, bsum);

  c_f2b_k<<<(3 * 65536 + 255) / 256, 256, 0, stream>>>(Ws, Wsb, 3 * 65536);
  c_f2b_k<<<(3 * 65536 + 255) / 256, 256, 0, stream>>>(Win, Winb, 3 * 65536);
  c_f2b_k<<<(3 * 65536 + 255) / 256, 256, 0, stream>>>(Wout, Woutb, 3 * 65536);
  prep_mlp_k<<<256, 256, 0, stream>>>(mw1, mb1, mw2, Wcombb, W2b, bcomb);

  auto run_gemm768 = [&](const ushort* h, ushort* Yout, int M, int l) {
    dim3 gg((M + 127) / 128, 6);
    gemm768t_k<<<gg, 256, 0, stream>>>(h, Wsb + (size_t)l * 65536, Winb + (size_t)l * 65536,
                                       Woutb + (size_t)l * 65536, Yout, M);
  };
  auto bn = [&](int l) { return bsum + l * 256; };
  const int aggN = (Nn + 7) / 8;
  const int agg2N = (2 * Nn + 7) / 8;

  // ---- encoder #1 (ones mask)
  copyxb_k<<<(Nn * Dd / 4 + 255) / 256, 256, 0, stream>>>(x, xb);
  run_gemm768(xb, Yx, Nn, 0);  // persistent: reused by batched L0
  aggepi_k<0, 1><<<aggN, 256, 0, stream>>>(
      Yx, hB, Aones, off_in, in_src, off_out, out_dst, nullptr, nullptr,
      bn(0), gma, bta, rmn, rvr, Nn);
  run_gemm768(hB, Ybuf, Nn, 1);
  aggepi_k<0, 0><<<aggN, 256, 0, stream>>>(
      Ybuf, hA, nullptr, off_in, in_src, off_out, out_dst, nullptr, nullptr,
      bn(1), gma + 256, bta + 256, rmn + 256, rvr + 256, Nn);
  run_gemm768(hA, Ybuf, Nn, 2);
  aggepi_k<0, 0><<<aggN, 256, 0, stream>>>(
      Ybuf, hB, nullptr, off_in, in_src, off_out, out_dst, nullptr, nullptr,
      bn(2), gma + 512, bta + 512, rmn + 512, rvr + 512, Nn);
  // node_emb = hB

  gemb_sum_k<<<Nn / 16, 256, 0, stream>>>(hB, batch, gemb_orig, 0);
  gemb_scale_k<<<Bb, 256, 0, stream>>>(gemb_orig, cntf);
  anchor_k<<<Bb, 256, 0, stream>>>(gemb_orig, anchors, s_orig);

  // ---- packed projection P = [emb@W1a^T + b1 | emb@W1b^T] (Pb aliases Ybuf)
  {
    dim3 gp((Nn + 63) / 64, 2);
    mfma_gemm2_k<3><<<gp, 256, 0, stream>>>(hB, Wcombb, Pb, Nn, bcomb);
  }
  edge_mlp4_k<<<Ee / 64, 256, 0, stream>>>(Pb, out_srcn, out_dst, out_eid,
                                           W2b, mb2, mw3, mb3, maskp, moutA);
  permmask_k<<<(Ee + 255) / 256, 256, 0, stream>>>(maskp, in_eid, minA);

  // ---- batched encoders #2/#3 (mask & 1-mask)
  aggepi_k<1, 1><<<aggN, 256, 0, stream>>>(
      Yx, hA, Asub, off_in, in_src, off_out, out_dst, minA, moutA,
      bn(0), gma, bta, rmn, rvr, Nn);
  compl0_k<<<(Nn * 32 + 255) / 256, 256, 0, stream>>>(Yx, Aones, Asub, hA,
                                                      bn(0), gma, bta, rmn, rvr);
  // L1 (fused halves: M = 2N GEMM, dual-mode agg)
  run_gemm768(hA, Ybuf, 2 * Nn, 1);
  aggepi_k<2, 0><<<agg2N, 256, 0, stream>>>(
      Ybuf, hB, nullptr, off_in, in_src, off_out, out_dst, minA, moutA,
      bn(1), gma + 256, bta + 256, rmn + 256, rvr + 256, 2 * Nn);
  // L2
  run_gemm768(hB, Ybuf, 2 * Nn, 2);
  aggepi_k<2, 0><<<agg2N, 256, 0, stream>>>(
      Ybuf, hA, nullptr, off_in, in_src, off_out, out_dst, minA, moutA,
      bn(2), gma + 512, bta + 512, rmn + 512, rvr + 512, 2 * Nn);
  // hA = [h_sub; h_comp]

  gemb_sum_k<<<2 * (Nn / 16), 256, 0, stream>>>(hA, batch, gemb_sub, 1);
  gemb_scale_k<<<2 * Bb, 256, 0, stream>>>(gemb_sub, cntf);
  anchor_k<<<Bb, 256, 0, stream>>>(gemb_sub, anchors, s_sub);
  logits_k<<<2 * Bb, 256, 0, stream>>>(gemb_sub, gemb_comp, Wc, bc, logitsb);
  final_k<<<1, 64, 0, stream>>>(logitsb, labels, s_orig, s_sub, outF);
}

// Round 15
// 685.440 us; speedup vs baseline: 7.0470x; 1.0990x over previous
//
#include <hip/hip_runtime.h>
#include <hip/hip_bf16.h>

constexpr int Nn = 20000;
constexpr int Ee = 320000;
constexpr int Dd = 256;
constexpr int Bb = 16;
constexpr float EPSc = 1e-5f;

using v8s = __attribute__((ext_vector_type(8))) short;
using v4f = __attribute__((ext_vector_type(4))) float;
using v2f = __attribute__((ext_vector_type(2))) float;

__device__ __forceinline__ float b2f(ushort u) { return __uint_as_float(((unsigned)u) << 16); }
__device__ __forceinline__ ushort f2b(float f) {
  __hip_bfloat16 h = __float2bfloat16(f);
  return *reinterpret_cast<ushort*>(&h);
}

#ifndef __has_builtin
#define __has_builtin(x) 0
#endif
#if __has_builtin(__builtin_amdgcn_cvt_pk_f32_fp8) && __has_builtin(__builtin_amdgcn_cvt_pk_fp8_f32)
#define FP8CVT 1
#else
#define FP8CVT 0
#endif

__device__ __forceinline__ unsigned f2fp8(float v) {
#if FP8CVT
  return (unsigned)__builtin_amdgcn_cvt_pk_fp8_f32(v, 0.f, 0, false) & 0xFFu;
#else
  unsigned u = __float_as_uint(v);
  unsigned s = (u >> 24) & 0x80u;
  unsigned a = u & 0x7FFFFFFFu;
  if (a >= 0x43F00000u) return s | 0x7Eu;  // clamp to 448
  unsigned r = a + 0x0007FFFFu + ((a >> 20) & 1u);
  int e = (int)(r >> 23) - 120;
  if (e <= 0) return s;
  return s | ((unsigned)e << 3) | ((r >> 20) & 7u);
#endif
}

__device__ __forceinline__ void fp8x8_dec(unsigned lo, unsigned hi, float* f) {
#if FP8CVT
  v2f p0 = __builtin_amdgcn_cvt_pk_f32_fp8((int)lo, false);
  v2f p1 = __builtin_amdgcn_cvt_pk_f32_fp8((int)lo, true);
  v2f p2 = __builtin_amdgcn_cvt_pk_f32_fp8((int)hi, false);
  v2f p3 = __builtin_amdgcn_cvt_pk_f32_fp8((int)hi, true);
  f[0] = p0[0]; f[1] = p0[1]; f[2] = p1[0]; f[3] = p1[1];
  f[4] = p2[0]; f[5] = p2[1]; f[6] = p3[0]; f[7] = p3[1];
#else
#pragma unroll
  for (int j = 0; j < 8; ++j) {
    unsigned b = (j < 4) ? ((lo >> (8 * j)) & 0xFFu) : ((hi >> (8 * (j - 4))) & 0xFFu);
    unsigned s = (b & 0x80u) << 24;
    unsigned e = (b >> 3) & 15u, m = b & 7u;
    float x;
    if (e) x = __uint_as_float(s | ((e + 120u) << 23) | (m << 20));
    else { x = (float)(int)m * 0x1p-9f; if (s) x = -x; }
    f[j] = x;
  }
#endif
}

// ------------------------------------------------------------------ graph prep
__global__ void hist_edges_k(const int* __restrict__ src, const int* __restrict__ dst,
                             int* __restrict__ cin, int* __restrict__ cout) {
  int e = blockIdx.x * 256 + threadIdx.x;
  if (e < Ee) { atomicAdd(&cin[dst[e]], 1); atomicAdd(&cout[src[e]], 1); }
}

__global__ void cnt_batch_k(const int* __restrict__ batch, float* __restrict__ cntf) {
  int b = threadIdx.x;
  if (b < Bb) {
    int lo = 0, hi = Nn;
    while (lo < hi) { int mid = (lo + hi) >> 1; if (batch[mid] < b) lo = mid + 1; else hi = mid; }
    int lb = lo;
    lo = 0; hi = Nn;
    while (lo < hi) { int mid = (lo + hi) >> 1; if (batch[mid] <= b) lo = mid + 1; else hi = mid; }
    cntf[b] = (float)(lo - lb);
  }
}

__global__ __launch_bounds__(1024) void scan_k(const int* __restrict__ cin,
                                               const int* __restrict__ cout,
                                               int* __restrict__ off_in, int* __restrict__ off_out,
                                               int* __restrict__ cur_in, int* __restrict__ cur_out) {
  __shared__ int part[1024];
  const int tid = threadIdx.x;
  for (int which = 0; which < 2; ++which) {
    const int* cnt = which ? cout : cin;
    int* off = which ? off_out : off_in;
    int* curp = which ? cur_out : cur_in;
    int vals[20];
    int base = tid * 20;
    int local = 0;
#pragma unroll
    for (int i = 0; i < 20; ++i) {
      int idx = base + i;
      int v = (idx < Nn) ? cnt[idx] : 0;
      vals[i] = v; local += v;
    }
    part[tid] = local;
    __syncthreads();
    for (int ofs = 1; ofs < 1024; ofs <<= 1) {
      int t = (tid >= ofs) ? part[tid - ofs] : 0;
      __syncthreads();
      part[tid] += t;
      __syncthreads();
    }
    int run = part[tid] - local;
#pragma unroll
    for (int i = 0; i < 20; ++i) {
      int idx = base + i;
      if (idx < Nn) { off[idx] = run; curp[idx] = run; run += vals[i]; }
    }
    if (tid == 0) off[Nn] = Ee;
    __syncthreads();
  }
}

__global__ void scatter_k(const int* __restrict__ src, const int* __restrict__ dst,
                          int* __restrict__ cur_in, int* __restrict__ cur_out,
                          int* __restrict__ in_src, int* __restrict__ in_eid,
                          int* __restrict__ out_dst, int* __restrict__ out_eid,
                          int* __restrict__ out_srcn) {
  int e = blockIdx.x * 256 + threadIdx.x;
  if (e < Ee) {
    int d = dst[e], s = src[e];
    int p = atomicAdd(&cur_in[d], 1);  in_src[p] = s;  in_eid[p] = e;
    int q = atomicAdd(&cur_out[s], 1); out_dst[q] = d; out_eid[q] = e; out_srcn[q] = s;
  }
}

__global__ void prep_bsum_k(const float* __restrict__ bs, const float* __restrict__ bin,
                            const float* __restrict__ bout, float* __restrict__ bsum) {
  int t = threadIdx.x;
  for (int l = 0; l < 3; ++l) bsum[l * 256 + t] = bs[l * 256 + t] + bin[l * 256 + t] + bout[l * 256 + t];
}

__global__ void copyxb_k(const float* __restrict__ x, ushort* __restrict__ h) {
  const int n4 = Nn * Dd / 4;
  int i = blockIdx.x * 256 + threadIdx.x;
  if (i < n4) {
    float4 v = ((const float4*)x)[i];
    ushort4 o; o.x = f2b(v.x); o.y = f2b(v.y); o.z = f2b(v.z); o.w = f2b(v.w);
    ((ushort4*)h)[i] = o;
  }
}

__global__ void c_f2b_k(const float* __restrict__ s, ushort* __restrict__ d, int n) {
  int i = blockIdx.x * 256 + threadIdx.x;
  if (i < n) d[i] = f2b(s[i]);
}

__global__ void prep_mlp_k(const float* __restrict__ mw1, const float* __restrict__ mb1,
                           const float* __restrict__ mw2,
                           ushort* __restrict__ Wcombb, ushort* __restrict__ W2b,
                           float* __restrict__ bcomb) {
  int i = blockIdx.x * 256 + threadIdx.x;
  if (i < 65536) {
    int r = i >> 8, c = i & 255;
    float v = (r < 128) ? mw1[r * 512 + c] : mw1[(r - 128) * 512 + 256 + c];
    Wcombb[i] = f2b(v);
  }
  if (i < 8192) W2b[i] = f2b(mw2[i]);
  if (i < 256) bcomb[i] = (i < 128) ? mb1[i] : 0.f;
}

__global__ void permmask_k(const float* __restrict__ mask,
                           const int* __restrict__ in_eid, float* __restrict__ minA) {
  int i = blockIdx.x * 256 + threadIdx.x;
  if (i < Ee) minA[i] = mask[in_eid[i]];
}

// ------------------------------------------------------------------ GEMM768 tiled, LDS-staged 128x128
// EMIT8 0: bf16 out to Y ; 1: fp8 e4m3fn out to Y8
template <int EMIT8>
__global__ __launch_bounds__(256) void gemm768t_k(
    const ushort* __restrict__ A, const ushort* __restrict__ W0,
    const ushort* __restrict__ W1, const ushort* __restrict__ W2,
    ushort* __restrict__ Y, unsigned char* __restrict__ Y8, int M) {
  __shared__ ushort lds[10240];
  ushort* As = lds;
  ushort* Bs = lds + 5120;
  const int tid = threadIdx.x;
  const int wid = tid >> 6, lane = tid & 63;
  const int wr = wid & 1, wc = wid >> 1;
  const int m0 = blockIdx.x * 128;
  const int by = blockIdx.y;
  const int seg = by >> 1;
  const ushort* Wp = (seg == 0) ? W0 : ((seg == 1) ? W1 : W2);
  const int nb0 = (by & 1) * 128;
  const int lrow = lane & 15;
  const int klo = (lane >> 4) * 8;
  const int r0 = tid >> 2, c80 = (tid & 3) * 8;
  const int r1 = (tid + 256) >> 2, c81 = ((tid + 256) & 3) * 8;
  int ar0 = m0 + r0; if (ar0 >= M) ar0 = M - 1;
  int ar1 = m0 + r1; if (ar1 >= M) ar1 = M - 1;
  v4f acc[4][4] = {};
  for (int kc = 0; kc < 256; kc += 32) {
    __syncthreads();
    *(v8s*)&As[r0 * 40 + c80] = *(const v8s*)(A + (size_t)ar0 * 256 + kc + c80);
    *(v8s*)&As[r1 * 40 + c81] = *(const v8s*)(A + (size_t)ar1 * 256 + kc + c81);
    *(v8s*)&Bs[r0 * 40 + c80] = *(const v8s*)(Wp + (size_t)(nb0 + r0) * 256 + kc + c80);
    *(v8s*)&Bs[r1 * 40 + c81] = *(const v8s*)(Wp + (size_t)(nb0 + r1) * 256 + kc + c81);
    __syncthreads();
    v8s a[4], b[4];
#pragma unroll
    for (int f = 0; f < 4; ++f) {
      a[f] = *(const v8s*)&As[(wr * 64 + f * 16 + lrow) * 40 + klo];
      b[f] = *(const v8s*)&Bs[(wc * 64 + f * 16 + lrow) * 40 + klo];
    }
#pragma unroll
    for (int fi = 0; fi < 4; ++fi)
#pragma unroll
      for (int fj = 0; fj < 4; ++fj)
        acc[fi][fj] = __builtin_amdgcn_mfma_f32_16x16x32_bf16(a[fi], b[fj], acc[fi][fj], 0, 0, 0);
  }
  __syncthreads();
  const int colq = by * 128 + wc * 64;
  if (EMIT8) {
    unsigned char* ep = (unsigned char*)lds + wid * 3072;  // [32][96]
#pragma unroll
    for (int hf = 0; hf < 2; ++hf) {
#pragma unroll
      for (int fi = 0; fi < 2; ++fi) {
        const int fI = hf * 2 + fi;
        const int rl0 = fi * 16 + ((lane >> 4) << 2);
#pragma unroll
        for (int fj = 0; fj < 4; ++fj)
#pragma unroll
          for (int r = 0; r < 4; ++r)
            ep[(rl0 + r) * 96 + fj * 16 + lrow] = (unsigned char)f2fp8(acc[fI][fj][r]);
      }
#pragma unroll
      for (int i = 0; i < 2; ++i) {
        const int rl = (lane >> 2) + i * 16;
        const int cb = (lane & 3) * 16;
        uint4 val = *(const uint4*)&ep[rl * 96 + cb];
        const int grow = m0 + wr * 64 + hf * 32 + rl;
        if (grow < M)
          *(uint4*)(Y8 + (size_t)grow * 768 + colq + cb) = val;
      }
    }
  } else {
    ushort* ep = lds + wid * 2304;  // [32][72]
#pragma unroll
    for (int hf = 0; hf < 2; ++hf) {
#pragma unroll
      for (int fi = 0; fi < 2; ++fi) {
        const int fI = hf * 2 + fi;
        const int rl0 = fi * 16 + ((lane >> 4) << 2);
#pragma unroll
        for (int fj = 0; fj < 4; ++fj)
#pragma unroll
          for (int r = 0; r < 4; ++r)
            ep[(rl0 + r) * 72 + fj * 16 + lrow] = f2b(acc[fI][fj][r]);
      }
#pragma unroll
      for (int i = 0; i < 4; ++i) {
        const int rl = (lane >> 2) + (i & 1) * 16;
        const int oct = (lane & 3) + (i >> 1) * 4;
        v8s val = *(const v8s*)&ep[rl * 72 + oct * 8];
        const int grow = m0 + wr * 64 + hf * 32 + rl;
        if (grow < M)
          *(v8s*)(Y + (size_t)grow * 768 + colq + oct * 8) = val;
      }
    }
  }
}

// ------------------------------------------------------------------ agg + epilogue (bf16 tables)
// MODE 0: m=1 ; MODE 1: m=mask (batched L0 sub). WR 1: save raw agg sum.
template <int MODE, int WR>
__global__ __launch_bounds__(256) void aggepi_k(
    const ushort* __restrict__ Y, ushort* __restrict__ hout, ushort* __restrict__ raw,
    const int* __restrict__ off_in, const int* __restrict__ in_src,
    const int* __restrict__ off_out, const int* __restrict__ out_dst,
    const float* __restrict__ minA, const float* __restrict__ moutA,
    const float* __restrict__ bsum, const float* __restrict__ gma,
    const float* __restrict__ bta, const float* __restrict__ rmn, const float* __restrict__ rvr,
    int Mtot) {
  const int g = threadIdx.x >> 5;
  const int lane = threadIdx.x & 31;
  const int node = blockIdx.x * 8 + g;
  if (node >= Mtot) return;
  const int v = node;
  const int co = lane * 8;
  float acc[8] = {};
#pragma unroll
  for (int dir = 0; dir < 2; ++dir) {
    const int* offs = dir ? off_out : off_in;
    const int* nbr  = dir ? out_dst : in_src;
    const float* ma = dir ? moutA : minA;
    const ushort* Yg = Y + (dir ? 512 : 256) + co;
    const int s = offs[v], e = offs[v + 1];
    int i = s;
    for (; i + 4 <= e; i += 4) {
      int u[4]; float m[4];
#pragma unroll
      for (int t = 0; t < 4; ++t) {
        u[t] = nbr[i + t];
        m[t] = (MODE == 0) ? 1.f : ma[i + t];
      }
      v8s r[4];
#pragma unroll
      for (int t = 0; t < 4; ++t) r[t] = *(const v8s*)(Yg + (size_t)u[t] * 768);
#pragma unroll
      for (int t = 0; t < 4; ++t)
#pragma unroll
        for (int j = 0; j < 8; ++j) acc[j] += m[t] * b2f((ushort)r[t][j]);
    }
    for (; i < e; ++i) {
      int u = nbr[i];
      float m = (MODE == 0) ? 1.f : ma[i];
      v8s r = *(const v8s*)(Yg + (size_t)u * 768);
#pragma unroll
      for (int j = 0; j < 8; ++j) acc[j] += m * b2f((ushort)r[j]);
    }
  }
  if (WR) {
    v8s rw;
#pragma unroll
    for (int j = 0; j < 8; ++j) rw[j] = (short)f2b(acc[j]);
    *(v8s*)(raw + (size_t)v * 256 + co) = rw;
  }
  v8s ys = *(const v8s*)(Y + (size_t)v * 768 + co);
  v8s o;
#pragma unroll
  for (int j = 0; j < 8; ++j) {
    const int col = co + j;
    float val = acc[j] + b2f((ushort)ys[j]) + bsum[col];
    val = fmaxf(val, 0.f);
    val = (val - rmn[col]) * rsqrtf(rvr[col] + EPSc) * gma[col] + bta[col];
    o[j] = (short)f2b(val);
  }
  *(v8s*)(hout + (size_t)node * 256 + co) = o;
}

// ------------------------------------------------------------------ agg + epilogue (fp8 tables, dual-half batched)
__global__ __launch_bounds__(256) void aggepi8_k(
    const unsigned char* __restrict__ Y8, ushort* __restrict__ hout,
    const int* __restrict__ off_in, const int* __restrict__ in_src,
    const int* __restrict__ off_out, const int* __restrict__ out_dst,
    const float* __restrict__ minA, const float* __restrict__ moutA,
    const float* __restrict__ bsum, const float* __restrict__ gma,
    const float* __restrict__ bta, const float* __restrict__ rmn, const float* __restrict__ rvr) {
  const int g = threadIdx.x >> 5;
  const int lane = threadIdx.x & 31;
  const int node = blockIdx.x * 8 + g;
  if (node >= 2 * Nn) return;
  const int half = (node >= Nn) ? 1 : 0;
  const int v = node - half * Nn;
  const int co = lane * 8;
  float acc[8] = {};
#pragma unroll
  for (int dir = 0; dir < 2; ++dir) {
    const int* offs = dir ? off_out : off_in;
    const int* nbr  = dir ? out_dst : in_src;
    const float* ma = dir ? moutA : minA;
    const unsigned char* Yg = Y8 + (size_t)half * Nn * 768 + (dir ? 512 : 256) + co;
    const int s = offs[v], e = offs[v + 1];
    int i = s;
    for (; i + 4 <= e; i += 4) {
      int u[4]; float m[4];
#pragma unroll
      for (int t = 0; t < 4; ++t) {
        u[t] = nbr[i + t];
        float mv = ma[i + t];
        m[t] = half ? (1.f - mv) : mv;
      }
      uint2 r[4];
#pragma unroll
      for (int t = 0; t < 4; ++t) r[t] = *(const uint2*)(Yg + (size_t)u[t] * 768);
#pragma unroll
      for (int t = 0; t < 4; ++t) {
        float f[8];
        fp8x8_dec(r[t].x, r[t].y, f);
#pragma unroll
        for (int j = 0; j < 8; ++j) acc[j] += m[t] * f[j];
      }
    }
    for (; i < e; ++i) {
      int u = nbr[i];
      float mv = ma[i];
      float m = half ? (1.f - mv) : mv;
      uint2 r = *(const uint2*)(Yg + (size_t)u * 768);
      float f[8];
      fp8x8_dec(r.x, r.y, f);
#pragma unroll
      for (int j = 0; j < 8; ++j) acc[j] += m * f[j];
    }
  }
  uint2 rs = *(const uint2*)(Y8 + (size_t)(half * Nn + v) * 768 + co);
  float fs[8];
  fp8x8_dec(rs.x, rs.y, fs);
  v8s o;
#pragma unroll
  for (int j = 0; j < 8; ++j) {
    const int col = co + j;
    float val = acc[j] + fs[j] + bsum[col];
    val = fmaxf(val, 0.f);
    val = (val - rmn[col]) * rsqrtf(rvr[col] + EPSc) * gma[col] + bta[col];
    o[j] = (short)f2b(val);
  }
  *(v8s*)(hout + (size_t)node * 256 + co) = o;
}

// batched L0 comp half: out[N+v] = BN(relu(Yx_s[v] + (Aones - Asub) + bsum0))
__global__ void compl0_k(const ushort* __restrict__ Yx, const ushort* __restrict__ Aones,
                         const ushort* __restrict__ Asub, ushort* __restrict__ hout,
                         const float* __restrict__ bsum, const float* __restrict__ gma,
                         const float* __restrict__ bta, const float* __restrict__ rmn,
                         const float* __restrict__ rvr) {
  int i = blockIdx.x * 256 + threadIdx.x;
  if (i >= Nn * 32) return;
  const int v = i >> 5;
  const int co = (i & 31) * 8;
  v8s ys = *(const v8s*)(Yx + (size_t)v * 768 + co);
  v8s ao = *(const v8s*)(Aones + (size_t)v * 256 + co);
  v8s as = *(const v8s*)(Asub + (size_t)v * 256 + co);
  v8s o;
#pragma unroll
  for (int j = 0; j < 8; ++j) {
    const int col = co + j;
    float val = b2f((ushort)ys[j]) + b2f((ushort)ao[j]) - b2f((ushort)as[j]) + bsum[col];
    val = fmaxf(val, 0.f);
    val = (val - rmn[col]) * rsqrtf(rvr[col] + EPSc) * gma[col] + bta[col];
    o[j] = (short)f2b(val);
  }
  *(v8s*)(hout + (size_t)(Nn + v) * 256 + co) = o;
}

// ------------------------------------------------------------------ proj GEMM (mask MLP layer 1)
template <int EPI>
__global__ __launch_bounds__(256) void mfma_gemm2_k(
    const ushort* __restrict__ A, const ushort* __restrict__ W,
    ushort* __restrict__ Cout, int M, const float* __restrict__ bias) {
  __shared__ ushort eplds[4][32][72];
  const int tid = threadIdx.x;
  const int wid = tid >> 6, lane = tid & 63;
  const int wr = wid & 1, wc = wid >> 1;
  const int m0 = blockIdx.x * 64 + wr * 32;
  const int n0 = blockIdx.y * 128 + wc * 64;
  const int lrow = lane & 15;
  const int klo = (lane >> 4) * 8;
  int rowA[2];
#pragma unroll
  for (int fi = 0; fi < 2; ++fi) {
    int r = m0 + fi * 16 + lrow;
    rowA[fi] = (r < M) ? r : (M - 1);
  }
  v4f acc[2][4] = {};
#pragma unroll
  for (int c = 0; c < 8; ++c) {
    v8s a[2], b[4];
#pragma unroll
    for (int fi = 0; fi < 2; ++fi)
      a[fi] = *(const v8s*)(A + (size_t)rowA[fi] * 256 + c * 32 + klo);
#pragma unroll
    for (int fj = 0; fj < 4; ++fj)
      b[fj] = *(const v8s*)(W + (size_t)(n0 + fj * 16 + lrow) * 256 + c * 32 + klo);
#pragma unroll
    for (int fi = 0; fi < 2; ++fi)
#pragma unroll
      for (int fj = 0; fj < 4; ++fj)
        acc[fi][fj] = __builtin_amdgcn_mfma_f32_16x16x32_bf16(a[fi], b[fj], acc[fi][fj], 0, 0, 0);
  }
#pragma unroll
  for (int fj = 0; fj < 4; ++fj) {
    const int col = n0 + fj * 16 + lrow;
    const float bsv = bias ? bias[col] : 0.f;
#pragma unroll
    for (int fi = 0; fi < 2; ++fi) {
      const int rl0 = fi * 16 + ((lane >> 4) << 2);
#pragma unroll
      for (int r = 0; r < 4; ++r)
        eplds[wid][rl0 + r][fj * 16 + lrow] = f2b(acc[fi][fj][r] + bsv);
    }
  }
#pragma unroll
  for (int i = 0; i < 4; ++i) {
    const int rl = (lane >> 2) + (i & 1) * 16;
    const int oct = (lane & 3) + (i >> 1) * 4;
    v8s val = *(const v8s*)&eplds[wid][rl][oct * 8];
    const int grow = m0 + rl;
    if (grow < M)
      *(v8s*)(Cout + (size_t)grow * 256 + n0 + oct * 8) = val;
  }
}

// ------------------------------------------------------------------ edge MLP over out-CSR order
__global__ __launch_bounds__(256) void edge_mlp4_k(const ushort* __restrict__ P,
                                                   const int* __restrict__ out_srcn,
                                                   const int* __restrict__ out_dst,
                                                   const int* __restrict__ out_eid,
                                                   const ushort* __restrict__ W2b,
                                                   const float* __restrict__ b2, const float* __restrict__ w3,
                                                   const float* __restrict__ b3,
                                                   float* __restrict__ maskOut, float* __restrict__ moutA) {
  const int tid = threadIdx.x;
  const int w = tid >> 6, lane = tid & 63;
  const int e0 = blockIdx.x * 64 + w * 16;
  const int le = lane & 15;
  const int kq = lane >> 4;
  const int klo = kq * 8;
  const int pA = e0 + le;
  const int s_ = out_srcn[pA], d_ = out_dst[pA];
  const ushort* ps = P + (size_t)s_ * 256;
  const ushort* pd = P + (size_t)d_ * 256 + 128;
  v8s as[4], ad[4];
#pragma unroll
  for (int c = 0; c < 4; ++c) {
    as[c] = *(const v8s*)(ps + c * 32 + klo);
    ad[c] = *(const v8s*)(pd + c * 32 + klo);
  }
  v4f acc[4] = {};
#pragma unroll
  for (int c = 0; c < 4; ++c) {
    v8s h;
#pragma unroll
    for (int j = 0; j < 8; ++j) {
      float v = fmaxf(b2f((ushort)as[c][j]) + b2f((ushort)ad[c][j]), 0.f);
      h[j] = (short)f2b(v);
    }
#pragma unroll
    for (int fj = 0; fj < 4; ++fj) {
      v8s b = *(const v8s*)(W2b + (size_t)(fj * 16 + le) * 128 + c * 32 + klo);
      acc[fj] = __builtin_amdgcn_mfma_f32_16x16x32_bf16(h, b, acc[fj], 0, 0, 0);
    }
  }
  float b2v[4], w3v[4];
#pragma unroll
  for (int fj = 0; fj < 4; ++fj) { b2v[fj] = b2[fj * 16 + le]; w3v[fj] = w3[fj * 16 + le]; }
  const float b3v = b3[0];
#pragma unroll
  for (int r = 0; r < 4; ++r) {
    float val = 0.f;
#pragma unroll
    for (int fj = 0; fj < 4; ++fj)
      val += fmaxf(acc[fj][r] + b2v[fj], 0.f) * w3v[fj];
    val += __shfl_xor(val, 1);
    val += __shfl_xor(val, 2);
    val += __shfl_xor(val, 4);
    val += __shfl_xor(val, 8);
    if (le == 0) {
      int pos = e0 + kq * 4 + r;
      float sig = 1.0f / (1.0f + expf(-(val + b3v)));
      moutA[pos] = sig;
      maskOut[out_eid[pos]] = sig;
    }
  }
}

// ------------------------------------------------------------------ pooling / tails
__global__ __launch_bounds__(256) void gemb_sum_k(const ushort* __restrict__ h, const int* __restrict__ batch,
                                                  float* __restrict__ gsum, int batched) {
  const int halfBlocks = Nn / 16;
  int blk = blockIdx.x;
  int half = 0, bi = blk;
  if (batched) { half = (blk >= halfBlocks) ? 1 : 0; bi = blk - half * halfBlocks; }
  const int v0 = bi * 16;
  const int tid = threadIdx.x;
  const size_t base = (size_t)half * Nn;
  float* out = gsum + (size_t)half * (Bb * Dd);
  float acc = 0.0f;
  int curb = batch[v0];
  for (int i = 0; i < 16; ++i) {
    int v = v0 + i;
    int b = batch[v];
    if (b != curb) { atomicAdd(&out[curb * Dd + tid], acc); acc = 0.0f; curb = b; }
    acc += b2f(h[(base + v) * Dd + tid]);
  }
  atomicAdd(&out[curb * Dd + tid], acc);
}

__global__ void gemb_scale_k(float* __restrict__ g, const float* __restrict__ cntf) {
  int blk = blockIdx.x;
  int b = blk & 15;
  g[blk * Dd + threadIdx.x] /= fmaxf(cntf[b], 1.0f);
}

__global__ void anchor_k(const float* __restrict__ g, const float* __restrict__ anchors,
                         float* __restrict__ s_out) {
  __shared__ float red4[4];
  const int b = blockIdx.x, tid = threadIdx.x;
  float gv = g[b * Dd + tid];
  float total = 0.0f;
  for (int k = 0; k < 6; ++k) {
    float d = gv - anchors[k * Dd + tid];
    float v = d * d;
    for (int o = 32; o > 0; o >>= 1) v += __shfl_xor(v, o);
    if ((tid & 63) == 0) red4[tid >> 6] = v;
    __syncthreads();
    if (tid == 0) total += sqrtf(red4[0] + red4[1] + red4[2] + red4[3]);
    __syncthreads();
  }
  if (tid == 0) s_out[b] = total;
}

__global__ void logits_k(const float* __restrict__ gsub, const float* __restrict__ gcomp,
                         const float* __restrict__ Wc, const float* __restrict__ bc,
                         float* __restrict__ outL) {
  __shared__ float red4[4];
  const int blk = blockIdx.x;
  const int set = blk >> 4, b = blk & 15;
  const float* g = set ? gcomp : gsub;
  const int tid = threadIdx.x;
  float gv = g[b * Dd + tid];
  for (int c = 0; c < 2; ++c) {
    float v = gv * Wc[c * Dd + tid];
    for (int o = 32; o > 0; o >>= 1) v += __shfl_xor(v, o);
    if ((tid & 63) == 0) red4[tid >> 6] = v;
    __syncthreads();
    if (tid == 0) outL[set * 32 + b * 2 + c] = red4[0] + red4[1] + red4[2] + red4[3] + bc[c];
    __syncthreads();
  }
}

__global__ void final_k(const float* __restrict__ L, const int* __restrict__ labels,
                        const float* __restrict__ s_orig, const float* __restrict__ s_sub,
                        float* __restrict__ out) {
  if (threadIdx.x == 0) {
    float Lp = 0, Lu = 0, La = 0;
    const float u = 0.5f;
    for (int b = 0; b < 16; ++b) {
      float l0 = L[b * 2], l1 = L[b * 2 + 1];
      float m = fmaxf(l0, l1);
      float lse = m + logf(expf(l0 - m) + expf(l1 - m));
      int lab = labels[b];
      Lp += -((lab ? l1 : l0) - lse);
      float c0 = L[32 + b * 2], c1 = L[32 + b * 2 + 1];
      float mm = fmaxf(c0, c1);
      float e0 = expf(c0 - mm), e1 = expf(c1 - mm), Z = e0 + e1;
      Lu += u * (logf(u) - logf(e0 / Z + 1e-8f)) + u * (logf(u) - logf(e1 / Z + 1e-8f));
      float dd = s_sub[b] - s_orig[b];
      La += dd * dd;
    }
    Lp /= 16.0f; Lu /= 16.0f; La /= 16.0f;
    out[0] = 0.5f * Lp + 0.3f * Lu + 0.2f * La;
    out[1] = Lp; out[2] = Lu; out[3] = La;
  }
}

// ------------------------------------------------------------------ host
extern "C" void kernel_launch(void* const* d_in, const int* in_sizes, int n_in,
                              void* d_out, int out_size, void* d_ws, size_t ws_size,
                              hipStream_t stream) {
  (void)in_sizes; (void)n_in; (void)out_size; (void)ws_size;
  const float* x    = (const float*)d_in[0];
  const int* ei     = (const int*)d_in[1];
  const int* batch  = (const int*)d_in[2];
  const int* labels = (const int*)d_in[3];
  const float* mw1 = (const float*)d_in[4];
  const float* mb1 = (const float*)d_in[5];
  const float* mw2 = (const float*)d_in[6];
  const float* mb2 = (const float*)d_in[7];
  const float* mw3 = (const float*)d_in[8];
  const float* mb3 = (const float*)d_in[9];
  const float* Ws   = (const float*)d_in[10];
  const float* bs   = (const float*)d_in[11];
  const float* Win  = (const float*)d_in[12];
  const float* bin_ = (const float*)d_in[13];
  const float* Wout = (const float*)d_in[14];
  const float* bout = (const float*)d_in[15];
  const float* gma  = (const float*)d_in[16];
  const float* bta  = (const float*)d_in[17];
  const float* rmn  = (const float*)d_in[18];
  const float* rvr  = (const float*)d_in[19];
  const float* anchors = (const float*)d_in[20];
  const float* Wc   = (const float*)d_in[21];
  const float* bc   = (const float*)d_in[22];
  const int* srcp = ei;
  const int* dstp = ei + Ee;

  const size_t NH = (size_t)Nn * Dd;
  const size_t NY = (size_t)Nn * 768;
  ushort* xb   = (ushort*)d_ws;
  ushort* hA   = xb + NH;              // 2NH
  ushort* hB   = hA + 2 * NH;          // 2NH
  ushort* Yx   = hB + 2 * NH;          // NY (persistent L0 projection of x)
  ushort* Ybuf = Yx + NY;              // 2NY region (bf16 Y / fp8 Y8 / Pb alias)
  ushort* Pb   = Ybuf;
  unsigned char* Y8 = (unsigned char*)Ybuf;
  ushort* Aones = Ybuf + 2 * NY;       // NH
  ushort* Asub  = Aones + NH;          // NH
  ushort* Wsb   = Asub + NH;
  ushort* Winb  = Wsb + 3 * 65536;
  ushort* Woutb = Winb + 3 * 65536;
  ushort* Wcombb = Woutb + 3 * 65536;
  ushort* W2b    = Wcombb + 65536;
  float* bcomb = (float*)(W2b + 8192);
  float* minA  = bcomb + 256;
  float* moutA = minA + Ee;
  int* off_in   = (int*)(moutA + Ee);
  int* off_out  = off_in + (Nn + 1);
  int* cur_in   = off_out + (Nn + 1);
  int* cur_out  = cur_in + Nn;
  int* in_src   = cur_out + Nn;
  int* in_eid   = in_src + Ee;
  int* out_dst  = in_eid + Ee;
  int* out_eid  = out_dst + Ee;
  int* out_srcn = out_eid + Ee;
  int* counts_in  = out_srcn + Ee;
  int* counts_out = counts_in + Nn;
  float* cntf      = (float*)(counts_out + Nn);
  float* gemb_orig = cntf + Bb;
  float* gemb_sub  = gemb_orig + Bb * Dd;
  float* gemb_comp = gemb_sub + Bb * Dd;
  float* bsum    = gemb_comp + Bb * Dd;
  float* s_orig  = bsum + 3 * Dd;
  float* s_sub   = s_orig + Bb;
  float* logitsb = s_sub + Bb;

  float* outF = (float*)d_out;
  float* maskp = outF + 4;

  const size_t zero_bytes = (char*)bsum - (char*)counts_in;
  hipMemsetAsync(counts_in, 0, zero_bytes, stream);

  hist_edges_k<<<(Ee + 255) / 256, 256, 0, stream>>>(srcp, dstp, counts_in, counts_out);
  cnt_batch_k<<<1, 64, 0, stream>>>(batch, cntf);
  scan_k<<<1, 1024, 0, stream>>>(counts_in, counts_out, off_in, off_out, cur_in, cur_out);
  scatter_k<<<(Ee + 255) / 256, 256, 0, stream>>>(srcp, dstp, cur_in, cur_out, in_src, in_eid,
                                                  out_dst, out_eid, out_srcn);
  prep_bsum_k<<<1, 256, 0, stream>>>(bs, bin_, bout, bsum);

  c_f2b_k<<<(3 * 65536 + 255) / 256, 256, 0, stream>>>(Ws, Wsb, 3 * 65536);
  c_f2b_k<<<(3 * 65536 + 255) / 256, 256, 0, stream>>>(Win, Winb, 3 * 65536);
  c_f2b_k<<<(3 * 65536 + 255) / 256, 256, 0, stream>>>(Wout, Woutb, 3 * 65536);
  prep_mlp_k<<<256, 256, 0, stream>>>(mw1, mb1, mw2, Wcombb, W2b, bcomb);

  auto run_gemm768 = [&](const ushort* h, ushort* Yout, int M, int l) {
    dim3 gg((M + 127) / 128, 6);
    gemm768t_k<0><<<gg, 256, 0, stream>>>(h, Wsb + (size_t)l * 65536, Winb + (size_t)l * 65536,
                                          Woutb + (size_t)l * 65536, Yout, nullptr, M);
  };
  auto run_gemm768_8 = [&](const ushort* h, int M, int l) {
    dim3 gg((M + 127) / 128, 6);
    gemm768t_k<1><<<gg, 256, 0, stream>>>(h, Wsb + (size_t)l * 65536, Winb + (size_t)l * 65536,
                                          Woutb + (size_t)l * 65536, nullptr, Y8, M);
  };
  auto bn = [&](int l) { return bsum + l * 256; };
  const int aggN = (Nn + 7) / 8;
  const int agg2N = (2 * Nn + 7) / 8;

  // ---- encoder #1 (ones mask), bf16 throughout
  copyxb_k<<<(Nn * Dd / 4 + 255) / 256, 256, 0, stream>>>(x, xb);
  run_gemm768(xb, Yx, Nn, 0);  // persistent: reused by batched L0
  aggepi_k<0, 1><<<aggN, 256, 0, stream>>>(
      Yx, hB, Aones, off_in, in_src, off_out, out_dst, nullptr, nullptr,
      bn(0), gma, bta, rmn, rvr, Nn);
  run_gemm768(hB, Ybuf, Nn, 1);
  aggepi_k<0, 0><<<aggN, 256, 0, stream>>>(
      Ybuf, hA, nullptr, off_in, in_src, off_out, out_dst, nullptr, nullptr,
      bn(1), gma + 256, bta + 256, rmn + 256, rvr + 256, Nn);
  run_gemm768(hA, Ybuf, Nn, 2);
  aggepi_k<0, 0><<<aggN, 256, 0, stream>>>(
      Ybuf, hB, nullptr, off_in, in_src, off_out, out_dst, nullptr, nullptr,
      bn(2), gma + 512, bta + 512, rmn + 512, rvr + 512, Nn);
  // node_emb = hB

  gemb_sum_k<<<Nn / 16, 256, 0, stream>>>(hB, batch, gemb_orig, 0);
  gemb_scale_k<<<Bb, 256, 0, stream>>>(gemb_orig, cntf);
  anchor_k<<<Bb, 256, 0, stream>>>(gemb_orig, anchors, s_orig);

  // ---- packed projection P = [emb@W1a^T + b1 | emb@W1b^T] (Pb aliases Ybuf)
  {
    dim3 gp((Nn + 63) / 64, 2);
    mfma_gemm2_k<3><<<gp, 256, 0, stream>>>(hB, Wcombb, Pb, Nn, bcomb);
  }
  edge_mlp4_k<<<Ee / 64, 256, 0, stream>>>(Pb, out_srcn, out_dst, out_eid,
                                           W2b, mb2, mw3, mb3, maskp, moutA);
  permmask_k<<<(Ee + 255) / 256, 256, 0, stream>>>(maskp, in_eid, minA);

  // ---- batched encoders #2/#3 (mask & 1-mask)
  // L0: Yx reused (bf16); sub = masked agg of Yx; comp = ones - sub
  aggepi_k<1, 1><<<aggN, 256, 0, stream>>>(
      Yx, hA, Asub, off_in, in_src, off_out, out_dst, minA, moutA,
      bn(0), gma, bta, rmn, rvr, Nn);
  compl0_k<<<(Nn * 32 + 255) / 256, 256, 0, stream>>>(Yx, Aones, Asub, hA,
                                                      bn(0), gma, bta, rmn, rvr);
  // L1 (fp8 Y table + dual-half fp8 agg)
  run_gemm768_8(hA, 2 * Nn, 1);
  aggepi8_k<<<agg2N, 256, 0, stream>>>(
      Y8, hB, off_in, in_src, off_out, out_dst, minA, moutA,
      bn(1), gma + 256, bta + 256, rmn + 256, rvr + 256);
  // L2
  run_gemm768_8(hB, 2 * Nn, 2);
  aggepi8_k<<<agg2N, 256, 0, stream>>>(
      Y8, hA, off_in, in_src, off_out, out_dst, minA, moutA,
      bn(2), gma + 512, bta + 512, rmn + 512, rvr + 512);
  // hA = [h_sub; h_comp]

  gemb_sum_k<<<2 * (Nn / 16), 256, 0, stream>>>(hA, batch, gemb_sub, 1);
  gemb_scale_k<<<2 * Bb, 256, 0, stream>>>(gemb_sub, cntf);
  anchor_k<<<Bb, 256, 0, stream>>>(gemb_sub, anchors, s_sub);
  logits_k<<<2 * Bb, 256, 0, stream>>>(gemb_sub, gemb_comp, Wc, bc, logitsb);
  final_k<<<1, 64, 0, stream>>>(logitsb, labels, s_orig, s_sub, outF);
}